// Round 1
// baseline (11252.438 us; speedup 1.0000x reference)
//
#include <hip/hip_runtime.h>
#include <math.h>

// Problem constants (match reference)
constexpr int Bc = 4, Mc = 512, Nc = 1024, Fc = 256;
constexpr int KCc = 16;
constexpr float INFF = 3.0e38f;

__device__ __forceinline__ float blk_sum(float v, float* red) {
  int t = threadIdx.x;
  red[t] = v;
  __syncthreads();
  for (int s = 128; s > 0; s >>= 1) {
    if (t < s) red[t] += red[t + s];
    __syncthreads();
  }
  float r = red[0];
  __syncthreads();
  return r;
}

// ---- spherical coords of points relative to centroid -> out (B,3,P) ----
__global__ __launch_bounds__(256) void scf_kernel(const float* __restrict__ xyz,
                                                  float* __restrict__ out, int P) {
  __shared__ float red[256];
  int b = blockIdx.x;
  const float* x = xyz + (size_t)b * P * 3;
  float sx = 0.f, sy = 0.f, sz = 0.f;
  for (int i = threadIdx.x; i < P; i += 256) {
    sx += x[3 * i]; sy += x[3 * i + 1]; sz += x[3 * i + 2];
  }
  float mx = blk_sum(sx, red) / (float)P;
  float my = blk_sum(sy, red) / (float)P;
  float mz = blk_sum(sz, red) / (float)P;
  for (int i = threadIdx.x; i < P; i += 256) {
    float a = x[3 * i] - mx, c = x[3 * i + 1] - my, d = x[3 * i + 2] - mz;
    float r = sqrtf(a * a + c * c + d * d + 1e-8f);
    float ct = d / r;
    ct = fminf(1.f, fmaxf(-1.f, ct));
    out[((size_t)b * 3 + 0) * P + i] = r;
    out[((size_t)b * 3 + 1) * P + i] = acosf(ct);
    out[((size_t)b * 3 + 2) * P + i] = atan2f(c, a);
  }
}

// ---- per-point sorted distances to KC nearest neighbors (excl. self) ----
template <int P>
__global__ __launch_bounds__(256) void knn_kernel(const float* __restrict__ xyz,
                                                  float* __restrict__ desc) {
  __shared__ float d2s[P];
  __shared__ float rv[256];
  __shared__ int ri[256];
  int b = blockIdx.x / P, i = blockIdx.x % P;
  const float* x = xyz + (size_t)b * P * 3;
  float xi0 = x[3 * i], xi1 = x[3 * i + 1], xi2 = x[3 * i + 2];
  for (int j = threadIdx.x; j < P; j += 256) {
    float dx = x[3 * j] - xi0, dy = x[3 * j + 1] - xi1, dz = x[3 * j + 2] - xi2;
    d2s[j] = dx * dx + dy * dy + dz * dz;
  }
  __syncthreads();
  for (int round = 0; round < KCc + 1; ++round) {
    float bv = INFF; int bi = P;
    for (int j = threadIdx.x; j < P; j += 256) {
      float v = d2s[j];
      if (v < bv || (v == bv && j < bi)) { bv = v; bi = j; }
    }
    rv[threadIdx.x] = bv; ri[threadIdx.x] = bi;
    __syncthreads();
    for (int s = 128; s > 0; s >>= 1) {
      if (threadIdx.x < s) {
        float v2 = rv[threadIdx.x + s]; int i2 = ri[threadIdx.x + s];
        if (v2 < rv[threadIdx.x] || (v2 == rv[threadIdx.x] && i2 < ri[threadIdx.x])) {
          rv[threadIdx.x] = v2; ri[threadIdx.x] = i2;
        }
      }
      __syncthreads();
    }
    if (threadIdx.x == 0) {
      if (round > 0) desc[((size_t)b * P + i) * KCc + (round - 1)] = sqrtf(rv[0]);
      d2s[ri[0]] = INFF;
    }
    __syncthreads();
  }
}

// ---- candidate pruning: top-24 by bc dist -> top-8 by xyz -> top-4 by scf ----
__global__ __launch_bounds__(256) void select_kernel(
    const float* __restrict__ tbc, const float* __restrict__ sbc,
    const float* __restrict__ txyz, const float* __restrict__ sxyz,
    const float* __restrict__ sd, const float* __restrict__ td,
    int* __restrict__ idx_s) {
  __shared__ float dbc[Mc];
  __shared__ float rv[256];
  __shared__ int ri[256];
  __shared__ int cand[24];
  int b = blockIdx.x / Nc, n = blockIdx.x % Nc;
  const float* sb = sbc + ((size_t)b * Nc + n) * 9;
  float sreg[9];
#pragma unroll
  for (int c = 0; c < 9; ++c) sreg[c] = sb[c];
  for (int m = threadIdx.x; m < Mc; m += 256) {
    const float* tb = tbc + ((size_t)b * Mc + m) * 9;
    float acc = 0.f;
#pragma unroll
    for (int c = 0; c < 9; ++c) { float d = tb[c] - sreg[c]; acc += d * d; }
    dbc[m] = acc;
  }
  __syncthreads();
  for (int round = 0; round < 24; ++round) {
    float bv = INFF; int bi = Mc;
    for (int m = threadIdx.x; m < Mc; m += 256) {
      float v = dbc[m];
      if (v < bv || (v == bv && m < bi)) { bv = v; bi = m; }
    }
    rv[threadIdx.x] = bv; ri[threadIdx.x] = bi;
    __syncthreads();
    for (int s = 128; s > 0; s >>= 1) {
      if (threadIdx.x < s) {
        float v2 = rv[threadIdx.x + s]; int i2 = ri[threadIdx.x + s];
        if (v2 < rv[threadIdx.x] || (v2 == rv[threadIdx.x] && i2 < ri[threadIdx.x])) {
          rv[threadIdx.x] = v2; ri[threadIdx.x] = i2;
        }
      }
      __syncthreads();
    }
    if (threadIdx.x == 0) { cand[round] = ri[0]; dbc[ri[0]] = INFF; }
    __syncthreads();
  }
  if (threadIdx.x == 0) {
    const float* sp = sxyz + ((size_t)b * Nc + n) * 3;
    float sx = sp[0], sy = sp[1], sz = sp[2];
    float dv[24];
    for (int t2 = 0; t2 < 24; ++t2) {
      const float* tp = txyz + ((size_t)b * Mc + cand[t2]) * 3;
      float dx = tp[0] - sx, dy = tp[1] - sy, dz = tp[2] - sz;
      dv[t2] = dx * dx + dy * dy + dz * dz;
    }
    int c8[8]; bool used[24];
    for (int t2 = 0; t2 < 24; ++t2) used[t2] = false;
    for (int r = 0; r < 8; ++r) {
      float bv = INFF; int bt = -1, bm = 0x7fffffff;
      for (int t2 = 0; t2 < 24; ++t2) {
        if (used[t2]) continue;
        int m = cand[t2];
        if (bt < 0 || dv[t2] < bv || (dv[t2] == bv && m < bm)) { bv = dv[t2]; bt = t2; bm = m; }
      }
      used[bt] = true; c8[r] = bm;
    }
    const float* sdp = sd + ((size_t)b * Nc + n) * KCc;
    float sdr[16];
    for (int t2 = 0; t2 < 16; ++t2) sdr[t2] = sdp[t2];
    float dscf[8];
    for (int r = 0; r < 8; ++r) {
      const float* tdp = td + ((size_t)b * Mc + c8[r]) * KCc;
      float acc = 0.f;
      for (int t2 = 0; t2 < 16; ++t2) { float d = sdr[t2] - tdp[t2]; acc += d * d; }
      dscf[r] = acc;
    }
    bool u8[8] = {false, false, false, false, false, false, false, false};
    for (int r = 0; r < 4; ++r) {
      float bv = INFF; int bt = -1, bm = 0x7fffffff;
      for (int t2 = 0; t2 < 8; ++t2) {
        if (u8[t2]) continue;
        if (bt < 0 || dscf[t2] < bv || (dscf[t2] == bv && c8[t2] < bm)) { bv = dscf[t2]; bt = t2; bm = c8[t2]; }
      }
      u8[bt] = true;
      idx_s[(((size_t)b * Nc + n) << 2) + r] = bm;
    }
  }
}

// ---- grouping + 3-layer shared MLP -> h (B,N,5,256) ----
__global__ __launch_bounds__(256) void mlp_kernel(
    const float* __restrict__ sfeat, const float* __restrict__ tfeat,
    const float* __restrict__ sscf, const float* __restrict__ tscf,
    const int* __restrict__ idx_s,
    const float* __restrict__ w1, const float* __restrict__ g1, const float* __restrict__ b1,
    const float* __restrict__ w2, const float* __restrict__ g2, const float* __restrict__ b2,
    const float* __restrict__ w3, const float* __restrict__ g3, const float* __restrict__ b3,
    float* __restrict__ hout) {
  __shared__ float xin[5][259];
  __shared__ float hb1[5][256];
  __shared__ float hb2[5][256];
  __shared__ int ms[4];
  int b = blockIdx.x / Nc, n = blockIdx.x % Nc;
  int t = threadIdx.x;
  if (t < 4) ms[t] = idx_s[(((size_t)b * Nc + n) << 2) + t];
  __syncthreads();
  xin[0][t] = sfeat[((size_t)b * Fc + t) * Nc + n];
  if (t < 3) xin[0][256 + t] = sscf[((size_t)b * 3 + t) * Nc + n];
  for (int k = 1; k < 5; ++k) {
    int m = ms[k - 1];
    xin[k][t] = tfeat[((size_t)b * Fc + t) * Mc + m];
    if (t < 3) xin[k][256 + t] = tscf[((size_t)b * 3 + t) * Mc + m];
  }
  __syncthreads();
  {
    const float* wr = w1 + (size_t)t * 259;
    float gg = g1[t], bb = b1[t];
    for (int k = 0; k < 5; ++k) {
      float acc = 0.f;
      for (int c = 0; c < 259; ++c) acc += wr[c] * xin[k][c];
      hb1[k][t] = fmaxf(0.f, gg * acc + bb);
    }
  }
  __syncthreads();
  {
    const float* wr = w2 + (size_t)t * 256;
    float gg = g2[t], bb = b2[t];
    for (int k = 0; k < 5; ++k) {
      float acc = 0.f;
      for (int c = 0; c < 256; ++c) acc += wr[c] * hb1[k][c];
      hb2[k][t] = fmaxf(0.f, gg * acc + bb);
    }
  }
  __syncthreads();
  {
    const float* wr = w3 + (size_t)t * 256;
    float gg = g3[t], bb = b3[t];
    float* dst = hout + ((size_t)b * Nc + n) * 5 * 256;
    for (int k = 0; k < 5; ++k) {
      float acc = 0.f;
      for (int c = 0; c < 256; ++c) acc += wr[c] * hb2[k][c];
      dst[k * 256 + t] = fmaxf(0.f, gg * acc + bb);
    }
  }
}

// ---- point transformer (only i=0 needed) + residual + inorm + fea layer ----
__global__ __launch_bounds__(256) void attn_kernel(
    const float* __restrict__ hbuf, const int* __restrict__ idx_s,
    const float* __restrict__ sxyz, const float* __restrict__ sbc,
    const float* __restrict__ txyz, const float* __restrict__ tbc,
    const float* __restrict__ wqkv,
    const float* __restrict__ pw1, const float* __restrict__ pb1,
    const float* __restrict__ pw2, const float* __restrict__ pb2,
    const float* __restrict__ aw1, const float* __restrict__ ab1,
    const float* __restrict__ aw2, const float* __restrict__ ab2,
    const float* __restrict__ sfeat,
    const float* __restrict__ fw1, const float* __restrict__ fg1, const float* __restrict__ fb1,
    const float* __restrict__ fw2, const float* __restrict__ fb2v,
    float* __restrict__ yout) {
  __shared__ float xs[5][256];
  __shared__ float kb[5][256];
  __shared__ float vb[5][256];
  __shared__ float pe[5][256];
  __shared__ float q0[256];
  __shared__ float t64[320];
  __shared__ float pc[5][12];
  __shared__ float hh[5][1024];
  __shared__ float red[256];
  int b = blockIdx.x / Nc, n = blockIdx.x % Nc;
  int t = threadIdx.x;
  const float* hs = hbuf + ((size_t)b * Nc + n) * 5 * 256;
  for (int k = 0; k < 5; ++k) xs[k][t] = hs[k * 256 + t];
  if (t < 5) {
    int k = t;
    if (k == 0) {
      for (int c = 0; c < 3; ++c) pc[0][c] = sxyz[((size_t)b * Nc + n) * 3 + c];
      for (int c = 0; c < 9; ++c) pc[0][3 + c] = sbc[((size_t)b * Nc + n) * 9 + c];
    } else {
      int m = idx_s[(((size_t)b * Nc + n) << 2) + (k - 1)];
      for (int c = 0; c < 3; ++c) pc[k][c] = txyz[((size_t)b * Mc + m) * 3 + c];
      for (int c = 0; c < 9; ++c) pc[k][3 + c] = tbc[((size_t)b * Mc + m) * 9 + c];
    }
  }
  __syncthreads();
  // qkv (q only for i=0; k,v for all 5)
  {
    const float* wq = wqkv + (size_t)t * 256;
    const float* wk = wqkv + (size_t)(256 + t) * 256;
    const float* wv = wqkv + (size_t)(512 + t) * 256;
    float acc = 0.f;
    for (int c = 0; c < 256; ++c) acc += wq[c] * xs[0][c];
    q0[t] = acc;
    for (int j = 0; j < 5; ++j) {
      float ak = 0.f, av = 0.f;
      for (int c = 0; c < 256; ++c) { float xv = xs[j][c]; ak += wk[c] * xv; av += wv[c] * xv; }
      kb[j][t] = ak; vb[j][t] = av;
    }
  }
  // pe hidden layer (64) for rel_pos(0,j)
  for (int it = t; it < 320; it += 256) {
    int j = it >> 6, h = it & 63;
    float acc = pb1[h];
    const float* w = pw1 + h * 12;
#pragma unroll
    for (int p = 0; p < 12; ++p) acc += w[p] * (pc[0][p] - pc[j][p]);
    t64[it] = fmaxf(acc, 0.f);
  }
  __syncthreads();
  {
    const float* wr = pw2 + (size_t)t * 64;
    for (int j = 0; j < 5; ++j) {
      float acc = pb2[t];
      const float* tj = t64 + j * 64;
      for (int h = 0; h < 64; ++h) acc += wr[h] * tj[h];
      pe[j][t] = acc;
    }
  }
  // sim_in = q0 - k + pe (overwrite kb; own slots only)
  for (int j = 0; j < 5; ++j) kb[j][t] = q0[t] - kb[j][t] + pe[j][t];
  __syncthreads();
  // amlp hidden (1024)
  for (int r = 0; r < 4; ++r) {
    int row = t + 256 * r;
    const float* w = aw1 + (size_t)row * 256;
    float bias = ab1[row];
    for (int j = 0; j < 5; ++j) {
      float acc = bias;
      for (int c = 0; c < 256; ++c) acc += w[c] * kb[j][c];
      hh[j][row] = fmaxf(acc, 0.f);
    }
  }
  __syncthreads();
  float sim[5];
  {
    const float* wr = aw2 + (size_t)t * 1024;
    for (int j = 0; j < 5; ++j) {
      float acc = ab2[t];
      const float* hj = hh[j];
      for (int c = 0; c < 1024; ++c) acc += wr[c] * hj[c];
      sim[j] = acc;
    }
  }
  float mx = sim[0];
  for (int j = 1; j < 5; ++j) mx = fmaxf(mx, sim[j]);
  float ssum = 0.f;
  for (int j = 0; j < 5; ++j) { sim[j] = expf(sim[j] - mx); ssum += sim[j]; }
  float inv = 1.f / ssum;
  float agg = 0.f;
  for (int j = 0; j < 5; ++j) agg += (sim[j] * inv) * (vb[j][t] + pe[j][t]);
  // residual + instance norm over channels
  float ff = agg + sfeat[((size_t)b * Fc + t) * Nc + n];
  float mu = blk_sum(ff, red) * (1.f / 256.f);
  float dfv = ff - mu;
  float var = blk_sum(dfv * dfv, red) * (1.f / 256.f);
  float ffn = dfv / sqrtf(var + 1e-5f);
  q0[t] = ffn;   // reuse q0 as normalized ff
  __syncthreads();
  float a1;
  {
    const float* wr = fw1 + (size_t)t * 256;
    float acc = 0.f;
    for (int c = 0; c < 256; ++c) acc += wr[c] * q0[c];
    a1 = fmaxf(0.f, fg1[t] * acc + fb1[t]);
  }
  __syncthreads();
  t64[t] = a1;   // reuse t64 as fea hidden
  __syncthreads();
  float y2;
  {
    const float* wr = fw2 + (size_t)t * 256;
    float acc = fb2v[t];
    for (int c = 0; c < 256; ++c) acc += wr[c] * t64[c];
    y2 = acc;
  }
  float z = y2 + q0[t];
  float mu2 = blk_sum(z, red) * (1.f / 256.f);
  float dz = z - mu2;
  float var2 = blk_sum(dz * dz, red) * (1.f / 256.f);
  yout[((size_t)b * Nc + n) * 256 + t] = dz / sqrtf(var2 + 1e-5f);
}

// ---- PointSIFT: per-octant nearest neighbor within radius ----
__global__ __launch_bounds__(256) void sift_idx_kernel(const float* __restrict__ sxyz,
                                                       int* __restrict__ sidx) {
  __shared__ float sv[256 * 8];
  __shared__ int si[256 * 8];
  int b = blockIdx.x / Nc, i = blockIdx.x % Nc;
  int t = threadIdx.x;
  const float* x = sxyz + (size_t)b * Nc * 3;
  float xi0 = x[3 * i], xi1 = x[3 * i + 1], xi2 = x[3 * i + 2];
  float bv[8]; int bi[8];
#pragma unroll
  for (int o = 0; o < 8; ++o) { bv[o] = INFF; bi[o] = Nc; }
  for (int j = t; j < Nc; j += 256) {
    float dx = x[3 * j] - xi0, dy = x[3 * j + 1] - xi1, dz = x[3 * j + 2] - xi2;
    float d2 = dx * dx + dy * dy + dz * dz;
    if (d2 <= 0.25f && d2 > 0.f) {
      int oc = (dx > 0.f ? 4 : 0) + (dy > 0.f ? 2 : 0) + (dz > 0.f ? 1 : 0);
      if (d2 < bv[oc] || (d2 == bv[oc] && j < bi[oc])) { bv[oc] = d2; bi[oc] = j; }
    }
  }
#pragma unroll
  for (int o = 0; o < 8; ++o) { sv[t * 8 + o] = bv[o]; si[t * 8 + o] = bi[o]; }
  __syncthreads();
  for (int s = 128; s > 0; s >>= 1) {
    if (t < s) {
#pragma unroll
      for (int o = 0; o < 8; ++o) {
        float v2 = sv[(t + s) * 8 + o]; int i2 = si[(t + s) * 8 + o];
        if (v2 < sv[t * 8 + o] || (v2 == sv[t * 8 + o] && i2 < si[t * 8 + o])) {
          sv[t * 8 + o] = v2; si[t * 8 + o] = i2;
        }
      }
    }
    __syncthreads();
  }
  if (t < 8) {
    int j = (sv[t] < INFF) ? si[t] : i;
    sidx[(((size_t)b * Nc + i) << 3) + t] = j;
  }
}

// ---- SIFT conv stage 1: gather + (1,2)/(1,2) conv -> (B*N,256,4) ----
__global__ __launch_bounds__(256) void sift_conv1_kernel(
    const float* __restrict__ sxyz, const int* __restrict__ sidx,
    const float* __restrict__ yin,
    const float* __restrict__ w1, const float* __restrict__ g1, const float* __restrict__ b1,
    float* __restrict__ gout) {
  __shared__ float xin[8][259];
  __shared__ int js[8];
  int b = blockIdx.x / Nc, i = blockIdx.x % Nc;
  int t = threadIdx.x;
  if (t < 8) js[t] = sidx[(((size_t)b * Nc + i) << 3) + t];
  __syncthreads();
  for (int o = 0; o < 8; ++o) {
    int j = js[o];
    xin[o][3 + t] = yin[((size_t)b * Nc + j) * 256 + t];
    if (t < 3) xin[o][t] = sxyz[((size_t)b * Nc + j) * 3 + t] - sxyz[((size_t)b * Nc + i) * 3 + t];
  }
  __syncthreads();
  const float* wr = w1 + (size_t)t * 518;
  float gg = g1[t], bb = b1[t];
  float* dst = gout + ((size_t)blockIdx.x * 256 + t) * 4;
  for (int p = 0; p < 4; ++p) {
    float acc = 0.f;
    const float* xa = xin[2 * p];
    const float* xb = xin[2 * p + 1];
    for (int c = 0; c < 259; ++c) acc += xa[c] * wr[2 * c] + xb[c] * wr[2 * c + 1];
    dst[p] = fmaxf(0.f, gg * acc + bb);
  }
}

// ---- SIFT conv stages 2+3 fused + residual add into y (B,N,256) ----
__global__ __launch_bounds__(256) void sift_conv23_kernel(
    const float* __restrict__ gin,
    const float* __restrict__ w2, const float* __restrict__ g2, const float* __restrict__ b2,
    const float* __restrict__ w3, const float* __restrict__ g3, const float* __restrict__ b3,
    float* __restrict__ yio) {
  __shared__ float in1[256][4];
  __shared__ float h2[256][2];
  int t = threadIdx.x;
  const float* src = gin + (size_t)blockIdx.x * 1024;
#pragma unroll
  for (int q = 0; q < 4; ++q) in1[t][q] = src[t * 4 + q];
  __syncthreads();
  {
    const float* wr = w2 + (size_t)t * 512;
    float gg = g2[t], bb = b2[t];
    for (int p = 0; p < 2; ++p) {
      float acc = 0.f;
      for (int c = 0; c < 256; ++c) acc += in1[c][2 * p] * wr[2 * c] + in1[c][2 * p + 1] * wr[2 * c + 1];
      h2[t][p] = fmaxf(0.f, gg * acc + bb);
    }
  }
  __syncthreads();
  {
    const float* wr = w3 + (size_t)t * 512;
    float acc = 0.f;
    for (int c = 0; c < 256; ++c) acc += h2[c][0] * wr[2 * c] + h2[c][1] * wr[2 * c + 1];
    float r = fmaxf(0.f, g3[t] * acc + b3[t]);
    yio[(size_t)blockIdx.x * 256 + t] += r;
  }
}

// ---- final transpose (B,N,C) -> (B,C,N) into d_out ----
__global__ __launch_bounds__(256) void transpose_kernel(const float* __restrict__ yin,
                                                        float* __restrict__ out) {
  size_t idx = (size_t)blockIdx.x * 256 + threadIdx.x;
  int n = (int)(idx % Nc);
  size_t r = idx / Nc;
  int c = (int)(r % Fc);
  int b = (int)(r / Fc);
  out[idx] = yin[(((size_t)b * Nc + n) * 256) + c];
}

extern "C" void kernel_launch(void* const* d_in, const int* in_sizes, int n_in,
                              void* d_out, int out_size, void* d_ws, size_t ws_size,
                              hipStream_t stream) {
  (void)in_sizes; (void)n_in; (void)out_size; (void)ws_size;
  const float* tfeat = (const float*)d_in[0];
  const float* sfeat = (const float*)d_in[1];
  const float* txyz  = (const float*)d_in[2];
  const float* sxyz  = (const float*)d_in[3];
  const float* tbc   = (const float*)d_in[4];
  const float* sbc   = (const float*)d_in[5];
  const float* mw1 = (const float*)d_in[6];
  const float* mg1 = (const float*)d_in[7];
  const float* mb1 = (const float*)d_in[8];
  const float* mw2 = (const float*)d_in[9];
  const float* mg2 = (const float*)d_in[10];
  const float* mb2 = (const float*)d_in[11];
  const float* mw3 = (const float*)d_in[12];
  const float* mg3 = (const float*)d_in[13];
  const float* mb3 = (const float*)d_in[14];
  const float* fw1 = (const float*)d_in[15];
  const float* fg1 = (const float*)d_in[16];
  const float* fb1 = (const float*)d_in[17];
  const float* fw2 = (const float*)d_in[18];
  const float* fb2 = (const float*)d_in[19];
  const float* wqkv = (const float*)d_in[20];
  const float* pw1 = (const float*)d_in[21];
  const float* pb1 = (const float*)d_in[22];
  const float* pw2 = (const float*)d_in[23];
  const float* pb2 = (const float*)d_in[24];
  const float* aw1 = (const float*)d_in[25];
  const float* ab1 = (const float*)d_in[26];
  const float* aw2 = (const float*)d_in[27];
  const float* ab2 = (const float*)d_in[28];
  const float* o1w1 = (const float*)d_in[29];
  const float* o1g1 = (const float*)d_in[30];
  const float* o1b1 = (const float*)d_in[31];
  const float* o1w2 = (const float*)d_in[32];
  const float* o1g2 = (const float*)d_in[33];
  const float* o1b2 = (const float*)d_in[34];
  const float* o1w3 = (const float*)d_in[35];
  const float* o1g3 = (const float*)d_in[36];
  const float* o1b3 = (const float*)d_in[37];
  const float* o2w1 = (const float*)d_in[38];
  const float* o2g1 = (const float*)d_in[39];
  const float* o2b1 = (const float*)d_in[40];
  const float* o2w2 = (const float*)d_in[41];
  const float* o2g2 = (const float*)d_in[42];
  const float* o2b2 = (const float*)d_in[43];
  const float* o2w3 = (const float*)d_in[44];
  const float* o2g3 = (const float*)d_in[45];
  const float* o2b3 = (const float*)d_in[46];

  // workspace layout (floats / ints), ~25 MB total, h-buffer reused for g1out
  float* ws = (float*)d_ws;
  float* sd   = ws;                    // B*N*16   = 65536
  float* td   = sd + 65536;            // B*M*16   = 32768
  float* sscf = td + 32768;            // B*3*N    = 12288
  float* tscf = sscf + 12288;          // B*3*M    = 6144
  int*   idxs = (int*)(tscf + 6144);   // B*N*4    = 16384 ints
  int*   sidx = idxs + 16384;          // B*N*8    = 32768 ints
  float* yws  = (float*)(sidx + 32768);// B*N*256  = 1048576
  float* hbuf = yws + 1048576;         // B*N*5*256 = 5242880
  float* g1o  = hbuf;                  // aliased: B*N*256*4 = 4194304 (h consumed first)

  scf_kernel<<<Bc, 256, 0, stream>>>(sxyz, sscf, Nc);
  scf_kernel<<<Bc, 256, 0, stream>>>(txyz, tscf, Mc);
  knn_kernel<Nc><<<Bc * Nc, 256, 0, stream>>>(sxyz, sd);
  knn_kernel<Mc><<<Bc * Mc, 256, 0, stream>>>(txyz, td);
  select_kernel<<<Bc * Nc, 256, 0, stream>>>(tbc, sbc, txyz, sxyz, sd, td, idxs);
  mlp_kernel<<<Bc * Nc, 256, 0, stream>>>(sfeat, tfeat, sscf, tscf, idxs,
                                          mw1, mg1, mb1, mw2, mg2, mb2, mw3, mg3, mb3, hbuf);
  attn_kernel<<<Bc * Nc, 256, 0, stream>>>(hbuf, idxs, sxyz, sbc, txyz, tbc, wqkv,
                                           pw1, pb1, pw2, pb2, aw1, ab1, aw2, ab2,
                                           sfeat, fw1, fg1, fb1, fw2, fb2, yws);
  sift_idx_kernel<<<Bc * Nc, 256, 0, stream>>>(sxyz, sidx);
  // OE module 1
  sift_conv1_kernel<<<Bc * Nc, 256, 0, stream>>>(sxyz, sidx, yws, o1w1, o1g1, o1b1, g1o);
  sift_conv23_kernel<<<Bc * Nc, 256, 0, stream>>>(g1o, o1w2, o1g2, o1b2, o1w3, o1g3, o1b3, yws);
  // OE module 2
  sift_conv1_kernel<<<Bc * Nc, 256, 0, stream>>>(sxyz, sidx, yws, o2w1, o2g1, o2b1, g1o);
  sift_conv23_kernel<<<Bc * Nc, 256, 0, stream>>>(g1o, o2w2, o2g2, o2b2, o2w3, o2g3, o2b3, yws);
  transpose_kernel<<<(Bc * Fc * Nc) / 256, 256, 0, stream>>>(yws, (float*)d_out);
}

// Round 2
// 4493.208 us; speedup vs baseline: 2.5043x; 2.5043x over previous
//
#include <hip/hip_runtime.h>
#include <math.h>

// Problem constants (match reference)
constexpr int Bc = 4, Mc = 512, Nc = 1024, Fc = 256;
constexpr int KCc = 16;
constexpr float INFF = 3.0e38f;

__device__ __forceinline__ float blk_sum(float v, float* red) {
  int t = threadIdx.x;
  red[t] = v;
  __syncthreads();
  for (int s = 128; s > 0; s >>= 1) {
    if (t < s) red[t] += red[t + s];
    __syncthreads();
  }
  float r = red[0];
  __syncthreads();
  return r;
}

__device__ __forceinline__ float dot4(float4 a, float4 b) {
  return a.x * b.x + a.y * b.y + a.z * b.z + a.w * b.w;
}

// ---- spherical coords of points relative to centroid -> out (B,3,P) ----
__global__ __launch_bounds__(256) void scf_kernel(const float* __restrict__ xyz,
                                                  float* __restrict__ out, int P) {
  __shared__ float red[256];
  int b = blockIdx.x;
  const float* x = xyz + (size_t)b * P * 3;
  float sx = 0.f, sy = 0.f, sz = 0.f;
  for (int i = threadIdx.x; i < P; i += 256) {
    sx += x[3 * i]; sy += x[3 * i + 1]; sz += x[3 * i + 2];
  }
  float mx = blk_sum(sx, red) / (float)P;
  float my = blk_sum(sy, red) / (float)P;
  float mz = blk_sum(sz, red) / (float)P;
  for (int i = threadIdx.x; i < P; i += 256) {
    float a = x[3 * i] - mx, c = x[3 * i + 1] - my, d = x[3 * i + 2] - mz;
    float r = sqrtf(a * a + c * c + d * d + 1e-8f);
    float ct = d / r;
    ct = fminf(1.f, fmaxf(-1.f, ct));
    out[((size_t)b * 3 + 0) * P + i] = r;
    out[((size_t)b * 3 + 1) * P + i] = acosf(ct);
    out[((size_t)b * 3 + 2) * P + i] = atan2f(c, a);
  }
}

// ---- per-point sorted distances to KC nearest neighbors (excl. self) ----
template <int P>
__global__ __launch_bounds__(256) void knn_kernel(const float* __restrict__ xyz,
                                                  float* __restrict__ desc) {
  __shared__ float d2s[P];
  __shared__ float rv[256];
  __shared__ int ri[256];
  int b = blockIdx.x / P, i = blockIdx.x % P;
  const float* x = xyz + (size_t)b * P * 3;
  float xi0 = x[3 * i], xi1 = x[3 * i + 1], xi2 = x[3 * i + 2];
  for (int j = threadIdx.x; j < P; j += 256) {
    float dx = x[3 * j] - xi0, dy = x[3 * j + 1] - xi1, dz = x[3 * j + 2] - xi2;
    d2s[j] = dx * dx + dy * dy + dz * dz;
  }
  __syncthreads();
  for (int round = 0; round < KCc + 1; ++round) {
    float bv = INFF; int bi = P;
    for (int j = threadIdx.x; j < P; j += 256) {
      float v = d2s[j];
      if (v < bv || (v == bv && j < bi)) { bv = v; bi = j; }
    }
    rv[threadIdx.x] = bv; ri[threadIdx.x] = bi;
    __syncthreads();
    for (int s = 128; s > 0; s >>= 1) {
      if (threadIdx.x < s) {
        float v2 = rv[threadIdx.x + s]; int i2 = ri[threadIdx.x + s];
        if (v2 < rv[threadIdx.x] || (v2 == rv[threadIdx.x] && i2 < ri[threadIdx.x])) {
          rv[threadIdx.x] = v2; ri[threadIdx.x] = i2;
        }
      }
      __syncthreads();
    }
    if (threadIdx.x == 0) {
      if (round > 0) desc[((size_t)b * P + i) * KCc + (round - 1)] = sqrtf(rv[0]);
      d2s[ri[0]] = INFF;
    }
    __syncthreads();
  }
}

// ---- candidate pruning: top-24 by bc dist -> top-8 by xyz -> top-4 by scf ----
__global__ __launch_bounds__(256) void select_kernel(
    const float* __restrict__ tbc, const float* __restrict__ sbc,
    const float* __restrict__ txyz, const float* __restrict__ sxyz,
    const float* __restrict__ sd, const float* __restrict__ td,
    int* __restrict__ idx_s) {
  __shared__ float dbc[Mc];
  __shared__ float rv[256];
  __shared__ int ri[256];
  __shared__ int cand[24];
  int b = blockIdx.x / Nc, n = blockIdx.x % Nc;
  const float* sb = sbc + ((size_t)b * Nc + n) * 9;
  float sreg[9];
#pragma unroll
  for (int c = 0; c < 9; ++c) sreg[c] = sb[c];
  for (int m = threadIdx.x; m < Mc; m += 256) {
    const float* tb = tbc + ((size_t)b * Mc + m) * 9;
    float acc = 0.f;
#pragma unroll
    for (int c = 0; c < 9; ++c) { float d = tb[c] - sreg[c]; acc += d * d; }
    dbc[m] = acc;
  }
  __syncthreads();
  for (int round = 0; round < 24; ++round) {
    float bv = INFF; int bi = Mc;
    for (int m = threadIdx.x; m < Mc; m += 256) {
      float v = dbc[m];
      if (v < bv || (v == bv && m < bi)) { bv = v; bi = m; }
    }
    rv[threadIdx.x] = bv; ri[threadIdx.x] = bi;
    __syncthreads();
    for (int s = 128; s > 0; s >>= 1) {
      if (threadIdx.x < s) {
        float v2 = rv[threadIdx.x + s]; int i2 = ri[threadIdx.x + s];
        if (v2 < rv[threadIdx.x] || (v2 == rv[threadIdx.x] && i2 < ri[threadIdx.x])) {
          rv[threadIdx.x] = v2; ri[threadIdx.x] = i2;
        }
      }
      __syncthreads();
    }
    if (threadIdx.x == 0) { cand[round] = ri[0]; dbc[ri[0]] = INFF; }
    __syncthreads();
  }
  if (threadIdx.x == 0) {
    const float* sp = sxyz + ((size_t)b * Nc + n) * 3;
    float sx = sp[0], sy = sp[1], sz = sp[2];
    float dv[24];
    for (int t2 = 0; t2 < 24; ++t2) {
      const float* tp = txyz + ((size_t)b * Mc + cand[t2]) * 3;
      float dx = tp[0] - sx, dy = tp[1] - sy, dz = tp[2] - sz;
      dv[t2] = dx * dx + dy * dy + dz * dz;
    }
    int c8[8]; bool used[24];
    for (int t2 = 0; t2 < 24; ++t2) used[t2] = false;
    for (int r = 0; r < 8; ++r) {
      float bv = INFF; int bt = -1, bm = 0x7fffffff;
      for (int t2 = 0; t2 < 24; ++t2) {
        if (used[t2]) continue;
        int m = cand[t2];
        if (bt < 0 || dv[t2] < bv || (dv[t2] == bv && m < bm)) { bv = dv[t2]; bt = t2; bm = m; }
      }
      used[bt] = true; c8[r] = bm;
    }
    const float* sdp = sd + ((size_t)b * Nc + n) * KCc;
    float sdr[16];
    for (int t2 = 0; t2 < 16; ++t2) sdr[t2] = sdp[t2];
    float dscf[8];
    for (int r = 0; r < 8; ++r) {
      const float* tdp = td + ((size_t)b * Mc + c8[r]) * KCc;
      float acc = 0.f;
      for (int t2 = 0; t2 < 16; ++t2) { float d = sdr[t2] - tdp[t2]; acc += d * d; }
      dscf[r] = acc;
    }
    bool u8[8] = {false, false, false, false, false, false, false, false};
    for (int r = 0; r < 4; ++r) {
      float bv = INFF; int bt = -1, bm = 0x7fffffff;
      for (int t2 = 0; t2 < 8; ++t2) {
        if (u8[t2]) continue;
        if (bt < 0 || dscf[t2] < bv || (dscf[t2] == bv && c8[t2] < bm)) { bv = dscf[t2]; bt = t2; bm = c8[t2]; }
      }
      u8[bt] = true;
      idx_s[(((size_t)b * Nc + n) << 2) + r] = bm;
    }
  }
}

// ---- grouping + 3-layer shared MLP -> h (B,N,5,256) ----
__global__ __launch_bounds__(256) void mlp_kernel(
    const float* __restrict__ sfeat, const float* __restrict__ tfeat,
    const float* __restrict__ sscf, const float* __restrict__ tscf,
    const int* __restrict__ idx_s,
    const float* __restrict__ w1, const float* __restrict__ g1, const float* __restrict__ b1,
    const float* __restrict__ w2, const float* __restrict__ g2, const float* __restrict__ b2,
    const float* __restrict__ w3, const float* __restrict__ g3, const float* __restrict__ b3,
    float* __restrict__ hout) {
  __shared__ __align__(16) float xin[5][260];
  __shared__ __align__(16) float hb1[5][256];
  __shared__ __align__(16) float hb2[5][256];
  __shared__ int ms[4];
  int b = blockIdx.x / Nc, n = blockIdx.x % Nc;
  int t = threadIdx.x;
  if (t < 4) ms[t] = idx_s[(((size_t)b * Nc + n) << 2) + t];
  __syncthreads();
  xin[0][t] = sfeat[((size_t)b * Fc + t) * Nc + n];
  if (t < 3) xin[0][256 + t] = sscf[((size_t)b * 3 + t) * Nc + n];
  for (int k = 1; k < 5; ++k) {
    int m = ms[k - 1];
    xin[k][t] = tfeat[((size_t)b * Fc + t) * Mc + m];
    if (t < 3) xin[k][256 + t] = tscf[((size_t)b * 3 + t) * Mc + m];
  }
  __syncthreads();
  {
    const float* wr = w1 + (size_t)t * 259;
    float acc[5] = {0.f, 0.f, 0.f, 0.f, 0.f};
    for (int c = 0; c < 259; ++c) {
      float w = wr[c];
#pragma unroll
      for (int k = 0; k < 5; ++k) acc[k] += w * xin[k][c];
    }
    float gg = g1[t], bb = b1[t];
#pragma unroll
    for (int k = 0; k < 5; ++k) hb1[k][t] = fmaxf(0.f, gg * acc[k] + bb);
  }
  __syncthreads();
  {
    const float4* wr4 = (const float4*)(w2 + (size_t)t * 256);
    float acc[5] = {0.f, 0.f, 0.f, 0.f, 0.f};
    for (int c4 = 0; c4 < 64; ++c4) {
      float4 w = wr4[c4];
#pragma unroll
      for (int k = 0; k < 5; ++k) acc[k] += dot4(w, ((const float4*)hb1[k])[c4]);
    }
    float gg = g2[t], bb = b2[t];
#pragma unroll
    for (int k = 0; k < 5; ++k) hb2[k][t] = fmaxf(0.f, gg * acc[k] + bb);
  }
  __syncthreads();
  {
    const float4* wr4 = (const float4*)(w3 + (size_t)t * 256);
    float acc[5] = {0.f, 0.f, 0.f, 0.f, 0.f};
    for (int c4 = 0; c4 < 64; ++c4) {
      float4 w = wr4[c4];
#pragma unroll
      for (int k = 0; k < 5; ++k) acc[k] += dot4(w, ((const float4*)hb2[k])[c4]);
    }
    float gg = g3[t], bb = b3[t];
    float* dst = hout + ((size_t)b * Nc + n) * 5 * 256;
#pragma unroll
    for (int k = 0; k < 5; ++k) dst[k * 256 + t] = fmaxf(0.f, gg * acc[k] + bb);
  }
}

// ---- point transformer (only i=0 needed) + residual + inorm + fea layer ----
__global__ __launch_bounds__(256) void attn_kernel(
    const float* __restrict__ hbuf, const int* __restrict__ idx_s,
    const float* __restrict__ sxyz, const float* __restrict__ sbc,
    const float* __restrict__ txyz, const float* __restrict__ tbc,
    const float* __restrict__ wqkv,
    const float* __restrict__ pw1, const float* __restrict__ pb1,
    const float* __restrict__ pw2, const float* __restrict__ pb2,
    const float* __restrict__ aw1, const float* __restrict__ ab1,
    const float* __restrict__ aw2, const float* __restrict__ ab2,
    const float* __restrict__ sfeat,
    const float* __restrict__ fw1, const float* __restrict__ fg1, const float* __restrict__ fb1,
    const float* __restrict__ fw2, const float* __restrict__ fb2v,
    float* __restrict__ yout) {
  __shared__ __align__(16) float xs[5][256];   // later reused as hch
  __shared__ __align__(16) float kb[5][256];   // later sim_in
  __shared__ __align__(16) float vb[5][256];   // later v+pe
  __shared__ __align__(16) float q0[256];
  __shared__ __align__(16) float t64[320];
  __shared__ float pc[5][12];
  __shared__ float red[256];
  int b = blockIdx.x / Nc, n = blockIdx.x % Nc;
  int t = threadIdx.x;
  const float* hs = hbuf + ((size_t)b * Nc + n) * 5 * 256;
  for (int k = 0; k < 5; ++k) xs[k][t] = hs[k * 256 + t];
  if (t < 5) {
    int k = t;
    if (k == 0) {
      for (int c = 0; c < 3; ++c) pc[0][c] = sxyz[((size_t)b * Nc + n) * 3 + c];
      for (int c = 0; c < 9; ++c) pc[0][3 + c] = sbc[((size_t)b * Nc + n) * 9 + c];
    } else {
      int m = idx_s[(((size_t)b * Nc + n) << 2) + (k - 1)];
      for (int c = 0; c < 3; ++c) pc[k][c] = txyz[((size_t)b * Mc + m) * 3 + c];
      for (int c = 0; c < 9; ++c) pc[k][3 + c] = tbc[((size_t)b * Mc + m) * 9 + c];
    }
  }
  __syncthreads();
  // qkv: q only for token 0; k,v for all 5. One pass over weights, 5-way reuse.
  {
    const float4* wq4 = (const float4*)(wqkv + (size_t)t * 256);
    const float4* wk4 = (const float4*)(wqkv + (size_t)(256 + t) * 256);
    const float4* wv4 = (const float4*)(wqkv + (size_t)(512 + t) * 256);
    float accq = 0.f, ak[5] = {0.f, 0.f, 0.f, 0.f, 0.f}, av[5] = {0.f, 0.f, 0.f, 0.f, 0.f};
    for (int c4 = 0; c4 < 64; ++c4) {
      float4 wk = wk4[c4], wv = wv4[c4];
      float4 x0 = ((const float4*)xs[0])[c4];
      accq += dot4(wq4[c4], x0);
      ak[0] += dot4(wk, x0); av[0] += dot4(wv, x0);
#pragma unroll
      for (int j = 1; j < 5; ++j) {
        float4 x = ((const float4*)xs[j])[c4];
        ak[j] += dot4(wk, x); av[j] += dot4(wv, x);
      }
    }
    q0[t] = accq;
#pragma unroll
    for (int j = 0; j < 5; ++j) { kb[j][t] = ak[j]; vb[j][t] = av[j]; }
  }
  // pe hidden layer (5 x 64) for rel_pos(0,j)
  for (int it = t; it < 320; it += 256) {
    int j = it >> 6, h = it & 63;
    float acc = pb1[h];
    const float* w = pw1 + h * 12;
#pragma unroll
    for (int p = 0; p < 12; ++p) acc += w[p] * (pc[0][p] - pc[j][p]);
    t64[it] = fmaxf(acc, 0.f);
  }
  __syncthreads();
  // pe output, folded: kb <- q0 - k + pe (sim_in), vb <- v + pe
  {
    const float4* pw24 = (const float4*)(pw2 + (size_t)t * 64);
    float pb2t = pb2[t];
    float qv = q0[t];
#pragma unroll
    for (int j = 0; j < 5; ++j) {
      float acc = pb2t;
      const float4* tj4 = (const float4*)(t64 + j * 64);
      for (int h4 = 0; h4 < 16; ++h4) acc += dot4(pw24[h4], tj4[h4]);
      kb[j][t] = qv - kb[j][t] + acc;
      vb[j][t] = vb[j][t] + acc;
    }
  }
  __syncthreads();
  // amlp: 4 chunks of 256 hidden rows; thread t owns row ch*256+t for ALL 5 j.
  float (*hch)[256] = xs;  // reuse xs storage
  float sim[5];
#pragma unroll
  for (int j = 0; j < 5; ++j) sim[j] = ab2[t];
  const float* aw2row = aw2 + (size_t)t * 1024;
  for (int ch = 0; ch < 4; ++ch) {
    int r = ch * 256 + t;
    const float4* w4 = (const float4*)(aw1 + (size_t)r * 256);
    float acc[5];
    float bias = ab1[r];
#pragma unroll
    for (int j = 0; j < 5; ++j) acc[j] = bias;
    for (int c4 = 0; c4 < 64; ++c4) {
      float4 w = w4[c4];
#pragma unroll
      for (int j = 0; j < 5; ++j) acc[j] += dot4(w, ((const float4*)kb[j])[c4]);
    }
#pragma unroll
    for (int j = 0; j < 5; ++j) hch[j][t] = fmaxf(acc[j], 0.f);
    __syncthreads();
    const float4* a24 = (const float4*)(aw2row + ch * 256);
    for (int rr4 = 0; rr4 < 64; ++rr4) {
      float4 w = a24[rr4];
#pragma unroll
      for (int j = 0; j < 5; ++j) sim[j] += dot4(w, ((const float4*)hch[j])[rr4]);
    }
    __syncthreads();
  }
  // softmax over j (per output dim d = t) + aggregate with v+pe
  float mx = sim[0];
#pragma unroll
  for (int j = 1; j < 5; ++j) mx = fmaxf(mx, sim[j]);
  float ssum = 0.f;
#pragma unroll
  for (int j = 0; j < 5; ++j) { sim[j] = expf(sim[j] - mx); ssum += sim[j]; }
  float inv = 1.f / ssum;
  float agg = 0.f;
#pragma unroll
  for (int j = 0; j < 5; ++j) agg += (sim[j] * inv) * vb[j][t];
  // residual + instance norm over channels
  float ff = agg + sfeat[((size_t)b * Fc + t) * Nc + n];
  float mu = blk_sum(ff, red) * (1.f / 256.f);
  float dfv = ff - mu;
  float var = blk_sum(dfv * dfv, red) * (1.f / 256.f);
  float ffn = dfv / sqrtf(var + 1e-5f);
  q0[t] = ffn;  // reuse q0 as normalized ff
  __syncthreads();
  float a1;
  {
    const float4* wr4 = (const float4*)(fw1 + (size_t)t * 256);
    float acc = 0.f;
    for (int c4 = 0; c4 < 64; ++c4) acc += dot4(wr4[c4], ((const float4*)q0)[c4]);
    a1 = fmaxf(0.f, fg1[t] * acc + fb1[t]);
  }
  __syncthreads();
  t64[t] = a1;  // reuse t64 as fea hidden
  __syncthreads();
  float y2;
  {
    const float4* wr4 = (const float4*)(fw2 + (size_t)t * 256);
    float acc = fb2v[t];
    for (int c4 = 0; c4 < 64; ++c4) acc += dot4(wr4[c4], ((const float4*)t64)[c4]);
    y2 = acc;
  }
  float z = y2 + q0[t];
  float mu2 = blk_sum(z, red) * (1.f / 256.f);
  float dz = z - mu2;
  float var2 = blk_sum(dz * dz, red) * (1.f / 256.f);
  yout[((size_t)b * Nc + n) * 256 + t] = dz / sqrtf(var2 + 1e-5f);
}

// ---- PointSIFT: per-octant nearest neighbor within radius ----
__global__ __launch_bounds__(256) void sift_idx_kernel(const float* __restrict__ sxyz,
                                                       int* __restrict__ sidx) {
  __shared__ float sv[256 * 8];
  __shared__ int si[256 * 8];
  int b = blockIdx.x / Nc, i = blockIdx.x % Nc;
  int t = threadIdx.x;
  const float* x = sxyz + (size_t)b * Nc * 3;
  float xi0 = x[3 * i], xi1 = x[3 * i + 1], xi2 = x[3 * i + 2];
  float bv[8]; int bi[8];
#pragma unroll
  for (int o = 0; o < 8; ++o) { bv[o] = INFF; bi[o] = Nc; }
  for (int j = t; j < Nc; j += 256) {
    float dx = x[3 * j] - xi0, dy = x[3 * j + 1] - xi1, dz = x[3 * j + 2] - xi2;
    float d2 = dx * dx + dy * dy + dz * dz;
    if (d2 <= 0.25f && d2 > 0.f) {
      int oc = (dx > 0.f ? 4 : 0) + (dy > 0.f ? 2 : 0) + (dz > 0.f ? 1 : 0);
      if (d2 < bv[oc] || (d2 == bv[oc] && j < bi[oc])) { bv[oc] = d2; bi[oc] = j; }
    }
  }
#pragma unroll
  for (int o = 0; o < 8; ++o) { sv[t * 8 + o] = bv[o]; si[t * 8 + o] = bi[o]; }
  __syncthreads();
  for (int s = 128; s > 0; s >>= 1) {
    if (t < s) {
#pragma unroll
      for (int o = 0; o < 8; ++o) {
        float v2 = sv[(t + s) * 8 + o]; int i2 = si[(t + s) * 8 + o];
        if (v2 < sv[t * 8 + o] || (v2 == sv[t * 8 + o] && i2 < si[t * 8 + o])) {
          sv[t * 8 + o] = v2; si[t * 8 + o] = i2;
        }
      }
    }
    __syncthreads();
  }
  if (t < 8) {
    int j = (sv[t] < INFF) ? si[t] : i;
    sidx[(((size_t)b * Nc + i) << 3) + t] = j;
  }
}

// ---- SIFT conv stage 1: gather + (1,2)/(1,2) conv -> (B*N,256,4) ----
__global__ __launch_bounds__(256) void sift_conv1_kernel(
    const float* __restrict__ sxyz, const int* __restrict__ sidx,
    const float* __restrict__ yin,
    const float* __restrict__ w1, const float* __restrict__ g1, const float* __restrict__ b1,
    float* __restrict__ gout) {
  __shared__ float xin[8][259];
  __shared__ int js[8];
  int b = blockIdx.x / Nc, i = blockIdx.x % Nc;
  int t = threadIdx.x;
  if (t < 8) js[t] = sidx[(((size_t)b * Nc + i) << 3) + t];
  __syncthreads();
  for (int o = 0; o < 8; ++o) {
    int j = js[o];
    xin[o][3 + t] = yin[((size_t)b * Nc + j) * 256 + t];
    if (t < 3) xin[o][t] = sxyz[((size_t)b * Nc + j) * 3 + t] - sxyz[((size_t)b * Nc + i) * 3 + t];
  }
  __syncthreads();
  const float* wr = w1 + (size_t)t * 518;
  float acc[4] = {0.f, 0.f, 0.f, 0.f};
  for (int c = 0; c < 259; ++c) {
    float wa = wr[2 * c], wb = wr[2 * c + 1];
#pragma unroll
    for (int p = 0; p < 4; ++p)
      acc[p] += xin[2 * p][c] * wa + xin[2 * p + 1][c] * wb;
  }
  float gg = g1[t], bb = b1[t];
  float* dst = gout + ((size_t)blockIdx.x * 256 + t) * 4;
#pragma unroll
  for (int p = 0; p < 4; ++p) dst[p] = fmaxf(0.f, gg * acc[p] + bb);
}

// ---- SIFT conv stages 2+3 fused + residual add into y (B,N,256) ----
__global__ __launch_bounds__(256) void sift_conv23_kernel(
    const float* __restrict__ gin,
    const float* __restrict__ w2, const float* __restrict__ g2, const float* __restrict__ b2,
    const float* __restrict__ w3, const float* __restrict__ g3, const float* __restrict__ b3,
    float* __restrict__ yio) {
  __shared__ __align__(16) float in1[256][4];
  __shared__ __align__(16) float h2[512];
  int t = threadIdx.x;
  const float* src = gin + (size_t)blockIdx.x * 1024;
#pragma unroll
  for (int q = 0; q < 4; ++q) in1[t][q] = src[t * 4 + q];
  __syncthreads();
  {
    const float4* wr4 = (const float4*)(w2 + (size_t)t * 512);
    float gg = g2[t], bb = b2[t];
    float acc0 = 0.f, acc1 = 0.f;
    for (int c2 = 0; c2 < 128; ++c2) {
      float4 w = wr4[c2];
      float4 i0 = ((const float4*)in1)[2 * c2];
      float4 i1 = ((const float4*)in1)[2 * c2 + 1];
      acc0 += i0.x * w.x + i0.y * w.y + i1.x * w.z + i1.y * w.w;
      acc1 += i0.z * w.x + i0.w * w.y + i1.z * w.z + i1.w * w.w;
    }
    h2[2 * t] = fmaxf(0.f, gg * acc0 + bb);
    h2[2 * t + 1] = fmaxf(0.f, gg * acc1 + bb);
  }
  __syncthreads();
  {
    const float4* wr4 = (const float4*)(w3 + (size_t)t * 512);
    float acc = 0.f;
    for (int c2 = 0; c2 < 128; ++c2) acc += dot4(wr4[c2], ((const float4*)h2)[c2]);
    float r = fmaxf(0.f, g3[t] * acc + b3[t]);
    yio[(size_t)blockIdx.x * 256 + t] += r;
  }
}

// ---- final transpose (B,N,C) -> (B,C,N) into d_out ----
__global__ __launch_bounds__(256) void transpose_kernel(const float* __restrict__ yin,
                                                        float* __restrict__ out) {
  size_t idx = (size_t)blockIdx.x * 256 + threadIdx.x;
  int n = (int)(idx % Nc);
  size_t r = idx / Nc;
  int c = (int)(r % Fc);
  int b = (int)(r / Fc);
  out[idx] = yin[(((size_t)b * Nc + n) * 256) + c];
}

extern "C" void kernel_launch(void* const* d_in, const int* in_sizes, int n_in,
                              void* d_out, int out_size, void* d_ws, size_t ws_size,
                              hipStream_t stream) {
  (void)in_sizes; (void)n_in; (void)out_size; (void)ws_size;
  const float* tfeat = (const float*)d_in[0];
  const float* sfeat = (const float*)d_in[1];
  const float* txyz  = (const float*)d_in[2];
  const float* sxyz  = (const float*)d_in[3];
  const float* tbc   = (const float*)d_in[4];
  const float* sbc   = (const float*)d_in[5];
  const float* mw1 = (const float*)d_in[6];
  const float* mg1 = (const float*)d_in[7];
  const float* mb1 = (const float*)d_in[8];
  const float* mw2 = (const float*)d_in[9];
  const float* mg2 = (const float*)d_in[10];
  const float* mb2 = (const float*)d_in[11];
  const float* mw3 = (const float*)d_in[12];
  const float* mg3 = (const float*)d_in[13];
  const float* mb3 = (const float*)d_in[14];
  const float* fw1 = (const float*)d_in[15];
  const float* fg1 = (const float*)d_in[16];
  const float* fb1 = (const float*)d_in[17];
  const float* fw2 = (const float*)d_in[18];
  const float* fb2 = (const float*)d_in[19];
  const float* wqkv = (const float*)d_in[20];
  const float* pw1 = (const float*)d_in[21];
  const float* pb1 = (const float*)d_in[22];
  const float* pw2 = (const float*)d_in[23];
  const float* pb2 = (const float*)d_in[24];
  const float* aw1 = (const float*)d_in[25];
  const float* ab1 = (const float*)d_in[26];
  const float* aw2 = (const float*)d_in[27];
  const float* ab2 = (const float*)d_in[28];
  const float* o1w1 = (const float*)d_in[29];
  const float* o1g1 = (const float*)d_in[30];
  const float* o1b1 = (const float*)d_in[31];
  const float* o1w2 = (const float*)d_in[32];
  const float* o1g2 = (const float*)d_in[33];
  const float* o1b2 = (const float*)d_in[34];
  const float* o1w3 = (const float*)d_in[35];
  const float* o1g3 = (const float*)d_in[36];
  const float* o1b3 = (const float*)d_in[37];
  const float* o2w1 = (const float*)d_in[38];
  const float* o2g1 = (const float*)d_in[39];
  const float* o2b1 = (const float*)d_in[40];
  const float* o2w2 = (const float*)d_in[41];
  const float* o2g2 = (const float*)d_in[42];
  const float* o2b2 = (const float*)d_in[43];
  const float* o2w3 = (const float*)d_in[44];
  const float* o2g3 = (const float*)d_in[45];
  const float* o2b3 = (const float*)d_in[46];

  // workspace layout (floats / ints), ~25 MB total, h-buffer reused for g1out
  float* ws = (float*)d_ws;
  float* sd   = ws;                    // B*N*16   = 65536
  float* td   = sd + 65536;            // B*M*16   = 32768
  float* sscf = td + 32768;            // B*3*N    = 12288
  float* tscf = sscf + 12288;          // B*3*M    = 6144
  int*   idxs = (int*)(tscf + 6144);   // B*N*4    = 16384 ints
  int*   sidx = idxs + 16384;          // B*N*8    = 32768 ints
  float* yws  = (float*)(sidx + 32768);// B*N*256  = 1048576
  float* hbuf = yws + 1048576;         // B*N*5*256 = 5242880
  float* g1o  = hbuf;                  // aliased: B*N*256*4 = 4194304 (h consumed first)

  scf_kernel<<<Bc, 256, 0, stream>>>(sxyz, sscf, Nc);
  scf_kernel<<<Bc, 256, 0, stream>>>(txyz, tscf, Mc);
  knn_kernel<Nc><<<Bc * Nc, 256, 0, stream>>>(sxyz, sd);
  knn_kernel<Mc><<<Bc * Mc, 256, 0, stream>>>(txyz, td);
  select_kernel<<<Bc * Nc, 256, 0, stream>>>(tbc, sbc, txyz, sxyz, sd, td, idxs);
  mlp_kernel<<<Bc * Nc, 256, 0, stream>>>(sfeat, tfeat, sscf, tscf, idxs,
                                          mw1, mg1, mb1, mw2, mg2, mb2, mw3, mg3, mb3, hbuf);
  attn_kernel<<<Bc * Nc, 256, 0, stream>>>(hbuf, idxs, sxyz, sbc, txyz, tbc, wqkv,
                                           pw1, pb1, pw2, pb2, aw1, ab1, aw2, ab2,
                                           sfeat, fw1, fg1, fb1, fw2, fb2, yws);
  sift_idx_kernel<<<Bc * Nc, 256, 0, stream>>>(sxyz, sidx);
  // OE module 1
  sift_conv1_kernel<<<Bc * Nc, 256, 0, stream>>>(sxyz, sidx, yws, o1w1, o1g1, o1b1, g1o);
  sift_conv23_kernel<<<Bc * Nc, 256, 0, stream>>>(g1o, o1w2, o1g2, o1b2, o1w3, o1g3, o1b3, yws);
  // OE module 2
  sift_conv1_kernel<<<Bc * Nc, 256, 0, stream>>>(sxyz, sidx, yws, o2w1, o2g1, o2b1, g1o);
  sift_conv23_kernel<<<Bc * Nc, 256, 0, stream>>>(g1o, o2w2, o2g2, o2b2, o2w3, o2g3, o2b3, yws);
  transpose_kernel<<<(Bc * Fc * Nc) / 256, 256, 0, stream>>>(yws, (float*)d_out);
}

// Round 3
// 2692.747 us; speedup vs baseline: 4.1788x; 1.6686x over previous
//
#include <hip/hip_runtime.h>
#include <math.h>

// Problem constants (match reference)
constexpr int Bc = 4, Mc = 512, Nc = 1024, Fc = 256;
constexpr int KCc = 16;
constexpr float INFF = 3.0e38f;

__device__ __forceinline__ float blk_sum(float v, float* red) {
  int t = threadIdx.x;
  red[t] = v;
  __syncthreads();
  for (int s = 128; s > 0; s >>= 1) {
    if (t < s) red[t] += red[t + s];
    __syncthreads();
  }
  float r = red[0];
  __syncthreads();
  return r;
}

__device__ __forceinline__ float dot4(float4 a, float4 b) {
  return a.x * b.x + a.y * b.y + a.z * b.z + a.w * b.w;
}

// ---- spherical coords of points relative to centroid -> out (B,3,P) ----
__global__ __launch_bounds__(256) void scf_kernel(const float* __restrict__ xyz,
                                                  float* __restrict__ out, int P) {
  __shared__ float red[256];
  int b = blockIdx.x;
  const float* x = xyz + (size_t)b * P * 3;
  float sx = 0.f, sy = 0.f, sz = 0.f;
  for (int i = threadIdx.x; i < P; i += 256) {
    sx += x[3 * i]; sy += x[3 * i + 1]; sz += x[3 * i + 2];
  }
  float mx = blk_sum(sx, red) / (float)P;
  float my = blk_sum(sy, red) / (float)P;
  float mz = blk_sum(sz, red) / (float)P;
  for (int i = threadIdx.x; i < P; i += 256) {
    float a = x[3 * i] - mx, c = x[3 * i + 1] - my, d = x[3 * i + 2] - mz;
    float r = sqrtf(a * a + c * c + d * d + 1e-8f);
    float ct = d / r;
    ct = fminf(1.f, fmaxf(-1.f, ct));
    out[((size_t)b * 3 + 0) * P + i] = r;
    out[((size_t)b * 3 + 1) * P + i] = acosf(ct);
    out[((size_t)b * 3 + 2) * P + i] = atan2f(c, a);
  }
}

// ---- per-point sorted distances to KC nearest neighbors (excl. self) ----
template <int P>
__global__ __launch_bounds__(256) void knn_kernel(const float* __restrict__ xyz,
                                                  float* __restrict__ desc) {
  __shared__ float d2s[P];
  __shared__ float rv[256];
  __shared__ int ri[256];
  int b = blockIdx.x / P, i = blockIdx.x % P;
  const float* x = xyz + (size_t)b * P * 3;
  float xi0 = x[3 * i], xi1 = x[3 * i + 1], xi2 = x[3 * i + 2];
  for (int j = threadIdx.x; j < P; j += 256) {
    float dx = x[3 * j] - xi0, dy = x[3 * j + 1] - xi1, dz = x[3 * j + 2] - xi2;
    d2s[j] = dx * dx + dy * dy + dz * dz;
  }
  __syncthreads();
  for (int round = 0; round < KCc + 1; ++round) {
    float bv = INFF; int bi = P;
    for (int j = threadIdx.x; j < P; j += 256) {
      float v = d2s[j];
      if (v < bv || (v == bv && j < bi)) { bv = v; bi = j; }
    }
    rv[threadIdx.x] = bv; ri[threadIdx.x] = bi;
    __syncthreads();
    for (int s = 128; s > 0; s >>= 1) {
      if (threadIdx.x < s) {
        float v2 = rv[threadIdx.x + s]; int i2 = ri[threadIdx.x + s];
        if (v2 < rv[threadIdx.x] || (v2 == rv[threadIdx.x] && i2 < ri[threadIdx.x])) {
          rv[threadIdx.x] = v2; ri[threadIdx.x] = i2;
        }
      }
      __syncthreads();
    }
    if (threadIdx.x == 0) {
      if (round > 0) desc[((size_t)b * P + i) * KCc + (round - 1)] = sqrtf(rv[0]);
      d2s[ri[0]] = INFF;
    }
    __syncthreads();
  }
}

// ---- candidate pruning: top-24 by bc dist -> top-8 by xyz -> top-4 by scf ----
__global__ __launch_bounds__(256) void select_kernel(
    const float* __restrict__ tbc, const float* __restrict__ sbc,
    const float* __restrict__ txyz, const float* __restrict__ sxyz,
    const float* __restrict__ sd, const float* __restrict__ td,
    int* __restrict__ idx_s) {
  __shared__ float dbc[Mc];
  __shared__ float rv[256];
  __shared__ int ri[256];
  __shared__ int cand[24];
  int b = blockIdx.x / Nc, n = blockIdx.x % Nc;
  const float* sb = sbc + ((size_t)b * Nc + n) * 9;
  float sreg[9];
#pragma unroll
  for (int c = 0; c < 9; ++c) sreg[c] = sb[c];
  for (int m = threadIdx.x; m < Mc; m += 256) {
    const float* tb = tbc + ((size_t)b * Mc + m) * 9;
    float acc = 0.f;
#pragma unroll
    for (int c = 0; c < 9; ++c) { float d = tb[c] - sreg[c]; acc += d * d; }
    dbc[m] = acc;
  }
  __syncthreads();
  for (int round = 0; round < 24; ++round) {
    float bv = INFF; int bi = Mc;
    for (int m = threadIdx.x; m < Mc; m += 256) {
      float v = dbc[m];
      if (v < bv || (v == bv && m < bi)) { bv = v; bi = m; }
    }
    rv[threadIdx.x] = bv; ri[threadIdx.x] = bi;
    __syncthreads();
    for (int s = 128; s > 0; s >>= 1) {
      if (threadIdx.x < s) {
        float v2 = rv[threadIdx.x + s]; int i2 = ri[threadIdx.x + s];
        if (v2 < rv[threadIdx.x] || (v2 == rv[threadIdx.x] && i2 < ri[threadIdx.x])) {
          rv[threadIdx.x] = v2; ri[threadIdx.x] = i2;
        }
      }
      __syncthreads();
    }
    if (threadIdx.x == 0) { cand[round] = ri[0]; dbc[ri[0]] = INFF; }
    __syncthreads();
  }
  if (threadIdx.x == 0) {
    const float* sp = sxyz + ((size_t)b * Nc + n) * 3;
    float sx = sp[0], sy = sp[1], sz = sp[2];
    float dv[24];
    for (int t2 = 0; t2 < 24; ++t2) {
      const float* tp = txyz + ((size_t)b * Mc + cand[t2]) * 3;
      float dx = tp[0] - sx, dy = tp[1] - sy, dz = tp[2] - sz;
      dv[t2] = dx * dx + dy * dy + dz * dz;
    }
    int c8[8]; bool used[24];
    for (int t2 = 0; t2 < 24; ++t2) used[t2] = false;
    for (int r = 0; r < 8; ++r) {
      float bv = INFF; int bt = -1, bm = 0x7fffffff;
      for (int t2 = 0; t2 < 24; ++t2) {
        if (used[t2]) continue;
        int m = cand[t2];
        if (bt < 0 || dv[t2] < bv || (dv[t2] == bv && m < bm)) { bv = dv[t2]; bt = t2; bm = m; }
      }
      used[bt] = true; c8[r] = bm;
    }
    const float* sdp = sd + ((size_t)b * Nc + n) * KCc;
    float sdr[16];
    for (int t2 = 0; t2 < 16; ++t2) sdr[t2] = sdp[t2];
    float dscf[8];
    for (int r = 0; r < 8; ++r) {
      const float* tdp = td + ((size_t)b * Mc + c8[r]) * KCc;
      float acc = 0.f;
      for (int t2 = 0; t2 < 16; ++t2) { float d = sdr[t2] - tdp[t2]; acc += d * d; }
      dscf[r] = acc;
    }
    bool u8[8] = {false, false, false, false, false, false, false, false};
    for (int r = 0; r < 4; ++r) {
      float bv = INFF; int bt = -1, bm = 0x7fffffff;
      for (int t2 = 0; t2 < 8; ++t2) {
        if (u8[t2]) continue;
        if (bt < 0 || dscf[t2] < bv || (dscf[t2] == bv && c8[t2] < bm)) { bv = dscf[t2]; bt = t2; bm = c8[t2]; }
      }
      u8[bt] = true;
      idx_s[(((size_t)b * Nc + n) << 2) + r] = bm;
    }
  }
}

// ---- grouping + 3-layer shared MLP, 4 tokens/block -> h (token,5,256) ----
__global__ __launch_bounds__(256) void mlp_kernel(
    const float* __restrict__ sfeat, const float* __restrict__ tfeat,
    const float* __restrict__ sscf, const float* __restrict__ tscf,
    const int* __restrict__ idx_s,
    const float* __restrict__ w1, const float* __restrict__ g1, const float* __restrict__ b1,
    const float* __restrict__ w2, const float* __restrict__ g2, const float* __restrict__ b2,
    const float* __restrict__ w3, const float* __restrict__ g3, const float* __restrict__ b3,
    float* __restrict__ hout) {
  __shared__ __align__(16) float xin[4][5][260];   // input; later reused as hb2
  __shared__ __align__(16) float hb1[4][5][260];
  __shared__ int ms[4][4];
  int t = threadIdx.x;
  int tau0 = blockIdx.x * 4;
  int b = tau0 / Nc, n0 = tau0 % Nc;
  if (t < 16) {
    int s = t >> 2, k = t & 3;
    ms[s][k] = idx_s[(((size_t)b * Nc + n0 + s) << 2) + k];
  }
  __syncthreads();
  for (int s = 0; s < 4; ++s) {
    int n = n0 + s;
    xin[s][0][t] = sfeat[((size_t)b * Fc + t) * Nc + n];
    if (t < 3) xin[s][0][256 + t] = sscf[((size_t)b * 3 + t) * Nc + n];
    for (int k = 1; k < 5; ++k) {
      int m = ms[s][k - 1];
      xin[s][k][t] = tfeat[((size_t)b * Fc + t) * Mc + m];
      if (t < 3) xin[s][k][256 + t] = tscf[((size_t)b * 3 + t) * Mc + m];
    }
  }
  __syncthreads();
  float acc[4][5];
  {
    const float* wr = w1 + (size_t)t * 259;
#pragma unroll
    for (int s = 0; s < 4; ++s)
#pragma unroll
      for (int j = 0; j < 5; ++j) acc[s][j] = 0.f;
    for (int c = 0; c < 259; ++c) {
      float w = wr[c];
#pragma unroll
      for (int s = 0; s < 4; ++s)
#pragma unroll
        for (int j = 0; j < 5; ++j) acc[s][j] += w * xin[s][j][c];
    }
    float gg = g1[t], bb = b1[t];
#pragma unroll
    for (int s = 0; s < 4; ++s)
#pragma unroll
      for (int j = 0; j < 5; ++j) hb1[s][j][t] = fmaxf(0.f, gg * acc[s][j] + bb);
  }
  __syncthreads();
  {
    const float4* wr4 = (const float4*)(w2 + (size_t)t * 256);
#pragma unroll
    for (int s = 0; s < 4; ++s)
#pragma unroll
      for (int j = 0; j < 5; ++j) acc[s][j] = 0.f;
    for (int c4 = 0; c4 < 64; ++c4) {
      float4 w = wr4[c4];
#pragma unroll
      for (int s = 0; s < 4; ++s)
#pragma unroll
        for (int j = 0; j < 5; ++j) acc[s][j] += dot4(w, ((const float4*)hb1[s][j])[c4]);
    }
    float gg = g2[t], bb = b2[t];
    // xin is dead (all reads completed before hb1-write barrier) -> reuse as hb2
#pragma unroll
    for (int s = 0; s < 4; ++s)
#pragma unroll
      for (int j = 0; j < 5; ++j) xin[s][j][t] = fmaxf(0.f, gg * acc[s][j] + bb);
  }
  __syncthreads();
  {
    const float4* wr4 = (const float4*)(w3 + (size_t)t * 256);
#pragma unroll
    for (int s = 0; s < 4; ++s)
#pragma unroll
      for (int j = 0; j < 5; ++j) acc[s][j] = 0.f;
    for (int c4 = 0; c4 < 64; ++c4) {
      float4 w = wr4[c4];
#pragma unroll
      for (int s = 0; s < 4; ++s)
#pragma unroll
        for (int j = 0; j < 5; ++j) acc[s][j] += dot4(w, ((const float4*)xin[s][j])[c4]);
    }
    float gg = g3[t], bb = b3[t];
#pragma unroll
    for (int s = 0; s < 4; ++s) {
      float* dst = hout + ((size_t)(tau0 + s)) * 5 * 256;
#pragma unroll
      for (int j = 0; j < 5; ++j) dst[j * 256 + t] = fmaxf(0.f, gg * acc[s][j] + bb);
    }
  }
}

// ---- point transformer (i=0 only) + residual + inorm + fea, 4 tokens/block ----
__global__ __launch_bounds__(256) void attn_kernel(
    const float* __restrict__ hbuf, const int* __restrict__ idx_s,
    const float* __restrict__ sxyz, const float* __restrict__ sbc,
    const float* __restrict__ txyz, const float* __restrict__ tbc,
    const float* __restrict__ wqkv,
    const float* __restrict__ pw1, const float* __restrict__ pb1,
    const float* __restrict__ pw2, const float* __restrict__ pb2,
    const float* __restrict__ aw1, const float* __restrict__ ab1,
    const float* __restrict__ aw2, const float* __restrict__ ab2,
    const float* __restrict__ sfeat,
    const float* __restrict__ fw1, const float* __restrict__ fg1, const float* __restrict__ fb1,
    const float* __restrict__ fw2, const float* __restrict__ fb2v,
    float* __restrict__ yout) {
  __shared__ __align__(16) float sa[4][5][256];   // xs, then hch
  __shared__ __align__(16) float kb4[4][5][256];  // sim_in
  __shared__ __align__(16) float q04[4][256];     // normalized ff for fea
  __shared__ __align__(16) float t64x[4][5][64];  // pe hidden; later fea hidden [4][256]
  __shared__ float pc4[4][5][12];
  __shared__ float red[256];
  int t = threadIdx.x;
  int tau0 = blockIdx.x * 4;
  int b = tau0 / Nc, n0 = tau0 % Nc;
  for (int s = 0; s < 4; ++s) {
    const float* hs = hbuf + ((size_t)(tau0 + s)) * 5 * 256;
#pragma unroll
    for (int k = 0; k < 5; ++k) sa[s][k][t] = hs[k * 256 + t];
  }
  if (t < 20) {
    int s = t / 5, k = t % 5;
    int n = n0 + s;
    if (k == 0) {
      for (int c = 0; c < 3; ++c) pc4[s][0][c] = sxyz[((size_t)b * Nc + n) * 3 + c];
      for (int c = 0; c < 9; ++c) pc4[s][0][3 + c] = sbc[((size_t)b * Nc + n) * 9 + c];
    } else {
      int m = idx_s[(((size_t)b * Nc + n) << 2) + (k - 1)];
      for (int c = 0; c < 3; ++c) pc4[s][k][c] = txyz[((size_t)b * Mc + m) * 3 + c];
      for (int c = 0; c < 9; ++c) pc4[s][k][3 + c] = tbc[((size_t)b * Mc + m) * 9 + c];
    }
  }
  __syncthreads();
  // qkv: one pass over the 3 weight rows, 4 tokens x 5 slots reuse
  float accq[4], ak[4][5], av[4][5];
#pragma unroll
  for (int s = 0; s < 4; ++s) {
    accq[s] = 0.f;
#pragma unroll
    for (int j = 0; j < 5; ++j) { ak[s][j] = 0.f; av[s][j] = 0.f; }
  }
  {
    const float4* wq4 = (const float4*)(wqkv + (size_t)t * 256);
    const float4* wk4 = (const float4*)(wqkv + (size_t)(256 + t) * 256);
    const float4* wv4 = (const float4*)(wqkv + (size_t)(512 + t) * 256);
    for (int c4 = 0; c4 < 64; ++c4) {
      float4 wq = wq4[c4], wk = wk4[c4], wv = wv4[c4];
#pragma unroll
      for (int s = 0; s < 4; ++s) {
        float4 x0 = ((const float4*)sa[s][0])[c4];
        accq[s] += dot4(wq, x0);
        ak[s][0] += dot4(wk, x0); av[s][0] += dot4(wv, x0);
#pragma unroll
        for (int j = 1; j < 5; ++j) {
          float4 x = ((const float4*)sa[s][j])[c4];
          ak[s][j] += dot4(wk, x); av[s][j] += dot4(wv, x);
        }
      }
    }
  }
  // pe hidden layer: 4 tokens x 5 slots x 64 hidden = 1280 entries
  for (int it = t; it < 1280; it += 256) {
    int s = it / 320, r = it % 320;
    int j = r >> 6, h = r & 63;
    float acc = pb1[h];
    const float* w = pw1 + h * 12;
#pragma unroll
    for (int p = 0; p < 12; ++p) acc += w[p] * (pc4[s][0][p] - pc4[s][j][p]);
    t64x[s][j][h] = fmaxf(acc, 0.f);
  }
  __syncthreads();
  // pe out + fold: kb4 <- q - k + pe (sim_in); av <- v + pe (stays in regs)
  {
    const float4* pw24 = (const float4*)(pw2 + (size_t)t * 64);
    float pb2t = pb2[t];
#pragma unroll
    for (int s = 0; s < 4; ++s) {
#pragma unroll
      for (int j = 0; j < 5; ++j) {
        float acc = pb2t;
        const float4* tj4 = (const float4*)t64x[s][j];
#pragma unroll
        for (int h4 = 0; h4 < 16; ++h4) acc += dot4(pw24[h4], tj4[h4]);
        kb4[s][j][t] = accq[s] - ak[s][j] + acc;
        av[s][j] += acc;
      }
    }
  }
  __syncthreads();
  // amlp: 4 chunks of 256 hidden rows; thread t owns row ch*256+t for all (s,j)
  float sim[4][5];
#pragma unroll
  for (int s = 0; s < 4; ++s)
#pragma unroll
    for (int j = 0; j < 5; ++j) sim[s][j] = ab2[t];
  const float* aw2row = aw2 + (size_t)t * 1024;
  for (int ch = 0; ch < 4; ++ch) {
    int r = ch * 256 + t;
    const float4* w4 = (const float4*)(aw1 + (size_t)r * 256);
    float bias = ab1[r];
    float acc[4][5];
#pragma unroll
    for (int s = 0; s < 4; ++s)
#pragma unroll
      for (int j = 0; j < 5; ++j) acc[s][j] = bias;
    for (int c4 = 0; c4 < 64; ++c4) {
      float4 w = w4[c4];
#pragma unroll
      for (int s = 0; s < 4; ++s)
#pragma unroll
        for (int j = 0; j < 5; ++j) acc[s][j] += dot4(w, ((const float4*)kb4[s][j])[c4]);
    }
#pragma unroll
    for (int s = 0; s < 4; ++s)
#pragma unroll
      for (int j = 0; j < 5; ++j) sa[s][j][t] = fmaxf(acc[s][j], 0.f);
    __syncthreads();
    const float4* a24 = (const float4*)(aw2row + ch * 256);
    for (int rr4 = 0; rr4 < 64; ++rr4) {
      float4 w = a24[rr4];
#pragma unroll
      for (int s = 0; s < 4; ++s)
#pragma unroll
        for (int j = 0; j < 5; ++j) sim[s][j] += dot4(w, ((const float4*)sa[s][j])[rr4]);
    }
    __syncthreads();
  }
  // softmax over j + aggregate with v+pe; residual + instance norm
  for (int s = 0; s < 4; ++s) {
    float mx = sim[s][0];
#pragma unroll
    for (int j = 1; j < 5; ++j) mx = fmaxf(mx, sim[s][j]);
    float ssum = 0.f;
    float e[5];
#pragma unroll
    for (int j = 0; j < 5; ++j) { e[j] = expf(sim[s][j] - mx); ssum += e[j]; }
    float inv = 1.f / ssum;
    float agg = 0.f;
#pragma unroll
    for (int j = 0; j < 5; ++j) agg += (e[j] * inv) * av[s][j];
    float ff = agg + sfeat[((size_t)b * Fc + t) * Nc + (n0 + s)];
    float mu = blk_sum(ff, red) * (1.f / 256.f);
    float dfv = ff - mu;
    float var = blk_sum(dfv * dfv, red) * (1.f / 256.f);
    q04[s][t] = dfv / sqrtf(var + 1e-5f);
  }
  __syncthreads();
  // fea layer 1 (multi-token weight reuse); t64x reused as [4][256] hidden
  float* t64f = &t64x[0][0][0];
  {
    const float4* f14 = (const float4*)(fw1 + (size_t)t * 256);
    float acc1[4] = {0.f, 0.f, 0.f, 0.f};
    for (int c4 = 0; c4 < 64; ++c4) {
      float4 w = f14[c4];
#pragma unroll
      for (int s = 0; s < 4; ++s) acc1[s] += dot4(w, ((const float4*)q04[s])[c4]);
    }
    float gg = fg1[t], bb = fb1[t];
    __syncthreads();
#pragma unroll
    for (int s = 0; s < 4; ++s) t64f[s * 256 + t] = fmaxf(0.f, gg * acc1[s] + bb);
  }
  __syncthreads();
  float y2[4];
  {
    const float4* f24 = (const float4*)(fw2 + (size_t)t * 256);
    float fb = fb2v[t];
#pragma unroll
    for (int s = 0; s < 4; ++s) y2[s] = fb;
    for (int c4 = 0; c4 < 64; ++c4) {
      float4 w = f24[c4];
#pragma unroll
      for (int s = 0; s < 4; ++s) y2[s] += dot4(w, ((const float4*)(t64f + s * 256))[c4]);
    }
  }
  for (int s = 0; s < 4; ++s) {
    float z = y2[s] + q04[s][t];
    float mu2 = blk_sum(z, red) * (1.f / 256.f);
    float dz = z - mu2;
    float var2 = blk_sum(dz * dz, red) * (1.f / 256.f);
    yout[((size_t)(tau0 + s)) * 256 + t] = dz / sqrtf(var2 + 1e-5f);
  }
}

// ---- PointSIFT: per-octant nearest neighbor within radius ----
__global__ __launch_bounds__(256) void sift_idx_kernel(const float* __restrict__ sxyz,
                                                       int* __restrict__ sidx) {
  __shared__ float sv[256 * 8];
  __shared__ int si[256 * 8];
  int b = blockIdx.x / Nc, i = blockIdx.x % Nc;
  int t = threadIdx.x;
  const float* x = sxyz + (size_t)b * Nc * 3;
  float xi0 = x[3 * i], xi1 = x[3 * i + 1], xi2 = x[3 * i + 2];
  float bv[8]; int bi[8];
#pragma unroll
  for (int o = 0; o < 8; ++o) { bv[o] = INFF; bi[o] = Nc; }
  for (int j = t; j < Nc; j += 256) {
    float dx = x[3 * j] - xi0, dy = x[3 * j + 1] - xi1, dz = x[3 * j + 2] - xi2;
    float d2 = dx * dx + dy * dy + dz * dz;
    if (d2 <= 0.25f && d2 > 0.f) {
      int oc = (dx > 0.f ? 4 : 0) + (dy > 0.f ? 2 : 0) + (dz > 0.f ? 1 : 0);
      if (d2 < bv[oc] || (d2 == bv[oc] && j < bi[oc])) { bv[oc] = d2; bi[oc] = j; }
    }
  }
#pragma unroll
  for (int o = 0; o < 8; ++o) { sv[t * 8 + o] = bv[o]; si[t * 8 + o] = bi[o]; }
  __syncthreads();
  for (int s = 128; s > 0; s >>= 1) {
    if (t < s) {
#pragma unroll
      for (int o = 0; o < 8; ++o) {
        float v2 = sv[(t + s) * 8 + o]; int i2 = si[(t + s) * 8 + o];
        if (v2 < sv[t * 8 + o] || (v2 == sv[t * 8 + o] && i2 < si[t * 8 + o])) {
          sv[t * 8 + o] = v2; si[t * 8 + o] = i2;
        }
      }
    }
    __syncthreads();
  }
  if (t < 8) {
    int j = (sv[t] < INFF) ? si[t] : i;
    sidx[(((size_t)b * Nc + i) << 3) + t] = j;
  }
}

// ---- SIFT conv stage 1, 4 points/block: gather + (1,2)/(1,2) conv ----
__global__ __launch_bounds__(256) void sift_conv1_kernel(
    const float* __restrict__ sxyz, const int* __restrict__ sidx,
    const float* __restrict__ yin,
    const float* __restrict__ w1, const float* __restrict__ g1, const float* __restrict__ b1,
    float* __restrict__ gout) {
  __shared__ float xin[4][8][260];
  __shared__ int js[4][8];
  int t = threadIdx.x;
  int i0 = blockIdx.x * 4;
  int b = i0 / Nc, n_base = i0 % Nc;
  if (t < 32) {
    int s = t >> 3, o = t & 7;
    js[s][o] = sidx[(((size_t)b * Nc + n_base + s) << 3) + o];
  }
  __syncthreads();
  for (int s = 0; s < 4; ++s) {
    int i = n_base + s;
#pragma unroll
    for (int o = 0; o < 8; ++o) {
      int j = js[s][o];
      xin[s][o][3 + t] = yin[((size_t)b * Nc + j) * 256 + t];
      if (t < 3) xin[s][o][t] = sxyz[((size_t)b * Nc + j) * 3 + t] - sxyz[((size_t)b * Nc + i) * 3 + t];
    }
  }
  __syncthreads();
  const float2* wr2 = (const float2*)(w1 + (size_t)t * 518);
  float acc[4][4];
#pragma unroll
  for (int s = 0; s < 4; ++s)
#pragma unroll
    for (int p = 0; p < 4; ++p) acc[s][p] = 0.f;
  for (int c = 0; c < 259; ++c) {
    float2 w = wr2[c];
#pragma unroll
    for (int s = 0; s < 4; ++s)
#pragma unroll
      for (int p = 0; p < 4; ++p)
        acc[s][p] += xin[s][2 * p][c] * w.x + xin[s][2 * p + 1][c] * w.y;
  }
  float gg = g1[t], bb = b1[t];
#pragma unroll
  for (int s = 0; s < 4; ++s) {
    float* dst = gout + ((size_t)(i0 + s) * 256 + t) * 4;
#pragma unroll
    for (int p = 0; p < 4; ++p) dst[p] = fmaxf(0.f, gg * acc[s][p] + bb);
  }
}

// ---- SIFT conv stages 2+3 fused, 4 points/block + residual add ----
__global__ __launch_bounds__(256) void sift_conv23_kernel(
    const float* __restrict__ gin,
    const float* __restrict__ w2, const float* __restrict__ g2, const float* __restrict__ b2,
    const float* __restrict__ w3, const float* __restrict__ g3, const float* __restrict__ b3,
    float* __restrict__ yio) {
  __shared__ __align__(16) float in1[4][256][4];
  __shared__ __align__(16) float h2[4][512];
  int t = threadIdx.x;
  int i0 = blockIdx.x * 4;
  for (int s = 0; s < 4; ++s) {
    const float* src = gin + (size_t)(i0 + s) * 1024;
#pragma unroll
    for (int q = 0; q < 4; ++q) in1[s][t][q] = src[t * 4 + q];
  }
  __syncthreads();
  {
    const float4* wr4 = (const float4*)(w2 + (size_t)t * 512);
    float acc0[4] = {0.f, 0.f, 0.f, 0.f}, acc1[4] = {0.f, 0.f, 0.f, 0.f};
    for (int c2 = 0; c2 < 128; ++c2) {
      float4 w = wr4[c2];
#pragma unroll
      for (int s = 0; s < 4; ++s) {
        float4 v0 = ((const float4*)in1[s])[2 * c2];
        float4 v1 = ((const float4*)in1[s])[2 * c2 + 1];
        acc0[s] += v0.x * w.x + v0.y * w.y + v1.x * w.z + v1.y * w.w;
        acc1[s] += v0.z * w.x + v0.w * w.y + v1.z * w.z + v1.w * w.w;
      }
    }
    float gg = g2[t], bb = b2[t];
#pragma unroll
    for (int s = 0; s < 4; ++s) {
      h2[s][2 * t] = fmaxf(0.f, gg * acc0[s] + bb);
      h2[s][2 * t + 1] = fmaxf(0.f, gg * acc1[s] + bb);
    }
  }
  __syncthreads();
  {
    const float4* wr4 = (const float4*)(w3 + (size_t)t * 512);
    float acc[4] = {0.f, 0.f, 0.f, 0.f};
    for (int c2 = 0; c2 < 128; ++c2) {
      float4 w = wr4[c2];
#pragma unroll
      for (int s = 0; s < 4; ++s) acc[s] += dot4(w, ((const float4*)h2[s])[c2]);
    }
#pragma unroll
    for (int s = 0; s < 4; ++s) {
      float r = fmaxf(0.f, g3[t] * acc[s] + b3[t]);
      yio[(size_t)(i0 + s) * 256 + t] += r;
    }
  }
}

// ---- final transpose (B,N,C) -> (B,C,N) into d_out ----
__global__ __launch_bounds__(256) void transpose_kernel(const float* __restrict__ yin,
                                                        float* __restrict__ out) {
  size_t idx = (size_t)blockIdx.x * 256 + threadIdx.x;
  int n = (int)(idx % Nc);
  size_t r = idx / Nc;
  int c = (int)(r % Fc);
  int b = (int)(r / Fc);
  out[idx] = yin[(((size_t)b * Nc + n) * 256) + c];
}

extern "C" void kernel_launch(void* const* d_in, const int* in_sizes, int n_in,
                              void* d_out, int out_size, void* d_ws, size_t ws_size,
                              hipStream_t stream) {
  (void)in_sizes; (void)n_in; (void)out_size; (void)ws_size;
  const float* tfeat = (const float*)d_in[0];
  const float* sfeat = (const float*)d_in[1];
  const float* txyz  = (const float*)d_in[2];
  const float* sxyz  = (const float*)d_in[3];
  const float* tbc   = (const float*)d_in[4];
  const float* sbc   = (const float*)d_in[5];
  const float* mw1 = (const float*)d_in[6];
  const float* mg1 = (const float*)d_in[7];
  const float* mb1 = (const float*)d_in[8];
  const float* mw2 = (const float*)d_in[9];
  const float* mg2 = (const float*)d_in[10];
  const float* mb2 = (const float*)d_in[11];
  const float* mw3 = (const float*)d_in[12];
  const float* mg3 = (const float*)d_in[13];
  const float* mb3 = (const float*)d_in[14];
  const float* fw1 = (const float*)d_in[15];
  const float* fg1 = (const float*)d_in[16];
  const float* fb1 = (const float*)d_in[17];
  const float* fw2 = (const float*)d_in[18];
  const float* fb2 = (const float*)d_in[19];
  const float* wqkv = (const float*)d_in[20];
  const float* pw1 = (const float*)d_in[21];
  const float* pb1 = (const float*)d_in[22];
  const float* pw2 = (const float*)d_in[23];
  const float* pb2 = (const float*)d_in[24];
  const float* aw1 = (const float*)d_in[25];
  const float* ab1 = (const float*)d_in[26];
  const float* aw2 = (const float*)d_in[27];
  const float* ab2 = (const float*)d_in[28];
  const float* o1w1 = (const float*)d_in[29];
  const float* o1g1 = (const float*)d_in[30];
  const float* o1b1 = (const float*)d_in[31];
  const float* o1w2 = (const float*)d_in[32];
  const float* o1g2 = (const float*)d_in[33];
  const float* o1b2 = (const float*)d_in[34];
  const float* o1w3 = (const float*)d_in[35];
  const float* o1g3 = (const float*)d_in[36];
  const float* o1b3 = (const float*)d_in[37];
  const float* o2w1 = (const float*)d_in[38];
  const float* o2g1 = (const float*)d_in[39];
  const float* o2b1 = (const float*)d_in[40];
  const float* o2w2 = (const float*)d_in[41];
  const float* o2g2 = (const float*)d_in[42];
  const float* o2b2 = (const float*)d_in[43];
  const float* o2w3 = (const float*)d_in[44];
  const float* o2g3 = (const float*)d_in[45];
  const float* o2b3 = (const float*)d_in[46];

  // workspace layout (floats / ints), ~25 MB total, h-buffer reused for g1out
  float* ws = (float*)d_ws;
  float* sd   = ws;                    // B*N*16   = 65536
  float* td   = sd + 65536;            // B*M*16   = 32768
  float* sscf = td + 32768;            // B*3*N    = 12288
  float* tscf = sscf + 12288;          // B*3*M    = 6144
  int*   idxs = (int*)(tscf + 6144);   // B*N*4    = 16384 ints
  int*   sidx = idxs + 16384;          // B*N*8    = 32768 ints
  float* yws  = (float*)(sidx + 32768);// B*N*256  = 1048576
  float* hbuf = yws + 1048576;         // B*N*5*256 = 5242880
  float* g1o  = hbuf;                  // aliased: B*N*256*4 = 4194304 (h consumed first)

  scf_kernel<<<Bc, 256, 0, stream>>>(sxyz, sscf, Nc);
  scf_kernel<<<Bc, 256, 0, stream>>>(txyz, tscf, Mc);
  knn_kernel<Nc><<<Bc * Nc, 256, 0, stream>>>(sxyz, sd);
  knn_kernel<Mc><<<Bc * Mc, 256, 0, stream>>>(txyz, td);
  select_kernel<<<Bc * Nc, 256, 0, stream>>>(tbc, sbc, txyz, sxyz, sd, td, idxs);
  mlp_kernel<<<Bc * Nc / 4, 256, 0, stream>>>(sfeat, tfeat, sscf, tscf, idxs,
                                              mw1, mg1, mb1, mw2, mg2, mb2, mw3, mg3, mb3, hbuf);
  attn_kernel<<<Bc * Nc / 4, 256, 0, stream>>>(hbuf, idxs, sxyz, sbc, txyz, tbc, wqkv,
                                               pw1, pb1, pw2, pb2, aw1, ab1, aw2, ab2,
                                               sfeat, fw1, fg1, fb1, fw2, fb2, yws);
  sift_idx_kernel<<<Bc * Nc, 256, 0, stream>>>(sxyz, sidx);
  // OE module 1
  sift_conv1_kernel<<<Bc * Nc / 4, 256, 0, stream>>>(sxyz, sidx, yws, o1w1, o1g1, o1b1, g1o);
  sift_conv23_kernel<<<Bc * Nc / 4, 256, 0, stream>>>(g1o, o1w2, o1g2, o1b2, o1w3, o1g3, o1b3, yws);
  // OE module 2
  sift_conv1_kernel<<<Bc * Nc / 4, 256, 0, stream>>>(sxyz, sidx, yws, o2w1, o2g1, o2b1, g1o);
  sift_conv23_kernel<<<Bc * Nc / 4, 256, 0, stream>>>(g1o, o2w2, o2g2, o2b2, o2w3, o2g3, o2b3, yws);
  transpose_kernel<<<(Bc * Fc * Nc) / 256, 256, 0, stream>>>(yws, (float*)d_out);
}

// Round 4
// 1959.985 us; speedup vs baseline: 5.7411x; 1.3739x over previous
//
#include <hip/hip_runtime.h>
#include <hip/hip_bf16.h>
#include <math.h>

// Problem constants (match reference)
constexpr int Bc = 4, Mc = 512, Nc = 1024, Fc = 256;
constexpr int KCc = 16;
constexpr float INFF = 3.0e38f;

typedef __attribute__((ext_vector_type(8))) short short8b;  // 8 bf16 (4 VGPRs)
typedef __attribute__((ext_vector_type(4))) float f32x4;

__device__ __forceinline__ short f2bf(float f) {
  __hip_bfloat16 h = __float2bfloat16(f);
  return *reinterpret_cast<short*>(&h);
}
__device__ __forceinline__ float bf2f(short s) {
  unsigned int u = ((unsigned int)(unsigned short)s) << 16;
  return __uint_as_float(u);
}

__device__ __forceinline__ float blk_sum(float v, float* red) {
  int t = threadIdx.x;
  red[t] = v;
  __syncthreads();
  for (int s = 128; s > 0; s >>= 1) {
    if (t < s) red[t] += red[t + s];
    __syncthreads();
  }
  float r = red[0];
  __syncthreads();
  return r;
}

__device__ __forceinline__ float dot4(float4 a, float4 b) {
  return a.x * b.x + a.y * b.y + a.z * b.z + a.w * b.w;
}

// ---- weight pre-conversion to bf16 (runs every launch; deterministic) ----
__global__ __launch_bounds__(256) void wconv_plain(const float* __restrict__ src,
                                                   short* __restrict__ dst, int n) {
  int i = blockIdx.x * 256 + threadIdx.x;
  if (i < n) dst[i] = f2bf(src[i]);
}
__global__ __launch_bounds__(256) void wconv_pad(const float* __restrict__ src,
                                                 short* __restrict__ dst,
                                                 int rows, int K, int Kp) {
  int i = blockIdx.x * 256 + threadIdx.x;
  if (i < rows * Kp) {
    int r = i / Kp, c = i % Kp;
    dst[i] = (c < K) ? f2bf(src[r * K + c]) : (short)0;
  }
}

// ---- spherical coords of points relative to centroid -> out (B,3,P) ----
__global__ __launch_bounds__(256) void scf_kernel(const float* __restrict__ xyz,
                                                  float* __restrict__ out, int P) {
  __shared__ float red[256];
  int b = blockIdx.x;
  const float* x = xyz + (size_t)b * P * 3;
  float sx = 0.f, sy = 0.f, sz = 0.f;
  for (int i = threadIdx.x; i < P; i += 256) {
    sx += x[3 * i]; sy += x[3 * i + 1]; sz += x[3 * i + 2];
  }
  float mx = blk_sum(sx, red) / (float)P;
  float my = blk_sum(sy, red) / (float)P;
  float mz = blk_sum(sz, red) / (float)P;
  for (int i = threadIdx.x; i < P; i += 256) {
    float a = x[3 * i] - mx, c = x[3 * i + 1] - my, d = x[3 * i + 2] - mz;
    float r = sqrtf(a * a + c * c + d * d + 1e-8f);
    float ct = d / r;
    ct = fminf(1.f, fmaxf(-1.f, ct));
    out[((size_t)b * 3 + 0) * P + i] = r;
    out[((size_t)b * 3 + 1) * P + i] = acosf(ct);
    out[((size_t)b * 3 + 2) * P + i] = atan2f(c, a);
  }
}

// ---- per-point sorted distances to KC nearest neighbors (excl. self) ----
template <int P>
__global__ __launch_bounds__(256) void knn_kernel(const float* __restrict__ xyz,
                                                  float* __restrict__ desc) {
  __shared__ float d2s[P];
  __shared__ float rv[256];
  __shared__ int ri[256];
  int b = blockIdx.x / P, i = blockIdx.x % P;
  const float* x = xyz + (size_t)b * P * 3;
  float xi0 = x[3 * i], xi1 = x[3 * i + 1], xi2 = x[3 * i + 2];
  for (int j = threadIdx.x; j < P; j += 256) {
    float dx = x[3 * j] - xi0, dy = x[3 * j + 1] - xi1, dz = x[3 * j + 2] - xi2;
    d2s[j] = dx * dx + dy * dy + dz * dz;
  }
  __syncthreads();
  for (int round = 0; round < KCc + 1; ++round) {
    float bv = INFF; int bi = P;
    for (int j = threadIdx.x; j < P; j += 256) {
      float v = d2s[j];
      if (v < bv || (v == bv && j < bi)) { bv = v; bi = j; }
    }
    rv[threadIdx.x] = bv; ri[threadIdx.x] = bi;
    __syncthreads();
    for (int s = 128; s > 0; s >>= 1) {
      if (threadIdx.x < s) {
        float v2 = rv[threadIdx.x + s]; int i2 = ri[threadIdx.x + s];
        if (v2 < rv[threadIdx.x] || (v2 == rv[threadIdx.x] && i2 < ri[threadIdx.x])) {
          rv[threadIdx.x] = v2; ri[threadIdx.x] = i2;
        }
      }
      __syncthreads();
    }
    if (threadIdx.x == 0) {
      if (round > 0) desc[((size_t)b * P + i) * KCc + (round - 1)] = sqrtf(rv[0]);
      d2s[ri[0]] = INFF;
    }
    __syncthreads();
  }
}

// ---- candidate pruning: top-24 by bc dist -> top-8 by xyz -> top-4 by scf ----
__global__ __launch_bounds__(256) void select_kernel(
    const float* __restrict__ tbc, const float* __restrict__ sbc,
    const float* __restrict__ txyz, const float* __restrict__ sxyz,
    const float* __restrict__ sd, const float* __restrict__ td,
    int* __restrict__ idx_s) {
  __shared__ float dbc[Mc];
  __shared__ float rv[256];
  __shared__ int ri[256];
  __shared__ int cand[24];
  int b = blockIdx.x / Nc, n = blockIdx.x % Nc;
  const float* sb = sbc + ((size_t)b * Nc + n) * 9;
  float sreg[9];
#pragma unroll
  for (int c = 0; c < 9; ++c) sreg[c] = sb[c];
  for (int m = threadIdx.x; m < Mc; m += 256) {
    const float* tb = tbc + ((size_t)b * Mc + m) * 9;
    float acc = 0.f;
#pragma unroll
    for (int c = 0; c < 9; ++c) { float d = tb[c] - sreg[c]; acc += d * d; }
    dbc[m] = acc;
  }
  __syncthreads();
  for (int round = 0; round < 24; ++round) {
    float bv = INFF; int bi = Mc;
    for (int m = threadIdx.x; m < Mc; m += 256) {
      float v = dbc[m];
      if (v < bv || (v == bv && m < bi)) { bv = v; bi = m; }
    }
    rv[threadIdx.x] = bv; ri[threadIdx.x] = bi;
    __syncthreads();
    for (int s = 128; s > 0; s >>= 1) {
      if (threadIdx.x < s) {
        float v2 = rv[threadIdx.x + s]; int i2 = ri[threadIdx.x + s];
        if (v2 < rv[threadIdx.x] || (v2 == rv[threadIdx.x] && i2 < ri[threadIdx.x])) {
          rv[threadIdx.x] = v2; ri[threadIdx.x] = i2;
        }
      }
      __syncthreads();
    }
    if (threadIdx.x == 0) { cand[round] = ri[0]; dbc[ri[0]] = INFF; }
    __syncthreads();
  }
  if (threadIdx.x == 0) {
    const float* sp = sxyz + ((size_t)b * Nc + n) * 3;
    float sx = sp[0], sy = sp[1], sz = sp[2];
    float dv[24];
    for (int t2 = 0; t2 < 24; ++t2) {
      const float* tp = txyz + ((size_t)b * Mc + cand[t2]) * 3;
      float dx = tp[0] - sx, dy = tp[1] - sy, dz = tp[2] - sz;
      dv[t2] = dx * dx + dy * dy + dz * dz;
    }
    int c8[8]; bool used[24];
    for (int t2 = 0; t2 < 24; ++t2) used[t2] = false;
    for (int r = 0; r < 8; ++r) {
      float bv = INFF; int bt = -1, bm = 0x7fffffff;
      for (int t2 = 0; t2 < 24; ++t2) {
        if (used[t2]) continue;
        int m = cand[t2];
        if (bt < 0 || dv[t2] < bv || (dv[t2] == bv && m < bm)) { bv = dv[t2]; bt = t2; bm = m; }
      }
      used[bt] = true; c8[r] = bm;
    }
    const float* sdp = sd + ((size_t)b * Nc + n) * KCc;
    float sdr[16];
    for (int t2 = 0; t2 < 16; ++t2) sdr[t2] = sdp[t2];
    float dscf[8];
    for (int r = 0; r < 8; ++r) {
      const float* tdp = td + ((size_t)b * Mc + c8[r]) * KCc;
      float acc = 0.f;
      for (int t2 = 0; t2 < 16; ++t2) { float d = sdr[t2] - tdp[t2]; acc += d * d; }
      dscf[r] = acc;
    }
    bool u8[8] = {false, false, false, false, false, false, false, false};
    for (int r = 0; r < 4; ++r) {
      float bv = INFF; int bt = -1, bm = 0x7fffffff;
      for (int t2 = 0; t2 < 8; ++t2) {
        if (u8[t2]) continue;
        if (bt < 0 || dscf[t2] < bv || (dscf[t2] == bv && c8[t2] < bm)) { bv = dscf[t2]; bt = t2; bm = c8[t2]; }
      }
      u8[bt] = true;
      idx_s[(((size_t)b * Nc + n) << 2) + r] = bm;
    }
  }
}

// ---- grouping + 3-layer MLP via bf16 MFMA, 4 tokens/block -> hbufS bf16 ----
// B-tiles in LDS: col-major [32 cols][K] bf16, byte XOR-swizzled by ((col&7)<<4).
__global__ __launch_bounds__(256) void mlp_kernel(
    const float* __restrict__ sfeat, const float* __restrict__ tfeat,
    const float* __restrict__ sscf, const float* __restrict__ tscf,
    const int* __restrict__ idx_s,
    const short* __restrict__ w1bf, const float* __restrict__ g1, const float* __restrict__ b1,
    const short* __restrict__ w2bf, const float* __restrict__ g2, const float* __restrict__ b2,
    const short* __restrict__ w3bf, const float* __restrict__ g3, const float* __restrict__ b3,
    short* __restrict__ houtS) {
  __shared__ __align__(16) char smem[34816];
  char* B1 = smem;            // [32][288] bf16 = 18432 B ; B3 aliases [0,16384)
  char* B2 = smem + 18432;    // [32][256] bf16 = 16384 B
  __shared__ int ms[16];
  int t = threadIdx.x;
  int tau0 = blockIdx.x * 4;
  int b = tau0 / Nc, n0 = tau0 % Nc;
  if (t < 16) ms[t] = idx_s[(((size_t)b * Nc + n0 + (t >> 2)) << 2) + (t & 3)];
  __syncthreads();
  // build B1: cols = s*5+j, K=288 (256 feat + 3 scf + pad)
  for (int s = 0; s < 4; ++s) {
    int n = n0 + s;
    {
      int col = s * 5; int cx = (col & 7) << 4;
      *(short*)(B1 + ((col * 576 + t * 2) ^ cx)) = f2bf(sfeat[((size_t)b * Fc + t) * Nc + n]);
      if (t < 32) {
        float v = (t < 3) ? sscf[((size_t)b * 3 + t) * Nc + n] : 0.f;
        *(short*)(B1 + ((col * 576 + (256 + t) * 2) ^ cx)) = f2bf(v);
      }
    }
    for (int k = 1; k < 5; ++k) {
      int m = ms[s * 4 + k - 1];
      int col = s * 5 + k; int cx = (col & 7) << 4;
      *(short*)(B1 + ((col * 576 + t * 2) ^ cx)) = f2bf(tfeat[((size_t)b * Fc + t) * Mc + m]);
      if (t < 32) {
        float v = (t < 3) ? tscf[((size_t)b * 3 + t) * Mc + m] : 0.f;
        *(short*)(B1 + ((col * 576 + (256 + t) * 2) ^ cx)) = f2bf(v);
      }
    }
  }
  for (int col = 20; col < 32; ++col) {
    int cx = (col & 7) << 4;
    *(short*)(B1 + ((col * 576 + t * 2) ^ cx)) = 0;
    if (t < 32) *(short*)(B1 + ((col * 576 + (256 + t) * 2) ^ cx)) = 0;
  }
  __syncthreads();
  int w = t >> 6, l = t & 63, lg = l >> 4, lr = l & 15;
  // GEMM1: [256 rows][288 K] x [288][32 cols] -> B2
#pragma unroll
  for (int i = 0; i < 4; ++i) {
    int rt = w * 4 + i;
    const short* Ab = w1bf + (size_t)(rt * 16 + lr) * 288;
#pragma unroll
    for (int ct = 0; ct < 2; ++ct) {
      int col = ct * 16 + lr; int cx = (col & 7) << 4;
      f32x4 acc = {0.f, 0.f, 0.f, 0.f};
#pragma unroll
      for (int kk = 0; kk < 9; ++kk) {
        short8b a = *(const short8b*)(Ab + kk * 32 + lg * 8);
        short8b bb = *(const short8b*)(B1 + ((col * 576 + kk * 64 + lg * 16) ^ cx));
        acc = __builtin_amdgcn_mfma_f32_16x16x32_bf16(a, bb, acc, 0, 0, 0);
      }
      int r0 = rt * 16 + lg * 4;
      float4 gg = *(const float4*)(g1 + r0), bs = *(const float4*)(b1 + r0);
      ushort4 hv;
      hv.x = (unsigned short)f2bf(fmaxf(gg.x * acc[0] + bs.x, 0.f));
      hv.y = (unsigned short)f2bf(fmaxf(gg.y * acc[1] + bs.y, 0.f));
      hv.z = (unsigned short)f2bf(fmaxf(gg.z * acc[2] + bs.z, 0.f));
      hv.w = (unsigned short)f2bf(fmaxf(gg.w * acc[3] + bs.w, 0.f));
      *(ushort4*)(B2 + ((col * 512 + r0 * 2) ^ cx)) = hv;
    }
  }
  __syncthreads();
  // GEMM2: [256][256] x B2 -> B3 (alias B1)
#pragma unroll
  for (int i = 0; i < 4; ++i) {
    int rt = w * 4 + i;
    const short* Ab = w2bf + (size_t)(rt * 16 + lr) * 256;
#pragma unroll
    for (int ct = 0; ct < 2; ++ct) {
      int col = ct * 16 + lr; int cx = (col & 7) << 4;
      f32x4 acc = {0.f, 0.f, 0.f, 0.f};
#pragma unroll
      for (int kk = 0; kk < 8; ++kk) {
        short8b a = *(const short8b*)(Ab + kk * 32 + lg * 8);
        short8b bb = *(const short8b*)(B2 + ((col * 512 + kk * 64 + lg * 16) ^ cx));
        acc = __builtin_amdgcn_mfma_f32_16x16x32_bf16(a, bb, acc, 0, 0, 0);
      }
      int r0 = rt * 16 + lg * 4;
      float4 gg = *(const float4*)(g2 + r0), bs = *(const float4*)(b2 + r0);
      ushort4 hv;
      hv.x = (unsigned short)f2bf(fmaxf(gg.x * acc[0] + bs.x, 0.f));
      hv.y = (unsigned short)f2bf(fmaxf(gg.y * acc[1] + bs.y, 0.f));
      hv.z = (unsigned short)f2bf(fmaxf(gg.z * acc[2] + bs.z, 0.f));
      hv.w = (unsigned short)f2bf(fmaxf(gg.w * acc[3] + bs.w, 0.f));
      *(ushort4*)(B1 + ((col * 512 + r0 * 2) ^ cx)) = hv;
    }
  }
  __syncthreads();
  // GEMM3: [256][256] x B3 -> hbufS (bf16, global)
#pragma unroll
  for (int i = 0; i < 4; ++i) {
    int rt = w * 4 + i;
    const short* Ab = w3bf + (size_t)(rt * 16 + lr) * 256;
#pragma unroll
    for (int ct = 0; ct < 2; ++ct) {
      int col = ct * 16 + lr; int cx = (col & 7) << 4;
      f32x4 acc = {0.f, 0.f, 0.f, 0.f};
#pragma unroll
      for (int kk = 0; kk < 8; ++kk) {
        short8b a = *(const short8b*)(Ab + kk * 32 + lg * 8);
        short8b bb = *(const short8b*)(B1 + ((col * 512 + kk * 64 + lg * 16) ^ cx));
        acc = __builtin_amdgcn_mfma_f32_16x16x32_bf16(a, bb, acc, 0, 0, 0);
      }
      if (col < 20) {
        int r0 = rt * 16 + lg * 4;
        float4 gg = *(const float4*)(g3 + r0), bs = *(const float4*)(b3 + r0);
        ushort4 hv;
        hv.x = (unsigned short)f2bf(fmaxf(gg.x * acc[0] + bs.x, 0.f));
        hv.y = (unsigned short)f2bf(fmaxf(gg.y * acc[1] + bs.y, 0.f));
        hv.z = (unsigned short)f2bf(fmaxf(gg.z * acc[2] + bs.z, 0.f));
        hv.w = (unsigned short)f2bf(fmaxf(gg.w * acc[3] + bs.w, 0.f));
        int s = col / 5, j = col % 5;
        *(ushort4*)(houtS + ((size_t)(tau0 + s) * 5 + j) * 256 + r0) = hv;
      }
    }
  }
}

// ---- point transformer (i=0 only): qkv/pe f32 VALU + amlp bf16 MFMA ----
__global__ __launch_bounds__(256) void attn_kernel(
    const short* __restrict__ hbufS, const int* __restrict__ idx_s,
    const float* __restrict__ sxyz, const float* __restrict__ sbc,
    const float* __restrict__ txyz, const float* __restrict__ tbc,
    const float* __restrict__ wqkv,
    const float* __restrict__ pw1, const float* __restrict__ pb1,
    const float* __restrict__ pw2, const float* __restrict__ pb2,
    const short* __restrict__ aw1bf, const float* __restrict__ ab1,
    const short* __restrict__ aw2bf, const float* __restrict__ ab2,
    const float* __restrict__ sfeat,
    const float* __restrict__ fw1, const float* __restrict__ fg1, const float* __restrict__ fb1,
    const float* __restrict__ fw2, const float* __restrict__ fb2v,
    float* __restrict__ yout) {
  __shared__ __align__(16) char smem[38912];
  float* saF  = (float*)smem;              // [20][256] f32, phases 0-1
  char*  kbB  = smem;                      // KB bf16 [32][256], phases 3-4
  char*  HpB  = smem + 16384;              // H panel bf16 [32][256], phase 4
  float* simF = (float*)smem;              // [20][260] f32, phases 5-6
  float* peH  = (float*)(smem + 25920);    // pe hidden [20][64] f32, phases 2-3
  float* feaH = (float*)(smem + 25920);    // fea hidden [4][256] f32, phase 6
  float* q04  = (float*)(smem + 32768);    // [4][256] f32
  float* pc4  = (float*)(smem + 36864);    // [20][12] f32
  float* red  = (float*)(smem + 37888);    // [256]
  int t = threadIdx.x;
  int tau0 = blockIdx.x * 4;
  int b = tau0 / Nc, n0 = tau0 % Nc;
  // phase 0: load x (bf16 -> f32 LDS) + pos vectors
  for (int s = 0; s < 4; ++s) {
    const short* hs = hbufS + (size_t)(tau0 + s) * 1280;
#pragma unroll
    for (int k = 0; k < 5; ++k) saF[(s * 5 + k) * 256 + t] = bf2f(hs[k * 256 + t]);
  }
  if (t < 20) {
    int s = t / 5, k = t % 5;
    int n = n0 + s;
    float* pd = pc4 + t * 12;
    if (k == 0) {
      for (int c = 0; c < 3; ++c) pd[c] = sxyz[((size_t)b * Nc + n) * 3 + c];
      for (int c = 0; c < 9; ++c) pd[3 + c] = sbc[((size_t)b * Nc + n) * 9 + c];
    } else {
      int m = idx_s[(((size_t)b * Nc + n) << 2) + (k - 1)];
      for (int c = 0; c < 3; ++c) pd[c] = txyz[((size_t)b * Mc + m) * 3 + c];
      for (int c = 0; c < 9; ++c) pd[3 + c] = tbc[((size_t)b * Mc + m) * 9 + c];
    }
  }
  __syncthreads();
  // phase 1: qkv (f32 VALU, broadcast LDS reads, 4-token weight reuse)
  float accq[4], ak[4][5], av[4][5];
#pragma unroll
  for (int s = 0; s < 4; ++s) {
    accq[s] = 0.f;
#pragma unroll
    for (int j = 0; j < 5; ++j) { ak[s][j] = 0.f; av[s][j] = 0.f; }
  }
  {
    const float4* wq4 = (const float4*)(wqkv + (size_t)t * 256);
    const float4* wk4 = (const float4*)(wqkv + (size_t)(256 + t) * 256);
    const float4* wv4 = (const float4*)(wqkv + (size_t)(512 + t) * 256);
    for (int c4 = 0; c4 < 64; ++c4) {
      float4 wq = wq4[c4], wk = wk4[c4], wv = wv4[c4];
#pragma unroll
      for (int s = 0; s < 4; ++s) {
        float4 x0 = ((const float4*)(saF + (s * 5) * 256))[c4];
        accq[s] += dot4(wq, x0);
        ak[s][0] += dot4(wk, x0); av[s][0] += dot4(wv, x0);
#pragma unroll
        for (int j = 1; j < 5; ++j) {
          float4 x = ((const float4*)(saF + (s * 5 + j) * 256))[c4];
          ak[s][j] += dot4(wk, x); av[s][j] += dot4(wv, x);
        }
      }
    }
  }
  // phase 2: pe hidden (20 x 64)
  for (int it = t; it < 1280; it += 256) {
    int sj = it >> 6, h = it & 63;
    int s = sj / 5;
    float acc = pb1[h];
    const float* wv = pw1 + h * 12;
    const float* p0 = pc4 + (s * 5) * 12;
    const float* pj = pc4 + sj * 12;
#pragma unroll
    for (int p = 0; p < 12; ++p) acc += wv[p] * (p0[p] - pj[p]);
    peH[sj * 64 + h] = fmaxf(acc, 0.f);
  }
  __syncthreads();
  // phase 3: pe out + fold -> KB bf16 tile (sim_in), av += pe
  {
    const float4* pw24 = (const float4*)(pw2 + (size_t)t * 64);
    float pb2t = pb2[t];
#pragma unroll
    for (int s = 0; s < 4; ++s) {
#pragma unroll
      for (int j = 0; j < 5; ++j) {
        float acc = pb2t;
        const float4* tj4 = (const float4*)(peH + (s * 5 + j) * 64);
#pragma unroll
        for (int h4 = 0; h4 < 16; ++h4) acc += dot4(pw24[h4], tj4[h4]);
        int col = s * 5 + j;
        *(short*)(kbB + ((col * 512 + t * 2) ^ ((col & 7) << 4))) =
            f2bf(accq[s] - ak[s][j] + acc);
        av[s][j] += acc;
      }
    }
#pragma unroll
    for (int col = 20; col < 32; ++col)
      *(short*)(kbB + ((col * 512 + t * 2) ^ ((col & 7) << 4))) = 0;
  }
  __syncthreads();
  // phase 4: amlp via MFMA, 4 panels of 256 hidden rows
  int w = t >> 6, l = t & 63, lg = l >> 4, lr = l & 15;
  f32x4 sacc[4][2];
#pragma unroll
  for (int i = 0; i < 4; ++i)
#pragma unroll
    for (int ct = 0; ct < 2; ++ct) sacc[i][ct] = (f32x4){0.f, 0.f, 0.f, 0.f};
  for (int p = 0; p < 4; ++p) {
    // GEMM1: H rows [256p,256p+256) = relu(aw1 . KB + ab1) -> HpB
#pragma unroll
    for (int i = 0; i < 4; ++i) {
      int rtl = w * 4 + i;
      const short* Ab = aw1bf + (size_t)(p * 256 + rtl * 16 + lr) * 256;
#pragma unroll
      for (int ct = 0; ct < 2; ++ct) {
        int col = ct * 16 + lr; int cx = (col & 7) << 4;
        f32x4 acc = {0.f, 0.f, 0.f, 0.f};
#pragma unroll
        for (int kk = 0; kk < 8; ++kk) {
          short8b a = *(const short8b*)(Ab + kk * 32 + lg * 8);
          short8b bb = *(const short8b*)(kbB + ((col * 512 + kk * 64 + lg * 16) ^ cx));
          acc = __builtin_amdgcn_mfma_f32_16x16x32_bf16(a, bb, acc, 0, 0, 0);
        }
        int r0 = rtl * 16 + lg * 4;
        float4 bias = *(const float4*)(ab1 + p * 256 + r0);
        ushort4 hv;
        hv.x = (unsigned short)f2bf(fmaxf(acc[0] + bias.x, 0.f));
        hv.y = (unsigned short)f2bf(fmaxf(acc[1] + bias.y, 0.f));
        hv.z = (unsigned short)f2bf(fmaxf(acc[2] + bias.z, 0.f));
        hv.w = (unsigned short)f2bf(fmaxf(acc[3] + bias.w, 0.f));
        *(ushort4*)(HpB + ((col * 512 + r0 * 2) ^ cx)) = hv;
      }
    }
    __syncthreads();
    // GEMM2 partial: sim += aw2[:, panel] . H
#pragma unroll
    for (int i = 0; i < 4; ++i) {
      const short* Ab = aw2bf + (size_t)((w * 4 + i) * 16 + lr) * 1024 + p * 256;
#pragma unroll
      for (int ct = 0; ct < 2; ++ct) {
        int col = ct * 16 + lr; int cx = (col & 7) << 4;
        f32x4 acc = sacc[i][ct];
#pragma unroll
        for (int kk = 0; kk < 8; ++kk) {
          short8b a = *(const short8b*)(Ab + kk * 32 + lg * 8);
          short8b bb = *(const short8b*)(HpB + ((col * 512 + kk * 64 + lg * 16) ^ cx));
          acc = __builtin_amdgcn_mfma_f32_16x16x32_bf16(a, bb, acc, 0, 0, 0);
        }
        sacc[i][ct] = acc;
      }
    }
    __syncthreads();
  }
  // phase 5: sim (+ab2) -> simF [20 cols][260]
#pragma unroll
  for (int i = 0; i < 4; ++i) {
#pragma unroll
    for (int ct = 0; ct < 2; ++ct) {
      int col = ct * 16 + lr;
      if (col < 20) {
        int r0 = w * 64 + i * 16 + lg * 4;
        float4 bias = *(const float4*)(ab2 + r0);
        float4 v;
        v.x = sacc[i][ct][0] + bias.x; v.y = sacc[i][ct][1] + bias.y;
        v.z = sacc[i][ct][2] + bias.z; v.w = sacc[i][ct][3] + bias.w;
        *(float4*)(simF + col * 260 + r0) = v;
      }
    }
  }
  __syncthreads();
  // phase 6: softmax over j + aggregate + residual + instance norm
#pragma unroll
  for (int s = 0; s < 4; ++s) {
    float sv[5];
#pragma unroll
    for (int j = 0; j < 5; ++j) sv[j] = simF[(s * 5 + j) * 260 + t];
    float mx = sv[0];
#pragma unroll
    for (int j = 1; j < 5; ++j) mx = fmaxf(mx, sv[j]);
    float ssum = 0.f;
#pragma unroll
    for (int j = 0; j < 5; ++j) { sv[j] = expf(sv[j] - mx); ssum += sv[j]; }
    float inv = 1.f / ssum;
    float agg = 0.f;
#pragma unroll
    for (int j = 0; j < 5; ++j) agg += (sv[j] * inv) * av[s][j];
    float ff = agg + sfeat[((size_t)b * Fc + t) * Nc + (n0 + s)];
    float mu = blk_sum(ff, red) * (1.f / 256.f);
    float dfv = ff - mu;
    float var = blk_sum(dfv * dfv, red) * (1.f / 256.f);
    q04[s * 256 + t] = dfv / sqrtf(var + 1e-5f);
  }
  __syncthreads();
  // fea layer 1 (4-token weight reuse)
  {
    const float4* f14 = (const float4*)(fw1 + (size_t)t * 256);
    float acc1[4] = {0.f, 0.f, 0.f, 0.f};
    for (int c4 = 0; c4 < 64; ++c4) {
      float4 wv = f14[c4];
#pragma unroll
      for (int s = 0; s < 4; ++s) acc1[s] += dot4(wv, ((const float4*)(q04 + s * 256))[c4]);
    }
    float gg = fg1[t], bb = fb1[t];
#pragma unroll
    for (int s = 0; s < 4; ++s) feaH[s * 256 + t] = fmaxf(0.f, gg * acc1[s] + bb);
  }
  __syncthreads();
  float y2[4];
  {
    const float4* f24 = (const float4*)(fw2 + (size_t)t * 256);
    float fb = fb2v[t];
#pragma unroll
    for (int s = 0; s < 4; ++s) y2[s] = fb;
    for (int c4 = 0; c4 < 64; ++c4) {
      float4 wv = f24[c4];
#pragma unroll
      for (int s = 0; s < 4; ++s) y2[s] += dot4(wv, ((const float4*)(feaH + s * 256))[c4]);
    }
  }
#pragma unroll
  for (int s = 0; s < 4; ++s) {
    float z = y2[s] + q04[s * 256 + t];
    float mu2 = blk_sum(z, red) * (1.f / 256.f);
    float dz = z - mu2;
    float var2 = blk_sum(dz * dz, red) * (1.f / 256.f);
    yout[((size_t)(tau0 + s)) * 256 + t] = dz / sqrtf(var2 + 1e-5f);
  }
}

// ---- PointSIFT: per-octant nearest neighbor within radius ----
__global__ __launch_bounds__(256) void sift_idx_kernel(const float* __restrict__ sxyz,
                                                       int* __restrict__ sidx) {
  __shared__ float sv[256 * 8];
  __shared__ int si[256 * 8];
  int b = blockIdx.x / Nc, i = blockIdx.x % Nc;
  int t = threadIdx.x;
  const float* x = sxyz + (size_t)b * Nc * 3;
  float xi0 = x[3 * i], xi1 = x[3 * i + 1], xi2 = x[3 * i + 2];
  float bv[8]; int bi[8];
#pragma unroll
  for (int o = 0; o < 8; ++o) { bv[o] = INFF; bi[o] = Nc; }
  for (int j = t; j < Nc; j += 256) {
    float dx = x[3 * j] - xi0, dy = x[3 * j + 1] - xi1, dz = x[3 * j + 2] - xi2;
    float d2 = dx * dx + dy * dy + dz * dz;
    if (d2 <= 0.25f && d2 > 0.f) {
      int oc = (dx > 0.f ? 4 : 0) + (dy > 0.f ? 2 : 0) + (dz > 0.f ? 1 : 0);
      if (d2 < bv[oc] || (d2 == bv[oc] && j < bi[oc])) { bv[oc] = d2; bi[oc] = j; }
    }
  }
#pragma unroll
  for (int o = 0; o < 8; ++o) { sv[t * 8 + o] = bv[o]; si[t * 8 + o] = bi[o]; }
  __syncthreads();
  for (int s = 128; s > 0; s >>= 1) {
    if (t < s) {
#pragma unroll
      for (int o = 0; o < 8; ++o) {
        float v2 = sv[(t + s) * 8 + o]; int i2 = si[(t + s) * 8 + o];
        if (v2 < sv[t * 8 + o] || (v2 == sv[t * 8 + o] && i2 < si[t * 8 + o])) {
          sv[t * 8 + o] = v2; si[t * 8 + o] = i2;
        }
      }
    }
    __syncthreads();
  }
  if (t < 8) {
    int j = (sv[t] < INFF) ? si[t] : i;
    sidx[(((size_t)b * Nc + i) << 3) + t] = j;
  }
}

// ---- SIFT conv stage 1, 4 points/block: gather + (1,2)/(1,2) conv ----
__global__ __launch_bounds__(256) void sift_conv1_kernel(
    const float* __restrict__ sxyz, const int* __restrict__ sidx,
    const float* __restrict__ yin,
    const float* __restrict__ w1, const float* __restrict__ g1, const float* __restrict__ b1,
    float* __restrict__ gout) {
  __shared__ float xin[4][8][260];
  __shared__ int js[4][8];
  int t = threadIdx.x;
  int i0 = blockIdx.x * 4;
  int b = i0 / Nc, n_base = i0 % Nc;
  if (t < 32) {
    int s = t >> 3, o = t & 7;
    js[s][o] = sidx[(((size_t)b * Nc + n_base + s) << 3) + o];
  }
  __syncthreads();
  for (int s = 0; s < 4; ++s) {
    int i = n_base + s;
#pragma unroll
    for (int o = 0; o < 8; ++o) {
      int j = js[s][o];
      xin[s][o][3 + t] = yin[((size_t)b * Nc + j) * 256 + t];
      if (t < 3) xin[s][o][t] = sxyz[((size_t)b * Nc + j) * 3 + t] - sxyz[((size_t)b * Nc + i) * 3 + t];
    }
  }
  __syncthreads();
  const float2* wr2 = (const float2*)(w1 + (size_t)t * 518);
  float acc[4][4];
#pragma unroll
  for (int s = 0; s < 4; ++s)
#pragma unroll
    for (int p = 0; p < 4; ++p) acc[s][p] = 0.f;
  for (int c = 0; c < 259; ++c) {
    float2 w = wr2[c];
#pragma unroll
    for (int s = 0; s < 4; ++s)
#pragma unroll
      for (int p = 0; p < 4; ++p)
        acc[s][p] += xin[s][2 * p][c] * w.x + xin[s][2 * p + 1][c] * w.y;
  }
  float gg = g1[t], bb = b1[t];
#pragma unroll
  for (int s = 0; s < 4; ++s) {
    float* dst = gout + ((size_t)(i0 + s) * 256 + t) * 4;
#pragma unroll
    for (int p = 0; p < 4; ++p) dst[p] = fmaxf(0.f, gg * acc[s][p] + bb);
  }
}

// ---- SIFT conv stages 2+3 fused, 4 points/block + residual add ----
__global__ __launch_bounds__(256) void sift_conv23_kernel(
    const float* __restrict__ gin,
    const float* __restrict__ w2, const float* __restrict__ g2, const float* __restrict__ b2,
    const float* __restrict__ w3, const float* __restrict__ g3, const float* __restrict__ b3,
    float* __restrict__ yio) {
  __shared__ __align__(16) float in1[4][256][4];
  __shared__ __align__(16) float h2[4][512];
  int t = threadIdx.x;
  int i0 = blockIdx.x * 4;
  for (int s = 0; s < 4; ++s) {
    const float* src = gin + (size_t)(i0 + s) * 1024;
#pragma unroll
    for (int q = 0; q < 4; ++q) in1[s][t][q] = src[t * 4 + q];
  }
  __syncthreads();
  {
    const float4* wr4 = (const float4*)(w2 + (size_t)t * 512);
    float acc0[4] = {0.f, 0.f, 0.f, 0.f}, acc1[4] = {0.f, 0.f, 0.f, 0.f};
    for (int c2 = 0; c2 < 128; ++c2) {
      float4 w = wr4[c2];
#pragma unroll
      for (int s = 0; s < 4; ++s) {
        float4 v0 = ((const float4*)in1[s])[2 * c2];
        float4 v1 = ((const float4*)in1[s])[2 * c2 + 1];
        acc0[s] += v0.x * w.x + v0.y * w.y + v1.x * w.z + v1.y * w.w;
        acc1[s] += v0.z * w.x + v0.w * w.y + v1.z * w.z + v1.w * w.w;
      }
    }
    float gg = g2[t], bb = b2[t];
#pragma unroll
    for (int s = 0; s < 4; ++s) {
      h2[s][2 * t] = fmaxf(0.f, gg * acc0[s] + bb);
      h2[s][2 * t + 1] = fmaxf(0.f, gg * acc1[s] + bb);
    }
  }
  __syncthreads();
  {
    const float4* wr4 = (const float4*)(w3 + (size_t)t * 512);
    float acc[4] = {0.f, 0.f, 0.f, 0.f};
    for (int c2 = 0; c2 < 128; ++c2) {
      float4 w = wr4[c2];
#pragma unroll
      for (int s = 0; s < 4; ++s) acc[s] += dot4(w, ((const float4*)h2[s])[c2]);
    }
#pragma unroll
    for (int s = 0; s < 4; ++s) {
      float r = fmaxf(0.f, g3[t] * acc[s] + b3[t]);
      yio[(size_t)(i0 + s) * 256 + t] += r;
    }
  }
}

// ---- final transpose (B,N,C) -> (B,C,N) into d_out ----
__global__ __launch_bounds__(256) void transpose_kernel(const float* __restrict__ yin,
                                                        float* __restrict__ out) {
  size_t idx = (size_t)blockIdx.x * 256 + threadIdx.x;
  int n = (int)(idx % Nc);
  size_t r = idx / Nc;
  int c = (int)(r % Fc);
  int b = (int)(r / Fc);
  out[idx] = yin[(((size_t)b * Nc + n) * 256) + c];
}

extern "C" void kernel_launch(void* const* d_in, const int* in_sizes, int n_in,
                              void* d_out, int out_size, void* d_ws, size_t ws_size,
                              hipStream_t stream) {
  (void)in_sizes; (void)n_in; (void)out_size; (void)ws_size;
  const float* tfeat = (const float*)d_in[0];
  const float* sfeat = (const float*)d_in[1];
  const float* txyz  = (const float*)d_in[2];
  const float* sxyz  = (const float*)d_in[3];
  const float* tbc   = (const float*)d_in[4];
  const float* sbc   = (const float*)d_in[5];
  const float* mw1 = (const float*)d_in[6];
  const float* mg1 = (const float*)d_in[7];
  const float* mb1 = (const float*)d_in[8];
  const float* mw2 = (const float*)d_in[9];
  const float* mg2 = (const float*)d_in[10];
  const float* mb2 = (const float*)d_in[11];
  const float* mw3 = (const float*)d_in[12];
  const float* mg3 = (const float*)d_in[13];
  const float* mb3 = (const float*)d_in[14];
  const float* fw1 = (const float*)d_in[15];
  const float* fg1 = (const float*)d_in[16];
  const float* fb1 = (const float*)d_in[17];
  const float* fw2 = (const float*)d_in[18];
  const float* fb2 = (const float*)d_in[19];
  const float* wqkv = (const float*)d_in[20];
  const float* pw1 = (const float*)d_in[21];
  const float* pb1 = (const float*)d_in[22];
  const float* pw2 = (const float*)d_in[23];
  const float* pb2 = (const float*)d_in[24];
  const float* aw1 = (const float*)d_in[25];
  const float* ab1 = (const float*)d_in[26];
  const float* aw2 = (const float*)d_in[27];
  const float* ab2 = (const float*)d_in[28];
  const float* o1w1 = (const float*)d_in[29];
  const float* o1g1 = (const float*)d_in[30];
  const float* o1b1 = (const float*)d_in[31];
  const float* o1w2 = (const float*)d_in[32];
  const float* o1g2 = (const float*)d_in[33];
  const float* o1b2 = (const float*)d_in[34];
  const float* o1w3 = (const float*)d_in[35];
  const float* o1g3 = (const float*)d_in[36];
  const float* o1b3 = (const float*)d_in[37];
  const float* o2w1 = (const float*)d_in[38];
  const float* o2g1 = (const float*)d_in[39];
  const float* o2b1 = (const float*)d_in[40];
  const float* o2w2 = (const float*)d_in[41];
  const float* o2g2 = (const float*)d_in[42];
  const float* o2b2 = (const float*)d_in[43];
  const float* o2w3 = (const float*)d_in[44];
  const float* o2g3 = (const float*)d_in[45];
  const float* o2b3 = (const float*)d_in[46];

  // workspace layout: f32 region, then bf16 (short) region; ~16.8 MB total
  float* ws = (float*)d_ws;
  float* sd   = ws;                      // B*N*16   = 65536 f32
  float* td   = sd + 65536;              // B*M*16   = 32768
  float* sscf = td + 32768;              // B*3*N    = 12288
  float* tscf = sscf + 12288;            // B*3*M    = 6144
  int*   idxs = (int*)(tscf + 6144);     // B*N*4    = 16384 ints
  int*   sidx = idxs + 16384;            // B*N*8    = 32768 ints
  float* yws  = (float*)(sidx + 32768);  // B*N*256  = 1048576 f32
  short* sbase  = (short*)(yws + 1048576);
  short* hbufS  = sbase;                 // B*N*5*256 bf16 = 5242880 shorts
  short* aw1bf  = sbase + 5242880;       // 1024*256
  short* aw2bf  = aw1bf + 262144;        // 256*1024
  short* mw1bf  = aw2bf + 262144;        // 256*288 (padded)
  short* mw2bf  = mw1bf + 73728;         // 256*256
  short* mw3bf  = mw2bf + 65536;         // 256*256
  float* g1o    = (float*)sbase;         // sift scratch 4 MB, used after attn (hbufS dead)

  // weight conversion (cheap; re-run every launch, deterministic)
  wconv_plain<<<(262144 + 255) / 256, 256, 0, stream>>>(aw1, aw1bf, 262144);
  wconv_plain<<<(262144 + 255) / 256, 256, 0, stream>>>(aw2, aw2bf, 262144);
  wconv_plain<<<(65536 + 255) / 256, 256, 0, stream>>>(mw2, mw2bf, 65536);
  wconv_plain<<<(65536 + 255) / 256, 256, 0, stream>>>(mw3, mw3bf, 65536);
  wconv_pad<<<(73728 + 255) / 256, 256, 0, stream>>>(mw1, mw1bf, 256, 259, 288);

  scf_kernel<<<Bc, 256, 0, stream>>>(sxyz, sscf, Nc);
  scf_kernel<<<Bc, 256, 0, stream>>>(txyz, tscf, Mc);
  knn_kernel<Nc><<<Bc * Nc, 256, 0, stream>>>(sxyz, sd);
  knn_kernel<Mc><<<Bc * Mc, 256, 0, stream>>>(txyz, td);
  select_kernel<<<Bc * Nc, 256, 0, stream>>>(tbc, sbc, txyz, sxyz, sd, td, idxs);
  mlp_kernel<<<Bc * Nc / 4, 256, 0, stream>>>(sfeat, tfeat, sscf, tscf, idxs,
                                              mw1bf, mg1, mb1, mw2bf, mg2, mb2,
                                              mw3bf, mg3, mb3, hbufS);
  attn_kernel<<<Bc * Nc / 4, 256, 0, stream>>>(hbufS, idxs, sxyz, sbc, txyz, tbc, wqkv,
                                               pw1, pb1, pw2, pb2, aw1bf, ab1, aw2bf, ab2,
                                               sfeat, fw1, fg1, fb1, fw2, fb2, yws);
  sift_idx_kernel<<<Bc * Nc, 256, 0, stream>>>(sxyz, sidx);
  // OE module 1
  sift_conv1_kernel<<<Bc * Nc / 4, 256, 0, stream>>>(sxyz, sidx, yws, o1w1, o1g1, o1b1, g1o);
  sift_conv23_kernel<<<Bc * Nc / 4, 256, 0, stream>>>(g1o, o1w2, o1g2, o1b2, o1w3, o1g3, o1b3, yws);
  // OE module 2
  sift_conv1_kernel<<<Bc * Nc / 4, 256, 0, stream>>>(sxyz, sidx, yws, o2w1, o2g1, o2b1, g1o);
  sift_conv23_kernel<<<Bc * Nc / 4, 256, 0, stream>>>(g1o, o2w2, o2g2, o2b2, o2w3, o2g3, o2b3, yws);
  transpose_kernel<<<(Bc * Fc * Nc) / 256, 256, 0, stream>>>(yws, (float*)d_out);
}

// Round 6
// 688.302 us; speedup vs baseline: 16.3481x; 2.8476x over previous
//
#include <hip/hip_runtime.h>
#include <hip/hip_bf16.h>
#include <math.h>

// Problem constants (match reference)
constexpr int Bc = 4, Mc = 512, Nc = 1024, Fc = 256;
constexpr int KCc = 16;
constexpr float INFF = 3.0e38f;

typedef __attribute__((ext_vector_type(8))) short short8b;  // 8 bf16 (4 VGPRs)
typedef __attribute__((ext_vector_type(4))) float f32x4;

__device__ __forceinline__ short f2bf(float f) {
  __hip_bfloat16 h = __float2bfloat16(f);
  return *reinterpret_cast<short*>(&h);
}
__device__ __forceinline__ float bf2f(short s) {
  unsigned int u = ((unsigned int)(unsigned short)s) << 16;
  return __uint_as_float(u);
}

__device__ __forceinline__ float blk_sum(float v, float* red) {
  int t = threadIdx.x;
  red[t] = v;
  __syncthreads();
  for (int s = 128; s > 0; s >>= 1) {
    if (t < s) red[t] += red[t + s];
    __syncthreads();
  }
  float r = red[0];
  __syncthreads();
  return r;
}

__device__ __forceinline__ float dot4(float4 a, float4 b) {
  return a.x * b.x + a.y * b.y + a.z * b.z + a.w * b.w;
}

// ---- weight relayout: row-major f32 [rows][K] -> MFMA fragment-order bf16 ----
// dst[((rt*KT + kk)*64 + l)*8 + e] = W[rt*16 + (l&15)][kk*32 + (l>>4)*8 + e], 0-padded K->Kp
__global__ __launch_bounds__(256) void wconv_frag(const float* __restrict__ src,
                                                  short* __restrict__ dst,
                                                  int K, int KT, int n) {
  int i = blockIdx.x * 256 + threadIdx.x;
  if (i >= n) return;
  int e = i & 7, l = (i >> 3) & 63, q = i >> 9;
  int kk = q % KT, rt = q / KT;
  int r = rt * 16 + (l & 15);
  int k = kk * 32 + (l >> 4) * 8 + e;
  dst[i] = (k < K) ? f2bf(src[(size_t)r * K + k]) : (short)0;
}

// A = [-Wk | pw2], rows 256, K=Kp=320 (KT=10)
__global__ __launch_bounds__(256) void wbuild_kpe(const float* __restrict__ wqkv,
                                                  const float* __restrict__ pw2,
                                                  short* __restrict__ dst) {
  int i = blockIdx.x * 256 + threadIdx.x;
  if (i >= 81920) return;
  int e = i & 7, l = (i >> 3) & 63, q = i >> 9;
  int kk = q % 10, rt = q / 10;
  int r = rt * 16 + (l & 15);
  int k = kk * 32 + (l >> 4) * 8 + e;
  float v = (k < 256) ? -wqkv[(size_t)(256 + r) * 256 + k] : pw2[(size_t)r * 64 + (k - 256)];
  dst[i] = f2bf(v);
}
// A = [Wv | pw2]
__global__ __launch_bounds__(256) void wbuild_vpe(const float* __restrict__ wqkv,
                                                  const float* __restrict__ pw2,
                                                  short* __restrict__ dst) {
  int i = blockIdx.x * 256 + threadIdx.x;
  if (i >= 81920) return;
  int e = i & 7, l = (i >> 3) & 63, q = i >> 9;
  int kk = q % 10, rt = q / 10;
  int r = rt * 16 + (l & 15);
  int k = kk * 32 + (l >> 4) * 8 + e;
  float v = (k < 256) ? wqkv[(size_t)(512 + r) * 256 + k] : pw2[(size_t)r * 64 + (k - 256)];
  dst[i] = f2bf(v);
}

// ---- spherical coords of points relative to centroid -> out (B,3,P) ----
__global__ __launch_bounds__(256) void scf_kernel(const float* __restrict__ xyz,
                                                  float* __restrict__ out, int P) {
  __shared__ float red[256];
  int b = blockIdx.x;
  const float* x = xyz + (size_t)b * P * 3;
  float sx = 0.f, sy = 0.f, sz = 0.f;
  for (int i = threadIdx.x; i < P; i += 256) {
    sx += x[3 * i]; sy += x[3 * i + 1]; sz += x[3 * i + 2];
  }
  float mx = blk_sum(sx, red) / (float)P;
  float my = blk_sum(sy, red) / (float)P;
  float mz = blk_sum(sz, red) / (float)P;
  for (int i = threadIdx.x; i < P; i += 256) {
    float a = x[3 * i] - mx, c = x[3 * i + 1] - my, d = x[3 * i + 2] - mz;
    float r = sqrtf(a * a + c * c + d * d + 1e-8f);
    float ct = d / r;
    ct = fminf(1.f, fmaxf(-1.f, ct));
    out[((size_t)b * 3 + 0) * P + i] = r;
    out[((size_t)b * 3 + 1) * P + i] = acosf(ct);
    out[((size_t)b * 3 + 2) * P + i] = atan2f(c, a);
  }
}

// ---- per-point sorted distances to KC nearest neighbors (excl. self) ----
template <int P>
__global__ __launch_bounds__(256) void knn_kernel(const float* __restrict__ xyz,
                                                  float* __restrict__ desc) {
  __shared__ float d2s[P];
  __shared__ float rv[256];
  __shared__ int ri[256];
  int b = blockIdx.x / P, i = blockIdx.x % P;
  const float* x = xyz + (size_t)b * P * 3;
  float xi0 = x[3 * i], xi1 = x[3 * i + 1], xi2 = x[3 * i + 2];
  for (int j = threadIdx.x; j < P; j += 256) {
    float dx = x[3 * j] - xi0, dy = x[3 * j + 1] - xi1, dz = x[3 * j + 2] - xi2;
    d2s[j] = dx * dx + dy * dy + dz * dz;
  }
  __syncthreads();
  for (int round = 0; round < KCc + 1; ++round) {
    float bv = INFF; int bi = P;
    for (int j = threadIdx.x; j < P; j += 256) {
      float v = d2s[j];
      if (v < bv || (v == bv && j < bi)) { bv = v; bi = j; }
    }
    rv[threadIdx.x] = bv; ri[threadIdx.x] = bi;
    __syncthreads();
    for (int s = 128; s > 0; s >>= 1) {
      if (threadIdx.x < s) {
        float v2 = rv[threadIdx.x + s]; int i2 = ri[threadIdx.x + s];
        if (v2 < rv[threadIdx.x] || (v2 == rv[threadIdx.x] && i2 < ri[threadIdx.x])) {
          rv[threadIdx.x] = v2; ri[threadIdx.x] = i2;
        }
      }
      __syncthreads();
    }
    if (threadIdx.x == 0) {
      if (round > 0) desc[((size_t)b * P + i) * KCc + (round - 1)] = sqrtf(rv[0]);
      d2s[ri[0]] = INFF;
    }
    __syncthreads();
  }
}

// ---- candidate pruning: top-24 by bc dist -> top-8 by xyz -> top-4 by scf ----
__global__ __launch_bounds__(256) void select_kernel(
    const float* __restrict__ tbc, const float* __restrict__ sbc,
    const float* __restrict__ txyz, const float* __restrict__ sxyz,
    const float* __restrict__ sd, const float* __restrict__ td,
    int* __restrict__ idx_s) {
  __shared__ float dbc[Mc];
  __shared__ float rv[256];
  __shared__ int ri[256];
  __shared__ int cand[24];
  int b = blockIdx.x / Nc, n = blockIdx.x % Nc;
  const float* sb = sbc + ((size_t)b * Nc + n) * 9;
  float sreg[9];
#pragma unroll
  for (int c = 0; c < 9; ++c) sreg[c] = sb[c];
  for (int m = threadIdx.x; m < Mc; m += 256) {
    const float* tb = tbc + ((size_t)b * Mc + m) * 9;
    float acc = 0.f;
#pragma unroll
    for (int c = 0; c < 9; ++c) { float d = tb[c] - sreg[c]; acc += d * d; }
    dbc[m] = acc;
  }
  __syncthreads();
  for (int round = 0; round < 24; ++round) {
    float bv = INFF; int bi = Mc;
    for (int m = threadIdx.x; m < Mc; m += 256) {
      float v = dbc[m];
      if (v < bv || (v == bv && m < bi)) { bv = v; bi = m; }
    }
    rv[threadIdx.x] = bv; ri[threadIdx.x] = bi;
    __syncthreads();
    for (int s = 128; s > 0; s >>= 1) {
      if (threadIdx.x < s) {
        float v2 = rv[threadIdx.x + s]; int i2 = ri[threadIdx.x + s];
        if (v2 < rv[threadIdx.x] || (v2 == rv[threadIdx.x] && i2 < ri[threadIdx.x])) {
          rv[threadIdx.x] = v2; ri[threadIdx.x] = i2;
        }
      }
      __syncthreads();
    }
    if (threadIdx.x == 0) { cand[round] = ri[0]; dbc[ri[0]] = INFF; }
    __syncthreads();
  }
  if (threadIdx.x == 0) {
    const float* sp = sxyz + ((size_t)b * Nc + n) * 3;
    float sx = sp[0], sy = sp[1], sz = sp[2];
    float dv[24];
    for (int t2 = 0; t2 < 24; ++t2) {
      const float* tp = txyz + ((size_t)b * Mc + cand[t2]) * 3;
      float dx = tp[0] - sx, dy = tp[1] - sy, dz = tp[2] - sz;
      dv[t2] = dx * dx + dy * dy + dz * dz;
    }
    int c8[8]; bool used[24];
    for (int t2 = 0; t2 < 24; ++t2) used[t2] = false;
    for (int r = 0; r < 8; ++r) {
      float bv = INFF; int bt = -1, bm = 0x7fffffff;
      for (int t2 = 0; t2 < 24; ++t2) {
        if (used[t2]) continue;
        int m = cand[t2];
        if (bt < 0 || dv[t2] < bv || (dv[t2] == bv && m < bm)) { bv = dv[t2]; bt = t2; bm = m; }
      }
      used[bt] = true; c8[r] = bm;
    }
    const float* sdp = sd + ((size_t)b * Nc + n) * KCc;
    float sdr[16];
    for (int t2 = 0; t2 < 16; ++t2) sdr[t2] = sdp[t2];
    float dscf[8];
    for (int r = 0; r < 8; ++r) {
      const float* tdp = td + ((size_t)b * Mc + c8[r]) * KCc;
      float acc = 0.f;
      for (int t2 = 0; t2 < 16; ++t2) { float d = sdr[t2] - tdp[t2]; acc += d * d; }
      dscf[r] = acc;
    }
    bool u8[8] = {false, false, false, false, false, false, false, false};
    for (int r = 0; r < 4; ++r) {
      float bv = INFF; int bt = -1, bm = 0x7fffffff;
      for (int t2 = 0; t2 < 8; ++t2) {
        if (u8[t2]) continue;
        if (bt < 0 || dscf[t2] < bv || (dscf[t2] == bv && c8[t2] < bm)) { bv = dscf[t2]; bt = t2; bm = c8[t2]; }
      }
      u8[bt] = true;
      idx_s[(((size_t)b * Nc + n) << 2) + r] = bm;
    }
  }
}

// ---- grouping + 3-layer MLP via bf16 MFMA (frag-order A), 4 tokens/block ----
__global__ __launch_bounds__(256) void mlp_kernel(
    const float* __restrict__ sfeat, const float* __restrict__ tfeat,
    const float* __restrict__ sscf, const float* __restrict__ tscf,
    const int* __restrict__ idx_s,
    const short* __restrict__ w1f, const float* __restrict__ g1, const float* __restrict__ b1,
    const short* __restrict__ w2f, const float* __restrict__ g2, const float* __restrict__ b2,
    const short* __restrict__ w3f, const float* __restrict__ g3, const float* __restrict__ b3,
    short* __restrict__ houtS) {
  __shared__ __align__(16) char smem[34816];
  char* B1 = smem;            // [32 cols][288k] bf16 stride 576B; B3 aliases [0,16384)
  char* B2 = smem + 18432;    // [32 cols][256k] bf16 stride 512B
  __shared__ int ms[16];
  int t = threadIdx.x;
  int tau0 = blockIdx.x * 4;
  int b = tau0 / Nc, n0 = tau0 % Nc;
  if (t < 16) ms[t] = idx_s[(((size_t)b * Nc + n0 + (t >> 2)) << 2) + (t & 3)];
  __syncthreads();
  // NaN-safety: zero k-pad (k 259..287) for ALL cols; zero cols 20..31 (k 0..258).
  // 0*NaN = NaN and relu launders NaN -> 0, so garbage in these bytes silently
  // corrupts real outputs (root cause of the R5 failure).
  for (int z = t; z < 32 * 29; z += 256) {
    int col = z / 29, k = 259 + z % 29;
    *(short*)(B1 + ((col * 576 + 2 * k) ^ ((col & 7) << 4))) = 0;
  }
  for (int z = t; z < 12 * 259; z += 256) {
    int col = 20 + z / 259, k = z % 259;
    *(short*)(B1 + ((col * 576 + 2 * k) ^ ((col & 7) << 4))) = 0;
  }
  for (int s = 0; s < 4; ++s) {
    int n = n0 + s;
    {
      int col = s * 5; int cx = (col & 7) << 4;
      *(short*)(B1 + ((col * 576 + t * 2) ^ cx)) = f2bf(sfeat[((size_t)b * Fc + t) * Nc + n]);
      if (t < 3) *(short*)(B1 + ((col * 576 + (256 + t) * 2) ^ cx)) = f2bf(sscf[((size_t)b * 3 + t) * Nc + n]);
    }
    for (int k = 1; k < 5; ++k) {
      int m = ms[s * 4 + k - 1];
      int col = s * 5 + k; int cx = (col & 7) << 4;
      *(short*)(B1 + ((col * 576 + t * 2) ^ cx)) = f2bf(tfeat[((size_t)b * Fc + t) * Mc + m]);
      if (t < 3) *(short*)(B1 + ((col * 576 + (256 + t) * 2) ^ cx)) = f2bf(tscf[((size_t)b * 3 + t) * Mc + m]);
    }
  }
  __syncthreads();
  int l = t & 63, w = t >> 6, lg = l >> 4, lr = l & 15;
  // GEMM1: rows 256 x K 288 (KT=9)
  {
    f32x4 acc[4][2];
#pragma unroll
    for (int i = 0; i < 4; ++i) { acc[i][0] = (f32x4){0,0,0,0}; acc[i][1] = (f32x4){0,0,0,0}; }
    for (int kk = 0; kk < 9; ++kk) {
      int c1 = 16 + lr;
      short8b b0 = *(const short8b*)(B1 + ((lr * 576 + kk * 64 + lg * 16) ^ ((lr & 7) << 4)));
      short8b bb1 = *(const short8b*)(B1 + ((c1 * 576 + kk * 64 + lg * 16) ^ ((c1 & 7) << 4)));
#pragma unroll
      for (int i = 0; i < 4; ++i) {
        short8b a = *(const short8b*)(w1f + (((size_t)((w * 4 + i) * 9 + kk)) * 64 + l) * 8);
        acc[i][0] = __builtin_amdgcn_mfma_f32_16x16x32_bf16(a, b0, acc[i][0], 0, 0, 0);
        acc[i][1] = __builtin_amdgcn_mfma_f32_16x16x32_bf16(a, bb1, acc[i][1], 0, 0, 0);
      }
    }
    __syncthreads();
#pragma unroll
    for (int i = 0; i < 4; ++i) {
      int r0 = (w * 4 + i) * 16 + lg * 4;
      float4 gg = *(const float4*)(g1 + r0), bs = *(const float4*)(b1 + r0);
#pragma unroll
      for (int ct = 0; ct < 2; ++ct) {
        int col = ct * 16 + lr; int cx = (col & 7) << 4;
        ushort4 hv;
        hv.x = (unsigned short)f2bf(fmaxf(gg.x * acc[i][ct][0] + bs.x, 0.f));
        hv.y = (unsigned short)f2bf(fmaxf(gg.y * acc[i][ct][1] + bs.y, 0.f));
        hv.z = (unsigned short)f2bf(fmaxf(gg.z * acc[i][ct][2] + bs.z, 0.f));
        hv.w = (unsigned short)f2bf(fmaxf(gg.w * acc[i][ct][3] + bs.w, 0.f));
        *(ushort4*)(B2 + ((col * 512 + r0 * 2) ^ cx)) = hv;
      }
    }
  }
  __syncthreads();
  // GEMM2: 256 x 256 (KT=8), B2 -> B3 (alias B1)
  {
    f32x4 acc[4][2];
#pragma unroll
    for (int i = 0; i < 4; ++i) { acc[i][0] = (f32x4){0,0,0,0}; acc[i][1] = (f32x4){0,0,0,0}; }
    for (int kk = 0; kk < 8; ++kk) {
      int c1 = 16 + lr;
      short8b b0 = *(const short8b*)(B2 + ((lr * 512 + kk * 64 + lg * 16) ^ ((lr & 7) << 4)));
      short8b bb1 = *(const short8b*)(B2 + ((c1 * 512 + kk * 64 + lg * 16) ^ ((c1 & 7) << 4)));
#pragma unroll
      for (int i = 0; i < 4; ++i) {
        short8b a = *(const short8b*)(w2f + (((size_t)((w * 4 + i) * 8 + kk)) * 64 + l) * 8);
        acc[i][0] = __builtin_amdgcn_mfma_f32_16x16x32_bf16(a, b0, acc[i][0], 0, 0, 0);
        acc[i][1] = __builtin_amdgcn_mfma_f32_16x16x32_bf16(a, bb1, acc[i][1], 0, 0, 0);
      }
    }
    __syncthreads();
#pragma unroll
    for (int i = 0; i < 4; ++i) {
      int r0 = (w * 4 + i) * 16 + lg * 4;
      float4 gg = *(const float4*)(g2 + r0), bs = *(const float4*)(b2 + r0);
#pragma unroll
      for (int ct = 0; ct < 2; ++ct) {
        int col = ct * 16 + lr; int cx = (col & 7) << 4;
        ushort4 hv;
        hv.x = (unsigned short)f2bf(fmaxf(gg.x * acc[i][ct][0] + bs.x, 0.f));
        hv.y = (unsigned short)f2bf(fmaxf(gg.y * acc[i][ct][1] + bs.y, 0.f));
        hv.z = (unsigned short)f2bf(fmaxf(gg.z * acc[i][ct][2] + bs.z, 0.f));
        hv.w = (unsigned short)f2bf(fmaxf(gg.w * acc[i][ct][3] + bs.w, 0.f));
        *(ushort4*)(B1 + ((col * 512 + r0 * 2) ^ cx)) = hv;
      }
    }
  }
  __syncthreads();
  // GEMM3 -> houtS
  {
    f32x4 acc[4][2];
#pragma unroll
    for (int i = 0; i < 4; ++i) { acc[i][0] = (f32x4){0,0,0,0}; acc[i][1] = (f32x4){0,0,0,0}; }
    for (int kk = 0; kk < 8; ++kk) {
      int c1 = 16 + lr;
      short8b b0 = *(const short8b*)(B1 + ((lr * 512 + kk * 64 + lg * 16) ^ ((lr & 7) << 4)));
      short8b bb1 = *(const short8b*)(B1 + ((c1 * 512 + kk * 64 + lg * 16) ^ ((c1 & 7) << 4)));
#pragma unroll
      for (int i = 0; i < 4; ++i) {
        short8b a = *(const short8b*)(w3f + (((size_t)((w * 4 + i) * 8 + kk)) * 64 + l) * 8);
        acc[i][0] = __builtin_amdgcn_mfma_f32_16x16x32_bf16(a, b0, acc[i][0], 0, 0, 0);
        acc[i][1] = __builtin_amdgcn_mfma_f32_16x16x32_bf16(a, bb1, acc[i][1], 0, 0, 0);
      }
    }
#pragma unroll
    for (int i = 0; i < 4; ++i) {
      int r0 = (w * 4 + i) * 16 + lg * 4;
      float4 gg = *(const float4*)(g3 + r0), bs = *(const float4*)(b3 + r0);
#pragma unroll
      for (int ct = 0; ct < 2; ++ct) {
        int col = ct * 16 + lr;
        if (col < 20) {
          ushort4 hv;
          hv.x = (unsigned short)f2bf(fmaxf(gg.x * acc[i][ct][0] + bs.x, 0.f));
          hv.y = (unsigned short)f2bf(fmaxf(gg.y * acc[i][ct][1] + bs.y, 0.f));
          hv.z = (unsigned short)f2bf(fmaxf(gg.z * acc[i][ct][2] + bs.z, 0.f));
          hv.w = (unsigned short)f2bf(fmaxf(gg.w * acc[i][ct][3] + bs.w, 0.f));
          int s = col / 5, j = col % 5;
          *(ushort4*)(houtS + ((size_t)(tau0 + s) * 5 + j) * 256 + r0) = hv;
        }
      }
    }
  }
}

// ---- point transformer (i=0 only), all-MFMA, 4 tokens/block ----
__global__ __launch_bounds__(256) void attn_kernel(
    const short* __restrict__ hbufS, const int* __restrict__ idx_s,
    const float* __restrict__ sxyz, const float* __restrict__ sbc,
    const float* __restrict__ txyz, const float* __restrict__ tbc,
    const short* __restrict__ aqf, const short* __restrict__ akpef, const short* __restrict__ avpef,
    const float* __restrict__ pw1, const float* __restrict__ pb1, const float* __restrict__ pb2,
    const short* __restrict__ aw1f, const float* __restrict__ ab1,
    const short* __restrict__ aw2f, const float* __restrict__ ab2,
    const float* __restrict__ sfeat,
    const short* __restrict__ fw1f, const float* __restrict__ fg1, const float* __restrict__ fb1,
    const short* __restrict__ fw2f, const float* __restrict__ fb2v,
    float* __restrict__ yout) {
  __shared__ __align__(16) char smem[63744];
  char* Bx = smem;                         // [32 cols][320k] bf16, stride 640B
  char* KB = smem;                         // [32][256k] bf16 stride 512B (after P2)
  char* feaB = smem;                       // [16][256k] (P7+)
  char* vpeB = smem + 20480;               // [32][256k] bf16
  char* feaH = smem + 20480;               // [16][256k] (P8+)
  char* HpB = smem + 36864;                // [32][256k] bf16
  float* simF = (float*)(smem + 36864);    // [20][260] f32
  float* q04 = (float*)(smem + 57664);     // [4][256] f32
  float* pc4 = (float*)(smem + 61760);     // [20][12] f32
  float* red = (float*)(smem + 62720);     // [256] f32
  int t = threadIdx.x;
  int tau0 = blockIdx.x * 4;
  int b = tau0 / Nc, n0 = tau0 % Nc;
  // NaN-safety: zero Bx cols 20..31 entirely
  for (int z = t; z < 12 * 320; z += 256) {
    int col = 20 + z / 320, k = z % 320;
    *(short*)(Bx + ((col * 640 + 2 * k) ^ ((col & 7) << 4))) = 0;
  }
  // P0: x -> Bx cols (k<256), pos vectors -> pc4
  for (int s = 0; s < 4; ++s) {
    const short* hs = hbufS + (size_t)(tau0 + s) * 1280;
#pragma unroll
    for (int j = 0; j < 5; ++j) {
      int col = s * 5 + j; int cx = (col & 7) << 4;
      *(short*)(Bx + ((col * 640 + 2 * t) ^ cx)) = hs[j * 256 + t];
    }
  }
  if (t < 20) {
    int s = t / 5, k = t % 5;
    int n = n0 + s;
    float* pd = pc4 + t * 12;
    if (k == 0) {
      for (int c = 0; c < 3; ++c) pd[c] = sxyz[((size_t)b * Nc + n) * 3 + c];
      for (int c = 0; c < 9; ++c) pd[3 + c] = sbc[((size_t)b * Nc + n) * 9 + c];
    } else {
      int m = idx_s[(((size_t)b * Nc + n) << 2) + (k - 1)];
      for (int c = 0; c < 3; ++c) pd[c] = txyz[((size_t)b * Mc + m) * 3 + c];
      for (int c = 0; c < 9; ++c) pd[3 + c] = tbc[((size_t)b * Mc + m) * 9 + c];
    }
  }
  __syncthreads();
  // P1: pe hidden (relu) -> Bx k = 256+h
  for (int it = t; it < 1280; it += 256) {
    int sj = it >> 6, h = it & 63;
    int s = sj / 5;
    float acc = pb1[h];
    const float* wv = pw1 + h * 12;
    const float* p0 = pc4 + (s * 5) * 12;
    const float* pj = pc4 + sj * 12;
#pragma unroll
    for (int p = 0; p < 12; ++p) acc += wv[p] * (p0[p] - pj[p]);
    int cx = (sj & 7) << 4;
    *(short*)(Bx + ((sj * 640 + 512 + 2 * h) ^ cx)) = f2bf(fmaxf(acc, 0.f));
  }
  __syncthreads();
  int l = t & 63, w = t >> 6, lg = l >> 4, lr = l & 15;
  // P2: three GEMMs over Bx: (-k+pe), (v+pe) [K=320], q [K=256, ct0 only]
  f32x4 sA[4][2], vA[4][2], qA[4];
#pragma unroll
  for (int i = 0; i < 4; ++i) {
    sA[i][0] = (f32x4){0,0,0,0}; sA[i][1] = (f32x4){0,0,0,0};
    vA[i][0] = (f32x4){0,0,0,0}; vA[i][1] = (f32x4){0,0,0,0};
    qA[i] = (f32x4){0,0,0,0};
  }
  for (int kk = 0; kk < 10; ++kk) {
    int c1 = 16 + lr;
    short8b b0 = *(const short8b*)(Bx + ((lr * 640 + kk * 64 + lg * 16) ^ ((lr & 7) << 4)));
    short8b bb1 = *(const short8b*)(Bx + ((c1 * 640 + kk * 64 + lg * 16) ^ ((c1 & 7) << 4)));
#pragma unroll
    for (int i = 0; i < 4; ++i) {
      short8b ak = *(const short8b*)(akpef + (((size_t)((w * 4 + i) * 10 + kk)) * 64 + l) * 8);
      short8b av = *(const short8b*)(avpef + (((size_t)((w * 4 + i) * 10 + kk)) * 64 + l) * 8);
      sA[i][0] = __builtin_amdgcn_mfma_f32_16x16x32_bf16(ak, b0, sA[i][0], 0, 0, 0);
      sA[i][1] = __builtin_amdgcn_mfma_f32_16x16x32_bf16(ak, bb1, sA[i][1], 0, 0, 0);
      vA[i][0] = __builtin_amdgcn_mfma_f32_16x16x32_bf16(av, b0, vA[i][0], 0, 0, 0);
      vA[i][1] = __builtin_amdgcn_mfma_f32_16x16x32_bf16(av, bb1, vA[i][1], 0, 0, 0);
      if (kk < 8) {
        short8b aq = *(const short8b*)(aqf + (((size_t)((w * 4 + i) * 8 + kk)) * 64 + l) * 8);
        qA[i] = __builtin_amdgcn_mfma_f32_16x16x32_bf16(aq, b0, qA[i], 0, 0, 0);
      }
    }
  }
  __syncthreads();
  // P3: epilogue: KB = bf16(shfl(q) + sA + pb2), vpeB = bf16(vA + pb2)
#pragma unroll
  for (int i = 0; i < 4; ++i) {
    int r0 = (w * 4 + i) * 16 + lg * 4;
    float4 pb = *(const float4*)(pb2 + r0);
#pragma unroll
    for (int ct = 0; ct < 2; ++ct) {
      int col = ct * 16 + lr; int cx = (col & 7) << 4;
      int qsrc = (l & 48) | (ct == 0 ? (lr / 5) * 5 : 15);
      float q0v = __shfl(qA[i][0], qsrc);
      float q1v = __shfl(qA[i][1], qsrc);
      float q2v = __shfl(qA[i][2], qsrc);
      float q3v = __shfl(qA[i][3], qsrc);
      ushort4 kv, vv;
      kv.x = (unsigned short)f2bf(q0v + sA[i][ct][0] + pb.x);
      kv.y = (unsigned short)f2bf(q1v + sA[i][ct][1] + pb.y);
      kv.z = (unsigned short)f2bf(q2v + sA[i][ct][2] + pb.z);
      kv.w = (unsigned short)f2bf(q3v + sA[i][ct][3] + pb.w);
      vv.x = (unsigned short)f2bf(vA[i][ct][0] + pb.x);
      vv.y = (unsigned short)f2bf(vA[i][ct][1] + pb.y);
      vv.z = (unsigned short)f2bf(vA[i][ct][2] + pb.z);
      vv.w = (unsigned short)f2bf(vA[i][ct][3] + pb.w);
      *(ushort4*)(KB + ((col * 512 + r0 * 2) ^ cx)) = kv;
      *(ushort4*)(vpeB + ((col * 512 + r0 * 2) ^ cx)) = vv;
    }
  }
  __syncthreads();
  // P4: amlp via MFMA: 4 panels of 256 hidden rows
  f32x4 sacc[4][2];
#pragma unroll
  for (int i = 0; i < 4; ++i) { sacc[i][0] = (f32x4){0,0,0,0}; sacc[i][1] = (f32x4){0,0,0,0}; }
  for (int p = 0; p < 4; ++p) {
    f32x4 hacc[4][2];
#pragma unroll
    for (int i = 0; i < 4; ++i) { hacc[i][0] = (f32x4){0,0,0,0}; hacc[i][1] = (f32x4){0,0,0,0}; }
    for (int kk = 0; kk < 8; ++kk) {
      int c1 = 16 + lr;
      short8b b0 = *(const short8b*)(KB + ((lr * 512 + kk * 64 + lg * 16) ^ ((lr & 7) << 4)));
      short8b bb1 = *(const short8b*)(KB + ((c1 * 512 + kk * 64 + lg * 16) ^ ((c1 & 7) << 4)));
#pragma unroll
      for (int i = 0; i < 4; ++i) {
        int rtg = p * 16 + w * 4 + i;
        short8b a = *(const short8b*)(aw1f + (((size_t)(rtg * 8 + kk)) * 64 + l) * 8);
        hacc[i][0] = __builtin_amdgcn_mfma_f32_16x16x32_bf16(a, b0, hacc[i][0], 0, 0, 0);
        hacc[i][1] = __builtin_amdgcn_mfma_f32_16x16x32_bf16(a, bb1, hacc[i][1], 0, 0, 0);
      }
    }
#pragma unroll
    for (int i = 0; i < 4; ++i) {
      int r0l = (w * 4 + i) * 16 + lg * 4;
      float4 bias = *(const float4*)(ab1 + p * 256 + r0l);
#pragma unroll
      for (int ct = 0; ct < 2; ++ct) {
        int col = ct * 16 + lr; int cx = (col & 7) << 4;
        ushort4 hv;
        hv.x = (unsigned short)f2bf(fmaxf(hacc[i][ct][0] + bias.x, 0.f));
        hv.y = (unsigned short)f2bf(fmaxf(hacc[i][ct][1] + bias.y, 0.f));
        hv.z = (unsigned short)f2bf(fmaxf(hacc[i][ct][2] + bias.z, 0.f));
        hv.w = (unsigned short)f2bf(fmaxf(hacc[i][ct][3] + bias.w, 0.f));
        *(ushort4*)(HpB + ((col * 512 + r0l * 2) ^ cx)) = hv;
      }
    }
    __syncthreads();
    for (int kk = 0; kk < 8; ++kk) {
      int c1 = 16 + lr;
      short8b b0 = *(const short8b*)(HpB + ((lr * 512 + kk * 64 + lg * 16) ^ ((lr & 7) << 4)));
      short8b bb1 = *(const short8b*)(HpB + ((c1 * 512 + kk * 64 + lg * 16) ^ ((c1 & 7) << 4)));
      int kkg = p * 8 + kk;
#pragma unroll
      for (int i = 0; i < 4; ++i) {
        short8b a = *(const short8b*)(aw2f + (((size_t)((w * 4 + i) * 32 + kkg)) * 64 + l) * 8);
        sacc[i][0] = __builtin_amdgcn_mfma_f32_16x16x32_bf16(a, b0, sacc[i][0], 0, 0, 0);
        sacc[i][1] = __builtin_amdgcn_mfma_f32_16x16x32_bf16(a, bb1, sacc[i][1], 0, 0, 0);
      }
    }
    __syncthreads();
  }
  // P5: sim (+ab2) -> simF (cols < 20)
#pragma unroll
  for (int i = 0; i < 4; ++i) {
    int r0 = (w * 4 + i) * 16 + lg * 4;
    float4 bias = *(const float4*)(ab2 + r0);
#pragma unroll
    for (int ct = 0; ct < 2; ++ct) {
      int col = ct * 16 + lr;
      if (col < 20) {
        float4 v;
        v.x = sacc[i][ct][0] + bias.x; v.y = sacc[i][ct][1] + bias.y;
        v.z = sacc[i][ct][2] + bias.z; v.w = sacc[i][ct][3] + bias.w;
        *(float4*)(simF + col * 260 + r0) = v;
      }
    }
  }
  __syncthreads();
  // P6: softmax over j + aggregate + residual + instance norm -> q04
  for (int s = 0; s < 4; ++s) {
    float sv[5], vp[5];
#pragma unroll
    for (int j = 0; j < 5; ++j) {
      int sj = s * 5 + j;
      sv[j] = simF[sj * 260 + t];
      vp[j] = bf2f(*(const short*)(vpeB + ((sj * 512 + 2 * t) ^ ((sj & 7) << 4))));
    }
    float mx = sv[0];
#pragma unroll
    for (int j = 1; j < 5; ++j) mx = fmaxf(mx, sv[j]);
    float ssum = 0.f;
#pragma unroll
    for (int j = 0; j < 5; ++j) { sv[j] = expf(sv[j] - mx); ssum += sv[j]; }
    float inv = 1.f / ssum;
    float agg = 0.f;
#pragma unroll
    for (int j = 0; j < 5; ++j) agg += (sv[j] * inv) * vp[j];
    float ff = agg + sfeat[((size_t)b * Fc + t) * Nc + (n0 + s)];
    float mu = blk_sum(ff, red) * (1.f / 256.f);
    float dfv = ff - mu;
    float var = blk_sum(dfv * dfv, red) * (1.f / 256.f);
    q04[s * 256 + t] = dfv / sqrtf(var + 1e-5f);
  }
  __syncthreads();
  // P7: build feaB (cols 0-3); zero cols 4-15 (NaN safety)
#pragma unroll
  for (int s = 0; s < 4; ++s)
    *(short*)(feaB + ((s * 512 + 2 * t) ^ ((s & 7) << 4))) = f2bf(q04[s * 256 + t]);
  for (int z = t; z < 12 * 256; z += 256) {
    int col = 4 + z / 256, k = z % 256;
    *(short*)(feaB + ((col * 512 + 2 * k) ^ ((col & 7) << 4))) = 0;
  }
  __syncthreads();
  // P8: fea layer 1 (relu(g*acc+b)) -> feaH
  {
    f32x4 acc[4];
#pragma unroll
    for (int i = 0; i < 4; ++i) acc[i] = (f32x4){0,0,0,0};
    for (int kk = 0; kk < 8; ++kk) {
      short8b b0 = *(const short8b*)(feaB + ((lr * 512 + kk * 64 + lg * 16) ^ ((lr & 7) << 4)));
#pragma unroll
      for (int i = 0; i < 4; ++i) {
        short8b a = *(const short8b*)(fw1f + (((size_t)((w * 4 + i) * 8 + kk)) * 64 + l) * 8);
        acc[i] = __builtin_amdgcn_mfma_f32_16x16x32_bf16(a, b0, acc[i], 0, 0, 0);
      }
    }
    __syncthreads();
#pragma unroll
    for (int i = 0; i < 4; ++i) {
      int r0 = (w * 4 + i) * 16 + lg * 4;
      float4 gg = *(const float4*)(fg1 + r0), bs = *(const float4*)(fb1 + r0);
      int cx = (lr & 7) << 4;
      ushort4 hv;
      hv.x = (unsigned short)f2bf(fmaxf(gg.x * acc[i][0] + bs.x, 0.f));
      hv.y = (unsigned short)f2bf(fmaxf(gg.y * acc[i][1] + bs.y, 0.f));
      hv.z = (unsigned short)f2bf(fmaxf(gg.z * acc[i][2] + bs.z, 0.f));
      hv.w = (unsigned short)f2bf(fmaxf(gg.w * acc[i][3] + bs.w, 0.f));
      *(ushort4*)(feaH + ((lr * 512 + r0 * 2) ^ cx)) = hv;
    }
  }
  __syncthreads();
  // P9: fea layer 2 -> y2 into simF cols 0-3
  {
    f32x4 acc[4];
#pragma unroll
    for (int i = 0; i < 4; ++i) acc[i] = (f32x4){0,0,0,0};
    for (int kk = 0; kk < 8; ++kk) {
      short8b b0 = *(const short8b*)(feaH + ((lr * 512 + kk * 64 + lg * 16) ^ ((lr & 7) << 4)));
#pragma unroll
      for (int i = 0; i < 4; ++i) {
        short8b a = *(const short8b*)(fw2f + (((size_t)((w * 4 + i) * 8 + kk)) * 64 + l) * 8);
        acc[i] = __builtin_amdgcn_mfma_f32_16x16x32_bf16(a, b0, acc[i], 0, 0, 0);
      }
    }
#pragma unroll
    for (int i = 0; i < 4; ++i) {
      if (lr < 4) {
        int r0 = (w * 4 + i) * 16 + lg * 4;
        float4 bs = *(const float4*)(fb2v + r0);
        float4 v;
        v.x = acc[i][0] + bs.x; v.y = acc[i][1] + bs.y;
        v.z = acc[i][2] + bs.z; v.w = acc[i][3] + bs.w;
        *(float4*)(simF + lr * 260 + r0) = v;
      }
    }
  }
  __syncthreads();
  // P10: z = y2 + ffn; instance norm; out
  for (int s = 0; s < 4; ++s) {
    float z = simF[s * 260 + t] + q04[s * 256 + t];
    float mu2 = blk_sum(z, red) * (1.f / 256.f);
    float dz = z - mu2;
    float var2 = blk_sum(dz * dz, red) * (1.f / 256.f);
    yout[((size_t)(tau0 + s)) * 256 + t] = dz / sqrtf(var2 + 1e-5f);
  }
}

// ---- PointSIFT: per-octant nearest neighbor within radius ----
__global__ __launch_bounds__(256) void sift_idx_kernel(const float* __restrict__ sxyz,
                                                       int* __restrict__ sidx) {
  __shared__ float sv[256 * 8];
  __shared__ int si[256 * 8];
  int b = blockIdx.x / Nc, i = blockIdx.x % Nc;
  int t = threadIdx.x;
  const float* x = sxyz + (size_t)b * Nc * 3;
  float xi0 = x[3 * i], xi1 = x[3 * i + 1], xi2 = x[3 * i + 2];
  float bv[8]; int bi[8];
#pragma unroll
  for (int o = 0; o < 8; ++o) { bv[o] = INFF; bi[o] = Nc; }
  for (int j = t; j < Nc; j += 256) {
    float dx = x[3 * j] - xi0, dy = x[3 * j + 1] - xi1, dz = x[3 * j + 2] - xi2;
    float d2 = dx * dx + dy * dy + dz * dz;
    if (d2 <= 0.25f && d2 > 0.f) {
      int oc = (dx > 0.f ? 4 : 0) + (dy > 0.f ? 2 : 0) + (dz > 0.f ? 1 : 0);
      if (d2 < bv[oc] || (d2 == bv[oc] && j < bi[oc])) { bv[oc] = d2; bi[oc] = j; }
    }
  }
#pragma unroll
  for (int o = 0; o < 8; ++o) { sv[t * 8 + o] = bv[o]; si[t * 8 + o] = bi[o]; }
  __syncthreads();
  for (int s = 128; s > 0; s >>= 1) {
    if (t < s) {
#pragma unroll
      for (int o = 0; o < 8; ++o) {
        float v2 = sv[(t + s) * 8 + o]; int i2 = si[(t + s) * 8 + o];
        if (v2 < sv[t * 8 + o] || (v2 == sv[t * 8 + o] && i2 < si[t * 8 + o])) {
          sv[t * 8 + o] = v2; si[t * 8 + o] = i2;
        }
      }
    }
    __syncthreads();
  }
  if (t < 8) {
    int j = (sv[t] < INFF) ? si[t] : i;
    sidx[(((size_t)b * Nc + i) << 3) + t] = j;
  }
}

// ---- fused PointSIFT OE module: 3 (1,2)-convs via MFMA, 4 points/block ----
__global__ __launch_bounds__(256) void sift_oe_kernel(
    const float* __restrict__ sxyz, const int* __restrict__ sidx,
    const float* __restrict__ yin,
    const short* __restrict__ w1f, const float* __restrict__ g1, const float* __restrict__ b1,
    const short* __restrict__ w2f, const float* __restrict__ g2, const float* __restrict__ b2,
    const short* __restrict__ w3f, const float* __restrict__ g3, const float* __restrict__ b3,
    float* __restrict__ yout) {
  __shared__ __align__(16) char smem[33792];
  char* B1 = smem;            // [16 cols][544k] bf16, stride 1088B; B3 aliases [0,16384)
  char* B2 = smem + 17408;    // [16 cols][512k] bf16, stride 1024B
  char* B3 = smem;
  __shared__ int js[4][8];
  int t = threadIdx.x;
  int i0 = blockIdx.x * 4;
  int b = i0 / Nc, nb = i0 % Nc;
  if (t < 32) js[t >> 3][t & 7] = sidx[(((size_t)b * Nc + nb + (t >> 3)) << 3) + (t & 7)];
  // NaN-safety: zero k-pad (k 518..543) for all 16 cols
  for (int z = t; z < 16 * 26; z += 256) {
    int col = z / 26, k = 518 + z % 26;
    *(short*)(B1 + ((col * 1088 + 2 * k) ^ ((col & 7) << 4))) = 0;
  }
  __syncthreads();
  // build B1: col = s*4+p, k = 2c+t' (c: 0-2 gxyz, 3-258 feat)
  for (int s = 0; s < 4; ++s) {
    int ii = nb + s;
#pragma unroll
    for (int p = 0; p < 4; ++p) {
      int ja = js[s][2 * p], jb = js[s][2 * p + 1];
      int col = s * 4 + p; int cx = (col & 7) << 4;
      float va = yin[((size_t)b * Nc + ja) * 256 + t];
      float vb = yin[((size_t)b * Nc + jb) * 256 + t];
      unsigned int packed = (unsigned int)(unsigned short)f2bf(va) |
                            ((unsigned int)(unsigned short)f2bf(vb) << 16);
      *(unsigned int*)(B1 + ((col * 1088 + 12 + 4 * t) ^ cx)) = packed;
      if (t < 3) {
        float base = sxyz[((size_t)b * Nc + ii) * 3 + t];
        float ga = sxyz[((size_t)b * Nc + ja) * 3 + t] - base;
        float gb = sxyz[((size_t)b * Nc + jb) * 3 + t] - base;
        unsigned int pg = (unsigned int)(unsigned short)f2bf(ga) |
                          ((unsigned int)(unsigned short)f2bf(gb) << 16);
        *(unsigned int*)(B1 + ((col * 1088 + 4 * t) ^ cx)) = pg;
      }
    }
  }
  __syncthreads();
  int l = t & 63, w = t >> 6, lg = l >> 4, lr = l & 15;
  // GEMM1: 256 x K518 (KT=17) -> B2 in conv2-pair layout
  {
    f32x4 acc[4];
#pragma unroll
    for (int i = 0; i < 4; ++i) acc[i] = (f32x4){0,0,0,0};
    for (int kk = 0; kk < 17; ++kk) {
      short8b b0 = *(const short8b*)(B1 + ((lr * 1088 + kk * 64 + lg * 16) ^ ((lr & 7) << 4)));
#pragma unroll
      for (int i = 0; i < 4; ++i) {
        short8b a = *(const short8b*)(w1f + (((size_t)((w * 4 + i) * 17 + kk)) * 64 + l) * 8);
        acc[i] = __builtin_amdgcn_mfma_f32_16x16x32_bf16(a, b0, acc[i], 0, 0, 0);
      }
    }
    __syncthreads();
    int s = lr >> 2, p = lr & 3, p2 = p >> 1, tp = p & 1;
    int col2 = s * 2 + p2; int cx2 = (col2 & 7) << 4;
#pragma unroll
    for (int i = 0; i < 4; ++i) {
      int r0 = (w * 4 + i) * 16 + lg * 4;
      float4 gg = *(const float4*)(g1 + r0), bs = *(const float4*)(b1 + r0);
      *(short*)(B2 + ((col2 * 1024 + (2 * r0 + tp) * 2) ^ cx2)) =
          f2bf(fmaxf(gg.x * acc[i][0] + bs.x, 0.f));
      *(short*)(B2 + ((col2 * 1024 + (2 * (r0 + 1) + tp) * 2) ^ cx2)) =
          f2bf(fmaxf(gg.y * acc[i][1] + bs.y, 0.f));
      *(short*)(B2 + ((col2 * 1024 + (2 * (r0 + 2) + tp) * 2) ^ cx2)) =
          f2bf(fmaxf(gg.z * acc[i][2] + bs.z, 0.f));
      *(short*)(B2 + ((col2 * 1024 + (2 * (r0 + 3) + tp) * 2) ^ cx2)) =
          f2bf(fmaxf(gg.w * acc[i][3] + bs.w, 0.f));
    }
  }
  __syncthreads();
  // GEMM2: 256 x K512 (KT=16) -> B3 in conv3-pair layout
  {
    f32x4 acc[4];
#pragma unroll
    for (int i = 0; i < 4; ++i) acc[i] = (f32x4){0,0,0,0};
    for (int kk = 0; kk < 16; ++kk) {
      short8b b0 = *(const short8b*)(B2 + ((lr * 1024 + kk * 64 + lg * 16) ^ ((lr & 7) << 4)));
#pragma unroll
      for (int i = 0; i < 4; ++i) {
        short8b a = *(const short8b*)(w2f + (((size_t)((w * 4 + i) * 16 + kk)) * 64 + l) * 8);
        acc[i] = __builtin_amdgcn_mfma_f32_16x16x32_bf16(a, b0, acc[i], 0, 0, 0);
      }
    }
    __syncthreads();
    int s = lr >> 1, tp = lr & 1;
    int col3 = s; int cx3 = (col3 & 7) << 4;
#pragma unroll
    for (int i = 0; i < 4; ++i) {
      int r0 = (w * 4 + i) * 16 + lg * 4;
      float4 gg = *(const float4*)(g2 + r0), bs = *(const float4*)(b2 + r0);
      *(short*)(B3 + ((col3 * 1024 + (2 * r0 + tp) * 2) ^ cx3)) =
          f2bf(fmaxf(gg.x * acc[i][0] + bs.x, 0.f));
      *(short*)(B3 + ((col3 * 1024 + (2 * (r0 + 1) + tp) * 2) ^ cx3)) =
          f2bf(fmaxf(gg.y * acc[i][1] + bs.y, 0.f));
      *(short*)(B3 + ((col3 * 1024 + (2 * (r0 + 2) + tp) * 2) ^ cx3)) =
          f2bf(fmaxf(gg.z * acc[i][2] + bs.z, 0.f));
      *(short*)(B3 + ((col3 * 1024 + (2 * (r0 + 3) + tp) * 2) ^ cx3)) =
          f2bf(fmaxf(gg.w * acc[i][3] + bs.w, 0.f));
    }
  }
  __syncthreads();
  // GEMM3: 256 x K512 -> yout = yin + relu(g3*acc+b3)  (cols 0-3)
  {
    f32x4 acc[4];
#pragma unroll
    for (int i = 0; i < 4; ++i) acc[i] = (f32x4){0,0,0,0};
    for (int kk = 0; kk < 16; ++kk) {
      short8b b0 = *(const short8b*)(B3 + ((lr * 1024 + kk * 64 + lg * 16) ^ ((lr & 7) << 4)));
#pragma unroll
      for (int i = 0; i < 4; ++i) {
        short8b a = *(const short8b*)(w3f + (((size_t)((w * 4 + i) * 16 + kk)) * 64 + l) * 8);
        acc[i] = __builtin_amdgcn_mfma_f32_16x16x32_bf16(a, b0, acc[i], 0, 0, 0);
      }
    }
#pragma unroll
    for (int i = 0; i < 4; ++i) {
      if (lr < 4) {
        int s = lr;
        int r0 = (w * 4 + i) * 16 + lg * 4;
        float4 gg = *(const float4*)(g3 + r0), bs = *(const float4*)(b3 + r0);
        float4 yv = *(const float4*)(yin + ((size_t)(i0 + s)) * 256 + r0);
        float4 ov;
        ov.x = yv.x + fmaxf(gg.x * acc[i][0] + bs.x, 0.f);
        ov.y = yv.y + fmaxf(gg.y * acc[i][1] + bs.y, 0.f);
        ov.z = yv.z + fmaxf(gg.z * acc[i][2] + bs.z, 0.f);
        ov.w = yv.w + fmaxf(gg.w * acc[i][3] + bs.w, 0.f);
        *(float4*)(yout + ((size_t)(i0 + s)) * 256 + r0) = ov;
      }
    }
  }
}

// ---- final transpose (B,N,C) -> (B,C,N) into d_out ----
__global__ __launch_bounds__(256) void transpose_kernel(const float* __restrict__ yin,
                                                        float* __restrict__ out) {
  size_t idx = (size_t)blockIdx.x * 256 + threadIdx.x;
  int n = (int)(idx % Nc);
  size_t r = idx / Nc;
  int c = (int)(r % Fc);
  int b = (int)(r / Fc);
  out[idx] = yin[(((size_t)b * Nc + n) * 256) + c];
}

extern "C" void kernel_launch(void* const* d_in, const int* in_sizes, int n_in,
                              void* d_out, int out_size, void* d_ws, size_t ws_size,
                              hipStream_t stream) {
  (void)in_sizes; (void)n_in; (void)out_size; (void)ws_size;
  const float* tfeat = (const float*)d_in[0];
  const float* sfeat = (const float*)d_in[1];
  const float* txyz  = (const float*)d_in[2];
  const float* sxyz  = (const float*)d_in[3];
  const float* tbc   = (const float*)d_in[4];
  const float* sbc   = (const float*)d_in[5];
  const float* mw1 = (const float*)d_in[6];
  const float* mg1 = (const float*)d_in[7];
  const float* mb1 = (const float*)d_in[8];
  const float* mw2 = (const float*)d_in[9];
  const float* mg2 = (const float*)d_in[10];
  const float* mb2 = (const float*)d_in[11];
  const float* mw3 = (const float*)d_in[12];
  const float* mg3 = (const float*)d_in[13];
  const float* mb3 = (const float*)d_in[14];
  const float* fw1 = (const float*)d_in[15];
  const float* fg1 = (const float*)d_in[16];
  const float* fb1 = (const float*)d_in[17];
  const float* fw2 = (const float*)d_in[18];
  const float* fb2 = (const float*)d_in[19];
  const float* wqkv = (const float*)d_in[20];
  const float* pw1 = (const float*)d_in[21];
  const float* pb1 = (const float*)d_in[22];
  const float* pw2 = (const float*)d_in[23];
  const float* pb2 = (const float*)d_in[24];
  const float* aw1 = (const float*)d_in[25];
  const float* ab1 = (const float*)d_in[26];
  const float* aw2 = (const float*)d_in[27];
  const float* ab2 = (const float*)d_in[28];
  const float* o1w1 = (const float*)d_in[29];
  const float* o1g1 = (const float*)d_in[30];
  const float* o1b1 = (const float*)d_in[31];
  const float* o1w2 = (const float*)d_in[32];
  const float* o1g2 = (const float*)d_in[33];
  const float* o1b2 = (const float*)d_in[34];
  const float* o1w3 = (const float*)d_in[35];
  const float* o1g3 = (const float*)d_in[36];
  const float* o1b3 = (const float*)d_in[37];
  const float* o2w1 = (const float*)d_in[38];
  const float* o2g1 = (const float*)d_in[39];
  const float* o2b1 = (const float*)d_in[40];
  const float* o2w2 = (const float*)d_in[41];
  const float* o2g2 = (const float*)d_in[42];
  const float* o2b2 = (const float*)d_in[43];
  const float* o2w3 = (const float*)d_in[44];
  const float* o2g3 = (const float*)d_in[45];
  const float* o2b3 = (const float*)d_in[46];

  // workspace layout
  float* ws = (float*)d_ws;
  float* sd   = ws;                      // B*N*16 f32
  float* td   = sd + 65536;              // B*M*16
  float* sscf = td + 32768;              // B*3*N
  float* tscf = sscf + 12288;            // B*3*M
  int*   idxs = (int*)(tscf + 6144);     // B*N*4 ints
  int*   sidx = idxs + 16384;            // B*N*8 ints
  float* yws  = (float*)(sidx + 32768);  // B*N*256 f32
  short* sb   = (short*)(yws + 1048576);
  short* hbufS = sb;                     // 5,242,880 (dead after attn; ybuf2 aliases)
  short* mw1f  = sb + 5242880;           // 73,728
  short* mw2f  = mw1f + 73728;           // 65,536
  short* mw3f  = mw2f + 65536;           // 65,536
  short* aqf   = mw3f + 65536;           // 65,536
  short* akpef = aqf + 65536;            // 81,920
  short* avpef = akpef + 81920;          // 81,920
  short* aw1f  = avpef + 81920;          // 262,144
  short* aw2f  = aw1f + 262144;          // 262,144
  short* fw1f  = aw2f + 262144;          // 65,536
  short* fw2f  = fw1f + 65536;           // 65,536
  short* o1w1f = fw2f + 65536;           // 139,264
  short* o1w2f = o1w1f + 139264;         // 131,072
  short* o1w3f = o1w2f + 131072;         // 131,072
  short* o2w1f = o1w3f + 131072;         // 139,264
  short* o2w2f = o2w1f + 139264;         // 131,072
  short* o2w3f = o2w2f + 131072;         // 131,072
  float* ybuf2 = (float*)sb;             // sift ping-pong, aliases hbufS

  // weight relayout (re-run every launch, deterministic)
  wconv_frag<<<288, 256, 0, stream>>>(mw1, mw1f, 259, 9, 73728);
  wconv_frag<<<256, 256, 0, stream>>>(mw2, mw2f, 256, 8, 65536);
  wconv_frag<<<256, 256, 0, stream>>>(mw3, mw3f, 256, 8, 65536);
  wconv_frag<<<256, 256, 0, stream>>>(wqkv, aqf, 256, 8, 65536);
  wbuild_kpe<<<320, 256, 0, stream>>>(wqkv, pw2, akpef);
  wbuild_vpe<<<320, 256, 0, stream>>>(wqkv, pw2, avpef);
  wconv_frag<<<1024, 256, 0, stream>>>(aw1, aw1f, 256, 8, 262144);
  wconv_frag<<<1024, 256, 0, stream>>>(aw2, aw2f, 1024, 32, 262144);
  wconv_frag<<<256, 256, 0, stream>>>(fw1, fw1f, 256, 8, 65536);
  wconv_frag<<<256, 256, 0, stream>>>(fw2, fw2f, 256, 8, 65536);
  wconv_frag<<<544, 256, 0, stream>>>(o1w1, o1w1f, 518, 17, 139264);
  wconv_frag<<<512, 256, 0, stream>>>(o1w2, o1w2f, 512, 16, 131072);
  wconv_frag<<<512, 256, 0, stream>>>(o1w3, o1w3f, 512, 16, 131072);
  wconv_frag<<<544, 256, 0, stream>>>(o2w1, o2w1f, 518, 17, 139264);
  wconv_frag<<<512, 256, 0, stream>>>(o2w2, o2w2f, 512, 16, 131072);
  wconv_frag<<<512, 256, 0, stream>>>(o2w3, o2w3f, 512, 16, 131072);

  scf_kernel<<<Bc, 256, 0, stream>>>(sxyz, sscf, Nc);
  scf_kernel<<<Bc, 256, 0, stream>>>(txyz, tscf, Mc);
  knn_kernel<Nc><<<Bc * Nc, 256, 0, stream>>>(sxyz, sd);
  knn_kernel<Mc><<<Bc * Mc, 256, 0, stream>>>(txyz, td);
  select_kernel<<<Bc * Nc, 256, 0, stream>>>(tbc, sbc, txyz, sxyz, sd, td, idxs);
  mlp_kernel<<<Bc * Nc / 4, 256, 0, stream>>>(sfeat, tfeat, sscf, tscf, idxs,
                                              mw1f, mg1, mb1, mw2f, mg2, mb2,
                                              mw3f, mg3, mb3, hbufS);
  attn_kernel<<<Bc * Nc / 4, 256, 0, stream>>>(hbufS, idxs, sxyz, sbc, txyz, tbc,
                                               aqf, akpef, avpef, pw1, pb1, pb2,
                                               aw1f, ab1, aw2f, ab2,
                                               sfeat, fw1f, fg1, fb1, fw2f, fb2, yws);
  sift_idx_kernel<<<Bc * Nc, 256, 0, stream>>>(sxyz, sidx);
  // OE module 1: yws -> ybuf2 ; module 2: ybuf2 -> yws (ping-pong, no RW race)
  sift_oe_kernel<<<Bc * Nc / 4, 256, 0, stream>>>(sxyz, sidx, yws,
                                                  o1w1f, o1g1, o1b1, o1w2f, o1g2, o1b2,
                                                  o1w3f, o1g3, o1b3, ybuf2);
  sift_oe_kernel<<<Bc * Nc / 4, 256, 0, stream>>>(sxyz, sidx, ybuf2,
                                                  o2w1f, o2g1, o2b1, o2w2f, o2g2, o2b2,
                                                  o2w3f, o2g3, o2b3, yws);
  transpose_kernel<<<(Bc * Fc * Nc) / 256, 256, 0, stream>>>(yws, (float*)d_out);
}

// Round 7
// 577.468 us; speedup vs baseline: 19.4858x; 1.1919x over previous
//
#include <hip/hip_runtime.h>
#include <hip/hip_bf16.h>
#include <math.h>

// Problem constants (match reference)
constexpr int Bc = 4, Mc = 512, Nc = 1024, Fc = 256;
constexpr int KCc = 16;
constexpr float INFF = 3.0e38f;

typedef __attribute__((ext_vector_type(8))) short short8b;  // 8 bf16 (4 VGPRs)
typedef __attribute__((ext_vector_type(4))) float f32x4;

__device__ __forceinline__ short f2bf(float f) {
  __hip_bfloat16 h = __float2bfloat16(f);
  return *reinterpret_cast<short*>(&h);
}
__device__ __forceinline__ float bf2f(short s) {
  unsigned int u = ((unsigned int)(unsigned short)s) << 16;
  return __uint_as_float(u);
}
__device__ __forceinline__ unsigned long long umin64(unsigned long long a, unsigned long long b) {
  return a < b ? a : b;
}

__device__ __forceinline__ float blk_sum(float v, float* red) {
  int t = threadIdx.x;
  red[t] = v;
  __syncthreads();
  for (int s = 128; s > 0; s >>= 1) {
    if (t < s) red[t] += red[t + s];
    __syncthreads();
  }
  float r = red[0];
  __syncthreads();
  return r;
}

// ---- merged weight relayout: 16 jobs, one kernel ----
// dst region is contiguous in d_ws in job order. Jobs 4/5 are the fused
// [-Wk|pw2] / [Wv|pw2] builds; the rest are plain frag-order conversions.
struct WSrcs { const float* p[16]; };
__global__ __launch_bounds__(256) void wconv_all(WSrcs s, const float* __restrict__ pw2,
                                                 short* __restrict__ dstbase) {
  const int ofs[16] = {0, 73728, 139264, 204800, 270336, 352256, 434176, 696320,
                       958464, 1024000, 1089536, 1228800, 1359872, 1490944, 1630208, 1761280};
  const int Kt[16]  = {259, 256, 256, 256, 320, 320, 256, 1024, 256, 256, 518, 512, 512, 518, 512, 512};
  const int KTt[16] = {9, 8, 8, 8, 10, 10, 8, 32, 8, 8, 17, 16, 16, 17, 16, 16};
  int gi = blockIdx.x * 256 + threadIdx.x;
  if (gi >= 1892352) return;
  int job = 0;
#pragma unroll
  for (int j2 = 1; j2 < 16; ++j2)
    if (gi >= ofs[j2]) job = j2;
  int i = gi - ofs[job];
  int K = Kt[job], KT = KTt[job];
  int e = i & 7, l = (i >> 3) & 63, q = i >> 9;
  int kk = q % KT, rt = q / KT;
  int r = rt * 16 + (l & 15);
  int k = kk * 32 + (l >> 4) * 8 + e;
  float v;
  if (job == 4)
    v = (k < 256) ? -s.p[4][(size_t)(256 + r) * 256 + k] : pw2[(size_t)r * 64 + (k - 256)];
  else if (job == 5)
    v = (k < 256) ? s.p[5][(size_t)(512 + r) * 256 + k] : pw2[(size_t)r * 64 + (k - 256)];
  else
    v = (k < K) ? s.p[job][(size_t)r * K + k] : 0.f;
  dstbase[gi] = f2bf(v);
}

// ---- spherical coords of points relative to centroid -> out (B,3,P) ----
__global__ __launch_bounds__(256) void scf_kernel(const float* __restrict__ xyz,
                                                  float* __restrict__ out, int P) {
  __shared__ float red[256];
  int b = blockIdx.x;
  const float* x = xyz + (size_t)b * P * 3;
  float sx = 0.f, sy = 0.f, sz = 0.f;
  for (int i = threadIdx.x; i < P; i += 256) {
    sx += x[3 * i]; sy += x[3 * i + 1]; sz += x[3 * i + 2];
  }
  float mx = blk_sum(sx, red) / (float)P;
  float my = blk_sum(sy, red) / (float)P;
  float mz = blk_sum(sz, red) / (float)P;
  for (int i = threadIdx.x; i < P; i += 256) {
    float a = x[3 * i] - mx, c = x[3 * i + 1] - my, d = x[3 * i + 2] - mz;
    float r = sqrtf(a * a + c * c + d * d + 1e-8f);
    float ct = d / r;
    ct = fminf(1.f, fmaxf(-1.f, ct));
    out[((size_t)b * 3 + 0) * P + i] = r;
    out[((size_t)b * 3 + 1) * P + i] = acosf(ct);
    out[((size_t)b * 3 + 2) * P + i] = atan2f(c, a);
  }
}

// ---- KNN descriptor via shfl-butterfly argmin, register-resident d2 ----
// key = (f32bits(d2) << 32) | idx : u64-min == (min d2, tiebreak min idx)
template <int P>
__global__ __launch_bounds__(256) void knn_kernel(const float* __restrict__ xyz,
                                                  float* __restrict__ desc) {
  constexpr int E = P / 256;
  __shared__ unsigned long long red2[8];
  int b = blockIdx.x / P, i = blockIdx.x % P;
  int t = threadIdx.x;
  const float* x = xyz + (size_t)b * P * 3;
  float xi0 = x[3 * i], xi1 = x[3 * i + 1], xi2 = x[3 * i + 2];
  float d2r[E];
#pragma unroll
  for (int q = 0; q < E; ++q) {
    int j = t + q * 256;
    float dx = x[3 * j] - xi0, dy = x[3 * j + 1] - xi1, dz = x[3 * j + 2] - xi2;
    d2r[q] = dx * dx + dy * dy + dz * dz;
  }
  for (int round = 0; round < KCc + 1; ++round) {
    unsigned long long k = ~0ULL;
#pragma unroll
    for (int q = 0; q < E; ++q) {
      unsigned long long c =
          ((unsigned long long)__float_as_uint(d2r[q]) << 32) | (unsigned)(t + q * 256);
      k = umin64(k, c);
    }
#pragma unroll
    for (int m = 1; m < 64; m <<= 1) k = umin64(k, __shfl_xor(k, m));
    int pp = (round & 1) << 2;
    if ((t & 63) == 0) red2[pp | (t >> 6)] = k;
    __syncthreads();
    unsigned long long r = umin64(umin64(red2[pp], red2[pp | 1]),
                                  umin64(red2[pp | 2], red2[pp | 3]));
    int widx = (int)(unsigned)r;
    if (round > 0 && t == 0)
      desc[((size_t)b * P + i) * KCc + (round - 1)] = sqrtf(__uint_as_float((unsigned)(r >> 32)));
#pragma unroll
    for (int q = 0; q < E; ++q)
      if (widx == t + q * 256) d2r[q] = INFF;
  }
}

// ---- candidate pruning: top-24 by bc dist (shfl argmin) -> top-8 xyz -> top-4 scf ----
__global__ __launch_bounds__(256) void select_kernel(
    const float* __restrict__ tbc, const float* __restrict__ sbc,
    const float* __restrict__ txyz, const float* __restrict__ sxyz,
    const float* __restrict__ sd, const float* __restrict__ td,
    int* __restrict__ idx_s) {
  __shared__ unsigned long long red2[8];
  __shared__ int cand[24];
  int b = blockIdx.x / Nc, n = blockIdx.x % Nc;
  int t = threadIdx.x;
  const float* sb = sbc + ((size_t)b * Nc + n) * 9;
  float sreg[9];
#pragma unroll
  for (int c = 0; c < 9; ++c) sreg[c] = sb[c];
  float d2r[2];
#pragma unroll
  for (int q = 0; q < 2; ++q) {
    int m = t + q * 256;
    const float* tb = tbc + ((size_t)b * Mc + m) * 9;
    float acc = 0.f;
#pragma unroll
    for (int c = 0; c < 9; ++c) { float d = tb[c] - sreg[c]; acc += d * d; }
    d2r[q] = acc;
  }
  for (int round = 0; round < 24; ++round) {
    unsigned long long k = ~0ULL;
#pragma unroll
    for (int q = 0; q < 2; ++q) {
      unsigned long long c =
          ((unsigned long long)__float_as_uint(d2r[q]) << 32) | (unsigned)(t + q * 256);
      k = umin64(k, c);
    }
#pragma unroll
    for (int m = 1; m < 64; m <<= 1) k = umin64(k, __shfl_xor(k, m));
    int pp = (round & 1) << 2;
    if ((t & 63) == 0) red2[pp | (t >> 6)] = k;
    __syncthreads();
    unsigned long long r = umin64(umin64(red2[pp], red2[pp | 1]),
                                  umin64(red2[pp | 2], red2[pp | 3]));
    int widx = (int)(unsigned)r;
    if (t == 0) cand[round] = widx;
#pragma unroll
    for (int q = 0; q < 2; ++q)
      if (widx == t + q * 256) d2r[q] = INFF;
  }
  if (t == 0) {
    const float* sp = sxyz + ((size_t)b * Nc + n) * 3;
    float sx = sp[0], sy = sp[1], sz = sp[2];
    float dv[24];
    for (int t2 = 0; t2 < 24; ++t2) {
      const float* tp = txyz + ((size_t)b * Mc + cand[t2]) * 3;
      float dx = tp[0] - sx, dy = tp[1] - sy, dz = tp[2] - sz;
      dv[t2] = dx * dx + dy * dy + dz * dz;
    }
    int c8[8]; bool used[24];
    for (int t2 = 0; t2 < 24; ++t2) used[t2] = false;
    for (int r = 0; r < 8; ++r) {
      float bv = INFF; int bt = -1, bm = 0x7fffffff;
      for (int t2 = 0; t2 < 24; ++t2) {
        if (used[t2]) continue;
        int m = cand[t2];
        if (bt < 0 || dv[t2] < bv || (dv[t2] == bv && m < bm)) { bv = dv[t2]; bt = t2; bm = m; }
      }
      used[bt] = true; c8[r] = bm;
    }
    const float* sdp = sd + ((size_t)b * Nc + n) * KCc;
    float sdr[16];
    for (int t2 = 0; t2 < 16; ++t2) sdr[t2] = sdp[t2];
    float dscf[8];
    for (int r = 0; r < 8; ++r) {
      const float* tdp = td + ((size_t)b * Mc + c8[r]) * KCc;
      float acc = 0.f;
      for (int t2 = 0; t2 < 16; ++t2) { float d = sdr[t2] - tdp[t2]; acc += d * d; }
      dscf[r] = acc;
    }
    bool u8[8] = {false, false, false, false, false, false, false, false};
    for (int r = 0; r < 4; ++r) {
      float bv = INFF; int bt = -1, bm = 0x7fffffff;
      for (int t2 = 0; t2 < 8; ++t2) {
        if (u8[t2]) continue;
        if (bt < 0 || dscf[t2] < bv || (dscf[t2] == bv && c8[t2] < bm)) { bv = dscf[t2]; bt = t2; bm = c8[t2]; }
      }
      u8[bt] = true;
      idx_s[(((size_t)b * Nc + n) << 2) + r] = bm;
    }
  }
}

// ---- grouping + 3-layer MLP via bf16 MFMA (frag-order A), 4 tokens/block ----
__global__ __launch_bounds__(256) void mlp_kernel(
    const float* __restrict__ sfeat, const float* __restrict__ tfeat,
    const float* __restrict__ sscf, const float* __restrict__ tscf,
    const int* __restrict__ idx_s,
    const short* __restrict__ w1f, const float* __restrict__ g1, const float* __restrict__ b1,
    const short* __restrict__ w2f, const float* __restrict__ g2, const float* __restrict__ b2,
    const short* __restrict__ w3f, const float* __restrict__ g3, const float* __restrict__ b3,
    short* __restrict__ houtS) {
  __shared__ __align__(16) char smem[34816];
  char* B1 = smem;            // [32 cols][288k] bf16 stride 576B; B3 aliases [0,16384)
  char* B2 = smem + 18432;    // [32 cols][256k] bf16 stride 512B
  __shared__ int ms[16];
  int t = threadIdx.x;
  int tau0 = blockIdx.x * 4;
  int b = tau0 / Nc, n0 = tau0 % Nc;
  if (t < 16) ms[t] = idx_s[(((size_t)b * Nc + n0 + (t >> 2)) << 2) + (t & 3)];
  __syncthreads();
  // NaN-safety: zero k-pad (k 259..287) for ALL cols; zero cols 20..31 (k 0..258).
  for (int z = t; z < 32 * 29; z += 256) {
    int col = z / 29, k = 259 + z % 29;
    *(short*)(B1 + ((col * 576 + 2 * k) ^ ((col & 7) << 4))) = 0;
  }
  for (int z = t; z < 12 * 259; z += 256) {
    int col = 20 + z / 259, k = z % 259;
    *(short*)(B1 + ((col * 576 + 2 * k) ^ ((col & 7) << 4))) = 0;
  }
  for (int s = 0; s < 4; ++s) {
    int n = n0 + s;
    {
      int col = s * 5; int cx = (col & 7) << 4;
      *(short*)(B1 + ((col * 576 + t * 2) ^ cx)) = f2bf(sfeat[((size_t)b * Fc + t) * Nc + n]);
      if (t < 3) *(short*)(B1 + ((col * 576 + (256 + t) * 2) ^ cx)) = f2bf(sscf[((size_t)b * 3 + t) * Nc + n]);
    }
    for (int k = 1; k < 5; ++k) {
      int m = ms[s * 4 + k - 1];
      int col = s * 5 + k; int cx = (col & 7) << 4;
      *(short*)(B1 + ((col * 576 + t * 2) ^ cx)) = f2bf(tfeat[((size_t)b * Fc + t) * Mc + m]);
      if (t < 3) *(short*)(B1 + ((col * 576 + (256 + t) * 2) ^ cx)) = f2bf(tscf[((size_t)b * 3 + t) * Mc + m]);
    }
  }
  __syncthreads();
  int l = t & 63, w = t >> 6, lg = l >> 4, lr = l & 15;
  // GEMM1: rows 256 x K 288 (KT=9)
  {
    f32x4 acc[4][2];
#pragma unroll
    for (int i = 0; i < 4; ++i) { acc[i][0] = (f32x4){0,0,0,0}; acc[i][1] = (f32x4){0,0,0,0}; }
    for (int kk = 0; kk < 9; ++kk) {
      int c1 = 16 + lr;
      short8b b0 = *(const short8b*)(B1 + ((lr * 576 + kk * 64 + lg * 16) ^ ((lr & 7) << 4)));
      short8b bb1 = *(const short8b*)(B1 + ((c1 * 576 + kk * 64 + lg * 16) ^ ((c1 & 7) << 4)));
#pragma unroll
      for (int i = 0; i < 4; ++i) {
        short8b a = *(const short8b*)(w1f + (((size_t)((w * 4 + i) * 9 + kk)) * 64 + l) * 8);
        acc[i][0] = __builtin_amdgcn_mfma_f32_16x16x32_bf16(a, b0, acc[i][0], 0, 0, 0);
        acc[i][1] = __builtin_amdgcn_mfma_f32_16x16x32_bf16(a, bb1, acc[i][1], 0, 0, 0);
      }
    }
    __syncthreads();
#pragma unroll
    for (int i = 0; i < 4; ++i) {
      int r0 = (w * 4 + i) * 16 + lg * 4;
      float4 gg = *(const float4*)(g1 + r0), bs = *(const float4*)(b1 + r0);
#pragma unroll
      for (int ct = 0; ct < 2; ++ct) {
        int col = ct * 16 + lr; int cx = (col & 7) << 4;
        ushort4 hv;
        hv.x = (unsigned short)f2bf(fmaxf(gg.x * acc[i][ct][0] + bs.x, 0.f));
        hv.y = (unsigned short)f2bf(fmaxf(gg.y * acc[i][ct][1] + bs.y, 0.f));
        hv.z = (unsigned short)f2bf(fmaxf(gg.z * acc[i][ct][2] + bs.z, 0.f));
        hv.w = (unsigned short)f2bf(fmaxf(gg.w * acc[i][ct][3] + bs.w, 0.f));
        *(ushort4*)(B2 + ((col * 512 + r0 * 2) ^ cx)) = hv;
      }
    }
  }
  __syncthreads();
  // GEMM2: 256 x 256 (KT=8), B2 -> B3 (alias B1)
  {
    f32x4 acc[4][2];
#pragma unroll
    for (int i = 0; i < 4; ++i) { acc[i][0] = (f32x4){0,0,0,0}; acc[i][1] = (f32x4){0,0,0,0}; }
    for (int kk = 0; kk < 8; ++kk) {
      int c1 = 16 + lr;
      short8b b0 = *(const short8b*)(B2 + ((lr * 512 + kk * 64 + lg * 16) ^ ((lr & 7) << 4)));
      short8b bb1 = *(const short8b*)(B2 + ((c1 * 512 + kk * 64 + lg * 16) ^ ((c1 & 7) << 4)));
#pragma unroll
      for (int i = 0; i < 4; ++i) {
        short8b a = *(const short8b*)(w2f + (((size_t)((w * 4 + i) * 8 + kk)) * 64 + l) * 8);
        acc[i][0] = __builtin_amdgcn_mfma_f32_16x16x32_bf16(a, b0, acc[i][0], 0, 0, 0);
        acc[i][1] = __builtin_amdgcn_mfma_f32_16x16x32_bf16(a, bb1, acc[i][1], 0, 0, 0);
      }
    }
    __syncthreads();
#pragma unroll
    for (int i = 0; i < 4; ++i) {
      int r0 = (w * 4 + i) * 16 + lg * 4;
      float4 gg = *(const float4*)(g2 + r0), bs = *(const float4*)(b2 + r0);
#pragma unroll
      for (int ct = 0; ct < 2; ++ct) {
        int col = ct * 16 + lr; int cx = (col & 7) << 4;
        ushort4 hv;
        hv.x = (unsigned short)f2bf(fmaxf(gg.x * acc[i][ct][0] + bs.x, 0.f));
        hv.y = (unsigned short)f2bf(fmaxf(gg.y * acc[i][ct][1] + bs.y, 0.f));
        hv.z = (unsigned short)f2bf(fmaxf(gg.z * acc[i][ct][2] + bs.z, 0.f));
        hv.w = (unsigned short)f2bf(fmaxf(gg.w * acc[i][ct][3] + bs.w, 0.f));
        *(ushort4*)(B1 + ((col * 512 + r0 * 2) ^ cx)) = hv;
      }
    }
  }
  __syncthreads();
  // GEMM3 -> houtS
  {
    f32x4 acc[4][2];
#pragma unroll
    for (int i = 0; i < 4; ++i) { acc[i][0] = (f32x4){0,0,0,0}; acc[i][1] = (f32x4){0,0,0,0}; }
    for (int kk = 0; kk < 8; ++kk) {
      int c1 = 16 + lr;
      short8b b0 = *(const short8b*)(B1 + ((lr * 512 + kk * 64 + lg * 16) ^ ((lr & 7) << 4)));
      short8b bb1 = *(const short8b*)(B1 + ((c1 * 512 + kk * 64 + lg * 16) ^ ((c1 & 7) << 4)));
#pragma unroll
      for (int i = 0; i < 4; ++i) {
        short8b a = *(const short8b*)(w3f + (((size_t)((w * 4 + i) * 8 + kk)) * 64 + l) * 8);
        acc[i][0] = __builtin_amdgcn_mfma_f32_16x16x32_bf16(a, b0, acc[i][0], 0, 0, 0);
        acc[i][1] = __builtin_amdgcn_mfma_f32_16x16x32_bf16(a, bb1, acc[i][1], 0, 0, 0);
      }
    }
#pragma unroll
    for (int i = 0; i < 4; ++i) {
      int r0 = (w * 4 + i) * 16 + lg * 4;
      float4 gg = *(const float4*)(g3 + r0), bs = *(const float4*)(b3 + r0);
#pragma unroll
      for (int ct = 0; ct < 2; ++ct) {
        int col = ct * 16 + lr;
        if (col < 20) {
          ushort4 hv;
          hv.x = (unsigned short)f2bf(fmaxf(gg.x * acc[i][ct][0] + bs.x, 0.f));
          hv.y = (unsigned short)f2bf(fmaxf(gg.y * acc[i][ct][1] + bs.y, 0.f));
          hv.z = (unsigned short)f2bf(fmaxf(gg.z * acc[i][ct][2] + bs.z, 0.f));
          hv.w = (unsigned short)f2bf(fmaxf(gg.w * acc[i][ct][3] + bs.w, 0.f));
          int s = col / 5, j = col % 5;
          *(ushort4*)(houtS + ((size_t)(tau0 + s) * 5 + j) * 256 + r0) = hv;
        }
      }
    }
  }
}

// ---- point transformer (i=0 only), all-MFMA, 4 tokens/block, 52KB LDS ----
__global__ __launch_bounds__(256) void attn_kernel(
    const short* __restrict__ hbufS, const int* __restrict__ idx_s,
    const float* __restrict__ sxyz, const float* __restrict__ sbc,
    const float* __restrict__ txyz, const float* __restrict__ tbc,
    const short* __restrict__ aqf, const short* __restrict__ akpef, const short* __restrict__ avpef,
    const float* __restrict__ pw1, const float* __restrict__ pb1, const float* __restrict__ pb2,
    const short* __restrict__ aw1f, const float* __restrict__ ab1,
    const short* __restrict__ aw2f, const float* __restrict__ ab2,
    const float* __restrict__ sfeat,
    const short* __restrict__ fw1f, const float* __restrict__ fg1, const float* __restrict__ fb1,
    const short* __restrict__ fw2f, const float* __restrict__ fb2v,
    float* __restrict__ yout) {
  __shared__ __align__(16) char smem[53248];
  char* Bx   = smem;                      // [32][640]  P0-P2
  char* vpeB = smem;                      // [20][512]  P3..P6 (cols<20, overlays dead Bx)
  float* q04 = (float*)(smem + 10240);    // [4][256] f32  P6..P10
  char* feaB = smem + 14336;              // [16][512]  P7-P8
  char* feaH = smem + 22528;              // [16][512]  P8-P9
  float* y2F = (float*)(smem + 30720);    // [4][260] f32  P9-P10
  char* KB   = smem + 20480;              // [32][512]  P3-P4
  char* HpB  = smem + 36864;              // [32][512]  P4
  char* simS = smem + 36864;              // [20][528B] bf16  P5-P6 (overlays dead HpB)
  float* pc4 = (float*)(smem + 47424);    // [20][12]   P0-P1
  float* redf = (float*)(smem + 48384);   // [32] f32   P6,P10
  int t = threadIdx.x;
  int tau0 = blockIdx.x * 4;
  int b = tau0 / Nc, n0 = tau0 % Nc;
  // NaN-safety: zero Bx cols 20..31 entirely
  for (int z = t; z < 12 * 320; z += 256) {
    int col = 20 + z / 320, k = z % 320;
    *(short*)(Bx + ((col * 640 + 2 * k) ^ ((col & 7) << 4))) = 0;
  }
  // P0: x -> Bx cols (k<256), pos vectors -> pc4
  for (int s = 0; s < 4; ++s) {
    const short* hs = hbufS + (size_t)(tau0 + s) * 1280;
#pragma unroll
    for (int j = 0; j < 5; ++j) {
      int col = s * 5 + j; int cx = (col & 7) << 4;
      *(short*)(Bx + ((col * 640 + 2 * t) ^ cx)) = hs[j * 256 + t];
    }
  }
  if (t < 20) {
    int s = t / 5, k = t % 5;
    int n = n0 + s;
    float* pd = pc4 + t * 12;
    if (k == 0) {
      for (int c = 0; c < 3; ++c) pd[c] = sxyz[((size_t)b * Nc + n) * 3 + c];
      for (int c = 0; c < 9; ++c) pd[3 + c] = sbc[((size_t)b * Nc + n) * 9 + c];
    } else {
      int m = idx_s[(((size_t)b * Nc + n) << 2) + (k - 1)];
      for (int c = 0; c < 3; ++c) pd[c] = txyz[((size_t)b * Mc + m) * 3 + c];
      for (int c = 0; c < 9; ++c) pd[3 + c] = tbc[((size_t)b * Mc + m) * 9 + c];
    }
  }
  __syncthreads();
  // P1: pe hidden (relu) -> Bx k = 256+h
  for (int it = t; it < 1280; it += 256) {
    int sj = it >> 6, h = it & 63;
    int s = sj / 5;
    float acc = pb1[h];
    const float* wv = pw1 + h * 12;
    const float* p0 = pc4 + (s * 5) * 12;
    const float* pj = pc4 + sj * 12;
#pragma unroll
    for (int p = 0; p < 12; ++p) acc += wv[p] * (p0[p] - pj[p]);
    int cx = (sj & 7) << 4;
    *(short*)(Bx + ((sj * 640 + 512 + 2 * h) ^ cx)) = f2bf(fmaxf(acc, 0.f));
  }
  __syncthreads();
  int l = t & 63, w = t >> 6, lg = l >> 4, lr = l & 15;
  // P2: three GEMMs over Bx: (-k+pe), (v+pe) [K=320], q [K=256, ct0 only]
  f32x4 sA[4][2], vA[4][2], qA[4];
#pragma unroll
  for (int i = 0; i < 4; ++i) {
    sA[i][0] = (f32x4){0,0,0,0}; sA[i][1] = (f32x4){0,0,0,0};
    vA[i][0] = (f32x4){0,0,0,0}; vA[i][1] = (f32x4){0,0,0,0};
    qA[i] = (f32x4){0,0,0,0};
  }
  for (int kk = 0; kk < 10; ++kk) {
    int c1 = 16 + lr;
    short8b b0 = *(const short8b*)(Bx + ((lr * 640 + kk * 64 + lg * 16) ^ ((lr & 7) << 4)));
    short8b bb1 = *(const short8b*)(Bx + ((c1 * 640 + kk * 64 + lg * 16) ^ ((c1 & 7) << 4)));
#pragma unroll
    for (int i = 0; i < 4; ++i) {
      short8b ak = *(const short8b*)(akpef + (((size_t)((w * 4 + i) * 10 + kk)) * 64 + l) * 8);
      short8b av = *(const short8b*)(avpef + (((size_t)((w * 4 + i) * 10 + kk)) * 64 + l) * 8);
      sA[i][0] = __builtin_amdgcn_mfma_f32_16x16x32_bf16(ak, b0, sA[i][0], 0, 0, 0);
      sA[i][1] = __builtin_amdgcn_mfma_f32_16x16x32_bf16(ak, bb1, sA[i][1], 0, 0, 0);
      vA[i][0] = __builtin_amdgcn_mfma_f32_16x16x32_bf16(av, b0, vA[i][0], 0, 0, 0);
      vA[i][1] = __builtin_amdgcn_mfma_f32_16x16x32_bf16(av, bb1, vA[i][1], 0, 0, 0);
      if (kk < 8) {
        short8b aq = *(const short8b*)(aqf + (((size_t)((w * 4 + i) * 8 + kk)) * 64 + l) * 8);
        qA[i] = __builtin_amdgcn_mfma_f32_16x16x32_bf16(aq, b0, qA[i], 0, 0, 0);
      }
    }
  }
  __syncthreads();
  // P3: epilogue: KB = bf16(shfl(q) + sA + pb2), vpeB (cols<20) = bf16(vA + pb2)
#pragma unroll
  for (int i = 0; i < 4; ++i) {
    int r0 = (w * 4 + i) * 16 + lg * 4;
    float4 pb = *(const float4*)(pb2 + r0);
#pragma unroll
    for (int ct = 0; ct < 2; ++ct) {
      int col = ct * 16 + lr; int cx = (col & 7) << 4;
      int qsrc = (l & 48) | (ct == 0 ? (lr / 5) * 5 : 15);
      float q0v = __shfl(qA[i][0], qsrc);
      float q1v = __shfl(qA[i][1], qsrc);
      float q2v = __shfl(qA[i][2], qsrc);
      float q3v = __shfl(qA[i][3], qsrc);
      ushort4 kv, vv;
      kv.x = (unsigned short)f2bf(q0v + sA[i][ct][0] + pb.x);
      kv.y = (unsigned short)f2bf(q1v + sA[i][ct][1] + pb.y);
      kv.z = (unsigned short)f2bf(q2v + sA[i][ct][2] + pb.z);
      kv.w = (unsigned short)f2bf(q3v + sA[i][ct][3] + pb.w);
      vv.x = (unsigned short)f2bf(vA[i][ct][0] + pb.x);
      vv.y = (unsigned short)f2bf(vA[i][ct][1] + pb.y);
      vv.z = (unsigned short)f2bf(vA[i][ct][2] + pb.z);
      vv.w = (unsigned short)f2bf(vA[i][ct][3] + pb.w);
      *(ushort4*)(KB + ((col * 512 + r0 * 2) ^ cx)) = kv;
      if (col < 20) *(ushort4*)(vpeB + ((col * 512 + r0 * 2) ^ cx)) = vv;
    }
  }
  __syncthreads();
  // P4: amlp via MFMA: 4 panels of 256 hidden rows
  f32x4 sacc[4][2];
#pragma unroll
  for (int i = 0; i < 4; ++i) { sacc[i][0] = (f32x4){0,0,0,0}; sacc[i][1] = (f32x4){0,0,0,0}; }
  for (int p = 0; p < 4; ++p) {
    f32x4 hacc[4][2];
#pragma unroll
    for (int i = 0; i < 4; ++i) { hacc[i][0] = (f32x4){0,0,0,0}; hacc[i][1] = (f32x4){0,0,0,0}; }
    for (int kk = 0; kk < 8; ++kk) {
      int c1 = 16 + lr;
      short8b b0 = *(const short8b*)(KB + ((lr * 512 + kk * 64 + lg * 16) ^ ((lr & 7) << 4)));
      short8b bb1 = *(const short8b*)(KB + ((c1 * 512 + kk * 64 + lg * 16) ^ ((c1 & 7) << 4)));
#pragma unroll
      for (int i = 0; i < 4; ++i) {
        int rtg = p * 16 + w * 4 + i;
        short8b a = *(const short8b*)(aw1f + (((size_t)(rtg * 8 + kk)) * 64 + l) * 8);
        hacc[i][0] = __builtin_amdgcn_mfma_f32_16x16x32_bf16(a, b0, hacc[i][0], 0, 0, 0);
        hacc[i][1] = __builtin_amdgcn_mfma_f32_16x16x32_bf16(a, bb1, hacc[i][1], 0, 0, 0);
      }
    }
#pragma unroll
    for (int i = 0; i < 4; ++i) {
      int r0l = (w * 4 + i) * 16 + lg * 4;
      float4 bias = *(const float4*)(ab1 + p * 256 + r0l);
#pragma unroll
      for (int ct = 0; ct < 2; ++ct) {
        int col = ct * 16 + lr; int cx = (col & 7) << 4;
        ushort4 hv;
        hv.x = (unsigned short)f2bf(fmaxf(hacc[i][ct][0] + bias.x, 0.f));
        hv.y = (unsigned short)f2bf(fmaxf(hacc[i][ct][1] + bias.y, 0.f));
        hv.z = (unsigned short)f2bf(fmaxf(hacc[i][ct][2] + bias.z, 0.f));
        hv.w = (unsigned short)f2bf(fmaxf(hacc[i][ct][3] + bias.w, 0.f));
        *(ushort4*)(HpB + ((col * 512 + r0l * 2) ^ cx)) = hv;
      }
    }
    __syncthreads();
    for (int kk = 0; kk < 8; ++kk) {
      int c1 = 16 + lr;
      short8b b0 = *(const short8b*)(HpB + ((lr * 512 + kk * 64 + lg * 16) ^ ((lr & 7) << 4)));
      short8b bb1 = *(const short8b*)(HpB + ((c1 * 512 + kk * 64 + lg * 16) ^ ((c1 & 7) << 4)));
      int kkg = p * 8 + kk;
#pragma unroll
      for (int i = 0; i < 4; ++i) {
        short8b a = *(const short8b*)(aw2f + (((size_t)((w * 4 + i) * 32 + kkg)) * 64 + l) * 8);
        sacc[i][0] = __builtin_amdgcn_mfma_f32_16x16x32_bf16(a, b0, sacc[i][0], 0, 0, 0);
        sacc[i][1] = __builtin_amdgcn_mfma_f32_16x16x32_bf16(a, bb1, sacc[i][1], 0, 0, 0);
      }
    }
    __syncthreads();
  }
  // P5: sim (+ab2) -> simS bf16 (cols < 20)
#pragma unroll
  for (int i = 0; i < 4; ++i) {
    int r0 = (w * 4 + i) * 16 + lg * 4;
    float4 bias = *(const float4*)(ab2 + r0);
#pragma unroll
    for (int ct = 0; ct < 2; ++ct) {
      int col = ct * 16 + lr;
      if (col < 20) {
        ushort4 hv;
        hv.x = (unsigned short)f2bf(sacc[i][ct][0] + bias.x);
        hv.y = (unsigned short)f2bf(sacc[i][ct][1] + bias.y);
        hv.z = (unsigned short)f2bf(sacc[i][ct][2] + bias.z);
        hv.w = (unsigned short)f2bf(sacc[i][ct][3] + bias.w);
        *(ushort4*)(simS + col * 528 + r0 * 2) = hv;
      }
    }
  }
  __syncthreads();
  // P6: softmax over j + aggregate + residual; fused mean/var via shfl butterfly
  float ffv[4];
#pragma unroll
  for (int s = 0; s < 4; ++s) {
    float sv[5], vp[5];
#pragma unroll
    for (int j = 0; j < 5; ++j) {
      int sj = s * 5 + j;
      sv[j] = bf2f(*(const short*)(simS + sj * 528 + 2 * t));
      vp[j] = bf2f(*(const short*)(vpeB + ((sj * 512 + 2 * t) ^ ((sj & 7) << 4))));
    }
    float mx = sv[0];
#pragma unroll
    for (int j = 1; j < 5; ++j) mx = fmaxf(mx, sv[j]);
    float ssum = 0.f;
#pragma unroll
    for (int j = 0; j < 5; ++j) { sv[j] = expf(sv[j] - mx); ssum += sv[j]; }
    float inv = 1.f / ssum;
    float agg = 0.f;
#pragma unroll
    for (int j = 0; j < 5; ++j) agg += (sv[j] * inv) * vp[j];
    ffv[s] = agg + sfeat[((size_t)b * Fc + t) * Nc + (n0 + s)];
  }
  {
    float rv[8];
#pragma unroll
    for (int s = 0; s < 4; ++s) { rv[s] = ffv[s]; rv[4 + s] = ffv[s] * ffv[s]; }
#pragma unroll
    for (int m = 1; m < 64; m <<= 1)
#pragma unroll
      for (int i2 = 0; i2 < 8; ++i2) rv[i2] += __shfl_xor(rv[i2], m);
    if ((t & 63) == 0)
#pragma unroll
      for (int i2 = 0; i2 < 8; ++i2) redf[(t >> 6) * 8 + i2] = rv[i2];
    __syncthreads();
#pragma unroll
    for (int s = 0; s < 4; ++s) {
      float S = redf[s] + redf[8 + s] + redf[16 + s] + redf[24 + s];
      float Q = redf[4 + s] + redf[12 + s] + redf[20 + s] + redf[28 + s];
      float mu = S * (1.f / 256.f);
      float var = Q * (1.f / 256.f) - mu * mu;
      q04[s * 256 + t] = (ffv[s] - mu) / sqrtf(var + 1e-5f);
    }
  }
  __syncthreads();
  // P7: build feaB (cols 0-3); zero cols 4-15 (NaN safety)
#pragma unroll
  for (int s = 0; s < 4; ++s)
    *(short*)(feaB + ((s * 512 + 2 * t) ^ ((s & 7) << 4))) = f2bf(q04[s * 256 + t]);
  for (int z = t; z < 12 * 256; z += 256) {
    int col = 4 + z / 256, k = z % 256;
    *(short*)(feaB + ((col * 512 + 2 * k) ^ ((col & 7) << 4))) = 0;
  }
  __syncthreads();
  // P8: fea layer 1 (relu(g*acc+b)) -> feaH
  {
    f32x4 acc[4];
#pragma unroll
    for (int i = 0; i < 4; ++i) acc[i] = (f32x4){0,0,0,0};
    for (int kk = 0; kk < 8; ++kk) {
      short8b b0 = *(const short8b*)(feaB + ((lr * 512 + kk * 64 + lg * 16) ^ ((lr & 7) << 4)));
#pragma unroll
      for (int i = 0; i < 4; ++i) {
        short8b a = *(const short8b*)(fw1f + (((size_t)((w * 4 + i) * 8 + kk)) * 64 + l) * 8);
        acc[i] = __builtin_amdgcn_mfma_f32_16x16x32_bf16(a, b0, acc[i], 0, 0, 0);
      }
    }
    __syncthreads();
#pragma unroll
    for (int i = 0; i < 4; ++i) {
      int r0 = (w * 4 + i) * 16 + lg * 4;
      float4 gg = *(const float4*)(fg1 + r0), bs = *(const float4*)(fb1 + r0);
      int cx = (lr & 7) << 4;
      ushort4 hv;
      hv.x = (unsigned short)f2bf(fmaxf(gg.x * acc[i][0] + bs.x, 0.f));
      hv.y = (unsigned short)f2bf(fmaxf(gg.y * acc[i][1] + bs.y, 0.f));
      hv.z = (unsigned short)f2bf(fmaxf(gg.z * acc[i][2] + bs.z, 0.f));
      hv.w = (unsigned short)f2bf(fmaxf(gg.w * acc[i][3] + bs.w, 0.f));
      *(ushort4*)(feaH + ((lr * 512 + r0 * 2) ^ cx)) = hv;
    }
  }
  __syncthreads();
  // P9: fea layer 2 -> y2F cols 0-3
  {
    f32x4 acc[4];
#pragma unroll
    for (int i = 0; i < 4; ++i) acc[i] = (f32x4){0,0,0,0};
    for (int kk = 0; kk < 8; ++kk) {
      short8b b0 = *(const short8b*)(feaH + ((lr * 512 + kk * 64 + lg * 16) ^ ((lr & 7) << 4)));
#pragma unroll
      for (int i = 0; i < 4; ++i) {
        short8b a = *(const short8b*)(fw2f + (((size_t)((w * 4 + i) * 8 + kk)) * 64 + l) * 8);
        acc[i] = __builtin_amdgcn_mfma_f32_16x16x32_bf16(a, b0, acc[i], 0, 0, 0);
      }
    }
#pragma unroll
    for (int i = 0; i < 4; ++i) {
      if (lr < 4) {
        int r0 = (w * 4 + i) * 16 + lg * 4;
        float4 bs = *(const float4*)(fb2v + r0);
        float4 v;
        v.x = acc[i][0] + bs.x; v.y = acc[i][1] + bs.y;
        v.z = acc[i][2] + bs.z; v.w = acc[i][3] + bs.w;
        *(float4*)(y2F + lr * 260 + r0) = v;
      }
    }
  }
  __syncthreads();
  // P10: z = y2 + ffn; instance norm via shfl butterfly; out
  {
    float zv[4];
#pragma unroll
    for (int s = 0; s < 4; ++s) zv[s] = y2F[s * 260 + t] + q04[s * 256 + t];
    float rv[8];
#pragma unroll
    for (int s = 0; s < 4; ++s) { rv[s] = zv[s]; rv[4 + s] = zv[s] * zv[s]; }
#pragma unroll
    for (int m = 1; m < 64; m <<= 1)
#pragma unroll
      for (int i2 = 0; i2 < 8; ++i2) rv[i2] += __shfl_xor(rv[i2], m);
    if ((t & 63) == 0)
#pragma unroll
      for (int i2 = 0; i2 < 8; ++i2) redf[(t >> 6) * 8 + i2] = rv[i2];
    __syncthreads();
#pragma unroll
    for (int s = 0; s < 4; ++s) {
      float S = redf[s] + redf[8 + s] + redf[16 + s] + redf[24 + s];
      float Q = redf[4 + s] + redf[12 + s] + redf[20 + s] + redf[28 + s];
      float mu = S * (1.f / 256.f);
      float var = Q * (1.f / 256.f) - mu * mu;
      yout[((size_t)(tau0 + s)) * 256 + t] = (zv[s] - mu) / sqrtf(var + 1e-5f);
    }
  }
}

// ---- PointSIFT octant-NN via shfl-butterfly argmin per octant ----
__global__ __launch_bounds__(256) void sift_idx_kernel(const float* __restrict__ sxyz,
                                                       int* __restrict__ sidx) {
  __shared__ unsigned long long red8[32];
  int b = blockIdx.x / Nc, i = blockIdx.x % Nc;
  int t = threadIdx.x;
  const float* x = sxyz + (size_t)b * Nc * 3;
  float xi0 = x[3 * i], xi1 = x[3 * i + 1], xi2 = x[3 * i + 2];
  unsigned long long k8[8];
#pragma unroll
  for (int o = 0; o < 8; ++o) k8[o] = ~0ULL;
  for (int q = 0; q < 4; ++q) {
    int j = t + q * 256;
    float dx = x[3 * j] - xi0, dy = x[3 * j + 1] - xi1, dz = x[3 * j + 2] - xi2;
    float d2 = dx * dx + dy * dy + dz * dz;
    bool ok = (d2 <= 0.25f) && (d2 > 0.f);
    int oc = (dx > 0.f ? 4 : 0) + (dy > 0.f ? 2 : 0) + (dz > 0.f ? 1 : 0);
    unsigned long long c = ((unsigned long long)__float_as_uint(d2) << 32) | (unsigned)j;
#pragma unroll
    for (int o = 0; o < 8; ++o) {
      unsigned long long cc = (ok && oc == o) ? c : ~0ULL;
      k8[o] = umin64(k8[o], cc);
    }
  }
#pragma unroll
  for (int m = 1; m < 64; m <<= 1)
#pragma unroll
    for (int o = 0; o < 8; ++o) k8[o] = umin64(k8[o], __shfl_xor(k8[o], m));
  if ((t & 63) == 0)
#pragma unroll
    for (int o = 0; o < 8; ++o) red8[(t >> 6) * 8 + o] = k8[o];
  __syncthreads();
  if (t < 8) {
    unsigned long long r = umin64(umin64(red8[t], red8[8 + t]), umin64(red8[16 + t], red8[24 + t]));
    int j = (r == ~0ULL) ? i : (int)(unsigned)r;
    sidx[(((size_t)b * Nc + i) << 3) + t] = j;
  }
}

// ---- fused PointSIFT OE module: 3 (1,2)-convs via MFMA, 4 points/block ----
__global__ __launch_bounds__(256) void sift_oe_kernel(
    const float* __restrict__ sxyz, const int* __restrict__ sidx,
    const float* __restrict__ yin,
    const short* __restrict__ w1f, const float* __restrict__ g1, const float* __restrict__ b1,
    const short* __restrict__ w2f, const float* __restrict__ g2, const float* __restrict__ b2,
    const short* __restrict__ w3f, const float* __restrict__ g3, const float* __restrict__ b3,
    float* __restrict__ yout) {
  __shared__ __align__(16) char smem[33792];
  char* B1 = smem;            // [16 cols][544k] bf16, stride 1088B; B3 aliases [0,16384)
  char* B2 = smem + 17408;    // [16 cols][512k] bf16, stride 1024B
  char* B3 = smem;
  __shared__ int js[4][8];
  int t = threadIdx.x;
  int i0 = blockIdx.x * 4;
  int b = i0 / Nc, nb = i0 % Nc;
  if (t < 32) js[t >> 3][t & 7] = sidx[(((size_t)b * Nc + nb + (t >> 3)) << 3) + (t & 7)];
  // NaN-safety: zero k-pad (k 518..543) for all 16 cols
  for (int z = t; z < 16 * 26; z += 256) {
    int col = z / 26, k = 518 + z % 26;
    *(short*)(B1 + ((col * 1088 + 2 * k) ^ ((col & 7) << 4))) = 0;
  }
  __syncthreads();
  // build B1: col = s*4+p, k = 2c+t' (c: 0-2 gxyz, 3-258 feat)
  for (int s = 0; s < 4; ++s) {
    int ii = nb + s;
#pragma unroll
    for (int p = 0; p < 4; ++p) {
      int ja = js[s][2 * p], jb = js[s][2 * p + 1];
      int col = s * 4 + p; int cx = (col & 7) << 4;
      float va = yin[((size_t)b * Nc + ja) * 256 + t];
      float vb = yin[((size_t)b * Nc + jb) * 256 + t];
      unsigned int packed = (unsigned int)(unsigned short)f2bf(va) |
                            ((unsigned int)(unsigned short)f2bf(vb) << 16);
      *(unsigned int*)(B1 + ((col * 1088 + 12 + 4 * t) ^ cx)) = packed;
      if (t < 3) {
        float base = sxyz[((size_t)b * Nc + ii) * 3 + t];
        float ga = sxyz[((size_t)b * Nc + ja) * 3 + t] - base;
        float gb = sxyz[((size_t)b * Nc + jb) * 3 + t] - base;
        unsigned int pg = (unsigned int)(unsigned short)f2bf(ga) |
                          ((unsigned int)(unsigned short)f2bf(gb) << 16);
        *(unsigned int*)(B1 + ((col * 1088 + 4 * t) ^ cx)) = pg;
      }
    }
  }
  __syncthreads();
  int l = t & 63, w = t >> 6, lg = l >> 4, lr = l & 15;
  // GEMM1: 256 x K518 (KT=17) -> B2 in conv2-pair layout
  {
    f32x4 acc[4];
#pragma unroll
    for (int i = 0; i < 4; ++i) acc[i] = (f32x4){0,0,0,0};
    for (int kk = 0; kk < 17; ++kk) {
      short8b b0 = *(const short8b*)(B1 + ((lr * 1088 + kk * 64 + lg * 16) ^ ((lr & 7) << 4)));
#pragma unroll
      for (int i = 0; i < 4; ++i) {
        short8b a = *(const short8b*)(w1f + (((size_t)((w * 4 + i) * 17 + kk)) * 64 + l) * 8);
        acc[i] = __builtin_amdgcn_mfma_f32_16x16x32_bf16(a, b0, acc[i], 0, 0, 0);
      }
    }
    __syncthreads();
    int s = lr >> 2, p = lr & 3, p2 = p >> 1, tp = p & 1;
    int col2 = s * 2 + p2; int cx2 = (col2 & 7) << 4;
#pragma unroll
    for (int i = 0; i < 4; ++i) {
      int r0 = (w * 4 + i) * 16 + lg * 4;
      float4 gg = *(const float4*)(g1 + r0), bs = *(const float4*)(b1 + r0);
      *(short*)(B2 + ((col2 * 1024 + (2 * r0 + tp) * 2) ^ cx2)) =
          f2bf(fmaxf(gg.x * acc[i][0] + bs.x, 0.f));
      *(short*)(B2 + ((col2 * 1024 + (2 * (r0 + 1) + tp) * 2) ^ cx2)) =
          f2bf(fmaxf(gg.y * acc[i][1] + bs.y, 0.f));
      *(short*)(B2 + ((col2 * 1024 + (2 * (r0 + 2) + tp) * 2) ^ cx2)) =
          f2bf(fmaxf(gg.z * acc[i][2] + bs.z, 0.f));
      *(short*)(B2 + ((col2 * 1024 + (2 * (r0 + 3) + tp) * 2) ^ cx2)) =
          f2bf(fmaxf(gg.w * acc[i][3] + bs.w, 0.f));
    }
  }
  __syncthreads();
  // GEMM2: 256 x K512 (KT=16) -> B3 in conv3-pair layout
  {
    f32x4 acc[4];
#pragma unroll
    for (int i = 0; i < 4; ++i) acc[i] = (f32x4){0,0,0,0};
    for (int kk = 0; kk < 16; ++kk) {
      short8b b0 = *(const short8b*)(B2 + ((lr * 1024 + kk * 64 + lg * 16) ^ ((lr & 7) << 4)));
#pragma unroll
      for (int i = 0; i < 4; ++i) {
        short8b a = *(const short8b*)(w2f + (((size_t)((w * 4 + i) * 16 + kk)) * 64 + l) * 8);
        acc[i] = __builtin_amdgcn_mfma_f32_16x16x32_bf16(a, b0, acc[i], 0, 0, 0);
      }
    }
    __syncthreads();
    int s = lr >> 1, tp = lr & 1;
    int col3 = s; int cx3 = (col3 & 7) << 4;
#pragma unroll
    for (int i = 0; i < 4; ++i) {
      int r0 = (w * 4 + i) * 16 + lg * 4;
      float4 gg = *(const float4*)(g2 + r0), bs = *(const float4*)(b2 + r0);
      *(short*)(B3 + ((col3 * 1024 + (2 * r0 + tp) * 2) ^ cx3)) =
          f2bf(fmaxf(gg.x * acc[i][0] + bs.x, 0.f));
      *(short*)(B3 + ((col3 * 1024 + (2 * (r0 + 1) + tp) * 2) ^ cx3)) =
          f2bf(fmaxf(gg.y * acc[i][1] + bs.y, 0.f));
      *(short*)(B3 + ((col3 * 1024 + (2 * (r0 + 2) + tp) * 2) ^ cx3)) =
          f2bf(fmaxf(gg.z * acc[i][2] + bs.z, 0.f));
      *(short*)(B3 + ((col3 * 1024 + (2 * (r0 + 3) + tp) * 2) ^ cx3)) =
          f2bf(fmaxf(gg.w * acc[i][3] + bs.w, 0.f));
    }
  }
  __syncthreads();
  // GEMM3: 256 x K512 -> yout = yin + relu(g3*acc+b3)  (cols 0-3)
  {
    f32x4 acc[4];
#pragma unroll
    for (int i = 0; i < 4; ++i) acc[i] = (f32x4){0,0,0,0};
    for (int kk = 0; kk < 16; ++kk) {
      short8b b0 = *(const short8b*)(B3 + ((lr * 1024 + kk * 64 + lg * 16) ^ ((lr & 7) << 4)));
#pragma unroll
      for (int i = 0; i < 4; ++i) {
        short8b a = *(const short8b*)(w3f + (((size_t)((w * 4 + i) * 16 + kk)) * 64 + l) * 8);
        acc[i] = __builtin_amdgcn_mfma_f32_16x16x32_bf16(a, b0, acc[i], 0, 0, 0);
      }
    }
#pragma unroll
    for (int i = 0; i < 4; ++i) {
      if (lr < 4) {
        int s = lr;
        int r0 = (w * 4 + i) * 16 + lg * 4;
        float4 gg = *(const float4*)(g3 + r0), bs = *(const float4*)(b3 + r0);
        float4 yv = *(const float4*)(yin + ((size_t)(i0 + s)) * 256 + r0);
        float4 ov;
        ov.x = yv.x + fmaxf(gg.x * acc[i][0] + bs.x, 0.f);
        ov.y = yv.y + fmaxf(gg.y * acc[i][1] + bs.y, 0.f);
        ov.z = yv.z + fmaxf(gg.z * acc[i][2] + bs.z, 0.f);
        ov.w = yv.w + fmaxf(gg.w * acc[i][3] + bs.w, 0.f);
        *(float4*)(yout + ((size_t)(i0 + s)) * 256 + r0) = ov;
      }
    }
  }
}

// ---- final transpose (B,N,C) -> (B,C,N) into d_out ----
__global__ __launch_bounds__(256) void transpose_kernel(const float* __restrict__ yin,
                                                        float* __restrict__ out) {
  size_t idx = (size_t)blockIdx.x * 256 + threadIdx.x;
  int n = (int)(idx % Nc);
  size_t r = idx / Nc;
  int c = (int)(r % Fc);
  int b = (int)(r / Fc);
  out[idx] = yin[(((size_t)b * Nc + n) * 256) + c];
}

extern "C" void kernel_launch(void* const* d_in, const int* in_sizes, int n_in,
                              void* d_out, int out_size, void* d_ws, size_t ws_size,
                              hipStream_t stream) {
  (void)in_sizes; (void)n_in; (void)out_size; (void)ws_size;
  const float* tfeat = (const float*)d_in[0];
  const float* sfeat = (const float*)d_in[1];
  const float* txyz  = (const float*)d_in[2];
  const float* sxyz  = (const float*)d_in[3];
  const float* tbc   = (const float*)d_in[4];
  const float* sbc   = (const float*)d_in[5];
  const float* mw1 = (const float*)d_in[6];
  const float* mg1 = (const float*)d_in[7];
  const float* mb1 = (const float*)d_in[8];
  const float* mw2 = (const float*)d_in[9];
  const float* mg2 = (const float*)d_in[10];
  const float* mb2 = (const float*)d_in[11];
  const float* mw3 = (const float*)d_in[12];
  const float* mg3 = (const float*)d_in[13];
  const float* mb3 = (const float*)d_in[14];
  const float* fw1 = (const float*)d_in[15];
  const float* fg1 = (const float*)d_in[16];
  const float* fb1 = (const float*)d_in[17];
  const float* fw2 = (const float*)d_in[18];
  const float* fb2 = (const float*)d_in[19];
  const float* wqkv = (const float*)d_in[20];
  const float* pw1 = (const float*)d_in[21];
  const float* pb1 = (const float*)d_in[22];
  const float* pw2 = (const float*)d_in[23];
  const float* pb2 = (const float*)d_in[24];
  const float* aw1 = (const float*)d_in[25];
  const float* ab1 = (const float*)d_in[26];
  const float* aw2 = (const float*)d_in[27];
  const float* ab2 = (const float*)d_in[28];
  const float* o1w1 = (const float*)d_in[29];
  const float* o1g1 = (const float*)d_in[30];
  const float* o1b1 = (const float*)d_in[31];
  const float* o1w2 = (const float*)d_in[32];
  const float* o1g2 = (const float*)d_in[33];
  const float* o1b2 = (const float*)d_in[34];
  const float* o1w3 = (const float*)d_in[35];
  const float* o1g3 = (const float*)d_in[36];
  const float* o1b3 = (const float*)d_in[37];
  const float* o2w1 = (const float*)d_in[38];
  const float* o2g1 = (const float*)d_in[39];
  const float* o2b1 = (const float*)d_in[40];
  const float* o2w2 = (const float*)d_in[41];
  const float* o2g2 = (const float*)d_in[42];
  const float* o2b2 = (const float*)d_in[43];
  const float* o2w3 = (const float*)d_in[44];
  const float* o2g3 = (const float*)d_in[45];
  const float* o2b3 = (const float*)d_in[46];

  // workspace layout (identical to R6)
  float* ws = (float*)d_ws;
  float* sd   = ws;                      // B*N*16 f32
  float* td   = sd + 65536;              // B*M*16
  float* sscf = td + 32768;              // B*3*N
  float* tscf = sscf + 12288;            // B*3*M
  int*   idxs = (int*)(tscf + 6144);     // B*N*4 ints
  int*   sidx = idxs + 16384;            // B*N*8 ints
  float* yws  = (float*)(sidx + 32768);  // B*N*256 f32
  short* sb   = (short*)(yws + 1048576);
  short* hbufS = sb;                     // 5,242,880 (dead after attn; ybuf2 aliases)
  short* mw1f  = sb + 5242880;           // jobs dst base; contiguous in job order:
  short* mw2f  = mw1f + 73728;
  short* mw3f  = mw2f + 65536;
  short* aqf   = mw3f + 65536;
  short* akpef = aqf + 65536;
  short* avpef = akpef + 81920;
  short* aw1f  = avpef + 81920;
  short* aw2f  = aw1f + 262144;
  short* fw1f  = aw2f + 262144;
  short* fw2f  = fw1f + 65536;
  short* o1w1f = fw2f + 65536;
  short* o1w2f = o1w1f + 139264;
  short* o1w3f = o1w2f + 131072;
  short* o2w1f = o1w3f + 131072;
  short* o2w2f = o2w1f + 139264;
  short* o2w3f = o2w2f + 131072;
  float* ybuf2 = (float*)sb;             // sift ping-pong, aliases hbufS

  // merged weight relayout: 1 launch, 16 jobs
  WSrcs srcs;
  srcs.p[0] = mw1;  srcs.p[1] = mw2;  srcs.p[2] = mw3;  srcs.p[3] = wqkv;
  srcs.p[4] = wqkv; srcs.p[5] = wqkv; srcs.p[6] = aw1;  srcs.p[7] = aw2;
  srcs.p[8] = fw1;  srcs.p[9] = fw2;  srcs.p[10] = o1w1; srcs.p[11] = o1w2;
  srcs.p[12] = o1w3; srcs.p[13] = o2w1; srcs.p[14] = o2w2; srcs.p[15] = o2w3;
  wconv_all<<<7392, 256, 0, stream>>>(srcs, pw2, mw1f);

  scf_kernel<<<Bc, 256, 0, stream>>>(sxyz, sscf, Nc);
  scf_kernel<<<Bc, 256, 0, stream>>>(txyz, tscf, Mc);
  knn_kernel<Nc><<<Bc * Nc, 256, 0, stream>>>(sxyz, sd);
  knn_kernel<Mc><<<Bc * Mc, 256, 0, stream>>>(txyz, td);
  select_kernel<<<Bc * Nc, 256, 0, stream>>>(tbc, sbc, txyz, sxyz, sd, td, idxs);
  mlp_kernel<<<Bc * Nc / 4, 256, 0, stream>>>(sfeat, tfeat, sscf, tscf, idxs,
                                              mw1f, mg1, mb1, mw2f, mg2, mb2,
                                              mw3f, mg3, mb3, hbufS);
  attn_kernel<<<Bc * Nc / 4, 256, 0, stream>>>(hbufS, idxs, sxyz, sbc, txyz, tbc,
                                               aqf, akpef, avpef, pw1, pb1, pb2,
                                               aw1f, ab1, aw2f, ab2,
                                               sfeat, fw1f, fg1, fb1, fw2f, fb2, yws);
  sift_idx_kernel<<<Bc * Nc, 256, 0, stream>>>(sxyz, sidx);
  // OE module 1: yws -> ybuf2 ; module 2: ybuf2 -> yws (ping-pong, no RW race)
  sift_oe_kernel<<<Bc * Nc / 4, 256, 0, stream>>>(sxyz, sidx, yws,
                                                  o1w1f, o1g1, o1b1, o1w2f, o1g2, o1b2,
                                                  o1w3f, o1g3, o1b3, ybuf2);
  sift_oe_kernel<<<Bc * Nc / 4, 256, 0, stream>>>(sxyz, sidx, ybuf2,
                                                  o2w1f, o2g1, o2b1, o2w2f, o2g2, o2b2,
                                                  o2w3f, o2g3, o2b3, yws);
  transpose_kernel<<<(Bc * Fc * Nc) / 256, 256, 0, stream>>>(yws, (float*)d_out);
}

// Round 8
// 414.101 us; speedup vs baseline: 27.1732x; 1.3945x over previous
//
#include <hip/hip_runtime.h>
#include <hip/hip_bf16.h>
#include <math.h>

// Problem constants (match reference)
constexpr int Bc = 4, Mc = 512, Nc = 1024, Fc = 256;
constexpr int KCc = 16;
constexpr float INFF = 3.0e38f;

typedef __attribute__((ext_vector_type(8))) short short8b;  // 8 bf16 (4 VGPRs)
typedef __attribute__((ext_vector_type(4))) float f32x4;

__device__ __forceinline__ short f2bf(float f) {
  __hip_bfloat16 h = __float2bfloat16(f);
  return *reinterpret_cast<short*>(&h);
}
__device__ __forceinline__ float bf2f(short s) {
  unsigned int u = ((unsigned int)(unsigned short)s) << 16;
  return __uint_as_float(u);
}
__device__ __forceinline__ unsigned long long umin64(unsigned long long a, unsigned long long b) {
  return a < b ? a : b;
}

__device__ __forceinline__ float blk_sum(float v, float* red) {
  int t = threadIdx.x;
  red[t] = v;
  __syncthreads();
  for (int s = 128; s > 0; s >>= 1) {
    if (t < s) red[t] += red[t + s];
    __syncthreads();
  }
  float r = red[0];
  __syncthreads();
  return r;
}

// ---- merged weight relayout: 16 jobs, one kernel ----
struct WSrcs { const float* p[16]; };
__global__ __launch_bounds__(256) void wconv_all(WSrcs s, const float* __restrict__ pw2,
                                                 short* __restrict__ dstbase) {
  const int ofs[16] = {0, 73728, 139264, 204800, 270336, 352256, 434176, 696320,
                       958464, 1024000, 1089536, 1228800, 1359872, 1490944, 1630208, 1761280};
  const int Kt[16]  = {259, 256, 256, 256, 320, 320, 256, 1024, 256, 256, 518, 512, 512, 518, 512, 512};
  const int KTt[16] = {9, 8, 8, 8, 10, 10, 8, 32, 8, 8, 17, 16, 16, 17, 16, 16};
  int gi = blockIdx.x * 256 + threadIdx.x;
  if (gi >= 1892352) return;
  int job = 0;
#pragma unroll
  for (int j2 = 1; j2 < 16; ++j2)
    if (gi >= ofs[j2]) job = j2;
  int i = gi - ofs[job];
  int K = Kt[job], KT = KTt[job];
  int e = i & 7, l = (i >> 3) & 63, q = i >> 9;
  int kk = q % KT, rt = q / KT;
  int r = rt * 16 + (l & 15);
  int k = kk * 32 + (l >> 4) * 8 + e;
  float v;
  if (job == 4)
    v = (k < 256) ? -s.p[4][(size_t)(256 + r) * 256 + k] : pw2[(size_t)r * 64 + (k - 256)];
  else if (job == 5)
    v = (k < 256) ? s.p[5][(size_t)(512 + r) * 256 + k] : pw2[(size_t)r * 64 + (k - 256)];
  else
    v = (k < K) ? s.p[job][(size_t)r * K + k] : 0.f;
  dstbase[gi] = f2bf(v);
}

// ---- spherical coords of points relative to centroid -> out (B,3,P) ----
__global__ __launch_bounds__(256) void scf_kernel(const float* __restrict__ xyz,
                                                  float* __restrict__ out, int P) {
  __shared__ float red[256];
  int b = blockIdx.x;
  const float* x = xyz + (size_t)b * P * 3;
  float sx = 0.f, sy = 0.f, sz = 0.f;
  for (int i = threadIdx.x; i < P; i += 256) {
    sx += x[3 * i]; sy += x[3 * i + 1]; sz += x[3 * i + 2];
  }
  float mx = blk_sum(sx, red) / (float)P;
  float my = blk_sum(sy, red) / (float)P;
  float mz = blk_sum(sz, red) / (float)P;
  for (int i = threadIdx.x; i < P; i += 256) {
    float a = x[3 * i] - mx, c = x[3 * i + 1] - my, d = x[3 * i + 2] - mz;
    float r = sqrtf(a * a + c * c + d * d + 1e-8f);
    float ct = d / r;
    ct = fminf(1.f, fmaxf(-1.f, ct));
    out[((size_t)b * 3 + 0) * P + i] = r;
    out[((size_t)b * 3 + 1) * P + i] = acosf(ct);
    out[((size_t)b * 3 + 2) * P + i] = atan2f(c, a);
  }
}

// ---- KNN descriptor via shfl-butterfly argmin, register-resident d2 ----
template <int P>
__global__ __launch_bounds__(256) void knn_kernel(const float* __restrict__ xyz,
                                                  float* __restrict__ desc) {
  constexpr int E = P / 256;
  __shared__ unsigned long long red2[8];
  int b = blockIdx.x / P, i = blockIdx.x % P;
  int t = threadIdx.x;
  const float* x = xyz + (size_t)b * P * 3;
  float xi0 = x[3 * i], xi1 = x[3 * i + 1], xi2 = x[3 * i + 2];
  float d2r[E];
#pragma unroll
  for (int q = 0; q < E; ++q) {
    int j = t + q * 256;
    float dx = x[3 * j] - xi0, dy = x[3 * j + 1] - xi1, dz = x[3 * j + 2] - xi2;
    d2r[q] = dx * dx + dy * dy + dz * dz;
  }
  for (int round = 0; round < KCc + 1; ++round) {
    unsigned long long k = ~0ULL;
#pragma unroll
    for (int q = 0; q < E; ++q) {
      unsigned long long c =
          ((unsigned long long)__float_as_uint(d2r[q]) << 32) | (unsigned)(t + q * 256);
      k = umin64(k, c);
    }
#pragma unroll
    for (int m = 1; m < 64; m <<= 1) k = umin64(k, __shfl_xor(k, m));
    int pp = (round & 1) << 2;
    if ((t & 63) == 0) red2[pp | (t >> 6)] = k;
    __syncthreads();
    unsigned long long r = umin64(umin64(red2[pp], red2[pp | 1]),
                                  umin64(red2[pp | 2], red2[pp | 3]));
    int widx = (int)(unsigned)r;
    if (round > 0 && t == 0)
      desc[((size_t)b * P + i) * KCc + (round - 1)] = sqrtf(__uint_as_float((unsigned)(r >> 32)));
#pragma unroll
    for (int q = 0; q < E; ++q)
      if (widx == t + q * 256) d2r[q] = INFF;
  }
}

// ---- candidate pruning: top-24 by bc dist (shfl argmin) -> top-8 xyz -> top-4 scf ----
__global__ __launch_bounds__(256) void select_kernel(
    const float* __restrict__ tbc, const float* __restrict__ sbc,
    const float* __restrict__ txyz, const float* __restrict__ sxyz,
    const float* __restrict__ sd, const float* __restrict__ td,
    int* __restrict__ idx_s) {
  __shared__ unsigned long long red2[8];
  __shared__ int cand[24];
  int b = blockIdx.x / Nc, n = blockIdx.x % Nc;
  int t = threadIdx.x;
  const float* sb = sbc + ((size_t)b * Nc + n) * 9;
  float sreg[9];
#pragma unroll
  for (int c = 0; c < 9; ++c) sreg[c] = sb[c];
  float d2r[2];
#pragma unroll
  for (int q = 0; q < 2; ++q) {
    int m = t + q * 256;
    const float* tb = tbc + ((size_t)b * Mc + m) * 9;
    float acc = 0.f;
#pragma unroll
    for (int c = 0; c < 9; ++c) { float d = tb[c] - sreg[c]; acc += d * d; }
    d2r[q] = acc;
  }
  for (int round = 0; round < 24; ++round) {
    unsigned long long k = ~0ULL;
#pragma unroll
    for (int q = 0; q < 2; ++q) {
      unsigned long long c =
          ((unsigned long long)__float_as_uint(d2r[q]) << 32) | (unsigned)(t + q * 256);
      k = umin64(k, c);
    }
#pragma unroll
    for (int m = 1; m < 64; m <<= 1) k = umin64(k, __shfl_xor(k, m));
    int pp = (round & 1) << 2;
    if ((t & 63) == 0) red2[pp | (t >> 6)] = k;
    __syncthreads();
    unsigned long long r = umin64(umin64(red2[pp], red2[pp | 1]),
                                  umin64(red2[pp | 2], red2[pp | 3]));
    int widx = (int)(unsigned)r;
    if (t == 0) cand[round] = widx;
#pragma unroll
    for (int q = 0; q < 2; ++q)
      if (widx == t + q * 256) d2r[q] = INFF;
  }
  if (t == 0) {
    const float* sp = sxyz + ((size_t)b * Nc + n) * 3;
    float sx = sp[0], sy = sp[1], sz = sp[2];
    float dv[24];
    for (int t2 = 0; t2 < 24; ++t2) {
      const float* tp = txyz + ((size_t)b * Mc + cand[t2]) * 3;
      float dx = tp[0] - sx, dy = tp[1] - sy, dz = tp[2] - sz;
      dv[t2] = dx * dx + dy * dy + dz * dz;
    }
    int c8[8]; bool used[24];
    for (int t2 = 0; t2 < 24; ++t2) used[t2] = false;
    for (int r = 0; r < 8; ++r) {
      float bv = INFF; int bt = -1, bm = 0x7fffffff;
      for (int t2 = 0; t2 < 24; ++t2) {
        if (used[t2]) continue;
        int m = cand[t2];
        if (bt < 0 || dv[t2] < bv || (dv[t2] == bv && m < bm)) { bv = dv[t2]; bt = t2; bm = m; }
      }
      used[bt] = true; c8[r] = bm;
    }
    const float* sdp = sd + ((size_t)b * Nc + n) * KCc;
    float sdr[16];
    for (int t2 = 0; t2 < 16; ++t2) sdr[t2] = sdp[t2];
    float dscf[8];
    for (int r = 0; r < 8; ++r) {
      const float* tdp = td + ((size_t)b * Mc + c8[r]) * KCc;
      float acc = 0.f;
      for (int t2 = 0; t2 < 16; ++t2) { float d = sdr[t2] - tdp[t2]; acc += d * d; }
      dscf[r] = acc;
    }
    bool u8[8] = {false, false, false, false, false, false, false, false};
    for (int r = 0; r < 4; ++r) {
      float bv = INFF; int bt = -1, bm = 0x7fffffff;
      for (int t2 = 0; t2 < 8; ++t2) {
        if (u8[t2]) continue;
        if (bt < 0 || dscf[t2] < bv || (dscf[t2] == bv && c8[t2] < bm)) { bv = dscf[t2]; bt = t2; bm = c8[t2]; }
      }
      u8[bt] = true;
      idx_s[(((size_t)b * Nc + n) << 2) + r] = bm;
    }
  }
}

// ---- grouping + 3-layer MLP via bf16 MFMA (frag-order A), 4 tokens/block ----
__global__ __launch_bounds__(256) void mlp_kernel(
    const float* __restrict__ sfeat, const float* __restrict__ tfeat,
    const float* __restrict__ sscf, const float* __restrict__ tscf,
    const int* __restrict__ idx_s,
    const short* __restrict__ w1f, const float* __restrict__ g1, const float* __restrict__ b1,
    const short* __restrict__ w2f, const float* __restrict__ g2, const float* __restrict__ b2,
    const short* __restrict__ w3f, const float* __restrict__ g3, const float* __restrict__ b3,
    short* __restrict__ houtS) {
  __shared__ __align__(16) char smem[34816];
  char* B1 = smem;
  char* B2 = smem + 18432;
  __shared__ int ms[16];
  int t = threadIdx.x;
  int tau0 = blockIdx.x * 4;
  int b = tau0 / Nc, n0 = tau0 % Nc;
  if (t < 16) ms[t] = idx_s[(((size_t)b * Nc + n0 + (t >> 2)) << 2) + (t & 3)];
  __syncthreads();
  for (int z = t; z < 32 * 29; z += 256) {
    int col = z / 29, k = 259 + z % 29;
    *(short*)(B1 + ((col * 576 + 2 * k) ^ ((col & 7) << 4))) = 0;
  }
  for (int z = t; z < 12 * 259; z += 256) {
    int col = 20 + z / 259, k = z % 259;
    *(short*)(B1 + ((col * 576 + 2 * k) ^ ((col & 7) << 4))) = 0;
  }
  for (int s = 0; s < 4; ++s) {
    int n = n0 + s;
    {
      int col = s * 5; int cx = (col & 7) << 4;
      *(short*)(B1 + ((col * 576 + t * 2) ^ cx)) = f2bf(sfeat[((size_t)b * Fc + t) * Nc + n]);
      if (t < 3) *(short*)(B1 + ((col * 576 + (256 + t) * 2) ^ cx)) = f2bf(sscf[((size_t)b * 3 + t) * Nc + n]);
    }
    for (int k = 1; k < 5; ++k) {
      int m = ms[s * 4 + k - 1];
      int col = s * 5 + k; int cx = (col & 7) << 4;
      *(short*)(B1 + ((col * 576 + t * 2) ^ cx)) = f2bf(tfeat[((size_t)b * Fc + t) * Mc + m]);
      if (t < 3) *(short*)(B1 + ((col * 576 + (256 + t) * 2) ^ cx)) = f2bf(tscf[((size_t)b * 3 + t) * Mc + m]);
    }
  }
  __syncthreads();
  int l = t & 63, w = t >> 6, lg = l >> 4, lr = l & 15;
  {
    f32x4 acc[4][2];
#pragma unroll
    for (int i = 0; i < 4; ++i) { acc[i][0] = (f32x4){0,0,0,0}; acc[i][1] = (f32x4){0,0,0,0}; }
    for (int kk = 0; kk < 9; ++kk) {
      int c1 = 16 + lr;
      short8b b0 = *(const short8b*)(B1 + ((lr * 576 + kk * 64 + lg * 16) ^ ((lr & 7) << 4)));
      short8b bb1 = *(const short8b*)(B1 + ((c1 * 576 + kk * 64 + lg * 16) ^ ((c1 & 7) << 4)));
#pragma unroll
      for (int i = 0; i < 4; ++i) {
        short8b a = *(const short8b*)(w1f + (((size_t)((w * 4 + i) * 9 + kk)) * 64 + l) * 8);
        acc[i][0] = __builtin_amdgcn_mfma_f32_16x16x32_bf16(a, b0, acc[i][0], 0, 0, 0);
        acc[i][1] = __builtin_amdgcn_mfma_f32_16x16x32_bf16(a, bb1, acc[i][1], 0, 0, 0);
      }
    }
    __syncthreads();
#pragma unroll
    for (int i = 0; i < 4; ++i) {
      int r0 = (w * 4 + i) * 16 + lg * 4;
      float4 gg = *(const float4*)(g1 + r0), bs = *(const float4*)(b1 + r0);
#pragma unroll
      for (int ct = 0; ct < 2; ++ct) {
        int col = ct * 16 + lr; int cx = (col & 7) << 4;
        ushort4 hv;
        hv.x = (unsigned short)f2bf(fmaxf(gg.x * acc[i][ct][0] + bs.x, 0.f));
        hv.y = (unsigned short)f2bf(fmaxf(gg.y * acc[i][ct][1] + bs.y, 0.f));
        hv.z = (unsigned short)f2bf(fmaxf(gg.z * acc[i][ct][2] + bs.z, 0.f));
        hv.w = (unsigned short)f2bf(fmaxf(gg.w * acc[i][ct][3] + bs.w, 0.f));
        *(ushort4*)(B2 + ((col * 512 + r0 * 2) ^ cx)) = hv;
      }
    }
  }
  __syncthreads();
  {
    f32x4 acc[4][2];
#pragma unroll
    for (int i = 0; i < 4; ++i) { acc[i][0] = (f32x4){0,0,0,0}; acc[i][1] = (f32x4){0,0,0,0}; }
    for (int kk = 0; kk < 8; ++kk) {
      int c1 = 16 + lr;
      short8b b0 = *(const short8b*)(B2 + ((lr * 512 + kk * 64 + lg * 16) ^ ((lr & 7) << 4)));
      short8b bb1 = *(const short8b*)(B2 + ((c1 * 512 + kk * 64 + lg * 16) ^ ((c1 & 7) << 4)));
#pragma unroll
      for (int i = 0; i < 4; ++i) {
        short8b a = *(const short8b*)(w2f + (((size_t)((w * 4 + i) * 8 + kk)) * 64 + l) * 8);
        acc[i][0] = __builtin_amdgcn_mfma_f32_16x16x32_bf16(a, b0, acc[i][0], 0, 0, 0);
        acc[i][1] = __builtin_amdgcn_mfma_f32_16x16x32_bf16(a, bb1, acc[i][1], 0, 0, 0);
      }
    }
    __syncthreads();
#pragma unroll
    for (int i = 0; i < 4; ++i) {
      int r0 = (w * 4 + i) * 16 + lg * 4;
      float4 gg = *(const float4*)(g2 + r0), bs = *(const float4*)(b2 + r0);
#pragma unroll
      for (int ct = 0; ct < 2; ++ct) {
        int col = ct * 16 + lr; int cx = (col & 7) << 4;
        ushort4 hv;
        hv.x = (unsigned short)f2bf(fmaxf(gg.x * acc[i][ct][0] + bs.x, 0.f));
        hv.y = (unsigned short)f2bf(fmaxf(gg.y * acc[i][ct][1] + bs.y, 0.f));
        hv.z = (unsigned short)f2bf(fmaxf(gg.z * acc[i][ct][2] + bs.z, 0.f));
        hv.w = (unsigned short)f2bf(fmaxf(gg.w * acc[i][ct][3] + bs.w, 0.f));
        *(ushort4*)(B1 + ((col * 512 + r0 * 2) ^ cx)) = hv;
      }
    }
  }
  __syncthreads();
  {
    f32x4 acc[4][2];
#pragma unroll
    for (int i = 0; i < 4; ++i) { acc[i][0] = (f32x4){0,0,0,0}; acc[i][1] = (f32x4){0,0,0,0}; }
    for (int kk = 0; kk < 8; ++kk) {
      int c1 = 16 + lr;
      short8b b0 = *(const short8b*)(B1 + ((lr * 512 + kk * 64 + lg * 16) ^ ((lr & 7) << 4)));
      short8b bb1 = *(const short8b*)(B1 + ((c1 * 512 + kk * 64 + lg * 16) ^ ((c1 & 7) << 4)));
#pragma unroll
      for (int i = 0; i < 4; ++i) {
        short8b a = *(const short8b*)(w3f + (((size_t)((w * 4 + i) * 8 + kk)) * 64 + l) * 8);
        acc[i][0] = __builtin_amdgcn_mfma_f32_16x16x32_bf16(a, b0, acc[i][0], 0, 0, 0);
        acc[i][1] = __builtin_amdgcn_mfma_f32_16x16x32_bf16(a, bb1, acc[i][1], 0, 0, 0);
      }
    }
#pragma unroll
    for (int i = 0; i < 4; ++i) {
      int r0 = (w * 4 + i) * 16 + lg * 4;
      float4 gg = *(const float4*)(g3 + r0), bs = *(const float4*)(b3 + r0);
#pragma unroll
      for (int ct = 0; ct < 2; ++ct) {
        int col = ct * 16 + lr;
        if (col < 20) {
          ushort4 hv;
          hv.x = (unsigned short)f2bf(fmaxf(gg.x * acc[i][ct][0] + bs.x, 0.f));
          hv.y = (unsigned short)f2bf(fmaxf(gg.y * acc[i][ct][1] + bs.y, 0.f));
          hv.z = (unsigned short)f2bf(fmaxf(gg.z * acc[i][ct][2] + bs.z, 0.f));
          hv.w = (unsigned short)f2bf(fmaxf(gg.w * acc[i][ct][3] + bs.w, 0.f));
          int s = col / 5, j = col % 5;
          *(ushort4*)(houtS + ((size_t)(tau0 + s) * 5 + j) * 256 + r0) = hv;
        }
      }
    }
  }
}

// ---- point transformer (i=0 only), all-MFMA, 8 tokens/block, 512 threads ----
__global__ __launch_bounds__(512, 4) void attn_kernel(
    const short* __restrict__ hbufS, const int* __restrict__ idx_s,
    const float* __restrict__ sxyz, const float* __restrict__ sbc,
    const float* __restrict__ txyz, const float* __restrict__ tbc,
    const short* __restrict__ aqf, const short* __restrict__ akpef, const short* __restrict__ avpef,
    const float* __restrict__ pw1, const float* __restrict__ pb1, const float* __restrict__ pb2,
    const short* __restrict__ aw1f, const float* __restrict__ ab1,
    const short* __restrict__ aw2f, const float* __restrict__ ab2,
    const float* __restrict__ sfeat,
    const short* __restrict__ fw1f, const float* __restrict__ fg1, const float* __restrict__ fb1,
    const short* __restrict__ fw2f, const float* __restrict__ fb2v,
    float* __restrict__ yout) {
  __shared__ __align__(16) char smem[79872];
  char* Bx   = smem;                       // [48][640] P0-P2
  char* vpeB = smem;                       // [40][512] P3-P6 (overlays dead Bx)
  char* feaB = smem;                       // [16][512] P7-P8
  char* feaH = smem + 8192;                // [16][512] P8-P9
  float* y2F = (float*)(smem + 16384);     // [8][260] f32 P9-P10
  char* KB   = smem + 30720;               // [48][512] P3-P4
  char* simS = smem + 30720;               // [40][528] P5-P6 (overlays dead KB)
  char* HpB  = smem + 55296;               // [48][512] P4
  float* qF  = (float*)(smem + 55296);     // [8][256] f32 P2a-P3 (pre-HpB)
  float* q04 = (float*)(smem + 55296);     // [8][256] f32 P6-P10 (post-HpB)
  float* redf = (float*)(smem + 63488);    // [128] f32 P6,P10
  float* pc4 = (float*)(smem + 64000);     // [40][12] f32 P0-P1
  int t = threadIdx.x;
  int tau0 = blockIdx.x * 8;
  int b = tau0 / Nc, n0 = tau0 % Nc;
  int w = t >> 6, l = t & 63, lg = l >> 4, lr = l & 15;
  int h = t >> 8, ch = t & 255;
  // NaN-safety: zero Bx cols 40..47 entirely (8 cols x 320 k)
  for (int z = t; z < 2560; z += 512) {
    int col = 40 + z / 320, k = z % 320;
    *(short*)(Bx + ((col * 640 + 2 * k) ^ ((col & 7) << 4))) = 0;
  }
  // P0: x -> Bx cols (k<256); pos vectors -> pc4
  for (int sj = h; sj < 40; sj += 2) {
    int s = sj / 5, j = sj % 5;
    *(short*)(Bx + ((sj * 640 + 2 * ch) ^ ((sj & 7) << 4))) =
        hbufS[(size_t)(tau0 + s) * 1280 + j * 256 + ch];
  }
  if (t < 40) {
    int s = t / 5, k = t % 5;
    int n = n0 + s;
    float* pd = pc4 + t * 12;
    if (k == 0) {
      for (int c = 0; c < 3; ++c) pd[c] = sxyz[((size_t)b * Nc + n) * 3 + c];
      for (int c = 0; c < 9; ++c) pd[3 + c] = sbc[((size_t)b * Nc + n) * 9 + c];
    } else {
      int m = idx_s[(((size_t)b * Nc + n) << 2) + (k - 1)];
      for (int c = 0; c < 3; ++c) pd[c] = txyz[((size_t)b * Mc + m) * 3 + c];
      for (int c = 0; c < 9; ++c) pd[3 + c] = tbc[((size_t)b * Mc + m) * 9 + c];
    }
  }
  __syncthreads();
  // P1: pe hidden (relu) -> Bx k = 256+h  (40 sj x 64 hidden)
  for (int it = t; it < 2560; it += 512) {
    int sj = it >> 6, hh = it & 63;
    int s = sj / 5;
    float acc = pb1[hh];
    const float* wv = pw1 + hh * 12;
    const float* p0 = pc4 + (s * 5) * 12;
    const float* pj = pc4 + sj * 12;
#pragma unroll
    for (int p = 0; p < 12; ++p) acc += wv[p] * (p0[p] - pj[p]);
    *(short*)(Bx + ((sj * 640 + 512 + 2 * hh) ^ ((sj & 7) << 4))) = f2bf(fmaxf(acc, 0.f));
  }
  __syncthreads();
  // P2a: q GEMM (K=256) -> qF scratch
  {
    f32x4 qA[2][3];
#pragma unroll
    for (int i = 0; i < 2; ++i)
#pragma unroll
      for (int ct = 0; ct < 3; ++ct) qA[i][ct] = (f32x4){0,0,0,0};
    for (int kk = 0; kk < 8; ++kk) {
      short8b bq[3];
#pragma unroll
      for (int ct = 0; ct < 3; ++ct) {
        int col = ct * 16 + lr;
        bq[ct] = *(const short8b*)(Bx + ((col * 640 + kk * 64 + lg * 16) ^ ((col & 7) << 4)));
      }
#pragma unroll
      for (int i = 0; i < 2; ++i) {
        short8b a = *(const short8b*)(aqf + (((size_t)((w * 2 + i) * 8 + kk)) * 64 + l) * 8);
#pragma unroll
        for (int ct = 0; ct < 3; ++ct)
          qA[i][ct] = __builtin_amdgcn_mfma_f32_16x16x32_bf16(a, bq[ct], qA[i][ct], 0, 0, 0);
      }
    }
#pragma unroll
    for (int i = 0; i < 2; ++i) {
      int r0 = (w * 2 + i) * 16 + lg * 4;
#pragma unroll
      for (int ct = 0; ct < 3; ++ct) {
        int col = ct * 16 + lr;
        if (col < 40 && col % 5 == 0)
          *(f32x4*)(qF + (col / 5) * 256 + r0) = qA[i][ct];
      }
    }
  }
  // P2b: (-k+pe) and (v+pe) GEMMs, K=320
  f32x4 sA[2][3], vA[2][3];
#pragma unroll
  for (int i = 0; i < 2; ++i)
#pragma unroll
    for (int ct = 0; ct < 3; ++ct) { sA[i][ct] = (f32x4){0,0,0,0}; vA[i][ct] = (f32x4){0,0,0,0}; }
  for (int kk = 0; kk < 10; ++kk) {
    short8b bb[3];
#pragma unroll
    for (int ct = 0; ct < 3; ++ct) {
      int col = ct * 16 + lr;
      bb[ct] = *(const short8b*)(Bx + ((col * 640 + kk * 64 + lg * 16) ^ ((col & 7) << 4)));
    }
#pragma unroll
    for (int i = 0; i < 2; ++i) {
      short8b ak = *(const short8b*)(akpef + (((size_t)((w * 2 + i) * 10 + kk)) * 64 + l) * 8);
      short8b av = *(const short8b*)(avpef + (((size_t)((w * 2 + i) * 10 + kk)) * 64 + l) * 8);
#pragma unroll
      for (int ct = 0; ct < 3; ++ct) {
        sA[i][ct] = __builtin_amdgcn_mfma_f32_16x16x32_bf16(ak, bb[ct], sA[i][ct], 0, 0, 0);
        vA[i][ct] = __builtin_amdgcn_mfma_f32_16x16x32_bf16(av, bb[ct], vA[i][ct], 0, 0, 0);
      }
    }
  }
  __syncthreads();
  // P3: KB = bf16(q + sA + pb2) (cols<40; zeros 40-47); vpeB = bf16(vA + pb2) (cols<40)
#pragma unroll
  for (int i = 0; i < 2; ++i) {
    int r0 = (w * 2 + i) * 16 + lg * 4;
    float4 pb = *(const float4*)(pb2 + r0);
#pragma unroll
    for (int ct = 0; ct < 3; ++ct) {
      int col = ct * 16 + lr; int cx = (col & 7) << 4;
      if (col < 40) {
        int s = col / 5;
        f32x4 qv = *(const f32x4*)(qF + s * 256 + r0);
        ushort4 kv, vv;
        kv.x = (unsigned short)f2bf(qv[0] + sA[i][ct][0] + pb.x);
        kv.y = (unsigned short)f2bf(qv[1] + sA[i][ct][1] + pb.y);
        kv.z = (unsigned short)f2bf(qv[2] + sA[i][ct][2] + pb.z);
        kv.w = (unsigned short)f2bf(qv[3] + sA[i][ct][3] + pb.w);
        vv.x = (unsigned short)f2bf(vA[i][ct][0] + pb.x);
        vv.y = (unsigned short)f2bf(vA[i][ct][1] + pb.y);
        vv.z = (unsigned short)f2bf(vA[i][ct][2] + pb.z);
        vv.w = (unsigned short)f2bf(vA[i][ct][3] + pb.w);
        *(ushort4*)(KB + ((col * 512 + r0 * 2) ^ cx)) = kv;
        *(ushort4*)(vpeB + ((col * 512 + r0 * 2) ^ cx)) = vv;
      } else {
        ushort4 zz; zz.x = zz.y = zz.z = zz.w = 0;
        *(ushort4*)(KB + ((col * 512 + r0 * 2) ^ cx)) = zz;
      }
    }
  }
  __syncthreads();
  // P4: amlp via MFMA: 4 panels of 256 hidden rows
  f32x4 sacc[2][3];
#pragma unroll
  for (int i = 0; i < 2; ++i)
#pragma unroll
    for (int ct = 0; ct < 3; ++ct) sacc[i][ct] = (f32x4){0,0,0,0};
  for (int p = 0; p < 4; ++p) {
    f32x4 hacc[2][3];
#pragma unroll
    for (int i = 0; i < 2; ++i)
#pragma unroll
      for (int ct = 0; ct < 3; ++ct) hacc[i][ct] = (f32x4){0,0,0,0};
    for (int kk = 0; kk < 8; ++kk) {
      short8b bb[3];
#pragma unroll
      for (int ct = 0; ct < 3; ++ct) {
        int col = ct * 16 + lr;
        bb[ct] = *(const short8b*)(KB + ((col * 512 + kk * 64 + lg * 16) ^ ((col & 7) << 4)));
      }
#pragma unroll
      for (int i = 0; i < 2; ++i) {
        int rtg = p * 16 + w * 2 + i;
        short8b a = *(const short8b*)(aw1f + (((size_t)(rtg * 8 + kk)) * 64 + l) * 8);
#pragma unroll
        for (int ct = 0; ct < 3; ++ct)
          hacc[i][ct] = __builtin_amdgcn_mfma_f32_16x16x32_bf16(a, bb[ct], hacc[i][ct], 0, 0, 0);
      }
    }
#pragma unroll
    for (int i = 0; i < 2; ++i) {
      int r0l = (w * 2 + i) * 16 + lg * 4;
      float4 bias = *(const float4*)(ab1 + p * 256 + r0l);
#pragma unroll
      for (int ct = 0; ct < 3; ++ct) {
        int col = ct * 16 + lr; int cx = (col & 7) << 4;
        ushort4 hv;
        hv.x = (unsigned short)f2bf(fmaxf(hacc[i][ct][0] + bias.x, 0.f));
        hv.y = (unsigned short)f2bf(fmaxf(hacc[i][ct][1] + bias.y, 0.f));
        hv.z = (unsigned short)f2bf(fmaxf(hacc[i][ct][2] + bias.z, 0.f));
        hv.w = (unsigned short)f2bf(fmaxf(hacc[i][ct][3] + bias.w, 0.f));
        *(ushort4*)(HpB + ((col * 512 + r0l * 2) ^ cx)) = hv;
      }
    }
    __syncthreads();
    for (int kk = 0; kk < 8; ++kk) {
      short8b bb[3];
#pragma unroll
      for (int ct = 0; ct < 3; ++ct) {
        int col = ct * 16 + lr;
        bb[ct] = *(const short8b*)(HpB + ((col * 512 + kk * 64 + lg * 16) ^ ((col & 7) << 4)));
      }
      int kkg = p * 8 + kk;
#pragma unroll
      for (int i = 0; i < 2; ++i) {
        short8b a = *(const short8b*)(aw2f + (((size_t)((w * 2 + i) * 32 + kkg)) * 64 + l) * 8);
#pragma unroll
        for (int ct = 0; ct < 3; ++ct)
          sacc[i][ct] = __builtin_amdgcn_mfma_f32_16x16x32_bf16(a, bb[ct], sacc[i][ct], 0, 0, 0);
      }
    }
    __syncthreads();
  }
  // P5: sim (+ab2) -> simS bf16 (cols < 40)
#pragma unroll
  for (int i = 0; i < 2; ++i) {
    int r0 = (w * 2 + i) * 16 + lg * 4;
    float4 bias = *(const float4*)(ab2 + r0);
#pragma unroll
    for (int ct = 0; ct < 3; ++ct) {
      int col = ct * 16 + lr;
      if (col < 40) {
        ushort4 hv;
        hv.x = (unsigned short)f2bf(sacc[i][ct][0] + bias.x);
        hv.y = (unsigned short)f2bf(sacc[i][ct][1] + bias.y);
        hv.z = (unsigned short)f2bf(sacc[i][ct][2] + bias.z);
        hv.w = (unsigned short)f2bf(sacc[i][ct][3] + bias.w);
        *(ushort4*)(simS + col * 528 + r0 * 2) = hv;
      }
    }
  }
  __syncthreads();
  // P6: softmax + aggregate + residual + instance norm -> q04 (each half: 4 tokens)
  float ffv[4];
#pragma unroll
  for (int si = 0; si < 4; ++si) {
    int s = h * 4 + si;
    float sv[5], vp[5];
#pragma unroll
    for (int j = 0; j < 5; ++j) {
      int sj = s * 5 + j;
      sv[j] = bf2f(*(const short*)(simS + sj * 528 + 2 * ch));
      vp[j] = bf2f(*(const short*)(vpeB + ((sj * 512 + 2 * ch) ^ ((sj & 7) << 4))));
    }
    float mx = sv[0];
#pragma unroll
    for (int j = 1; j < 5; ++j) mx = fmaxf(mx, sv[j]);
    float ssum = 0.f;
#pragma unroll
    for (int j = 0; j < 5; ++j) { sv[j] = expf(sv[j] - mx); ssum += sv[j]; }
    float inv = 1.f / ssum;
    float agg = 0.f;
#pragma unroll
    for (int j = 0; j < 5; ++j) agg += (sv[j] * inv) * vp[j];
    ffv[si] = agg + sfeat[((size_t)b * Fc + ch) * Nc + (n0 + s)];
  }
  {
    float rv[8];
#pragma unroll
    for (int si = 0; si < 4; ++si) { rv[si] = ffv[si]; rv[4 + si] = ffv[si] * ffv[si]; }
#pragma unroll
    for (int m = 1; m < 64; m <<= 1)
#pragma unroll
      for (int i2 = 0; i2 < 8; ++i2) rv[i2] += __shfl_xor(rv[i2], m);
    if ((t & 63) == 0)
#pragma unroll
      for (int i2 = 0; i2 < 8; ++i2) redf[w * 8 + i2] = rv[i2];
    __syncthreads();
#pragma unroll
    for (int si = 0; si < 4; ++si) {
      int s = h * 4 + si;
      float S = 0.f, Q = 0.f;
#pragma unroll
      for (int q2 = 0; q2 < 4; ++q2) {
        S += redf[(h * 4 + q2) * 8 + si];
        Q += redf[(h * 4 + q2) * 8 + 4 + si];
      }
      float mu = S * (1.f / 256.f);
      float var = Q * (1.f / 256.f) - mu * mu;
      q04[s * 256 + ch] = (ffv[si] - mu) / sqrtf(var + 1e-5f);
    }
  }
  __syncthreads();
  // P7: feaB cols 0-7 from q04; zero cols 8-15
  for (int z = t; z < 16 * 256; z += 512) {
    int col = z >> 8, k = z & 255;
    short val = (col < 8) ? f2bf(q04[col * 256 + k]) : (short)0;
    *(short*)(feaB + ((col * 512 + 2 * k) ^ ((col & 7) << 4))) = val;
  }
  __syncthreads();
  // P8: fea layer 1 -> feaH
  {
    f32x4 acc[2];
#pragma unroll
    for (int i = 0; i < 2; ++i) acc[i] = (f32x4){0,0,0,0};
    for (int kk = 0; kk < 8; ++kk) {
      short8b b0 = *(const short8b*)(feaB + ((lr * 512 + kk * 64 + lg * 16) ^ ((lr & 7) << 4)));
#pragma unroll
      for (int i = 0; i < 2; ++i) {
        short8b a = *(const short8b*)(fw1f + (((size_t)((w * 2 + i) * 8 + kk)) * 64 + l) * 8);
        acc[i] = __builtin_amdgcn_mfma_f32_16x16x32_bf16(a, b0, acc[i], 0, 0, 0);
      }
    }
#pragma unroll
    for (int i = 0; i < 2; ++i) {
      int r0 = (w * 2 + i) * 16 + lg * 4;
      float4 gg = *(const float4*)(fg1 + r0), bs = *(const float4*)(fb1 + r0);
      int cx = (lr & 7) << 4;
      ushort4 hv;
      hv.x = (unsigned short)f2bf(fmaxf(gg.x * acc[i][0] + bs.x, 0.f));
      hv.y = (unsigned short)f2bf(fmaxf(gg.y * acc[i][1] + bs.y, 0.f));
      hv.z = (unsigned short)f2bf(fmaxf(gg.z * acc[i][2] + bs.z, 0.f));
      hv.w = (unsigned short)f2bf(fmaxf(gg.w * acc[i][3] + bs.w, 0.f));
      *(ushort4*)(feaH + ((lr * 512 + r0 * 2) ^ cx)) = hv;
    }
  }
  __syncthreads();
  // P9: fea layer 2 -> y2F cols 0-7
  {
    f32x4 acc[2];
#pragma unroll
    for (int i = 0; i < 2; ++i) acc[i] = (f32x4){0,0,0,0};
    for (int kk = 0; kk < 8; ++kk) {
      short8b b0 = *(const short8b*)(feaH + ((lr * 512 + kk * 64 + lg * 16) ^ ((lr & 7) << 4)));
#pragma unroll
      for (int i = 0; i < 2; ++i) {
        short8b a = *(const short8b*)(fw2f + (((size_t)((w * 2 + i) * 8 + kk)) * 64 + l) * 8);
        acc[i] = __builtin_amdgcn_mfma_f32_16x16x32_bf16(a, b0, acc[i], 0, 0, 0);
      }
    }
#pragma unroll
    for (int i = 0; i < 2; ++i) {
      if (lr < 8) {
        int r0 = (w * 2 + i) * 16 + lg * 4;
        float4 bs = *(const float4*)(fb2v + r0);
        float4 v;
        v.x = acc[i][0] + bs.x; v.y = acc[i][1] + bs.y;
        v.z = acc[i][2] + bs.z; v.w = acc[i][3] + bs.w;
        *(float4*)(y2F + lr * 260 + r0) = v;
      }
    }
  }
  __syncthreads();
  // P10: z = y2 + ffn; instance norm; out
  {
    float zv[4];
#pragma unroll
    for (int si = 0; si < 4; ++si) {
      int s = h * 4 + si;
      zv[si] = y2F[s * 260 + ch] + q04[s * 256 + ch];
    }
    float rv[8];
#pragma unroll
    for (int si = 0; si < 4; ++si) { rv[si] = zv[si]; rv[4 + si] = zv[si] * zv[si]; }
#pragma unroll
    for (int m = 1; m < 64; m <<= 1)
#pragma unroll
      for (int i2 = 0; i2 < 8; ++i2) rv[i2] += __shfl_xor(rv[i2], m);
    if ((t & 63) == 0)
#pragma unroll
      for (int i2 = 0; i2 < 8; ++i2) redf[w * 8 + i2] = rv[i2];
    __syncthreads();
#pragma unroll
    for (int si = 0; si < 4; ++si) {
      int s = h * 4 + si;
      float S = 0.f, Q = 0.f;
#pragma unroll
      for (int q2 = 0; q2 < 4; ++q2) {
        S += redf[(h * 4 + q2) * 8 + si];
        Q += redf[(h * 4 + q2) * 8 + 4 + si];
      }
      float mu = S * (1.f / 256.f);
      float var = Q * (1.f / 256.f) - mu * mu;
      yout[((size_t)(tau0 + s)) * 256 + ch] = (zv[si] - mu) / sqrtf(var + 1e-5f);
    }
  }
}

// ---- PointSIFT octant-NN via shfl-butterfly argmin per octant ----
__global__ __launch_bounds__(256) void sift_idx_kernel(const float* __restrict__ sxyz,
                                                       int* __restrict__ sidx) {
  __shared__ unsigned long long red8[32];
  int b = blockIdx.x / Nc, i = blockIdx.x % Nc;
  int t = threadIdx.x;
  const float* x = sxyz + (size_t)b * Nc * 3;
  float xi0 = x[3 * i], xi1 = x[3 * i + 1], xi2 = x[3 * i + 2];
  unsigned long long k8[8];
#pragma unroll
  for (int o = 0; o < 8; ++o) k8[o] = ~0ULL;
  for (int q = 0; q < 4; ++q) {
    int j = t + q * 256;
    float dx = x[3 * j] - xi0, dy = x[3 * j + 1] - xi1, dz = x[3 * j + 2] - xi2;
    float d2 = dx * dx + dy * dy + dz * dz;
    bool ok = (d2 <= 0.25f) && (d2 > 0.f);
    int oc = (dx > 0.f ? 4 : 0) + (dy > 0.f ? 2 : 0) + (dz > 0.f ? 1 : 0);
    unsigned long long c = ((unsigned long long)__float_as_uint(d2) << 32) | (unsigned)j;
#pragma unroll
    for (int o = 0; o < 8; ++o) {
      unsigned long long cc = (ok && oc == o) ? c : ~0ULL;
      k8[o] = umin64(k8[o], cc);
    }
  }
#pragma unroll
  for (int m = 1; m < 64; m <<= 1)
#pragma unroll
    for (int o = 0; o < 8; ++o) k8[o] = umin64(k8[o], __shfl_xor(k8[o], m));
  if ((t & 63) == 0)
#pragma unroll
    for (int o = 0; o < 8; ++o) red8[(t >> 6) * 8 + o] = k8[o];
  __syncthreads();
  if (t < 8) {
    unsigned long long r = umin64(umin64(red8[t], red8[8 + t]), umin64(red8[16 + t], red8[24 + t]));
    int j = (r == ~0ULL) ? i : (int)(unsigned)r;
    sidx[(((size_t)b * Nc + i) << 3) + t] = j;
  }
}

// ---- fused PointSIFT OE: 3 (1,2)-convs via MFMA, 8 points/block, 512 threads ----
__global__ __launch_bounds__(512, 4) void sift_oe_kernel(
    const float* __restrict__ sxyz, const int* __restrict__ sidx,
    const float* __restrict__ yin,
    const short* __restrict__ w1f, const float* __restrict__ g1, const float* __restrict__ b1,
    const short* __restrict__ w2f, const float* __restrict__ g2, const float* __restrict__ b2,
    const short* __restrict__ w3f, const float* __restrict__ g3, const float* __restrict__ b3,
    float* __restrict__ yout) {
  __shared__ __align__(16) char smem[51200];
  char* B1 = smem;            // [32 cols][544k] bf16, stride 1088B = 34816; B3 aliases
  char* B2 = smem + 34816;    // [16 cols][512k] bf16, stride 1024B = 16384
  char* B3 = smem;            // [16 cols][1024B] aliases B1
  __shared__ int js[8][8];
  int t = threadIdx.x;
  int i0 = blockIdx.x * 8;
  int b = i0 / Nc, nb = i0 % Nc;
  int h = t >> 8, ch = t & 255;
  if (t < 64) js[t >> 3][t & 7] = sidx[(((size_t)b * Nc + nb + (t >> 3)) << 3) + (t & 7)];
  // NaN-safety: zero k-pad (k 518..543) for all 32 cols
  for (int z = t; z < 32 * 26; z += 512) {
    int col = z / 26, k = 518 + z % 26;
    *(short*)(B1 + ((col * 1088 + 2 * k) ^ ((col & 7) << 4))) = 0;
  }
  __syncthreads();
  // build B1: col = s*4+p, k = 2c+tp (c: 0-2 gxyz, 3-258 feat); half h does points h*4..h*4+3
  for (int si = 0; si < 4; ++si) {
    int s = h * 4 + si;
    int ii = nb + s;
#pragma unroll
    for (int p = 0; p < 4; ++p) {
      int ja = js[s][2 * p], jb = js[s][2 * p + 1];
      int col = s * 4 + p; int cx = (col & 7) << 4;
      float va = yin[((size_t)b * Nc + ja) * 256 + ch];
      float vb = yin[((size_t)b * Nc + jb) * 256 + ch];
      unsigned int packed = (unsigned int)(unsigned short)f2bf(va) |
                            ((unsigned int)(unsigned short)f2bf(vb) << 16);
      *(unsigned int*)(B1 + ((col * 1088 + 12 + 4 * ch) ^ cx)) = packed;
      if (ch < 3) {
        float base = sxyz[((size_t)b * Nc + ii) * 3 + ch];
        float ga = sxyz[((size_t)b * Nc + ja) * 3 + ch] - base;
        float gb = sxyz[((size_t)b * Nc + jb) * 3 + ch] - base;
        unsigned int pg = (unsigned int)(unsigned short)f2bf(ga) |
                          ((unsigned int)(unsigned short)f2bf(gb) << 16);
        *(unsigned int*)(B1 + ((col * 1088 + 4 * ch) ^ cx)) = pg;
      }
    }
  }
  __syncthreads();
  int l = t & 63, w = t >> 6, lg = l >> 4, lr = l & 15;
  // GEMM1: 256 x K518 (KT=17), 32 cols -> B2 in conv2-pair layout (16 cols)
  {
    f32x4 acc[2][2];
#pragma unroll
    for (int i = 0; i < 2; ++i) { acc[i][0] = (f32x4){0,0,0,0}; acc[i][1] = (f32x4){0,0,0,0}; }
    for (int kk = 0; kk < 17; ++kk) {
      short8b b0[2];
#pragma unroll
      for (int ct = 0; ct < 2; ++ct) {
        int col = ct * 16 + lr;
        b0[ct] = *(const short8b*)(B1 + ((col * 1088 + kk * 64 + lg * 16) ^ ((col & 7) << 4)));
      }
#pragma unroll
      for (int i = 0; i < 2; ++i) {
        short8b a = *(const short8b*)(w1f + (((size_t)((w * 2 + i) * 17 + kk)) * 64 + l) * 8);
#pragma unroll
        for (int ct = 0; ct < 2; ++ct)
          acc[i][ct] = __builtin_amdgcn_mfma_f32_16x16x32_bf16(a, b0[ct], acc[i][ct], 0, 0, 0);
      }
    }
    __syncthreads();
#pragma unroll
    for (int i = 0; i < 2; ++i) {
      int r0 = (w * 2 + i) * 16 + lg * 4;
      float4 gg = *(const float4*)(g1 + r0), bs = *(const float4*)(b1 + r0);
#pragma unroll
      for (int ct = 0; ct < 2; ++ct) {
        int col = ct * 16 + lr;
        int s = col >> 2, p = col & 3, p2 = p >> 1, tp = p & 1;
        int col2 = s * 2 + p2; int cx2 = (col2 & 7) << 4;
        *(short*)(B2 + ((col2 * 1024 + (2 * r0 + tp) * 2) ^ cx2)) =
            f2bf(fmaxf(gg.x * acc[i][ct][0] + bs.x, 0.f));
        *(short*)(B2 + ((col2 * 1024 + (2 * (r0 + 1) + tp) * 2) ^ cx2)) =
            f2bf(fmaxf(gg.y * acc[i][ct][1] + bs.y, 0.f));
        *(short*)(B2 + ((col2 * 1024 + (2 * (r0 + 2) + tp) * 2) ^ cx2)) =
            f2bf(fmaxf(gg.z * acc[i][ct][2] + bs.z, 0.f));
        *(short*)(B2 + ((col2 * 1024 + (2 * (r0 + 3) + tp) * 2) ^ cx2)) =
            f2bf(fmaxf(gg.w * acc[i][ct][3] + bs.w, 0.f));
      }
    }
  }
  __syncthreads();
  // GEMM2: 256 x K512, 16 cols -> B3 in conv3-pair layout (8 cols)
  {
    f32x4 acc[2];
#pragma unroll
    for (int i = 0; i < 2; ++i) acc[i] = (f32x4){0,0,0,0};
    for (int kk = 0; kk < 16; ++kk) {
      short8b b0 = *(const short8b*)(B2 + ((lr * 1024 + kk * 64 + lg * 16) ^ ((lr & 7) << 4)));
#pragma unroll
      for (int i = 0; i < 2; ++i) {
        short8b a = *(const short8b*)(w2f + (((size_t)((w * 2 + i) * 16 + kk)) * 64 + l) * 8);
        acc[i] = __builtin_amdgcn_mfma_f32_16x16x32_bf16(a, b0, acc[i], 0, 0, 0);
      }
    }
    __syncthreads();
    int s = lr >> 1, tp = lr & 1;
    int col3 = s; int cx3 = (col3 & 7) << 4;
#pragma unroll
    for (int i = 0; i < 2; ++i) {
      int r0 = (w * 2 + i) * 16 + lg * 4;
      float4 gg = *(const float4*)(g2 + r0), bs = *(const float4*)(b2 + r0);
      *(short*)(B3 + ((col3 * 1024 + (2 * r0 + tp) * 2) ^ cx3)) =
          f2bf(fmaxf(gg.x * acc[i][0] + bs.x, 0.f));
      *(short*)(B3 + ((col3 * 1024 + (2 * (r0 + 1) + tp) * 2) ^ cx3)) =
          f2bf(fmaxf(gg.y * acc[i][1] + bs.y, 0.f));
      *(short*)(B3 + ((col3 * 1024 + (2 * (r0 + 2) + tp) * 2) ^ cx3)) =
          f2bf(fmaxf(gg.z * acc[i][2] + bs.z, 0.f));
      *(short*)(B3 + ((col3 * 1024 + (2 * (r0 + 3) + tp) * 2) ^ cx3)) =
          f2bf(fmaxf(gg.w * acc[i][3] + bs.w, 0.f));
    }
  }
  __syncthreads();
  // GEMM3: 256 x K512 -> yout = yin + relu(g3*acc+b3)  (cols 0-7)
  {
    f32x4 acc[2];
#pragma unroll
    for (int i = 0; i < 2; ++i) acc[i] = (f32x4){0,0,0,0};
    for (int kk = 0; kk < 16; ++kk) {
      short8b b0 = *(const short8b*)(B3 + ((lr * 1024 + kk * 64 + lg * 16) ^ ((lr & 7) << 4)));
#pragma unroll
      for (int i = 0; i < 2; ++i) {
        short8b a = *(const short8b*)(w3f + (((size_t)((w * 2 + i) * 16 + kk)) * 64 + l) * 8);
        acc[i] = __builtin_amdgcn_mfma_f32_16x16x32_bf16(a, b0, acc[i], 0, 0, 0);
      }
    }
#pragma unroll
    for (int i = 0; i < 2; ++i) {
      if (lr < 8) {
        int s = lr;
        int r0 = (w * 2 + i) * 16 + lg * 4;
        float4 gg = *(const float4*)(g3 + r0), bs = *(const float4*)(b3 + r0);
        float4 yv = *(const float4*)(yin + ((size_t)(i0 + s)) * 256 + r0);
        float4 ov;
        ov.x = yv.x + fmaxf(gg.x * acc[i][0] + bs.x, 0.f);
        ov.y = yv.y + fmaxf(gg.y * acc[i][1] + bs.y, 0.f);
        ov.z = yv.z + fmaxf(gg.z * acc[i][2] + bs.z, 0.f);
        ov.w = yv.w + fmaxf(gg.w * acc[i][3] + bs.w, 0.f);
        *(float4*)(yout + ((size_t)(i0 + s)) * 256 + r0) = ov;
      }
    }
  }
}

// ---- final transpose (B,N,C) -> (B,C,N) into d_out ----
__global__ __launch_bounds__(256) void transpose_kernel(const float* __restrict__ yin,
                                                        float* __restrict__ out) {
  size_t idx = (size_t)blockIdx.x * 256 + threadIdx.x;
  int n = (int)(idx % Nc);
  size_t r = idx / Nc;
  int c = (int)(r % Fc);
  int b = (int)(r / Fc);
  out[idx] = yin[(((size_t)b * Nc + n) * 256) + c];
}

extern "C" void kernel_launch(void* const* d_in, const int* in_sizes, int n_in,
                              void* d_out, int out_size, void* d_ws, size_t ws_size,
                              hipStream_t stream) {
  (void)in_sizes; (void)n_in; (void)out_size; (void)ws_size;
  const float* tfeat = (const float*)d_in[0];
  const float* sfeat = (const float*)d_in[1];
  const float* txyz  = (const float*)d_in[2];
  const float* sxyz  = (const float*)d_in[3];
  const float* tbc   = (const float*)d_in[4];
  const float* sbc   = (const float*)d_in[5];
  const float* mw1 = (const float*)d_in[6];
  const float* mg1 = (const float*)d_in[7];
  const float* mb1 = (const float*)d_in[8];
  const float* mw2 = (const float*)d_in[9];
  const float* mg2 = (const float*)d_in[10];
  const float* mb2 = (const float*)d_in[11];
  const float* mw3 = (const float*)d_in[12];
  const float* mg3 = (const float*)d_in[13];
  const float* mb3 = (const float*)d_in[14];
  const float* fw1 = (const float*)d_in[15];
  const float* fg1 = (const float*)d_in[16];
  const float* fb1 = (const float*)d_in[17];
  const float* fw2 = (const float*)d_in[18];
  const float* fb2 = (const float*)d_in[19];
  const float* wqkv = (const float*)d_in[20];
  const float* pw1 = (const float*)d_in[21];
  const float* pb1 = (const float*)d_in[22];
  const float* pw2 = (const float*)d_in[23];
  const float* pb2 = (const float*)d_in[24];
  const float* aw1 = (const float*)d_in[25];
  const float* ab1 = (const float*)d_in[26];
  const float* aw2 = (const float*)d_in[27];
  const float* ab2 = (const float*)d_in[28];
  const float* o1w1 = (const float*)d_in[29];
  const float* o1g1 = (const float*)d_in[30];
  const float* o1b1 = (const float*)d_in[31];
  const float* o1w2 = (const float*)d_in[32];
  const float* o1g2 = (const float*)d_in[33];
  const float* o1b2 = (const float*)d_in[34];
  const float* o1w3 = (const float*)d_in[35];
  const float* o1g3 = (const float*)d_in[36];
  const float* o1b3 = (const float*)d_in[37];
  const float* o2w1 = (const float*)d_in[38];
  const float* o2g1 = (const float*)d_in[39];
  const float* o2b1 = (const float*)d_in[40];
  const float* o2w2 = (const float*)d_in[41];
  const float* o2g2 = (const float*)d_in[42];
  const float* o2b2 = (const float*)d_in[43];
  const float* o2w3 = (const float*)d_in[44];
  const float* o2g3 = (const float*)d_in[45];
  const float* o2b3 = (const float*)d_in[46];

  // workspace layout (identical to R7)
  float* ws = (float*)d_ws;
  float* sd   = ws;
  float* td   = sd + 65536;
  float* sscf = td + 32768;
  float* tscf = sscf + 12288;
  int*   idxs = (int*)(tscf + 6144);
  int*   sidx = idxs + 16384;
  float* yws  = (float*)(sidx + 32768);
  short* sb   = (short*)(yws + 1048576);
  short* hbufS = sb;
  short* mw1f  = sb + 5242880;
  short* mw2f  = mw1f + 73728;
  short* mw3f  = mw2f + 65536;
  short* aqf   = mw3f + 65536;
  short* akpef = aqf + 65536;
  short* avpef = akpef + 81920;
  short* aw1f  = avpef + 81920;
  short* aw2f  = aw1f + 262144;
  short* fw1f  = aw2f + 262144;
  short* fw2f  = fw1f + 65536;
  short* o1w1f = fw2f + 65536;
  short* o1w2f = o1w1f + 139264;
  short* o1w3f = o1w2f + 131072;
  short* o2w1f = o1w3f + 131072;
  short* o2w2f = o2w1f + 139264;
  short* o2w3f = o2w2f + 131072;
  float* ybuf2 = (float*)sb;

  WSrcs srcs;
  srcs.p[0] = mw1;  srcs.p[1] = mw2;  srcs.p[2] = mw3;  srcs.p[3] = wqkv;
  srcs.p[4] = wqkv; srcs.p[5] = wqkv; srcs.p[6] = aw1;  srcs.p[7] = aw2;
  srcs.p[8] = fw1;  srcs.p[9] = fw2;  srcs.p[10] = o1w1; srcs.p[11] = o1w2;
  srcs.p[12] = o1w3; srcs.p[13] = o2w1; srcs.p[14] = o2w2; srcs.p[15] = o2w3;
  wconv_all<<<7392, 256, 0, stream>>>(srcs, pw2, mw1f);

  scf_kernel<<<Bc, 256, 0, stream>>>(sxyz, sscf, Nc);
  scf_kernel<<<Bc, 256, 0, stream>>>(txyz, tscf, Mc);
  knn_kernel<Nc><<<Bc * Nc, 256, 0, stream>>>(sxyz, sd);
  knn_kernel<Mc><<<Bc * Mc, 256, 0, stream>>>(txyz, td);
  select_kernel<<<Bc * Nc, 256, 0, stream>>>(tbc, sbc, txyz, sxyz, sd, td, idxs);
  mlp_kernel<<<Bc * Nc / 4, 256, 0, stream>>>(sfeat, tfeat, sscf, tscf, idxs,
                                              mw1f, mg1, mb1, mw2f, mg2, mb2,
                                              mw3f, mg3, mb3, hbufS);
  attn_kernel<<<Bc * Nc / 8, 512, 0, stream>>>(hbufS, idxs, sxyz, sbc, txyz, tbc,
                                               aqf, akpef, avpef, pw1, pb1, pb2,
                                               aw1f, ab1, aw2f, ab2,
                                               sfeat, fw1f, fg1, fb1, fw2f, fb2, yws);
  sift_idx_kernel<<<Bc * Nc, 256, 0, stream>>>(sxyz, sidx);
  sift_oe_kernel<<<Bc * Nc / 8, 512, 0, stream>>>(sxyz, sidx, yws,
                                                  o1w1f, o1g1, o1b1, o1w2f, o1g2, o1b2,
                                                  o1w3f, o1g3, o1b3, ybuf2);
  sift_oe_kernel<<<Bc * Nc / 8, 512, 0, stream>>>(sxyz, sidx, ybuf2,
                                                  o2w1f, o2g1, o2b1, o2w2f, o2g2, o2b2,
                                                  o2w3f, o2g3, o2b3, yws);
  transpose_kernel<<<(Bc * Fc * Nc) / 256, 256, 0, stream>>>(yws, (float*)d_out);
}

// Round 9
// 339.347 us; speedup vs baseline: 33.1591x; 1.2203x over previous
//
#include <hip/hip_runtime.h>
#include <hip/hip_bf16.h>
#include <math.h>

// Problem constants (match reference)
constexpr int Bc = 4, Mc = 512, Nc = 1024, Fc = 256;
constexpr int KCc = 16;
constexpr float INFF = 3.0e38f;

typedef __attribute__((ext_vector_type(8))) short short8b;  // 8 bf16 (4 VGPRs)
typedef __attribute__((ext_vector_type(4))) float f32x4;

__device__ __forceinline__ short f2bf(float f) {
  __hip_bfloat16 h = __float2bfloat16(f);
  return *reinterpret_cast<short*>(&h);
}
__device__ __forceinline__ float bf2f(short s) {
  unsigned int u = ((unsigned int)(unsigned short)s) << 16;
  return __uint_as_float(u);
}
__device__ __forceinline__ unsigned long long umin64(unsigned long long a, unsigned long long b) {
  return a < b ? a : b;
}

__device__ __forceinline__ float blk_sum(float v, float* red) {
  int t = threadIdx.x;
  red[t] = v;
  __syncthreads();
  for (int s = 128; s > 0; s >>= 1) {
    if (t < s) red[t] += red[t + s];
    __syncthreads();
  }
  float r = red[0];
  __syncthreads();
  return r;
}

// ---- merged weight relayout: 16 jobs, one kernel ----
struct WSrcs { const float* p[16]; };
__global__ __launch_bounds__(256) void wconv_all(WSrcs s, const float* __restrict__ pw2,
                                                 short* __restrict__ dstbase) {
  const int ofs[16] = {0, 73728, 139264, 204800, 270336, 352256, 434176, 696320,
                       958464, 1024000, 1089536, 1228800, 1359872, 1490944, 1630208, 1761280};
  const int Kt[16]  = {259, 256, 256, 256, 320, 320, 256, 1024, 256, 256, 518, 512, 512, 518, 512, 512};
  const int KTt[16] = {9, 8, 8, 8, 10, 10, 8, 32, 8, 8, 17, 16, 16, 17, 16, 16};
  int gi = blockIdx.x * 256 + threadIdx.x;
  if (gi >= 1892352) return;
  int job = 0;
#pragma unroll
  for (int j2 = 1; j2 < 16; ++j2)
    if (gi >= ofs[j2]) job = j2;
  int i = gi - ofs[job];
  int K = Kt[job], KT = KTt[job];
  int e = i & 7, l = (i >> 3) & 63, q = i >> 9;
  int kk = q % KT, rt = q / KT;
  int r = rt * 16 + (l & 15);
  int k = kk * 32 + (l >> 4) * 8 + e;
  float v;
  if (job == 4)
    v = (k < 256) ? -s.p[4][(size_t)(256 + r) * 256 + k] : pw2[(size_t)r * 64 + (k - 256)];
  else if (job == 5)
    v = (k < 256) ? s.p[5][(size_t)(512 + r) * 256 + k] : pw2[(size_t)r * 64 + (k - 256)];
  else
    v = (k < K) ? s.p[job][(size_t)r * K + k] : 0.f;
  dstbase[gi] = f2bf(v);
}

// ---- spherical coords of points relative to centroid -> out (B,3,P) ----
__global__ __launch_bounds__(256) void scf_kernel(const float* __restrict__ xyz,
                                                  float* __restrict__ out, int P) {
  __shared__ float red[256];
  int b = blockIdx.x;
  const float* x = xyz + (size_t)b * P * 3;
  float sx = 0.f, sy = 0.f, sz = 0.f;
  for (int i = threadIdx.x; i < P; i += 256) {
    sx += x[3 * i]; sy += x[3 * i + 1]; sz += x[3 * i + 2];
  }
  float mx = blk_sum(sx, red) / (float)P;
  float my = blk_sum(sy, red) / (float)P;
  float mz = blk_sum(sz, red) / (float)P;
  for (int i = threadIdx.x; i < P; i += 256) {
    float a = x[3 * i] - mx, c = x[3 * i + 1] - my, d = x[3 * i + 2] - mz;
    float r = sqrtf(a * a + c * c + d * d + 1e-8f);
    float ct = d / r;
    ct = fminf(1.f, fmaxf(-1.f, ct));
    out[((size_t)b * 3 + 0) * P + i] = r;
    out[((size_t)b * 3 + 1) * P + i] = acosf(ct);
    out[((size_t)b * 3 + 2) * P + i] = atan2f(c, a);
  }
}

// ---- KNN descriptor: ONE WAVE PER POINT, zero barriers ----
// 4 waves/block, each wave owns point pt = blockIdx*4 + wave. All P distances
// in wave registers (P/64 per lane); argmin rounds are pure shfl butterflies.
template <int P>
__global__ __launch_bounds__(256) void knn_kernel(const float* __restrict__ xyz,
                                                  float* __restrict__ desc) {
  constexpr int E = P / 64;
  int wv = threadIdx.x >> 6, l = threadIdx.x & 63;
  int pt = blockIdx.x * 4 + wv;
  int b = pt / P, i = pt % P;
  const float* x = xyz + (size_t)b * P * 3;
  float xi0 = x[3 * i], xi1 = x[3 * i + 1], xi2 = x[3 * i + 2];
  float d2r[E];
#pragma unroll
  for (int q = 0; q < E; ++q) {
    int j = q * 64 + l;
    float dx = x[3 * j] - xi0, dy = x[3 * j + 1] - xi1, dz = x[3 * j + 2] - xi2;
    d2r[q] = dx * dx + dy * dy + dz * dz;
  }
  for (int round = 0; round < KCc + 1; ++round) {
    unsigned long long k = ~0ULL;
#pragma unroll
    for (int q = 0; q < E; ++q) {
      unsigned long long c =
          ((unsigned long long)__float_as_uint(d2r[q]) << 32) | (unsigned)(q * 64 + l);
      k = umin64(k, c);
    }
#pragma unroll
    for (int m = 1; m < 64; m <<= 1) k = umin64(k, __shfl_xor(k, m));
    int widx = (int)(unsigned)k;
    if (round > 0 && l == 0)
      desc[((size_t)b * P + i) * KCc + (round - 1)] = sqrtf(__uint_as_float((unsigned)(k >> 32)));
    if ((widx & 63) == l) {
      int q = widx >> 6;
#pragma unroll
      for (int qq = 0; qq < E; ++qq)
        if (qq == q) d2r[qq] = INFF;
    }
  }
}

// ---- candidate pruning: ONE WAVE PER POINT, zero barriers ----
__global__ __launch_bounds__(256) void select_kernel(
    const float* __restrict__ tbc, const float* __restrict__ sbc,
    const float* __restrict__ txyz, const float* __restrict__ sxyz,
    const float* __restrict__ sd, const float* __restrict__ td,
    int* __restrict__ idx_s) {
  __shared__ int cand4[4][24];
  int wv = threadIdx.x >> 6, l = threadIdx.x & 63;
  int pt = blockIdx.x * 4 + wv;
  int b = pt / Nc, n = pt % Nc;
  const float* sb = sbc + ((size_t)b * Nc + n) * 9;
  float sreg[9];
#pragma unroll
  for (int c = 0; c < 9; ++c) sreg[c] = sb[c];
  float d2r[8];
#pragma unroll
  for (int q = 0; q < 8; ++q) {
    int m = q * 64 + l;
    const float* tb = tbc + ((size_t)b * Mc + m) * 9;
    float acc = 0.f;
#pragma unroll
    for (int c = 0; c < 9; ++c) { float d = tb[c] - sreg[c]; acc += d * d; }
    d2r[q] = acc;
  }
  for (int round = 0; round < 24; ++round) {
    unsigned long long k = ~0ULL;
#pragma unroll
    for (int q = 0; q < 8; ++q) {
      unsigned long long c =
          ((unsigned long long)__float_as_uint(d2r[q]) << 32) | (unsigned)(q * 64 + l);
      k = umin64(k, c);
    }
#pragma unroll
    for (int m = 1; m < 64; m <<= 1) k = umin64(k, __shfl_xor(k, m));
    int widx = (int)(unsigned)k;
    if (l == 0) cand4[wv][round] = widx;
    if ((widx & 63) == l) {
      int q = widx >> 6;
#pragma unroll
      for (int qq = 0; qq < 8; ++qq)
        if (qq == q) d2r[qq] = INFF;
    }
  }
  if (l == 0) {
    int* cand = cand4[wv];
    const float* sp = sxyz + ((size_t)b * Nc + n) * 3;
    float sx = sp[0], sy = sp[1], sz = sp[2];
    float dv[24];
    for (int t2 = 0; t2 < 24; ++t2) {
      const float* tp = txyz + ((size_t)b * Mc + cand[t2]) * 3;
      float dx = tp[0] - sx, dy = tp[1] - sy, dz = tp[2] - sz;
      dv[t2] = dx * dx + dy * dy + dz * dz;
    }
    int c8[8]; bool used[24];
    for (int t2 = 0; t2 < 24; ++t2) used[t2] = false;
    for (int r = 0; r < 8; ++r) {
      float bv = INFF; int bt = -1, bm = 0x7fffffff;
      for (int t2 = 0; t2 < 24; ++t2) {
        if (used[t2]) continue;
        int m = cand[t2];
        if (bt < 0 || dv[t2] < bv || (dv[t2] == bv && m < bm)) { bv = dv[t2]; bt = t2; bm = m; }
      }
      used[bt] = true; c8[r] = bm;
    }
    const float* sdp = sd + ((size_t)b * Nc + n) * KCc;
    float sdr[16];
    for (int t2 = 0; t2 < 16; ++t2) sdr[t2] = sdp[t2];
    float dscf[8];
    for (int r = 0; r < 8; ++r) {
      const float* tdp = td + ((size_t)b * Mc + c8[r]) * KCc;
      float acc = 0.f;
      for (int t2 = 0; t2 < 16; ++t2) { float d = sdr[t2] - tdp[t2]; acc += d * d; }
      dscf[r] = acc;
    }
    bool u8[8] = {false, false, false, false, false, false, false, false};
    for (int r = 0; r < 4; ++r) {
      float bv = INFF; int bt = -1, bm = 0x7fffffff;
      for (int t2 = 0; t2 < 8; ++t2) {
        if (u8[t2]) continue;
        if (bt < 0 || dscf[t2] < bv || (dscf[t2] == bv && c8[t2] < bm)) { bv = dscf[t2]; bt = t2; bm = c8[t2]; }
      }
      u8[bt] = true;
      idx_s[(((size_t)b * Nc + n) << 2) + r] = bm;
    }
  }
}

// ---- grouping + 3-layer MLP via bf16 MFMA (frag-order A), 4 tokens/block ----
__global__ __launch_bounds__(256) void mlp_kernel(
    const float* __restrict__ sfeat, const float* __restrict__ tfeat,
    const float* __restrict__ sscf, const float* __restrict__ tscf,
    const int* __restrict__ idx_s,
    const short* __restrict__ w1f, const float* __restrict__ g1, const float* __restrict__ b1,
    const short* __restrict__ w2f, const float* __restrict__ g2, const float* __restrict__ b2,
    const short* __restrict__ w3f, const float* __restrict__ g3, const float* __restrict__ b3,
    short* __restrict__ houtS) {
  __shared__ __align__(16) char smem[34816];
  char* B1 = smem;
  char* B2 = smem + 18432;
  __shared__ int ms[16];
  int t = threadIdx.x;
  int tau0 = blockIdx.x * 4;
  int b = tau0 / Nc, n0 = tau0 % Nc;
  if (t < 16) ms[t] = idx_s[(((size_t)b * Nc + n0 + (t >> 2)) << 2) + (t & 3)];
  __syncthreads();
  for (int z = t; z < 32 * 29; z += 256) {
    int col = z / 29, k = 259 + z % 29;
    *(short*)(B1 + ((col * 576 + 2 * k) ^ ((col & 7) << 4))) = 0;
  }
  for (int z = t; z < 12 * 259; z += 256) {
    int col = 20 + z / 259, k = z % 259;
    *(short*)(B1 + ((col * 576 + 2 * k) ^ ((col & 7) << 4))) = 0;
  }
  for (int s = 0; s < 4; ++s) {
    int n = n0 + s;
    {
      int col = s * 5; int cx = (col & 7) << 4;
      *(short*)(B1 + ((col * 576 + t * 2) ^ cx)) = f2bf(sfeat[((size_t)b * Fc + t) * Nc + n]);
      if (t < 3) *(short*)(B1 + ((col * 576 + (256 + t) * 2) ^ cx)) = f2bf(sscf[((size_t)b * 3 + t) * Nc + n]);
    }
    for (int k = 1; k < 5; ++k) {
      int m = ms[s * 4 + k - 1];
      int col = s * 5 + k; int cx = (col & 7) << 4;
      *(short*)(B1 + ((col * 576 + t * 2) ^ cx)) = f2bf(tfeat[((size_t)b * Fc + t) * Mc + m]);
      if (t < 3) *(short*)(B1 + ((col * 576 + (256 + t) * 2) ^ cx)) = f2bf(tscf[((size_t)b * 3 + t) * Mc + m]);
    }
  }
  __syncthreads();
  int l = t & 63, w = t >> 6, lg = l >> 4, lr = l & 15;
  {
    f32x4 acc[4][2];
#pragma unroll
    for (int i = 0; i < 4; ++i) { acc[i][0] = (f32x4){0,0,0,0}; acc[i][1] = (f32x4){0,0,0,0}; }
    for (int kk = 0; kk < 9; ++kk) {
      int c1 = 16 + lr;
      short8b b0 = *(const short8b*)(B1 + ((lr * 576 + kk * 64 + lg * 16) ^ ((lr & 7) << 4)));
      short8b bb1 = *(const short8b*)(B1 + ((c1 * 576 + kk * 64 + lg * 16) ^ ((c1 & 7) << 4)));
#pragma unroll
      for (int i = 0; i < 4; ++i) {
        short8b a = *(const short8b*)(w1f + (((size_t)((w * 4 + i) * 9 + kk)) * 64 + l) * 8);
        acc[i][0] = __builtin_amdgcn_mfma_f32_16x16x32_bf16(a, b0, acc[i][0], 0, 0, 0);
        acc[i][1] = __builtin_amdgcn_mfma_f32_16x16x32_bf16(a, bb1, acc[i][1], 0, 0, 0);
      }
    }
    __syncthreads();
#pragma unroll
    for (int i = 0; i < 4; ++i) {
      int r0 = (w * 4 + i) * 16 + lg * 4;
      float4 gg = *(const float4*)(g1 + r0), bs = *(const float4*)(b1 + r0);
#pragma unroll
      for (int ct = 0; ct < 2; ++ct) {
        int col = ct * 16 + lr; int cx = (col & 7) << 4;
        ushort4 hv;
        hv.x = (unsigned short)f2bf(fmaxf(gg.x * acc[i][ct][0] + bs.x, 0.f));
        hv.y = (unsigned short)f2bf(fmaxf(gg.y * acc[i][ct][1] + bs.y, 0.f));
        hv.z = (unsigned short)f2bf(fmaxf(gg.z * acc[i][ct][2] + bs.z, 0.f));
        hv.w = (unsigned short)f2bf(fmaxf(gg.w * acc[i][ct][3] + bs.w, 0.f));
        *(ushort4*)(B2 + ((col * 512 + r0 * 2) ^ cx)) = hv;
      }
    }
  }
  __syncthreads();
  {
    f32x4 acc[4][2];
#pragma unroll
    for (int i = 0; i < 4; ++i) { acc[i][0] = (f32x4){0,0,0,0}; acc[i][1] = (f32x4){0,0,0,0}; }
    for (int kk = 0; kk < 8; ++kk) {
      int c1 = 16 + lr;
      short8b b0 = *(const short8b*)(B2 + ((lr * 512 + kk * 64 + lg * 16) ^ ((lr & 7) << 4)));
      short8b bb1 = *(const short8b*)(B2 + ((c1 * 512 + kk * 64 + lg * 16) ^ ((c1 & 7) << 4)));
#pragma unroll
      for (int i = 0; i < 4; ++i) {
        short8b a = *(const short8b*)(w2f + (((size_t)((w * 4 + i) * 8 + kk)) * 64 + l) * 8);
        acc[i][0] = __builtin_amdgcn_mfma_f32_16x16x32_bf16(a, b0, acc[i][0], 0, 0, 0);
        acc[i][1] = __builtin_amdgcn_mfma_f32_16x16x32_bf16(a, bb1, acc[i][1], 0, 0, 0);
      }
    }
    __syncthreads();
#pragma unroll
    for (int i = 0; i < 4; ++i) {
      int r0 = (w * 4 + i) * 16 + lg * 4;
      float4 gg = *(const float4*)(g2 + r0), bs = *(const float4*)(b2 + r0);
#pragma unroll
      for (int ct = 0; ct < 2; ++ct) {
        int col = ct * 16 + lr; int cx = (col & 7) << 4;
        ushort4 hv;
        hv.x = (unsigned short)f2bf(fmaxf(gg.x * acc[i][ct][0] + bs.x, 0.f));
        hv.y = (unsigned short)f2bf(fmaxf(gg.y * acc[i][ct][1] + bs.y, 0.f));
        hv.z = (unsigned short)f2bf(fmaxf(gg.z * acc[i][ct][2] + bs.z, 0.f));
        hv.w = (unsigned short)f2bf(fmaxf(gg.w * acc[i][ct][3] + bs.w, 0.f));
        *(ushort4*)(B1 + ((col * 512 + r0 * 2) ^ cx)) = hv;
      }
    }
  }
  __syncthreads();
  {
    f32x4 acc[4][2];
#pragma unroll
    for (int i = 0; i < 4; ++i) { acc[i][0] = (f32x4){0,0,0,0}; acc[i][1] = (f32x4){0,0,0,0}; }
    for (int kk = 0; kk < 8; ++kk) {
      int c1 = 16 + lr;
      short8b b0 = *(const short8b*)(B1 + ((lr * 512 + kk * 64 + lg * 16) ^ ((lr & 7) << 4)));
      short8b bb1 = *(const short8b*)(B1 + ((c1 * 512 + kk * 64 + lg * 16) ^ ((c1 & 7) << 4)));
#pragma unroll
      for (int i = 0; i < 4; ++i) {
        short8b a = *(const short8b*)(w3f + (((size_t)((w * 4 + i) * 8 + kk)) * 64 + l) * 8);
        acc[i][0] = __builtin_amdgcn_mfma_f32_16x16x32_bf16(a, b0, acc[i][0], 0, 0, 0);
        acc[i][1] = __builtin_amdgcn_mfma_f32_16x16x32_bf16(a, bb1, acc[i][1], 0, 0, 0);
      }
    }
#pragma unroll
    for (int i = 0; i < 4; ++i) {
      int r0 = (w * 4 + i) * 16 + lg * 4;
      float4 gg = *(const float4*)(g3 + r0), bs = *(const float4*)(b3 + r0);
#pragma unroll
      for (int ct = 0; ct < 2; ++ct) {
        int col = ct * 16 + lr;
        if (col < 20) {
          ushort4 hv;
          hv.x = (unsigned short)f2bf(fmaxf(gg.x * acc[i][ct][0] + bs.x, 0.f));
          hv.y = (unsigned short)f2bf(fmaxf(gg.y * acc[i][ct][1] + bs.y, 0.f));
          hv.z = (unsigned short)f2bf(fmaxf(gg.z * acc[i][ct][2] + bs.z, 0.f));
          hv.w = (unsigned short)f2bf(fmaxf(gg.w * acc[i][ct][3] + bs.w, 0.f));
          int s = col / 5, j = col % 5;
          *(ushort4*)(houtS + ((size_t)(tau0 + s) * 5 + j) * 256 + r0) = hv;
        }
      }
    }
  }
}

// ---- point transformer (i=0 only), all-MFMA, 8 tokens/block, 512 threads ----
__global__ __launch_bounds__(512, 4) void attn_kernel(
    const short* __restrict__ hbufS, const int* __restrict__ idx_s,
    const float* __restrict__ sxyz, const float* __restrict__ sbc,
    const float* __restrict__ txyz, const float* __restrict__ tbc,
    const short* __restrict__ aqf, const short* __restrict__ akpef, const short* __restrict__ avpef,
    const float* __restrict__ pw1, const float* __restrict__ pb1, const float* __restrict__ pb2,
    const short* __restrict__ aw1f, const float* __restrict__ ab1,
    const short* __restrict__ aw2f, const float* __restrict__ ab2,
    const float* __restrict__ sfeat,
    const short* __restrict__ fw1f, const float* __restrict__ fg1, const float* __restrict__ fb1,
    const short* __restrict__ fw2f, const float* __restrict__ fb2v,
    float* __restrict__ yout) {
  __shared__ __align__(16) char smem[79872];
  char* Bx   = smem;
  char* vpeB = smem;
  char* feaB = smem;
  char* feaH = smem + 8192;
  float* y2F = (float*)(smem + 16384);
  char* KB   = smem + 30720;
  char* simS = smem + 30720;
  char* HpB  = smem + 55296;
  float* qF  = (float*)(smem + 55296);
  float* q04 = (float*)(smem + 55296);
  float* redf = (float*)(smem + 63488);
  float* pc4 = (float*)(smem + 64000);
  int t = threadIdx.x;
  int tau0 = blockIdx.x * 8;
  int b = tau0 / Nc, n0 = tau0 % Nc;
  int w = t >> 6, l = t & 63, lg = l >> 4, lr = l & 15;
  int h = t >> 8, ch = t & 255;
  for (int z = t; z < 2560; z += 512) {
    int col = 40 + z / 320, k = z % 320;
    *(short*)(Bx + ((col * 640 + 2 * k) ^ ((col & 7) << 4))) = 0;
  }
  for (int sj = h; sj < 40; sj += 2) {
    int s = sj / 5, j = sj % 5;
    *(short*)(Bx + ((sj * 640 + 2 * ch) ^ ((sj & 7) << 4))) =
        hbufS[(size_t)(tau0 + s) * 1280 + j * 256 + ch];
  }
  if (t < 40) {
    int s = t / 5, k = t % 5;
    int n = n0 + s;
    float* pd = pc4 + t * 12;
    if (k == 0) {
      for (int c = 0; c < 3; ++c) pd[c] = sxyz[((size_t)b * Nc + n) * 3 + c];
      for (int c = 0; c < 9; ++c) pd[3 + c] = sbc[((size_t)b * Nc + n) * 9 + c];
    } else {
      int m = idx_s[(((size_t)b * Nc + n) << 2) + (k - 1)];
      for (int c = 0; c < 3; ++c) pd[c] = txyz[((size_t)b * Mc + m) * 3 + c];
      for (int c = 0; c < 9; ++c) pd[3 + c] = tbc[((size_t)b * Mc + m) * 9 + c];
    }
  }
  __syncthreads();
  for (int it = t; it < 2560; it += 512) {
    int sj = it >> 6, hh = it & 63;
    int s = sj / 5;
    float acc = pb1[hh];
    const float* wv = pw1 + hh * 12;
    const float* p0 = pc4 + (s * 5) * 12;
    const float* pj = pc4 + sj * 12;
#pragma unroll
    for (int p = 0; p < 12; ++p) acc += wv[p] * (p0[p] - pj[p]);
    *(short*)(Bx + ((sj * 640 + 512 + 2 * hh) ^ ((sj & 7) << 4))) = f2bf(fmaxf(acc, 0.f));
  }
  __syncthreads();
  {
    f32x4 qA[2][3];
#pragma unroll
    for (int i = 0; i < 2; ++i)
#pragma unroll
      for (int ct = 0; ct < 3; ++ct) qA[i][ct] = (f32x4){0,0,0,0};
    for (int kk = 0; kk < 8; ++kk) {
      short8b bq[3];
#pragma unroll
      for (int ct = 0; ct < 3; ++ct) {
        int col = ct * 16 + lr;
        bq[ct] = *(const short8b*)(Bx + ((col * 640 + kk * 64 + lg * 16) ^ ((col & 7) << 4)));
      }
#pragma unroll
      for (int i = 0; i < 2; ++i) {
        short8b a = *(const short8b*)(aqf + (((size_t)((w * 2 + i) * 8 + kk)) * 64 + l) * 8);
#pragma unroll
        for (int ct = 0; ct < 3; ++ct)
          qA[i][ct] = __builtin_amdgcn_mfma_f32_16x16x32_bf16(a, bq[ct], qA[i][ct], 0, 0, 0);
      }
    }
#pragma unroll
    for (int i = 0; i < 2; ++i) {
      int r0 = (w * 2 + i) * 16 + lg * 4;
#pragma unroll
      for (int ct = 0; ct < 3; ++ct) {
        int col = ct * 16 + lr;
        if (col < 40 && col % 5 == 0)
          *(f32x4*)(qF + (col / 5) * 256 + r0) = qA[i][ct];
      }
    }
  }
  f32x4 sA[2][3], vA[2][3];
#pragma unroll
  for (int i = 0; i < 2; ++i)
#pragma unroll
    for (int ct = 0; ct < 3; ++ct) { sA[i][ct] = (f32x4){0,0,0,0}; vA[i][ct] = (f32x4){0,0,0,0}; }
  for (int kk = 0; kk < 10; ++kk) {
    short8b bb[3];
#pragma unroll
    for (int ct = 0; ct < 3; ++ct) {
      int col = ct * 16 + lr;
      bb[ct] = *(const short8b*)(Bx + ((col * 640 + kk * 64 + lg * 16) ^ ((col & 7) << 4)));
    }
#pragma unroll
    for (int i = 0; i < 2; ++i) {
      short8b ak = *(const short8b*)(akpef + (((size_t)((w * 2 + i) * 10 + kk)) * 64 + l) * 8);
      short8b av = *(const short8b*)(avpef + (((size_t)((w * 2 + i) * 10 + kk)) * 64 + l) * 8);
#pragma unroll
      for (int ct = 0; ct < 3; ++ct) {
        sA[i][ct] = __builtin_amdgcn_mfma_f32_16x16x32_bf16(ak, bb[ct], sA[i][ct], 0, 0, 0);
        vA[i][ct] = __builtin_amdgcn_mfma_f32_16x16x32_bf16(av, bb[ct], vA[i][ct], 0, 0, 0);
      }
    }
  }
  __syncthreads();
#pragma unroll
  for (int i = 0; i < 2; ++i) {
    int r0 = (w * 2 + i) * 16 + lg * 4;
    float4 pb = *(const float4*)(pb2 + r0);
#pragma unroll
    for (int ct = 0; ct < 3; ++ct) {
      int col = ct * 16 + lr; int cx = (col & 7) << 4;
      if (col < 40) {
        int s = col / 5;
        f32x4 qv = *(const f32x4*)(qF + s * 256 + r0);
        ushort4 kv, vv;
        kv.x = (unsigned short)f2bf(qv[0] + sA[i][ct][0] + pb.x);
        kv.y = (unsigned short)f2bf(qv[1] + sA[i][ct][1] + pb.y);
        kv.z = (unsigned short)f2bf(qv[2] + sA[i][ct][2] + pb.z);
        kv.w = (unsigned short)f2bf(qv[3] + sA[i][ct][3] + pb.w);
        vv.x = (unsigned short)f2bf(vA[i][ct][0] + pb.x);
        vv.y = (unsigned short)f2bf(vA[i][ct][1] + pb.y);
        vv.z = (unsigned short)f2bf(vA[i][ct][2] + pb.z);
        vv.w = (unsigned short)f2bf(vA[i][ct][3] + pb.w);
        *(ushort4*)(KB + ((col * 512 + r0 * 2) ^ cx)) = kv;
        *(ushort4*)(vpeB + ((col * 512 + r0 * 2) ^ cx)) = vv;
      } else {
        ushort4 zz; zz.x = zz.y = zz.z = zz.w = 0;
        *(ushort4*)(KB + ((col * 512 + r0 * 2) ^ cx)) = zz;
      }
    }
  }
  __syncthreads();
  f32x4 sacc[2][3];
#pragma unroll
  for (int i = 0; i < 2; ++i)
#pragma unroll
    for (int ct = 0; ct < 3; ++ct) sacc[i][ct] = (f32x4){0,0,0,0};
  for (int p = 0; p < 4; ++p) {
    f32x4 hacc[2][3];
#pragma unroll
    for (int i = 0; i < 2; ++i)
#pragma unroll
      for (int ct = 0; ct < 3; ++ct) hacc[i][ct] = (f32x4){0,0,0,0};
    for (int kk = 0; kk < 8; ++kk) {
      short8b bb[3];
#pragma unroll
      for (int ct = 0; ct < 3; ++ct) {
        int col = ct * 16 + lr;
        bb[ct] = *(const short8b*)(KB + ((col * 512 + kk * 64 + lg * 16) ^ ((col & 7) << 4)));
      }
#pragma unroll
      for (int i = 0; i < 2; ++i) {
        int rtg = p * 16 + w * 2 + i;
        short8b a = *(const short8b*)(aw1f + (((size_t)(rtg * 8 + kk)) * 64 + l) * 8);
#pragma unroll
        for (int ct = 0; ct < 3; ++ct)
          hacc[i][ct] = __builtin_amdgcn_mfma_f32_16x16x32_bf16(a, bb[ct], hacc[i][ct], 0, 0, 0);
      }
    }
#pragma unroll
    for (int i = 0; i < 2; ++i) {
      int r0l = (w * 2 + i) * 16 + lg * 4;
      float4 bias = *(const float4*)(ab1 + p * 256 + r0l);
#pragma unroll
      for (int ct = 0; ct < 3; ++ct) {
        int col = ct * 16 + lr; int cx = (col & 7) << 4;
        ushort4 hv;
        hv.x = (unsigned short)f2bf(fmaxf(hacc[i][ct][0] + bias.x, 0.f));
        hv.y = (unsigned short)f2bf(fmaxf(hacc[i][ct][1] + bias.y, 0.f));
        hv.z = (unsigned short)f2bf(fmaxf(hacc[i][ct][2] + bias.z, 0.f));
        hv.w = (unsigned short)f2bf(fmaxf(hacc[i][ct][3] + bias.w, 0.f));
        *(ushort4*)(HpB + ((col * 512 + r0l * 2) ^ cx)) = hv;
      }
    }
    __syncthreads();
    for (int kk = 0; kk < 8; ++kk) {
      short8b bb[3];
#pragma unroll
      for (int ct = 0; ct < 3; ++ct) {
        int col = ct * 16 + lr;
        bb[ct] = *(const short8b*)(HpB + ((col * 512 + kk * 64 + lg * 16) ^ ((col & 7) << 4)));
      }
      int kkg = p * 8 + kk;
#pragma unroll
      for (int i = 0; i < 2; ++i) {
        short8b a = *(const short8b*)(aw2f + (((size_t)((w * 2 + i) * 32 + kkg)) * 64 + l) * 8);
#pragma unroll
        for (int ct = 0; ct < 3; ++ct)
          sacc[i][ct] = __builtin_amdgcn_mfma_f32_16x16x32_bf16(a, bb[ct], sacc[i][ct], 0, 0, 0);
      }
    }
    __syncthreads();
  }
#pragma unroll
  for (int i = 0; i < 2; ++i) {
    int r0 = (w * 2 + i) * 16 + lg * 4;
    float4 bias = *(const float4*)(ab2 + r0);
#pragma unroll
    for (int ct = 0; ct < 3; ++ct) {
      int col = ct * 16 + lr;
      if (col < 40) {
        ushort4 hv;
        hv.x = (unsigned short)f2bf(sacc[i][ct][0] + bias.x);
        hv.y = (unsigned short)f2bf(sacc[i][ct][1] + bias.y);
        hv.z = (unsigned short)f2bf(sacc[i][ct][2] + bias.z);
        hv.w = (unsigned short)f2bf(sacc[i][ct][3] + bias.w);
        *(ushort4*)(simS + col * 528 + r0 * 2) = hv;
      }
    }
  }
  __syncthreads();
  float ffv[4];
#pragma unroll
  for (int si = 0; si < 4; ++si) {
    int s = h * 4 + si;
    float sv[5], vp[5];
#pragma unroll
    for (int j = 0; j < 5; ++j) {
      int sj = s * 5 + j;
      sv[j] = bf2f(*(const short*)(simS + sj * 528 + 2 * ch));
      vp[j] = bf2f(*(const short*)(vpeB + ((sj * 512 + 2 * ch) ^ ((sj & 7) << 4))));
    }
    float mx = sv[0];
#pragma unroll
    for (int j = 1; j < 5; ++j) mx = fmaxf(mx, sv[j]);
    float ssum = 0.f;
#pragma unroll
    for (int j = 0; j < 5; ++j) { sv[j] = expf(sv[j] - mx); ssum += sv[j]; }
    float inv = 1.f / ssum;
    float agg = 0.f;
#pragma unroll
    for (int j = 0; j < 5; ++j) agg += (sv[j] * inv) * vp[j];
    ffv[si] = agg + sfeat[((size_t)b * Fc + ch) * Nc + (n0 + s)];
  }
  {
    float rv[8];
#pragma unroll
    for (int si = 0; si < 4; ++si) { rv[si] = ffv[si]; rv[4 + si] = ffv[si] * ffv[si]; }
#pragma unroll
    for (int m = 1; m < 64; m <<= 1)
#pragma unroll
      for (int i2 = 0; i2 < 8; ++i2) rv[i2] += __shfl_xor(rv[i2], m);
    if ((t & 63) == 0)
#pragma unroll
      for (int i2 = 0; i2 < 8; ++i2) redf[w * 8 + i2] = rv[i2];
    __syncthreads();
#pragma unroll
    for (int si = 0; si < 4; ++si) {
      int s = h * 4 + si;
      float S = 0.f, Q = 0.f;
#pragma unroll
      for (int q2 = 0; q2 < 4; ++q2) {
        S += redf[(h * 4 + q2) * 8 + si];
        Q += redf[(h * 4 + q2) * 8 + 4 + si];
      }
      float mu = S * (1.f / 256.f);
      float var = Q * (1.f / 256.f) - mu * mu;
      q04[s * 256 + ch] = (ffv[si] - mu) / sqrtf(var + 1e-5f);
    }
  }
  __syncthreads();
  for (int z = t; z < 16 * 256; z += 512) {
    int col = z >> 8, k = z & 255;
    short val = (col < 8) ? f2bf(q04[col * 256 + k]) : (short)0;
    *(short*)(feaB + ((col * 512 + 2 * k) ^ ((col & 7) << 4))) = val;
  }
  __syncthreads();
  {
    f32x4 acc[2];
#pragma unroll
    for (int i = 0; i < 2; ++i) acc[i] = (f32x4){0,0,0,0};
    for (int kk = 0; kk < 8; ++kk) {
      short8b b0 = *(const short8b*)(feaB + ((lr * 512 + kk * 64 + lg * 16) ^ ((lr & 7) << 4)));
#pragma unroll
      for (int i = 0; i < 2; ++i) {
        short8b a = *(const short8b*)(fw1f + (((size_t)((w * 2 + i) * 8 + kk)) * 64 + l) * 8);
        acc[i] = __builtin_amdgcn_mfma_f32_16x16x32_bf16(a, b0, acc[i], 0, 0, 0);
      }
    }
#pragma unroll
    for (int i = 0; i < 2; ++i) {
      int r0 = (w * 2 + i) * 16 + lg * 4;
      float4 gg = *(const float4*)(fg1 + r0), bs = *(const float4*)(fb1 + r0);
      int cx = (lr & 7) << 4;
      ushort4 hv;
      hv.x = (unsigned short)f2bf(fmaxf(gg.x * acc[i][0] + bs.x, 0.f));
      hv.y = (unsigned short)f2bf(fmaxf(gg.y * acc[i][1] + bs.y, 0.f));
      hv.z = (unsigned short)f2bf(fmaxf(gg.z * acc[i][2] + bs.z, 0.f));
      hv.w = (unsigned short)f2bf(fmaxf(gg.w * acc[i][3] + bs.w, 0.f));
      *(ushort4*)(feaH + ((lr * 512 + r0 * 2) ^ cx)) = hv;
    }
  }
  __syncthreads();
  {
    f32x4 acc[2];
#pragma unroll
    for (int i = 0; i < 2; ++i) acc[i] = (f32x4){0,0,0,0};
    for (int kk = 0; kk < 8; ++kk) {
      short8b b0 = *(const short8b*)(feaH + ((lr * 512 + kk * 64 + lg * 16) ^ ((lr & 7) << 4)));
#pragma unroll
      for (int i = 0; i < 2; ++i) {
        short8b a = *(const short8b*)(fw2f + (((size_t)((w * 2 + i) * 8 + kk)) * 64 + l) * 8);
        acc[i] = __builtin_amdgcn_mfma_f32_16x16x32_bf16(a, b0, acc[i], 0, 0, 0);
      }
    }
#pragma unroll
    for (int i = 0; i < 2; ++i) {
      if (lr < 8) {
        int r0 = (w * 2 + i) * 16 + lg * 4;
        float4 bs = *(const float4*)(fb2v + r0);
        float4 v;
        v.x = acc[i][0] + bs.x; v.y = acc[i][1] + bs.y;
        v.z = acc[i][2] + bs.z; v.w = acc[i][3] + bs.w;
        *(float4*)(y2F + lr * 260 + r0) = v;
      }
    }
  }
  __syncthreads();
  {
    float zv[4];
#pragma unroll
    for (int si = 0; si < 4; ++si) {
      int s = h * 4 + si;
      zv[si] = y2F[s * 260 + ch] + q04[s * 256 + ch];
    }
    float rv[8];
#pragma unroll
    for (int si = 0; si < 4; ++si) { rv[si] = zv[si]; rv[4 + si] = zv[si] * zv[si]; }
#pragma unroll
    for (int m = 1; m < 64; m <<= 1)
#pragma unroll
      for (int i2 = 0; i2 < 8; ++i2) rv[i2] += __shfl_xor(rv[i2], m);
    if ((t & 63) == 0)
#pragma unroll
      for (int i2 = 0; i2 < 8; ++i2) redf[w * 8 + i2] = rv[i2];
    __syncthreads();
#pragma unroll
    for (int si = 0; si < 4; ++si) {
      int s = h * 4 + si;
      float S = 0.f, Q = 0.f;
#pragma unroll
      for (int q2 = 0; q2 < 4; ++q2) {
        S += redf[(h * 4 + q2) * 8 + si];
        Q += redf[(h * 4 + q2) * 8 + 4 + si];
      }
      float mu = S * (1.f / 256.f);
      float var = Q * (1.f / 256.f) - mu * mu;
      yout[((size_t)(tau0 + s)) * 256 + ch] = (zv[si] - mu) / sqrtf(var + 1e-5f);
    }
  }
}

// ---- PointSIFT octant-NN: ONE WAVE PER POINT, zero barriers ----
__global__ __launch_bounds__(256) void sift_idx_kernel(const float* __restrict__ sxyz,
                                                       int* __restrict__ sidx) {
  int wv = threadIdx.x >> 6, l = threadIdx.x & 63;
  int pt = blockIdx.x * 4 + wv;
  int b = pt / Nc, i = pt % Nc;
  const float* x = sxyz + (size_t)b * Nc * 3;
  float xi0 = x[3 * i], xi1 = x[3 * i + 1], xi2 = x[3 * i + 2];
  unsigned long long k8[8];
#pragma unroll
  for (int o = 0; o < 8; ++o) k8[o] = ~0ULL;
  for (int q = 0; q < 16; ++q) {
    int j = q * 64 + l;
    float dx = x[3 * j] - xi0, dy = x[3 * j + 1] - xi1, dz = x[3 * j + 2] - xi2;
    float d2 = dx * dx + dy * dy + dz * dz;
    bool ok = (d2 <= 0.25f) && (d2 > 0.f);
    int oc = (dx > 0.f ? 4 : 0) + (dy > 0.f ? 2 : 0) + (dz > 0.f ? 1 : 0);
    unsigned long long c = ((unsigned long long)__float_as_uint(d2) << 32) | (unsigned)j;
#pragma unroll
    for (int o = 0; o < 8; ++o) {
      unsigned long long cc = (ok && oc == o) ? c : ~0ULL;
      k8[o] = umin64(k8[o], cc);
    }
  }
#pragma unroll
  for (int m = 1; m < 64; m <<= 1)
#pragma unroll
    for (int o = 0; o < 8; ++o) k8[o] = umin64(k8[o], __shfl_xor(k8[o], m));
  if (l < 8) {
    unsigned long long r = ~0ULL;
#pragma unroll
    for (int o = 0; o < 8; ++o)
      if (l == o) r = k8[o];
    int j = (r == ~0ULL) ? i : (int)(unsigned)r;
    sidx[(((size_t)b * Nc + i) << 3) + l] = j;
  }
}

// ---- fused PointSIFT OE: 3 (1,2)-convs via MFMA, 8 points/block, 512 threads ----
__global__ __launch_bounds__(512, 4) void sift_oe_kernel(
    const float* __restrict__ sxyz, const int* __restrict__ sidx,
    const float* __restrict__ yin,
    const short* __restrict__ w1f, const float* __restrict__ g1, const float* __restrict__ b1,
    const short* __restrict__ w2f, const float* __restrict__ g2, const float* __restrict__ b2,
    const short* __restrict__ w3f, const float* __restrict__ g3, const float* __restrict__ b3,
    float* __restrict__ yout) {
  __shared__ __align__(16) char smem[51200];
  char* B1 = smem;
  char* B2 = smem + 34816;
  char* B3 = smem;
  __shared__ int js[8][8];
  int t = threadIdx.x;
  int i0 = blockIdx.x * 8;
  int b = i0 / Nc, nb = i0 % Nc;
  int h = t >> 8, ch = t & 255;
  if (t < 64) js[t >> 3][t & 7] = sidx[(((size_t)b * Nc + nb + (t >> 3)) << 3) + (t & 7)];
  for (int z = t; z < 32 * 26; z += 512) {
    int col = z / 26, k = 518 + z % 26;
    *(short*)(B1 + ((col * 1088 + 2 * k) ^ ((col & 7) << 4))) = 0;
  }
  __syncthreads();
  for (int si = 0; si < 4; ++si) {
    int s = h * 4 + si;
    int ii = nb + s;
#pragma unroll
    for (int p = 0; p < 4; ++p) {
      int ja = js[s][2 * p], jb = js[s][2 * p + 1];
      int col = s * 4 + p; int cx = (col & 7) << 4;
      float va = yin[((size_t)b * Nc + ja) * 256 + ch];
      float vb = yin[((size_t)b * Nc + jb) * 256 + ch];
      unsigned int packed = (unsigned int)(unsigned short)f2bf(va) |
                            ((unsigned int)(unsigned short)f2bf(vb) << 16);
      *(unsigned int*)(B1 + ((col * 1088 + 12 + 4 * ch) ^ cx)) = packed;
      if (ch < 3) {
        float base = sxyz[((size_t)b * Nc + ii) * 3 + ch];
        float ga = sxyz[((size_t)b * Nc + ja) * 3 + ch] - base;
        float gb = sxyz[((size_t)b * Nc + jb) * 3 + ch] - base;
        unsigned int pg = (unsigned int)(unsigned short)f2bf(ga) |
                          ((unsigned int)(unsigned short)f2bf(gb) << 16);
        *(unsigned int*)(B1 + ((col * 1088 + 4 * ch) ^ cx)) = pg;
      }
    }
  }
  __syncthreads();
  int l = t & 63, w = t >> 6, lg = l >> 4, lr = l & 15;
  {
    f32x4 acc[2][2];
#pragma unroll
    for (int i = 0; i < 2; ++i) { acc[i][0] = (f32x4){0,0,0,0}; acc[i][1] = (f32x4){0,0,0,0}; }
    for (int kk = 0; kk < 17; ++kk) {
      short8b b0[2];
#pragma unroll
      for (int ct = 0; ct < 2; ++ct) {
        int col = ct * 16 + lr;
        b0[ct] = *(const short8b*)(B1 + ((col * 1088 + kk * 64 + lg * 16) ^ ((col & 7) << 4)));
      }
#pragma unroll
      for (int i = 0; i < 2; ++i) {
        short8b a = *(const short8b*)(w1f + (((size_t)((w * 2 + i) * 17 + kk)) * 64 + l) * 8);
#pragma unroll
        for (int ct = 0; ct < 2; ++ct)
          acc[i][ct] = __builtin_amdgcn_mfma_f32_16x16x32_bf16(a, b0[ct], acc[i][ct], 0, 0, 0);
      }
    }
    __syncthreads();
#pragma unroll
    for (int i = 0; i < 2; ++i) {
      int r0 = (w * 2 + i) * 16 + lg * 4;
      float4 gg = *(const float4*)(g1 + r0), bs = *(const float4*)(b1 + r0);
#pragma unroll
      for (int ct = 0; ct < 2; ++ct) {
        int col = ct * 16 + lr;
        int s = col >> 2, p = col & 3, p2 = p >> 1, tp = p & 1;
        int col2 = s * 2 + p2; int cx2 = (col2 & 7) << 4;
        *(short*)(B2 + ((col2 * 1024 + (2 * r0 + tp) * 2) ^ cx2)) =
            f2bf(fmaxf(gg.x * acc[i][ct][0] + bs.x, 0.f));
        *(short*)(B2 + ((col2 * 1024 + (2 * (r0 + 1) + tp) * 2) ^ cx2)) =
            f2bf(fmaxf(gg.y * acc[i][ct][1] + bs.y, 0.f));
        *(short*)(B2 + ((col2 * 1024 + (2 * (r0 + 2) + tp) * 2) ^ cx2)) =
            f2bf(fmaxf(gg.z * acc[i][ct][2] + bs.z, 0.f));
        *(short*)(B2 + ((col2 * 1024 + (2 * (r0 + 3) + tp) * 2) ^ cx2)) =
            f2bf(fmaxf(gg.w * acc[i][ct][3] + bs.w, 0.f));
      }
    }
  }
  __syncthreads();
  {
    f32x4 acc[2];
#pragma unroll
    for (int i = 0; i < 2; ++i) acc[i] = (f32x4){0,0,0,0};
    for (int kk = 0; kk < 16; ++kk) {
      short8b b0 = *(const short8b*)(B2 + ((lr * 1024 + kk * 64 + lg * 16) ^ ((lr & 7) << 4)));
#pragma unroll
      for (int i = 0; i < 2; ++i) {
        short8b a = *(const short8b*)(w2f + (((size_t)((w * 2 + i) * 16 + kk)) * 64 + l) * 8);
        acc[i] = __builtin_amdgcn_mfma_f32_16x16x32_bf16(a, b0, acc[i], 0, 0, 0);
      }
    }
    __syncthreads();
    int s = lr >> 1, tp = lr & 1;
    int col3 = s; int cx3 = (col3 & 7) << 4;
#pragma unroll
    for (int i = 0; i < 2; ++i) {
      int r0 = (w * 2 + i) * 16 + lg * 4;
      float4 gg = *(const float4*)(g2 + r0), bs = *(const float4*)(b2 + r0);
      *(short*)(B3 + ((col3 * 1024 + (2 * r0 + tp) * 2) ^ cx3)) =
          f2bf(fmaxf(gg.x * acc[i][0] + bs.x, 0.f));
      *(short*)(B3 + ((col3 * 1024 + (2 * (r0 + 1) + tp) * 2) ^ cx3)) =
          f2bf(fmaxf(gg.y * acc[i][1] + bs.y, 0.f));
      *(short*)(B3 + ((col3 * 1024 + (2 * (r0 + 2) + tp) * 2) ^ cx3)) =
          f2bf(fmaxf(gg.z * acc[i][2] + bs.z, 0.f));
      *(short*)(B3 + ((col3 * 1024 + (2 * (r0 + 3) + tp) * 2) ^ cx3)) =
          f2bf(fmaxf(gg.w * acc[i][3] + bs.w, 0.f));
    }
  }
  __syncthreads();
  {
    f32x4 acc[2];
#pragma unroll
    for (int i = 0; i < 2; ++i) acc[i] = (f32x4){0,0,0,0};
    for (int kk = 0; kk < 16; ++kk) {
      short8b b0 = *(const short8b*)(B3 + ((lr * 1024 + kk * 64 + lg * 16) ^ ((lr & 7) << 4)));
#pragma unroll
      for (int i = 0; i < 2; ++i) {
        short8b a = *(const short8b*)(w3f + (((size_t)((w * 2 + i) * 16 + kk)) * 64 + l) * 8);
        acc[i] = __builtin_amdgcn_mfma_f32_16x16x32_bf16(a, b0, acc[i], 0, 0, 0);
      }
    }
#pragma unroll
    for (int i = 0; i < 2; ++i) {
      if (lr < 8) {
        int s = lr;
        int r0 = (w * 2 + i) * 16 + lg * 4;
        float4 gg = *(const float4*)(g3 + r0), bs = *(const float4*)(b3 + r0);
        float4 yv = *(const float4*)(yin + ((size_t)(i0 + s)) * 256 + r0);
        float4 ov;
        ov.x = yv.x + fmaxf(gg.x * acc[i][0] + bs.x, 0.f);
        ov.y = yv.y + fmaxf(gg.y * acc[i][1] + bs.y, 0.f);
        ov.z = yv.z + fmaxf(gg.z * acc[i][2] + bs.z, 0.f);
        ov.w = yv.w + fmaxf(gg.w * acc[i][3] + bs.w, 0.f);
        *(float4*)(yout + ((size_t)(i0 + s)) * 256 + r0) = ov;
      }
    }
  }
}

// ---- final transpose (B,N,C) -> (B,C,N) into d_out ----
__global__ __launch_bounds__(256) void transpose_kernel(const float* __restrict__ yin,
                                                        float* __restrict__ out) {
  size_t idx = (size_t)blockIdx.x * 256 + threadIdx.x;
  int n = (int)(idx % Nc);
  size_t r = idx / Nc;
  int c = (int)(r % Fc);
  int b = (int)(r / Fc);
  out[idx] = yin[(((size_t)b * Nc + n) * 256) + c];
}

extern "C" void kernel_launch(void* const* d_in, const int* in_sizes, int n_in,
                              void* d_out, int out_size, void* d_ws, size_t ws_size,
                              hipStream_t stream) {
  (void)in_sizes; (void)n_in; (void)out_size; (void)ws_size;
  const float* tfeat = (const float*)d_in[0];
  const float* sfeat = (const float*)d_in[1];
  const float* txyz  = (const float*)d_in[2];
  const float* sxyz  = (const float*)d_in[3];
  const float* tbc   = (const float*)d_in[4];
  const float* sbc   = (const float*)d_in[5];
  const float* mw1 = (const float*)d_in[6];
  const float* mg1 = (const float*)d_in[7];
  const float* mb1 = (const float*)d_in[8];
  const float* mw2 = (const float*)d_in[9];
  const float* mg2 = (const float*)d_in[10];
  const float* mb2 = (const float*)d_in[11];
  const float* mw3 = (const float*)d_in[12];
  const float* mg3 = (const float*)d_in[13];
  const float* mb3 = (const float*)d_in[14];
  const float* fw1 = (const float*)d_in[15];
  const float* fg1 = (const float*)d_in[16];
  const float* fb1 = (const float*)d_in[17];
  const float* fw2 = (const float*)d_in[18];
  const float* fb2 = (const float*)d_in[19];
  const float* wqkv = (const float*)d_in[20];
  const float* pw1 = (const float*)d_in[21];
  const float* pb1 = (const float*)d_in[22];
  const float* pw2 = (const float*)d_in[23];
  const float* pb2 = (const float*)d_in[24];
  const float* aw1 = (const float*)d_in[25];
  const float* ab1 = (const float*)d_in[26];
  const float* aw2 = (const float*)d_in[27];
  const float* ab2 = (const float*)d_in[28];
  const float* o1w1 = (const float*)d_in[29];
  const float* o1g1 = (const float*)d_in[30];
  const float* o1b1 = (const float*)d_in[31];
  const float* o1w2 = (const float*)d_in[32];
  const float* o1g2 = (const float*)d_in[33];
  const float* o1b2 = (const float*)d_in[34];
  const float* o1w3 = (const float*)d_in[35];
  const float* o1g3 = (const float*)d_in[36];
  const float* o1b3 = (const float*)d_in[37];
  const float* o2w1 = (const float*)d_in[38];
  const float* o2g1 = (const float*)d_in[39];
  const float* o2b1 = (const float*)d_in[40];
  const float* o2w2 = (const float*)d_in[41];
  const float* o2g2 = (const float*)d_in[42];
  const float* o2b2 = (const float*)d_in[43];
  const float* o2w3 = (const float*)d_in[44];
  const float* o2g3 = (const float*)d_in[45];
  const float* o2b3 = (const float*)d_in[46];

  // workspace layout (identical to R8)
  float* ws = (float*)d_ws;
  float* sd   = ws;
  float* td   = sd + 65536;
  float* sscf = td + 32768;
  float* tscf = sscf + 12288;
  int*   idxs = (int*)(tscf + 6144);
  int*   sidx = idxs + 16384;
  float* yws  = (float*)(sidx + 32768);
  short* sb   = (short*)(yws + 1048576);
  short* hbufS = sb;
  short* mw1f  = sb + 5242880;
  short* mw2f  = mw1f + 73728;
  short* mw3f  = mw2f + 65536;
  short* aqf   = mw3f + 65536;
  short* akpef = aqf + 65536;
  short* avpef = akpef + 81920;
  short* aw1f  = avpef + 81920;
  short* aw2f  = aw1f + 262144;
  short* fw1f  = aw2f + 262144;
  short* fw2f  = fw1f + 65536;
  short* o1w1f = fw2f + 65536;
  short* o1w2f = o1w1f + 139264;
  short* o1w3f = o1w2f + 131072;
  short* o2w1f = o1w3f + 131072;
  short* o2w2f = o2w1f + 139264;
  short* o2w3f = o2w2f + 131072;
  float* ybuf2 = (float*)sb;

  WSrcs srcs;
  srcs.p[0] = mw1;  srcs.p[1] = mw2;  srcs.p[2] = mw3;  srcs.p[3] = wqkv;
  srcs.p[4] = wqkv; srcs.p[5] = wqkv; srcs.p[6] = aw1;  srcs.p[7] = aw2;
  srcs.p[8] = fw1;  srcs.p[9] = fw2;  srcs.p[10] = o1w1; srcs.p[11] = o1w2;
  srcs.p[12] = o1w3; srcs.p[13] = o2w1; srcs.p[14] = o2w2; srcs.p[15] = o2w3;
  wconv_all<<<7392, 256, 0, stream>>>(srcs, pw2, mw1f);

  scf_kernel<<<Bc, 256, 0, stream>>>(sxyz, sscf, Nc);
  scf_kernel<<<Bc, 256, 0, stream>>>(txyz, tscf, Mc);
  knn_kernel<Nc><<<Bc * Nc / 4, 256, 0, stream>>>(sxyz, sd);
  knn_kernel<Mc><<<Bc * Mc / 4, 256, 0, stream>>>(txyz, td);
  select_kernel<<<Bc * Nc / 4, 256, 0, stream>>>(tbc, sbc, txyz, sxyz, sd, td, idxs);
  mlp_kernel<<<Bc * Nc / 4, 256, 0, stream>>>(sfeat, tfeat, sscf, tscf, idxs,
                                              mw1f, mg1, mb1, mw2f, mg2, mb2,
                                              mw3f, mg3, mb3, hbufS);
  attn_kernel<<<Bc * Nc / 8, 512, 0, stream>>>(hbufS, idxs, sxyz, sbc, txyz, tbc,
                                               aqf, akpef, avpef, pw1, pb1, pb2,
                                               aw1f, ab1, aw2f, ab2,
                                               sfeat, fw1f, fg1, fb1, fw2f, fb2, yws);
  sift_idx_kernel<<<Bc * Nc / 4, 256, 0, stream>>>(sxyz, sidx);
  sift_oe_kernel<<<Bc * Nc / 8, 512, 0, stream>>>(sxyz, sidx, yws,
                                                  o1w1f, o1g1, o1b1, o1w2f, o1g2, o1b2,
                                                  o1w3f, o1g3, o1b3, ybuf2);
  sift_oe_kernel<<<Bc * Nc / 8, 512, 0, stream>>>(sxyz, sidx, ybuf2,
                                                  o2w1f, o2g1, o2b1, o2w2f, o2g2, o2b2,
                                                  o2w3f, o2g3, o2b3, yws);
  transpose_kernel<<<(Bc * Fc * Nc) / 256, 256, 0, stream>>>(yws, (float*)d_out);
}

// Round 10
// 315.946 us; speedup vs baseline: 35.6150x; 1.0741x over previous
//
#include <hip/hip_runtime.h>
#include <hip/hip_bf16.h>
#include <math.h>

// Problem constants (match reference)
constexpr int Bc = 4, Mc = 512, Nc = 1024, Fc = 256;
constexpr int KCc = 16;
constexpr float INFF = 3.0e38f;

typedef __attribute__((ext_vector_type(8))) short short8b;  // 8 bf16 (4 VGPRs)
typedef __attribute__((ext_vector_type(4))) float f32x4;

__device__ __forceinline__ short f2bf(float f) {
  __hip_bfloat16 h = __float2bfloat16(f);
  return *reinterpret_cast<short*>(&h);
}
__device__ __forceinline__ float bf2f(short s) {
  unsigned int u = ((unsigned int)(unsigned short)s) << 16;
  return __uint_as_float(u);
}
__device__ __forceinline__ unsigned long long umin64(unsigned long long a, unsigned long long b) {
  return a < b ? a : b;
}

__device__ __forceinline__ float blk_sum(float v, float* red) {
  int t = threadIdx.x;
  red[t] = v;
  __syncthreads();
  for (int s = 128; s > 0; s >>= 1) {
    if (t < s) red[t] += red[t + s];
    __syncthreads();
  }
  float r = red[0];
  __syncthreads();
  return r;
}

// ---- merged weight relayout: 16 jobs, one kernel ----
struct WSrcs { const float* p[16]; };
__global__ __launch_bounds__(256) void wconv_all(WSrcs s, const float* __restrict__ pw2,
                                                 short* __restrict__ dstbase) {
  const int ofs[16] = {0, 73728, 139264, 204800, 270336, 352256, 434176, 696320,
                       958464, 1024000, 1089536, 1228800, 1359872, 1490944, 1630208, 1761280};
  const int Kt[16]  = {259, 256, 256, 256, 320, 320, 256, 1024, 256, 256, 518, 512, 512, 518, 512, 512};
  const int KTt[16] = {9, 8, 8, 8, 10, 10, 8, 32, 8, 8, 17, 16, 16, 17, 16, 16};
  int gi = blockIdx.x * 256 + threadIdx.x;
  if (gi >= 1892352) return;
  int job = 0;
#pragma unroll
  for (int j2 = 1; j2 < 16; ++j2)
    if (gi >= ofs[j2]) job = j2;
  int i = gi - ofs[job];
  int K = Kt[job], KT = KTt[job];
  int e = i & 7, l = (i >> 3) & 63, q = i >> 9;
  int kk = q % KT, rt = q / KT;
  int r = rt * 16 + (l & 15);
  int k = kk * 32 + (l >> 4) * 8 + e;
  float v;
  if (job == 4)
    v = (k < 256) ? -s.p[4][(size_t)(256 + r) * 256 + k] : pw2[(size_t)r * 64 + (k - 256)];
  else if (job == 5)
    v = (k < 256) ? s.p[5][(size_t)(512 + r) * 256 + k] : pw2[(size_t)r * 64 + (k - 256)];
  else
    v = (k < K) ? s.p[job][(size_t)r * K + k] : 0.f;
  dstbase[gi] = f2bf(v);
}

// ---- spherical coords of points relative to centroid -> out (B,3,P) ----
__global__ __launch_bounds__(256) void scf_kernel(const float* __restrict__ xyz,
                                                  float* __restrict__ out, int P) {
  __shared__ float red[256];
  int b = blockIdx.x;
  const float* x = xyz + (size_t)b * P * 3;
  float sx = 0.f, sy = 0.f, sz = 0.f;
  for (int i = threadIdx.x; i < P; i += 256) {
    sx += x[3 * i]; sy += x[3 * i + 1]; sz += x[3 * i + 2];
  }
  float mx = blk_sum(sx, red) / (float)P;
  float my = blk_sum(sy, red) / (float)P;
  float mz = blk_sum(sz, red) / (float)P;
  for (int i = threadIdx.x; i < P; i += 256) {
    float a = x[3 * i] - mx, c = x[3 * i + 1] - my, d = x[3 * i + 2] - mz;
    float r = sqrtf(a * a + c * c + d * d + 1e-8f);
    float ct = d / r;
    ct = fminf(1.f, fmaxf(-1.f, ct));
    out[((size_t)b * 3 + 0) * P + i] = r;
    out[((size_t)b * 3 + 1) * P + i] = acosf(ct);
    out[((size_t)b * 3 + 2) * P + i] = atan2f(c, a);
  }
}

// ---- KNN descriptor: ONE WAVE PER POINT, zero barriers ----
template <int P>
__global__ __launch_bounds__(256) void knn_kernel(const float* __restrict__ xyz,
                                                  float* __restrict__ desc) {
  constexpr int E = P / 64;
  int wv = threadIdx.x >> 6, l = threadIdx.x & 63;
  int pt = blockIdx.x * 4 + wv;
  int b = pt / P, i = pt % P;
  const float* x = xyz + (size_t)b * P * 3;
  float xi0 = x[3 * i], xi1 = x[3 * i + 1], xi2 = x[3 * i + 2];
  float d2r[E];
#pragma unroll
  for (int q = 0; q < E; ++q) {
    int j = q * 64 + l;
    float dx = x[3 * j] - xi0, dy = x[3 * j + 1] - xi1, dz = x[3 * j + 2] - xi2;
    d2r[q] = dx * dx + dy * dy + dz * dz;
  }
  for (int round = 0; round < KCc + 1; ++round) {
    unsigned long long k = ~0ULL;
#pragma unroll
    for (int q = 0; q < E; ++q) {
      unsigned long long c =
          ((unsigned long long)__float_as_uint(d2r[q]) << 32) | (unsigned)(q * 64 + l);
      k = umin64(k, c);
    }
#pragma unroll
    for (int m = 1; m < 64; m <<= 1) k = umin64(k, __shfl_xor(k, m));
    int widx = (int)(unsigned)k;
    if (round > 0 && l == 0)
      desc[((size_t)b * P + i) * KCc + (round - 1)] = sqrtf(__uint_as_float((unsigned)(k >> 32)));
    if ((widx & 63) == l) {
      int q = widx >> 6;
#pragma unroll
      for (int qq = 0; qq < E; ++qq)
        if (qq == q) d2r[qq] = INFF;
    }
  }
}

// ---- candidate pruning: ONE WAVE PER POINT, zero barriers ----
__global__ __launch_bounds__(256) void select_kernel(
    const float* __restrict__ tbc, const float* __restrict__ sbc,
    const float* __restrict__ txyz, const float* __restrict__ sxyz,
    const float* __restrict__ sd, const float* __restrict__ td,
    int* __restrict__ idx_s) {
  __shared__ int cand4[4][24];
  int wv = threadIdx.x >> 6, l = threadIdx.x & 63;
  int pt = blockIdx.x * 4 + wv;
  int b = pt / Nc, n = pt % Nc;
  const float* sb = sbc + ((size_t)b * Nc + n) * 9;
  float sreg[9];
#pragma unroll
  for (int c = 0; c < 9; ++c) sreg[c] = sb[c];
  float d2r[8];
#pragma unroll
  for (int q = 0; q < 8; ++q) {
    int m = q * 64 + l;
    const float* tb = tbc + ((size_t)b * Mc + m) * 9;
    float acc = 0.f;
#pragma unroll
    for (int c = 0; c < 9; ++c) { float d = tb[c] - sreg[c]; acc += d * d; }
    d2r[q] = acc;
  }
  for (int round = 0; round < 24; ++round) {
    unsigned long long k = ~0ULL;
#pragma unroll
    for (int q = 0; q < 8; ++q) {
      unsigned long long c =
          ((unsigned long long)__float_as_uint(d2r[q]) << 32) | (unsigned)(q * 64 + l);
      k = umin64(k, c);
    }
#pragma unroll
    for (int m = 1; m < 64; m <<= 1) k = umin64(k, __shfl_xor(k, m));
    int widx = (int)(unsigned)k;
    if (l == 0) cand4[wv][round] = widx;
    if ((widx & 63) == l) {
      int q = widx >> 6;
#pragma unroll
      for (int qq = 0; qq < 8; ++qq)
        if (qq == q) d2r[qq] = INFF;
    }
  }
  if (l == 0) {
    int* cand = cand4[wv];
    const float* sp = sxyz + ((size_t)b * Nc + n) * 3;
    float sx = sp[0], sy = sp[1], sz = sp[2];
    float dv[24];
    for (int t2 = 0; t2 < 24; ++t2) {
      const float* tp = txyz + ((size_t)b * Mc + cand[t2]) * 3;
      float dx = tp[0] - sx, dy = tp[1] - sy, dz = tp[2] - sz;
      dv[t2] = dx * dx + dy * dy + dz * dz;
    }
    int c8[8]; bool used[24];
    for (int t2 = 0; t2 < 24; ++t2) used[t2] = false;
    for (int r = 0; r < 8; ++r) {
      float bv = INFF; int bt = -1, bm = 0x7fffffff;
      for (int t2 = 0; t2 < 24; ++t2) {
        if (used[t2]) continue;
        int m = cand[t2];
        if (bt < 0 || dv[t2] < bv || (dv[t2] == bv && m < bm)) { bv = dv[t2]; bt = t2; bm = m; }
      }
      used[bt] = true; c8[r] = bm;
    }
    const float* sdp = sd + ((size_t)b * Nc + n) * KCc;
    float sdr[16];
    for (int t2 = 0; t2 < 16; ++t2) sdr[t2] = sdp[t2];
    float dscf[8];
    for (int r = 0; r < 8; ++r) {
      const float* tdp = td + ((size_t)b * Mc + c8[r]) * KCc;
      float acc = 0.f;
      for (int t2 = 0; t2 < 16; ++t2) { float d = sdr[t2] - tdp[t2]; acc += d * d; }
      dscf[r] = acc;
    }
    bool u8[8] = {false, false, false, false, false, false, false, false};
    for (int r = 0; r < 4; ++r) {
      float bv = INFF; int bt = -1, bm = 0x7fffffff;
      for (int t2 = 0; t2 < 8; ++t2) {
        if (u8[t2]) continue;
        if (bt < 0 || dscf[t2] < bv || (dscf[t2] == bv && c8[t2] < bm)) { bv = dscf[t2]; bt = t2; bm = c8[t2]; }
      }
      u8[bt] = true;
      idx_s[(((size_t)b * Nc + n) << 2) + r] = bm;
    }
  }
}

// ---- grouping + 3-layer MLP via bf16 MFMA, 8 tokens/block, 512 threads ----
__global__ __launch_bounds__(512, 4) void mlp_kernel(
    const float* __restrict__ sfeat, const float* __restrict__ tfeat,
    const float* __restrict__ sscf, const float* __restrict__ tscf,
    const int* __restrict__ idx_s,
    const short* __restrict__ w1f, const float* __restrict__ g1, const float* __restrict__ b1,
    const short* __restrict__ w2f, const float* __restrict__ g2, const float* __restrict__ b2,
    const short* __restrict__ w3f, const float* __restrict__ g3, const float* __restrict__ b3,
    short* __restrict__ houtS) {
  __shared__ __align__(16) char smem[52224];
  char* B1 = smem;            // [48 cols][288k] stride 576 = 27648 B; B3 aliases (24576 B)
  char* B2 = smem + 27648;    // [48 cols][256k] stride 512 = 24576 B
  char* B3 = smem;
  __shared__ int ms[32];
  int t = threadIdx.x;
  int tau0 = blockIdx.x * 8;
  int b = tau0 / Nc, n0 = tau0 % Nc;
  int h = t >> 8, ch = t & 255;
  if (t < 32) ms[t] = idx_s[(((size_t)b * Nc + n0 + (t >> 2)) << 2) + (t & 3)];
  __syncthreads();
  // NaN-safety: zero k-pad (k 259..287) for ALL 48 cols; zero cols 40..47 fully.
  for (int z = t; z < 48 * 29; z += 512) {
    int col = z / 29, k = 259 + z % 29;
    *(short*)(B1 + ((col * 576 + 2 * k) ^ ((col & 7) << 4))) = 0;
  }
  for (int z = t; z < 8 * 259; z += 512) {
    int col = 40 + z / 259, k = z % 259;
    *(short*)(B1 + ((col * 576 + 2 * k) ^ ((col & 7) << 4))) = 0;
  }
  for (int sj = h; sj < 40; sj += 2) {
    int s = sj / 5, j = sj % 5;
    int n = n0 + s;
    int cx = (sj & 7) << 4;
    if (j == 0) {
      *(short*)(B1 + ((sj * 576 + 2 * ch) ^ cx)) = f2bf(sfeat[((size_t)b * Fc + ch) * Nc + n]);
      if (ch < 3)
        *(short*)(B1 + ((sj * 576 + (256 + ch) * 2) ^ cx)) = f2bf(sscf[((size_t)b * 3 + ch) * Nc + n]);
    } else {
      int m = ms[s * 4 + j - 1];
      *(short*)(B1 + ((sj * 576 + 2 * ch) ^ cx)) = f2bf(tfeat[((size_t)b * Fc + ch) * Mc + m]);
      if (ch < 3)
        *(short*)(B1 + ((sj * 576 + (256 + ch) * 2) ^ cx)) = f2bf(tscf[((size_t)b * 3 + ch) * Mc + m]);
    }
  }
  __syncthreads();
  int l = t & 63, w = t >> 6, lg = l >> 4, lr = l & 15;
  // GEMM1: rows 256 x K288 (KT=9), 48 cols -> B2
  {
    f32x4 acc[2][3];
#pragma unroll
    for (int i = 0; i < 2; ++i)
#pragma unroll
      for (int ct = 0; ct < 3; ++ct) acc[i][ct] = (f32x4){0,0,0,0};
    for (int kk = 0; kk < 9; ++kk) {
      short8b bb[3];
#pragma unroll
      for (int ct = 0; ct < 3; ++ct) {
        int col = ct * 16 + lr;
        bb[ct] = *(const short8b*)(B1 + ((col * 576 + kk * 64 + lg * 16) ^ ((col & 7) << 4)));
      }
#pragma unroll
      for (int i = 0; i < 2; ++i) {
        short8b a = *(const short8b*)(w1f + (((size_t)((w * 2 + i) * 9 + kk)) * 64 + l) * 8);
#pragma unroll
        for (int ct = 0; ct < 3; ++ct)
          acc[i][ct] = __builtin_amdgcn_mfma_f32_16x16x32_bf16(a, bb[ct], acc[i][ct], 0, 0, 0);
      }
    }
    __syncthreads();
#pragma unroll
    for (int i = 0; i < 2; ++i) {
      int r0 = (w * 2 + i) * 16 + lg * 4;
      float4 gg = *(const float4*)(g1 + r0), bs = *(const float4*)(b1 + r0);
#pragma unroll
      for (int ct = 0; ct < 3; ++ct) {
        int col = ct * 16 + lr; int cx = (col & 7) << 4;
        ushort4 hv;
        hv.x = (unsigned short)f2bf(fmaxf(gg.x * acc[i][ct][0] + bs.x, 0.f));
        hv.y = (unsigned short)f2bf(fmaxf(gg.y * acc[i][ct][1] + bs.y, 0.f));
        hv.z = (unsigned short)f2bf(fmaxf(gg.z * acc[i][ct][2] + bs.z, 0.f));
        hv.w = (unsigned short)f2bf(fmaxf(gg.w * acc[i][ct][3] + bs.w, 0.f));
        *(ushort4*)(B2 + ((col * 512 + r0 * 2) ^ cx)) = hv;
      }
    }
  }
  __syncthreads();
  // GEMM2: 256 x 256 (KT=8), B2 -> B3 (alias B1)
  {
    f32x4 acc[2][3];
#pragma unroll
    for (int i = 0; i < 2; ++i)
#pragma unroll
      for (int ct = 0; ct < 3; ++ct) acc[i][ct] = (f32x4){0,0,0,0};
    for (int kk = 0; kk < 8; ++kk) {
      short8b bb[3];
#pragma unroll
      for (int ct = 0; ct < 3; ++ct) {
        int col = ct * 16 + lr;
        bb[ct] = *(const short8b*)(B2 + ((col * 512 + kk * 64 + lg * 16) ^ ((col & 7) << 4)));
      }
#pragma unroll
      for (int i = 0; i < 2; ++i) {
        short8b a = *(const short8b*)(w2f + (((size_t)((w * 2 + i) * 8 + kk)) * 64 + l) * 8);
#pragma unroll
        for (int ct = 0; ct < 3; ++ct)
          acc[i][ct] = __builtin_amdgcn_mfma_f32_16x16x32_bf16(a, bb[ct], acc[i][ct], 0, 0, 0);
      }
    }
    __syncthreads();
#pragma unroll
    for (int i = 0; i < 2; ++i) {
      int r0 = (w * 2 + i) * 16 + lg * 4;
      float4 gg = *(const float4*)(g2 + r0), bs = *(const float4*)(b2 + r0);
#pragma unroll
      for (int ct = 0; ct < 3; ++ct) {
        int col = ct * 16 + lr; int cx = (col & 7) << 4;
        ushort4 hv;
        hv.x = (unsigned short)f2bf(fmaxf(gg.x * acc[i][ct][0] + bs.x, 0.f));
        hv.y = (unsigned short)f2bf(fmaxf(gg.y * acc[i][ct][1] + bs.y, 0.f));
        hv.z = (unsigned short)f2bf(fmaxf(gg.z * acc[i][ct][2] + bs.z, 0.f));
        hv.w = (unsigned short)f2bf(fmaxf(gg.w * acc[i][ct][3] + bs.w, 0.f));
        *(ushort4*)(B3 + ((col * 512 + r0 * 2) ^ cx)) = hv;
      }
    }
  }
  __syncthreads();
  // GEMM3: 256 x 256 -> houtS (cols < 40)
  {
    f32x4 acc[2][3];
#pragma unroll
    for (int i = 0; i < 2; ++i)
#pragma unroll
      for (int ct = 0; ct < 3; ++ct) acc[i][ct] = (f32x4){0,0,0,0};
    for (int kk = 0; kk < 8; ++kk) {
      short8b bb[3];
#pragma unroll
      for (int ct = 0; ct < 3; ++ct) {
        int col = ct * 16 + lr;
        bb[ct] = *(const short8b*)(B3 + ((col * 512 + kk * 64 + lg * 16) ^ ((col & 7) << 4)));
      }
#pragma unroll
      for (int i = 0; i < 2; ++i) {
        short8b a = *(const short8b*)(w3f + (((size_t)((w * 2 + i) * 8 + kk)) * 64 + l) * 8);
#pragma unroll
        for (int ct = 0; ct < 3; ++ct)
          acc[i][ct] = __builtin_amdgcn_mfma_f32_16x16x32_bf16(a, bb[ct], acc[i][ct], 0, 0, 0);
      }
    }
#pragma unroll
    for (int i = 0; i < 2; ++i) {
      int r0 = (w * 2 + i) * 16 + lg * 4;
      float4 gg = *(const float4*)(g3 + r0), bs = *(const float4*)(b3 + r0);
#pragma unroll
      for (int ct = 0; ct < 3; ++ct) {
        int col = ct * 16 + lr;
        if (col < 40) {
          ushort4 hv;
          hv.x = (unsigned short)f2bf(fmaxf(gg.x * acc[i][ct][0] + bs.x, 0.f));
          hv.y = (unsigned short)f2bf(fmaxf(gg.y * acc[i][ct][1] + bs.y, 0.f));
          hv.z = (unsigned short)f2bf(fmaxf(gg.z * acc[i][ct][2] + bs.z, 0.f));
          hv.w = (unsigned short)f2bf(fmaxf(gg.w * acc[i][ct][3] + bs.w, 0.f));
          int s = col / 5, j = col % 5;
          *(ushort4*)(houtS + ((size_t)(tau0 + s) * 5 + j) * 256 + r0) = hv;
        }
      }
    }
  }
}

// ---- point transformer (i=0 only), all-MFMA, 8 tokens/block, 512 threads ----
__global__ __launch_bounds__(512, 4) void attn_kernel(
    const short* __restrict__ hbufS, const int* __restrict__ idx_s,
    const float* __restrict__ sxyz, const float* __restrict__ sbc,
    const float* __restrict__ txyz, const float* __restrict__ tbc,
    const short* __restrict__ aqf, const short* __restrict__ akpef, const short* __restrict__ avpef,
    const float* __restrict__ pw1, const float* __restrict__ pb1, const float* __restrict__ pb2,
    const short* __restrict__ aw1f, const float* __restrict__ ab1,
    const short* __restrict__ aw2f, const float* __restrict__ ab2,
    const float* __restrict__ sfeat,
    const short* __restrict__ fw1f, const float* __restrict__ fg1, const float* __restrict__ fb1,
    const short* __restrict__ fw2f, const float* __restrict__ fb2v,
    float* __restrict__ yout) {
  __shared__ __align__(16) char smem[79872];
  char* Bx   = smem;
  char* vpeB = smem;
  char* feaB = smem;
  char* feaH = smem + 8192;
  float* y2F = (float*)(smem + 16384);
  char* KB   = smem + 30720;
  char* simS = smem + 30720;
  char* HpB  = smem + 55296;
  float* qF  = (float*)(smem + 55296);
  float* q04 = (float*)(smem + 55296);
  float* redf = (float*)(smem + 63488);
  float* pc4 = (float*)(smem + 64000);
  int t = threadIdx.x;
  int tau0 = blockIdx.x * 8;
  int b = tau0 / Nc, n0 = tau0 % Nc;
  int w = t >> 6, l = t & 63, lg = l >> 4, lr = l & 15;
  int h = t >> 8, ch = t & 255;
  for (int z = t; z < 2560; z += 512) {
    int col = 40 + z / 320, k = z % 320;
    *(short*)(Bx + ((col * 640 + 2 * k) ^ ((col & 7) << 4))) = 0;
  }
  for (int sj = h; sj < 40; sj += 2) {
    int s = sj / 5, j = sj % 5;
    *(short*)(Bx + ((sj * 640 + 2 * ch) ^ ((sj & 7) << 4))) =
        hbufS[(size_t)(tau0 + s) * 1280 + j * 256 + ch];
  }
  if (t < 40) {
    int s = t / 5, k = t % 5;
    int n = n0 + s;
    float* pd = pc4 + t * 12;
    if (k == 0) {
      for (int c = 0; c < 3; ++c) pd[c] = sxyz[((size_t)b * Nc + n) * 3 + c];
      for (int c = 0; c < 9; ++c) pd[3 + c] = sbc[((size_t)b * Nc + n) * 9 + c];
    } else {
      int m = idx_s[(((size_t)b * Nc + n) << 2) + (k - 1)];
      for (int c = 0; c < 3; ++c) pd[c] = txyz[((size_t)b * Mc + m) * 3 + c];
      for (int c = 0; c < 9; ++c) pd[3 + c] = tbc[((size_t)b * Mc + m) * 9 + c];
    }
  }
  __syncthreads();
  for (int it = t; it < 2560; it += 512) {
    int sj = it >> 6, hh = it & 63;
    int s = sj / 5;
    float acc = pb1[hh];
    const float* wv = pw1 + hh * 12;
    const float* p0 = pc4 + (s * 5) * 12;
    const float* pj = pc4 + sj * 12;
#pragma unroll
    for (int p = 0; p < 12; ++p) acc += wv[p] * (p0[p] - pj[p]);
    *(short*)(Bx + ((sj * 640 + 512 + 2 * hh) ^ ((sj & 7) << 4))) = f2bf(fmaxf(acc, 0.f));
  }
  __syncthreads();
  {
    f32x4 qA[2][3];
#pragma unroll
    for (int i = 0; i < 2; ++i)
#pragma unroll
      for (int ct = 0; ct < 3; ++ct) qA[i][ct] = (f32x4){0,0,0,0};
    for (int kk = 0; kk < 8; ++kk) {
      short8b bq[3];
#pragma unroll
      for (int ct = 0; ct < 3; ++ct) {
        int col = ct * 16 + lr;
        bq[ct] = *(const short8b*)(Bx + ((col * 640 + kk * 64 + lg * 16) ^ ((col & 7) << 4)));
      }
#pragma unroll
      for (int i = 0; i < 2; ++i) {
        short8b a = *(const short8b*)(aqf + (((size_t)((w * 2 + i) * 8 + kk)) * 64 + l) * 8);
#pragma unroll
        for (int ct = 0; ct < 3; ++ct)
          qA[i][ct] = __builtin_amdgcn_mfma_f32_16x16x32_bf16(a, bq[ct], qA[i][ct], 0, 0, 0);
      }
    }
#pragma unroll
    for (int i = 0; i < 2; ++i) {
      int r0 = (w * 2 + i) * 16 + lg * 4;
#pragma unroll
      for (int ct = 0; ct < 3; ++ct) {
        int col = ct * 16 + lr;
        if (col < 40 && col % 5 == 0)
          *(f32x4*)(qF + (col / 5) * 256 + r0) = qA[i][ct];
      }
    }
  }
  f32x4 sA[2][3], vA[2][3];
#pragma unroll
  for (int i = 0; i < 2; ++i)
#pragma unroll
    for (int ct = 0; ct < 3; ++ct) { sA[i][ct] = (f32x4){0,0,0,0}; vA[i][ct] = (f32x4){0,0,0,0}; }
  for (int kk = 0; kk < 10; ++kk) {
    short8b bb[3];
#pragma unroll
    for (int ct = 0; ct < 3; ++ct) {
      int col = ct * 16 + lr;
      bb[ct] = *(const short8b*)(Bx + ((col * 640 + kk * 64 + lg * 16) ^ ((col & 7) << 4)));
    }
#pragma unroll
    for (int i = 0; i < 2; ++i) {
      short8b ak = *(const short8b*)(akpef + (((size_t)((w * 2 + i) * 10 + kk)) * 64 + l) * 8);
      short8b av = *(const short8b*)(avpef + (((size_t)((w * 2 + i) * 10 + kk)) * 64 + l) * 8);
#pragma unroll
      for (int ct = 0; ct < 3; ++ct) {
        sA[i][ct] = __builtin_amdgcn_mfma_f32_16x16x32_bf16(ak, bb[ct], sA[i][ct], 0, 0, 0);
        vA[i][ct] = __builtin_amdgcn_mfma_f32_16x16x32_bf16(av, bb[ct], vA[i][ct], 0, 0, 0);
      }
    }
  }
  __syncthreads();
#pragma unroll
  for (int i = 0; i < 2; ++i) {
    int r0 = (w * 2 + i) * 16 + lg * 4;
    float4 pb = *(const float4*)(pb2 + r0);
#pragma unroll
    for (int ct = 0; ct < 3; ++ct) {
      int col = ct * 16 + lr; int cx = (col & 7) << 4;
      if (col < 40) {
        int s = col / 5;
        f32x4 qv = *(const f32x4*)(qF + s * 256 + r0);
        ushort4 kv, vv;
        kv.x = (unsigned short)f2bf(qv[0] + sA[i][ct][0] + pb.x);
        kv.y = (unsigned short)f2bf(qv[1] + sA[i][ct][1] + pb.y);
        kv.z = (unsigned short)f2bf(qv[2] + sA[i][ct][2] + pb.z);
        kv.w = (unsigned short)f2bf(qv[3] + sA[i][ct][3] + pb.w);
        vv.x = (unsigned short)f2bf(vA[i][ct][0] + pb.x);
        vv.y = (unsigned short)f2bf(vA[i][ct][1] + pb.y);
        vv.z = (unsigned short)f2bf(vA[i][ct][2] + pb.z);
        vv.w = (unsigned short)f2bf(vA[i][ct][3] + pb.w);
        *(ushort4*)(KB + ((col * 512 + r0 * 2) ^ cx)) = kv;
        *(ushort4*)(vpeB + ((col * 512 + r0 * 2) ^ cx)) = vv;
      } else {
        ushort4 zz; zz.x = zz.y = zz.z = zz.w = 0;
        *(ushort4*)(KB + ((col * 512 + r0 * 2) ^ cx)) = zz;
      }
    }
  }
  __syncthreads();
  f32x4 sacc[2][3];
#pragma unroll
  for (int i = 0; i < 2; ++i)
#pragma unroll
    for (int ct = 0; ct < 3; ++ct) sacc[i][ct] = (f32x4){0,0,0,0};
  for (int p = 0; p < 4; ++p) {
    f32x4 hacc[2][3];
#pragma unroll
    for (int i = 0; i < 2; ++i)
#pragma unroll
      for (int ct = 0; ct < 3; ++ct) hacc[i][ct] = (f32x4){0,0,0,0};
    for (int kk = 0; kk < 8; ++kk) {
      short8b bb[3];
#pragma unroll
      for (int ct = 0; ct < 3; ++ct) {
        int col = ct * 16 + lr;
        bb[ct] = *(const short8b*)(KB + ((col * 512 + kk * 64 + lg * 16) ^ ((col & 7) << 4)));
      }
#pragma unroll
      for (int i = 0; i < 2; ++i) {
        int rtg = p * 16 + w * 2 + i;
        short8b a = *(const short8b*)(aw1f + (((size_t)(rtg * 8 + kk)) * 64 + l) * 8);
#pragma unroll
        for (int ct = 0; ct < 3; ++ct)
          hacc[i][ct] = __builtin_amdgcn_mfma_f32_16x16x32_bf16(a, bb[ct], hacc[i][ct], 0, 0, 0);
      }
    }
#pragma unroll
    for (int i = 0; i < 2; ++i) {
      int r0l = (w * 2 + i) * 16 + lg * 4;
      float4 bias = *(const float4*)(ab1 + p * 256 + r0l);
#pragma unroll
      for (int ct = 0; ct < 3; ++ct) {
        int col = ct * 16 + lr; int cx = (col & 7) << 4;
        ushort4 hv;
        hv.x = (unsigned short)f2bf(fmaxf(hacc[i][ct][0] + bias.x, 0.f));
        hv.y = (unsigned short)f2bf(fmaxf(hacc[i][ct][1] + bias.y, 0.f));
        hv.z = (unsigned short)f2bf(fmaxf(hacc[i][ct][2] + bias.z, 0.f));
        hv.w = (unsigned short)f2bf(fmaxf(hacc[i][ct][3] + bias.w, 0.f));
        *(ushort4*)(HpB + ((col * 512 + r0l * 2) ^ cx)) = hv;
      }
    }
    __syncthreads();
    for (int kk = 0; kk < 8; ++kk) {
      short8b bb[3];
#pragma unroll
      for (int ct = 0; ct < 3; ++ct) {
        int col = ct * 16 + lr;
        bb[ct] = *(const short8b*)(HpB + ((col * 512 + kk * 64 + lg * 16) ^ ((col & 7) << 4)));
      }
      int kkg = p * 8 + kk;
#pragma unroll
      for (int i = 0; i < 2; ++i) {
        short8b a = *(const short8b*)(aw2f + (((size_t)((w * 2 + i) * 32 + kkg)) * 64 + l) * 8);
#pragma unroll
        for (int ct = 0; ct < 3; ++ct)
          sacc[i][ct] = __builtin_amdgcn_mfma_f32_16x16x32_bf16(a, bb[ct], sacc[i][ct], 0, 0, 0);
      }
    }
    __syncthreads();
  }
#pragma unroll
  for (int i = 0; i < 2; ++i) {
    int r0 = (w * 2 + i) * 16 + lg * 4;
    float4 bias = *(const float4*)(ab2 + r0);
#pragma unroll
    for (int ct = 0; ct < 3; ++ct) {
      int col = ct * 16 + lr;
      if (col < 40) {
        ushort4 hv;
        hv.x = (unsigned short)f2bf(sacc[i][ct][0] + bias.x);
        hv.y = (unsigned short)f2bf(sacc[i][ct][1] + bias.y);
        hv.z = (unsigned short)f2bf(sacc[i][ct][2] + bias.z);
        hv.w = (unsigned short)f2bf(sacc[i][ct][3] + bias.w);
        *(ushort4*)(simS + col * 528 + r0 * 2) = hv;
      }
    }
  }
  __syncthreads();
  float ffv[4];
#pragma unroll
  for (int si = 0; si < 4; ++si) {
    int s = h * 4 + si;
    float sv[5], vp[5];
#pragma unroll
    for (int j = 0; j < 5; ++j) {
      int sj = s * 5 + j;
      sv[j] = bf2f(*(const short*)(simS + sj * 528 + 2 * ch));
      vp[j] = bf2f(*(const short*)(vpeB + ((sj * 512 + 2 * ch) ^ ((sj & 7) << 4))));
    }
    float mx = sv[0];
#pragma unroll
    for (int j = 1; j < 5; ++j) mx = fmaxf(mx, sv[j]);
    float ssum = 0.f;
#pragma unroll
    for (int j = 0; j < 5; ++j) { sv[j] = expf(sv[j] - mx); ssum += sv[j]; }
    float inv = 1.f / ssum;
    float agg = 0.f;
#pragma unroll
    for (int j = 0; j < 5; ++j) agg += (sv[j] * inv) * vp[j];
    ffv[si] = agg + sfeat[((size_t)b * Fc + ch) * Nc + (n0 + s)];
  }
  {
    float rv[8];
#pragma unroll
    for (int si = 0; si < 4; ++si) { rv[si] = ffv[si]; rv[4 + si] = ffv[si] * ffv[si]; }
#pragma unroll
    for (int m = 1; m < 64; m <<= 1)
#pragma unroll
      for (int i2 = 0; i2 < 8; ++i2) rv[i2] += __shfl_xor(rv[i2], m);
    if ((t & 63) == 0)
#pragma unroll
      for (int i2 = 0; i2 < 8; ++i2) redf[w * 8 + i2] = rv[i2];
    __syncthreads();
#pragma unroll
    for (int si = 0; si < 4; ++si) {
      int s = h * 4 + si;
      float S = 0.f, Q = 0.f;
#pragma unroll
      for (int q2 = 0; q2 < 4; ++q2) {
        S += redf[(h * 4 + q2) * 8 + si];
        Q += redf[(h * 4 + q2) * 8 + 4 + si];
      }
      float mu = S * (1.f / 256.f);
      float var = Q * (1.f / 256.f) - mu * mu;
      q04[s * 256 + ch] = (ffv[si] - mu) / sqrtf(var + 1e-5f);
    }
  }
  __syncthreads();
  for (int z = t; z < 16 * 256; z += 512) {
    int col = z >> 8, k = z & 255;
    short val = (col < 8) ? f2bf(q04[col * 256 + k]) : (short)0;
    *(short*)(feaB + ((col * 512 + 2 * k) ^ ((col & 7) << 4))) = val;
  }
  __syncthreads();
  {
    f32x4 acc[2];
#pragma unroll
    for (int i = 0; i < 2; ++i) acc[i] = (f32x4){0,0,0,0};
    for (int kk = 0; kk < 8; ++kk) {
      short8b b0 = *(const short8b*)(feaB + ((lr * 512 + kk * 64 + lg * 16) ^ ((lr & 7) << 4)));
#pragma unroll
      for (int i = 0; i < 2; ++i) {
        short8b a = *(const short8b*)(fw1f + (((size_t)((w * 2 + i) * 8 + kk)) * 64 + l) * 8);
        acc[i] = __builtin_amdgcn_mfma_f32_16x16x32_bf16(a, b0, acc[i], 0, 0, 0);
      }
    }
#pragma unroll
    for (int i = 0; i < 2; ++i) {
      int r0 = (w * 2 + i) * 16 + lg * 4;
      float4 gg = *(const float4*)(fg1 + r0), bs = *(const float4*)(fb1 + r0);
      int cx = (lr & 7) << 4;
      ushort4 hv;
      hv.x = (unsigned short)f2bf(fmaxf(gg.x * acc[i][0] + bs.x, 0.f));
      hv.y = (unsigned short)f2bf(fmaxf(gg.y * acc[i][1] + bs.y, 0.f));
      hv.z = (unsigned short)f2bf(fmaxf(gg.z * acc[i][2] + bs.z, 0.f));
      hv.w = (unsigned short)f2bf(fmaxf(gg.w * acc[i][3] + bs.w, 0.f));
      *(ushort4*)(feaH + ((lr * 512 + r0 * 2) ^ cx)) = hv;
    }
  }
  __syncthreads();
  {
    f32x4 acc[2];
#pragma unroll
    for (int i = 0; i < 2; ++i) acc[i] = (f32x4){0,0,0,0};
    for (int kk = 0; kk < 8; ++kk) {
      short8b b0 = *(const short8b*)(feaH + ((lr * 512 + kk * 64 + lg * 16) ^ ((lr & 7) << 4)));
#pragma unroll
      for (int i = 0; i < 2; ++i) {
        short8b a = *(const short8b*)(fw2f + (((size_t)((w * 2 + i) * 8 + kk)) * 64 + l) * 8);
        acc[i] = __builtin_amdgcn_mfma_f32_16x16x32_bf16(a, b0, acc[i], 0, 0, 0);
      }
    }
#pragma unroll
    for (int i = 0; i < 2; ++i) {
      if (lr < 8) {
        int r0 = (w * 2 + i) * 16 + lg * 4;
        float4 bs = *(const float4*)(fb2v + r0);
        float4 v;
        v.x = acc[i][0] + bs.x; v.y = acc[i][1] + bs.y;
        v.z = acc[i][2] + bs.z; v.w = acc[i][3] + bs.w;
        *(float4*)(y2F + lr * 260 + r0) = v;
      }
    }
  }
  __syncthreads();
  {
    float zv[4];
#pragma unroll
    for (int si = 0; si < 4; ++si) {
      int s = h * 4 + si;
      zv[si] = y2F[s * 260 + ch] + q04[s * 256 + ch];
    }
    float rv[8];
#pragma unroll
    for (int si = 0; si < 4; ++si) { rv[si] = zv[si]; rv[4 + si] = zv[si] * zv[si]; }
#pragma unroll
    for (int m = 1; m < 64; m <<= 1)
#pragma unroll
      for (int i2 = 0; i2 < 8; ++i2) rv[i2] += __shfl_xor(rv[i2], m);
    if ((t & 63) == 0)
#pragma unroll
      for (int i2 = 0; i2 < 8; ++i2) redf[w * 8 + i2] = rv[i2];
    __syncthreads();
#pragma unroll
    for (int si = 0; si < 4; ++si) {
      int s = h * 4 + si;
      float S = 0.f, Q = 0.f;
#pragma unroll
      for (int q2 = 0; q2 < 4; ++q2) {
        S += redf[(h * 4 + q2) * 8 + si];
        Q += redf[(h * 4 + q2) * 8 + 4 + si];
      }
      float mu = S * (1.f / 256.f);
      float var = Q * (1.f / 256.f) - mu * mu;
      yout[((size_t)(tau0 + s)) * 256 + ch] = (zv[si] - mu) / sqrtf(var + 1e-5f);
    }
  }
}

// ---- PointSIFT octant-NN: ONE WAVE PER POINT, zero barriers ----
__global__ __launch_bounds__(256) void sift_idx_kernel(const float* __restrict__ sxyz,
                                                       int* __restrict__ sidx) {
  int wv = threadIdx.x >> 6, l = threadIdx.x & 63;
  int pt = blockIdx.x * 4 + wv;
  int b = pt / Nc, i = pt % Nc;
  const float* x = sxyz + (size_t)b * Nc * 3;
  float xi0 = x[3 * i], xi1 = x[3 * i + 1], xi2 = x[3 * i + 2];
  unsigned long long k8[8];
#pragma unroll
  for (int o = 0; o < 8; ++o) k8[o] = ~0ULL;
  for (int q = 0; q < 16; ++q) {
    int j = q * 64 + l;
    float dx = x[3 * j] - xi0, dy = x[3 * j + 1] - xi1, dz = x[3 * j + 2] - xi2;
    float d2 = dx * dx + dy * dy + dz * dz;
    bool ok = (d2 <= 0.25f) && (d2 > 0.f);
    int oc = (dx > 0.f ? 4 : 0) + (dy > 0.f ? 2 : 0) + (dz > 0.f ? 1 : 0);
    unsigned long long c = ((unsigned long long)__float_as_uint(d2) << 32) | (unsigned)j;
#pragma unroll
    for (int o = 0; o < 8; ++o) {
      unsigned long long cc = (ok && oc == o) ? c : ~0ULL;
      k8[o] = umin64(k8[o], cc);
    }
  }
#pragma unroll
  for (int m = 1; m < 64; m <<= 1)
#pragma unroll
    for (int o = 0; o < 8; ++o) k8[o] = umin64(k8[o], __shfl_xor(k8[o], m));
  if (l < 8) {
    unsigned long long r = ~0ULL;
#pragma unroll
    for (int o = 0; o < 8; ++o)
      if (l == o) r = k8[o];
    int j = (r == ~0ULL) ? i : (int)(unsigned)r;
    sidx[(((size_t)b * Nc + i) << 3) + l] = j;
  }
}

// ---- fused PointSIFT OE: 3 (1,2)-convs via MFMA, 8 points/block, 512 threads ----
__global__ __launch_bounds__(512, 4) void sift_oe_kernel(
    const float* __restrict__ sxyz, const int* __restrict__ sidx,
    const float* __restrict__ yin,
    const short* __restrict__ w1f, const float* __restrict__ g1, const float* __restrict__ b1,
    const short* __restrict__ w2f, const float* __restrict__ g2, const float* __restrict__ b2,
    const short* __restrict__ w3f, const float* __restrict__ g3, const float* __restrict__ b3,
    float* __restrict__ yout) {
  __shared__ __align__(16) char smem[51200];
  char* B1 = smem;
  char* B2 = smem + 34816;
  char* B3 = smem;
  __shared__ int js[8][8];
  int t = threadIdx.x;
  int i0 = blockIdx.x * 8;
  int b = i0 / Nc, nb = i0 % Nc;
  int h = t >> 8, ch = t & 255;
  if (t < 64) js[t >> 3][t & 7] = sidx[(((size_t)b * Nc + nb + (t >> 3)) << 3) + (t & 7)];
  for (int z = t; z < 32 * 26; z += 512) {
    int col = z / 26, k = 518 + z % 26;
    *(short*)(B1 + ((col * 1088 + 2 * k) ^ ((col & 7) << 4))) = 0;
  }
  __syncthreads();
  for (int si = 0; si < 4; ++si) {
    int s = h * 4 + si;
    int ii = nb + s;
#pragma unroll
    for (int p = 0; p < 4; ++p) {
      int ja = js[s][2 * p], jb = js[s][2 * p + 1];
      int col = s * 4 + p; int cx = (col & 7) << 4;
      float va = yin[((size_t)b * Nc + ja) * 256 + ch];
      float vb = yin[((size_t)b * Nc + jb) * 256 + ch];
      unsigned int packed = (unsigned int)(unsigned short)f2bf(va) |
                            ((unsigned int)(unsigned short)f2bf(vb) << 16);
      *(unsigned int*)(B1 + ((col * 1088 + 12 + 4 * ch) ^ cx)) = packed;
      if (ch < 3) {
        float base = sxyz[((size_t)b * Nc + ii) * 3 + ch];
        float ga = sxyz[((size_t)b * Nc + ja) * 3 + ch] - base;
        float gb = sxyz[((size_t)b * Nc + jb) * 3 + ch] - base;
        unsigned int pg = (unsigned int)(unsigned short)f2bf(ga) |
                          ((unsigned int)(unsigned short)f2bf(gb) << 16);
        *(unsigned int*)(B1 + ((col * 1088 + 4 * ch) ^ cx)) = pg;
      }
    }
  }
  __syncthreads();
  int l = t & 63, w = t >> 6, lg = l >> 4, lr = l & 15;
  {
    f32x4 acc[2][2];
#pragma unroll
    for (int i = 0; i < 2; ++i) { acc[i][0] = (f32x4){0,0,0,0}; acc[i][1] = (f32x4){0,0,0,0}; }
    for (int kk = 0; kk < 17; ++kk) {
      short8b b0[2];
#pragma unroll
      for (int ct = 0; ct < 2; ++ct) {
        int col = ct * 16 + lr;
        b0[ct] = *(const short8b*)(B1 + ((col * 1088 + kk * 64 + lg * 16) ^ ((col & 7) << 4)));
      }
#pragma unroll
      for (int i = 0; i < 2; ++i) {
        short8b a = *(const short8b*)(w1f + (((size_t)((w * 2 + i) * 17 + kk)) * 64 + l) * 8);
#pragma unroll
        for (int ct = 0; ct < 2; ++ct)
          acc[i][ct] = __builtin_amdgcn_mfma_f32_16x16x32_bf16(a, b0[ct], acc[i][ct], 0, 0, 0);
      }
    }
    __syncthreads();
#pragma unroll
    for (int i = 0; i < 2; ++i) {
      int r0 = (w * 2 + i) * 16 + lg * 4;
      float4 gg = *(const float4*)(g1 + r0), bs = *(const float4*)(b1 + r0);
#pragma unroll
      for (int ct = 0; ct < 2; ++ct) {
        int col = ct * 16 + lr;
        int s = col >> 2, p = col & 3, p2 = p >> 1, tp = p & 1;
        int col2 = s * 2 + p2; int cx2 = (col2 & 7) << 4;
        *(short*)(B2 + ((col2 * 1024 + (2 * r0 + tp) * 2) ^ cx2)) =
            f2bf(fmaxf(gg.x * acc[i][ct][0] + bs.x, 0.f));
        *(short*)(B2 + ((col2 * 1024 + (2 * (r0 + 1) + tp) * 2) ^ cx2)) =
            f2bf(fmaxf(gg.y * acc[i][ct][1] + bs.y, 0.f));
        *(short*)(B2 + ((col2 * 1024 + (2 * (r0 + 2) + tp) * 2) ^ cx2)) =
            f2bf(fmaxf(gg.z * acc[i][ct][2] + bs.z, 0.f));
        *(short*)(B2 + ((col2 * 1024 + (2 * (r0 + 3) + tp) * 2) ^ cx2)) =
            f2bf(fmaxf(gg.w * acc[i][ct][3] + bs.w, 0.f));
      }
    }
  }
  __syncthreads();
  {
    f32x4 acc[2];
#pragma unroll
    for (int i = 0; i < 2; ++i) acc[i] = (f32x4){0,0,0,0};
    for (int kk = 0; kk < 16; ++kk) {
      short8b b0 = *(const short8b*)(B2 + ((lr * 1024 + kk * 64 + lg * 16) ^ ((lr & 7) << 4)));
#pragma unroll
      for (int i = 0; i < 2; ++i) {
        short8b a = *(const short8b*)(w2f + (((size_t)((w * 2 + i) * 16 + kk)) * 64 + l) * 8);
        acc[i] = __builtin_amdgcn_mfma_f32_16x16x32_bf16(a, b0, acc[i], 0, 0, 0);
      }
    }
    __syncthreads();
    int s = lr >> 1, tp = lr & 1;
    int col3 = s; int cx3 = (col3 & 7) << 4;
#pragma unroll
    for (int i = 0; i < 2; ++i) {
      int r0 = (w * 2 + i) * 16 + lg * 4;
      float4 gg = *(const float4*)(g2 + r0), bs = *(const float4*)(b2 + r0);
      *(short*)(B3 + ((col3 * 1024 + (2 * r0 + tp) * 2) ^ cx3)) =
          f2bf(fmaxf(gg.x * acc[i][0] + bs.x, 0.f));
      *(short*)(B3 + ((col3 * 1024 + (2 * (r0 + 1) + tp) * 2) ^ cx3)) =
          f2bf(fmaxf(gg.y * acc[i][1] + bs.y, 0.f));
      *(short*)(B3 + ((col3 * 1024 + (2 * (r0 + 2) + tp) * 2) ^ cx3)) =
          f2bf(fmaxf(gg.z * acc[i][2] + bs.z, 0.f));
      *(short*)(B3 + ((col3 * 1024 + (2 * (r0 + 3) + tp) * 2) ^ cx3)) =
          f2bf(fmaxf(gg.w * acc[i][3] + bs.w, 0.f));
    }
  }
  __syncthreads();
  {
    f32x4 acc[2];
#pragma unroll
    for (int i = 0; i < 2; ++i) acc[i] = (f32x4){0,0,0,0};
    for (int kk = 0; kk < 16; ++kk) {
      short8b b0 = *(const short8b*)(B3 + ((lr * 1024 + kk * 64 + lg * 16) ^ ((lr & 7) << 4)));
#pragma unroll
      for (int i = 0; i < 2; ++i) {
        short8b a = *(const short8b*)(w3f + (((size_t)((w * 2 + i) * 16 + kk)) * 64 + l) * 8);
        acc[i] = __builtin_amdgcn_mfma_f32_16x16x32_bf16(a, b0, acc[i], 0, 0, 0);
      }
    }
#pragma unroll
    for (int i = 0; i < 2; ++i) {
      if (lr < 8) {
        int s = lr;
        int r0 = (w * 2 + i) * 16 + lg * 4;
        float4 gg = *(const float4*)(g3 + r0), bs = *(const float4*)(b3 + r0);
        float4 yv = *(const float4*)(yin + ((size_t)(i0 + s)) * 256 + r0);
        float4 ov;
        ov.x = yv.x + fmaxf(gg.x * acc[i][0] + bs.x, 0.f);
        ov.y = yv.y + fmaxf(gg.y * acc[i][1] + bs.y, 0.f);
        ov.z = yv.z + fmaxf(gg.z * acc[i][2] + bs.z, 0.f);
        ov.w = yv.w + fmaxf(gg.w * acc[i][3] + bs.w, 0.f);
        *(float4*)(yout + ((size_t)(i0 + s)) * 256 + r0) = ov;
      }
    }
  }
}

// ---- final transpose (B,N,C) -> (B,C,N), LDS-tiled, coalesced both sides ----
__global__ __launch_bounds__(256) void transpose_kernel(const float* __restrict__ yin,
                                                        float* __restrict__ out) {
  __shared__ float tile[64][65];
  int bid = blockIdx.x;
  int b = bid >> 6;
  int tl = bid & 63;
  int n0 = (tl >> 2) * 64;
  int c0 = (tl & 3) * 64;
  int tx = threadIdx.x & 63, ty = threadIdx.x >> 6;
#pragma unroll
  for (int r = 0; r < 16; ++r) {
    int i = r * 4 + ty;
    tile[i][tx] = yin[((size_t)b * Nc + n0 + i) * 256 + c0 + tx];
  }
  __syncthreads();
#pragma unroll
  for (int r = 0; r < 16; ++r) {
    int j = r * 4 + ty;
    out[((size_t)b * Fc + c0 + j) * Nc + n0 + tx] = tile[tx][j];
  }
}

extern "C" void kernel_launch(void* const* d_in, const int* in_sizes, int n_in,
                              void* d_out, int out_size, void* d_ws, size_t ws_size,
                              hipStream_t stream) {
  (void)in_sizes; (void)n_in; (void)out_size; (void)ws_size;
  const float* tfeat = (const float*)d_in[0];
  const float* sfeat = (const float*)d_in[1];
  const float* txyz  = (const float*)d_in[2];
  const float* sxyz  = (const float*)d_in[3];
  const float* tbc   = (const float*)d_in[4];
  const float* sbc   = (const float*)d_in[5];
  const float* mw1 = (const float*)d_in[6];
  const float* mg1 = (const float*)d_in[7];
  const float* mb1 = (const float*)d_in[8];
  const float* mw2 = (const float*)d_in[9];
  const float* mg2 = (const float*)d_in[10];
  const float* mb2 = (const float*)d_in[11];
  const float* mw3 = (const float*)d_in[12];
  const float* mg3 = (const float*)d_in[13];
  const float* mb3 = (const float*)d_in[14];
  const float* fw1 = (const float*)d_in[15];
  const float* fg1 = (const float*)d_in[16];
  const float* fb1 = (const float*)d_in[17];
  const float* fw2 = (const float*)d_in[18];
  const float* fb2 = (const float*)d_in[19];
  const float* wqkv = (const float*)d_in[20];
  const float* pw1 = (const float*)d_in[21];
  const float* pb1 = (const float*)d_in[22];
  const float* pw2 = (const float*)d_in[23];
  const float* pb2 = (const float*)d_in[24];
  const float* aw1 = (const float*)d_in[25];
  const float* ab1 = (const float*)d_in[26];
  const float* aw2 = (const float*)d_in[27];
  const float* ab2 = (const float*)d_in[28];
  const float* o1w1 = (const float*)d_in[29];
  const float* o1g1 = (const float*)d_in[30];
  const float* o1b1 = (const float*)d_in[31];
  const float* o1w2 = (const float*)d_in[32];
  const float* o1g2 = (const float*)d_in[33];
  const float* o1b2 = (const float*)d_in[34];
  const float* o1w3 = (const float*)d_in[35];
  const float* o1g3 = (const float*)d_in[36];
  const float* o1b3 = (const float*)d_in[37];
  const float* o2w1 = (const float*)d_in[38];
  const float* o2g1 = (const float*)d_in[39];
  const float* o2b1 = (const float*)d_in[40];
  const float* o2w2 = (const float*)d_in[41];
  const float* o2g2 = (const float*)d_in[42];
  const float* o2b2 = (const float*)d_in[43];
  const float* o2w3 = (const float*)d_in[44];
  const float* o2g3 = (const float*)d_in[45];
  const float* o2b3 = (const float*)d_in[46];

  // workspace layout (identical to R9)
  float* ws = (float*)d_ws;
  float* sd   = ws;
  float* td   = sd + 65536;
  float* sscf = td + 32768;
  float* tscf = sscf + 12288;
  int*   idxs = (int*)(tscf + 6144);
  int*   sidx = idxs + 16384;
  float* yws  = (float*)(sidx + 32768);
  short* sb   = (short*)(yws + 1048576);
  short* hbufS = sb;
  short* mw1f  = sb + 5242880;
  short* mw2f  = mw1f + 73728;
  short* mw3f  = mw2f + 65536;
  short* aqf   = mw3f + 65536;
  short* akpef = aqf + 65536;
  short* avpef = akpef + 81920;
  short* aw1f  = avpef + 81920;
  short* aw2f  = aw1f + 262144;
  short* fw1f  = aw2f + 262144;
  short* fw2f  = fw1f + 65536;
  short* o1w1f = fw2f + 65536;
  short* o1w2f = o1w1f + 139264;
  short* o1w3f = o1w2f + 131072;
  short* o2w1f = o1w3f + 131072;
  short* o2w2f = o2w1f + 139264;
  short* o2w3f = o2w2f + 131072;
  float* ybuf2 = (float*)sb;

  WSrcs srcs;
  srcs.p[0] = mw1;  srcs.p[1] = mw2;  srcs.p[2] = mw3;  srcs.p[3] = wqkv;
  srcs.p[4] = wqkv; srcs.p[5] = wqkv; srcs.p[6] = aw1;  srcs.p[7] = aw2;
  srcs.p[8] = fw1;  srcs.p[9] = fw2;  srcs.p[10] = o1w1; srcs.p[11] = o1w2;
  srcs.p[12] = o1w3; srcs.p[13] = o2w1; srcs.p[14] = o2w2; srcs.p[15] = o2w3;
  wconv_all<<<7392, 256, 0, stream>>>(srcs, pw2, mw1f);

  scf_kernel<<<Bc, 256, 0, stream>>>(sxyz, sscf, Nc);
  scf_kernel<<<Bc, 256, 0, stream>>>(txyz, tscf, Mc);
  knn_kernel<Nc><<<Bc * Nc / 4, 256, 0, stream>>>(sxyz, sd);
  knn_kernel<Mc><<<Bc * Mc / 4, 256, 0, stream>>>(txyz, td);
  select_kernel<<<Bc * Nc / 4, 256, 0, stream>>>(tbc, sbc, txyz, sxyz, sd, td, idxs);
  mlp_kernel<<<Bc * Nc / 8, 512, 0, stream>>>(sfeat, tfeat, sscf, tscf, idxs,
                                              mw1f, mg1, mb1, mw2f, mg2, mb2,
                                              mw3f, mg3, mb3, hbufS);
  attn_kernel<<<Bc * Nc / 8, 512, 0, stream>>>(hbufS, idxs, sxyz, sbc, txyz, tbc,
                                               aqf, akpef, avpef, pw1, pb1, pb2,
                                               aw1f, ab1, aw2f, ab2,
                                               sfeat, fw1f, fg1, fb1, fw2f, fb2, yws);
  sift_idx_kernel<<<Bc * Nc / 4, 256, 0, stream>>>(sxyz, sidx);
  sift_oe_kernel<<<Bc * Nc / 8, 512, 0, stream>>>(sxyz, sidx, yws,
                                                  o1w1f, o1g1, o1b1, o1w2f, o1g2, o1b2,
                                                  o1w3f, o1g3, o1b3, ybuf2);
  sift_oe_kernel<<<Bc * Nc / 8, 512, 0, stream>>>(sxyz, sidx, ybuf2,
                                                  o2w1f, o2g1, o2b1, o2w2f, o2g2, o2b2,
                                                  o2w3f, o2g3, o2b3, yws);
  transpose_kernel<<<256, 256, 0, stream>>>(yws, (float*)d_out);
}